// Round 1
// baseline (1308.092 us; speedup 1.0000x reference)
//
#include <hip/hip_runtime.h>
#include <math.h>

#define PI_F 3.14159265358979323846f

// Problem constants
#define BB 4
#define SS 4096
#define DD 1024
#define HH 16
#define DHD 64
#define NFREQ 2049   // 4096/2 + 1
#define MHALF 2048   // half-size complex FFT length

__device__ __forceinline__ void modrelu_apply(float& zr, float& zi, float bias) {
    float mag = sqrtf(zr * zr + zi * zi);
    float scale = fmaxf(mag + bias, 0.0f) / fmaxf(mag, 1e-12f);
    zr *= scale; zi *= scale;
}

// ---------------- column-sum of x over S (two-pass, deterministic) -------------
// pass1: grid 256 = (b, s-chunk of 64); partial[blk][1024]
__global__ __launch_bounds__(256)
void colsum1_kernel(const float* __restrict__ x, float* __restrict__ partial) {
    int blk = blockIdx.x;
    int b = blk >> 6;
    int s0 = (blk & 63) * 64;
    int t = threadIdx.x;
    float acc0 = 0.f, acc1 = 0.f, acc2 = 0.f, acc3 = 0.f;
    const float* xp = x + ((size_t)b * SS + s0) * DD;
    for (int s = 0; s < 64; ++s) {
        const float* row = xp + (size_t)s * DD;
        acc0 += row[t];
        acc1 += row[t + 256];
        acc2 += row[t + 512];
        acc3 += row[t + 768];
    }
    float* pp = partial + (size_t)blk * DD;
    pp[t] = acc0; pp[t + 256] = acc1; pp[t + 512] = acc2; pp[t + 768] = acc3;
}

// pass2: grid (4 kchunks, 4 b)
__global__ __launch_bounds__(256)
void colsum2_kernel(const float* __restrict__ partial, float* __restrict__ xsum) {
    int b = blockIdx.y;
    int k = blockIdx.x * 256 + threadIdx.x;
    float acc = 0.f;
    for (int c = 0; c < 64; ++c)
        acc += partial[((size_t)(b * 64 + c)) * DD + k];
    xsum[b * DD + k] = acc;
}

// ---------------- mean_q = (xsum/S) @ Wq^T ; LayerNorm per head; mean over heads
// grid = 4 (one per b), 256 threads (4 waves)
__global__ __launch_bounds__(256)
void gates1_kernel(const float* __restrict__ xsum, const float* __restrict__ Wq,
                   const float* __restrict__ gamma, const float* __restrict__ beta,
                   float* __restrict__ q_shared) {
    __shared__ float xb[1024];
    __shared__ float mq[1024];
    __shared__ float qacc[4][64];
    int b = blockIdx.x;
    int t = threadIdx.x;
    for (int i = t; i < 1024; i += 256) xb[i] = xsum[b * DD + i] * (1.0f / 4096.0f);
    __syncthreads();
    int wv = t >> 6, l = t & 63;
    for (int jj = 0; jj < 256; ++jj) {
        int j = wv * 256 + jj;
        const float* wrow = Wq + (size_t)j * DD;
        float acc = 0.f;
        #pragma unroll 4
        for (int it = 0; it < 16; ++it)
            acc += xb[l + it * 64] * wrow[l + it * 64];
        for (int off = 32; off > 0; off >>= 1)
            acc += __shfl_down(acc, off, 64);
        if (l == 0) mq[j] = acc;
    }
    __syncthreads();
    // LayerNorm per head h (over the 64-dim), then accumulate head-mean
    float part = 0.f;
    for (int hh = 0; hh < 4; ++hh) {
        int h = wv * 4 + hh;
        float v = mq[h * 64 + l];
        float s1 = v, s2 = v * v;
        for (int off = 32; off > 0; off >>= 1) {
            s1 += __shfl_xor(s1, off, 64);
            s2 += __shfl_xor(s2, off, 64);
        }
        float mu = s1 * (1.0f / 64.0f);
        float var = s2 * (1.0f / 64.0f) - mu * mu;
        float qn = (v - mu) * rsqrtf(var + 1e-5f) * gamma[l] + beta[l];
        part += qn;
    }
    qacc[wv][l] = part;
    __syncthreads();
    if (t < 64) {
        float s = qacc[0][t] + qacc[1][t] + qacc[2][t] + qacc[3][t];
        q_shared[b * 64 + t] = s * (1.0f / 16.0f);
    }
}

// ---------------- hdn = gelu(q_shared @ w1^T + b1) ; grid 16 = (b, i-chunk)
__global__ __launch_bounds__(256)
void gates2_kernel(const float* __restrict__ q_shared, const float* __restrict__ w1,
                   const float* __restrict__ b1, float* __restrict__ hdn) {
    __shared__ float qs[64];
    int blk = blockIdx.x;
    int b = blk >> 2;
    int i0 = (blk & 3) * 256;
    int t = threadIdx.x;
    if (t < 64) qs[t] = q_shared[b * 64 + t];
    __syncthreads();
    int i = i0 + t;
    const float* wrow = w1 + (size_t)i * DHD;
    float acc = b1[i];
    #pragma unroll 8
    for (int d = 0; d < 64; ++d) acc += qs[d] * wrow[d];
    float g = 0.5f * acc * (1.0f + erff(acc * 0.70710678118654752f));
    hdn[b * DD + i] = g;
}

// ---------------- gri = hdn @ w2^T + b2 ; one wave per output row, all 4 b at once
// grid = ceil(4098/4) = 1025
__global__ __launch_bounds__(256)
void gates3_kernel(const float* __restrict__ hdn, const float* __restrict__ w2,
                   const float* __restrict__ b2, float* __restrict__ gri) {
    int t = threadIdx.x;
    int wv = t >> 6, l = t & 63;
    int r = blockIdx.x * 4 + wv;
    if (r >= 2 * NFREQ) return;
    const float* wrow = w2 + (size_t)r * DD;
    float a0 = 0.f, a1 = 0.f, a2 = 0.f, a3 = 0.f;
    for (int it = 0; it < 16; ++it) {
        int idx = l + it * 64;
        float wval = wrow[idx];
        a0 += hdn[idx] * wval;
        a1 += hdn[1024 + idx] * wval;
        a2 += hdn[2048 + idx] * wval;
        a3 += hdn[3072 + idx] * wval;
    }
    for (int off = 32; off > 0; off >>= 1) {
        a0 += __shfl_down(a0, off, 64);
        a1 += __shfl_down(a1, off, 64);
        a2 += __shfl_down(a2, off, 64);
        a3 += __shfl_down(a3, off, 64);
    }
    if (l == 0) {
        float bb = b2[r];
        gri[r] = a0 + bb;
        gri[2 * NFREQ + r] = a1 + bb;
        gri[2 * 2 * NFREQ + r] = a2 + bb;
        gri[3 * 2 * NFREQ + r] = a3 + bb;
    }
}

// ---------------- f32 tiled GEMM: C[M,N] = A(MxK) * B^T where B is [N][K] row-major.
// A_KMAJOR=false: A is [M][K] row-major (lda=K-stride). A_KMAJOR=true: A is [K][M] (lda=M-stride).
#define TM 128
#define TN 128
#define TK 16

template <bool A_KMAJOR>
__global__ __launch_bounds__(256)
void gemm_kernel(const float* __restrict__ A, const float* __restrict__ Bm,
                 float* __restrict__ C, int M, int N, int K, int lda, int ldb, int ldc) {
    __shared__ float As[TK][TM + 4];
    __shared__ float Bs[TK][TN + 4];
    int t = threadIdx.x;
    int tx = t & 15, ty = t >> 4;
    int n0 = blockIdx.x * TN;
    int m0 = blockIdx.y * TM;
    float acc[8][8] = {};
    for (int k0 = 0; k0 < K; k0 += TK) {
        __syncthreads();
        if (A_KMAJOR) {
            #pragma unroll
            for (int it = 0; it < 2; ++it) {
                int task = t * 2 + it;       // 0..511
                int kk = task >> 5;          // 16 rows
                int f = task & 31;           // 32 float4 per row
                float4 v = *(const float4*)&A[(size_t)(k0 + kk) * lda + m0 + f * 4];
                *(float4*)&As[kk][f * 4] = v;
            }
        } else {
            #pragma unroll
            for (int it = 0; it < 2; ++it) {
                int task = t * 2 + it;
                int r = task >> 2;           // 0..127
                int q = task & 3;
                float4 v = *(const float4*)&A[(size_t)(m0 + r) * lda + k0 + q * 4];
                As[q * 4 + 0][r] = v.x; As[q * 4 + 1][r] = v.y;
                As[q * 4 + 2][r] = v.z; As[q * 4 + 3][r] = v.w;
            }
        }
        #pragma unroll
        for (int it = 0; it < 2; ++it) {
            int task = t * 2 + it;
            int c = task >> 2;
            int q = task & 3;
            float4 v = *(const float4*)&Bm[(size_t)(n0 + c) * ldb + k0 + q * 4];
            Bs[q * 4 + 0][c] = v.x; Bs[q * 4 + 1][c] = v.y;
            Bs[q * 4 + 2][c] = v.z; Bs[q * 4 + 3][c] = v.w;
        }
        __syncthreads();
        #pragma unroll
        for (int kk = 0; kk < TK; ++kk) {
            float a[8], b[8];
            *(float4*)&a[0] = *(const float4*)&As[kk][ty * 4];
            *(float4*)&a[4] = *(const float4*)&As[kk][ty * 4 + 64];
            *(float4*)&b[0] = *(const float4*)&Bs[kk][tx * 4];
            *(float4*)&b[4] = *(const float4*)&Bs[kk][tx * 4 + 64];
            #pragma unroll
            for (int i = 0; i < 8; ++i)
                #pragma unroll
                for (int j = 0; j < 8; ++j)
                    acc[i][j] += a[i] * b[j];
        }
    }
    #pragma unroll
    for (int rh = 0; rh < 2; ++rh)
        #pragma unroll
        for (int r = 0; r < 4; ++r) {
            int row = m0 + ty * 4 + r + rh * 64;
            float* crow = C + (size_t)row * ldc + n0;
            *(float4*)&crow[tx * 4] = make_float4(acc[rh * 4 + r][0], acc[rh * 4 + r][1],
                                                  acc[rh * 4 + r][2], acc[rh * 4 + r][3]);
            *(float4*)&crow[tx * 4 + 64] = make_float4(acc[rh * 4 + r][4], acc[rh * 4 + r][5],
                                                       acc[rh * 4 + r][6], acc[rh * 4 + r][7]);
        }
}

// ---------------- fused rfft -> gates -> modReLU -> irfft, in-place per sequence
// buf layout: [j=0..1023][b=0..3][s=0..4095]; block w handles sequence w (b = w & 3).
__global__ __launch_bounds__(256)
void fft_gates_kernel(float* __restrict__ buf, const float* __restrict__ gri,
                      const float* __restrict__ modb) {
    __shared__ float re[MHALF];
    __shared__ float im[MHALF];
    int t = threadIdx.x;
    int w = blockIdx.x;
    int b = w & 3;
    float2* seq = (float2*)(buf + (size_t)w * SS);
    for (int m = t; m < MHALF; m += 256) {
        float2 v = seq[m];
        re[m] = v.x; im[m] = v.y;   // c[m] = x[2m] + i x[2m+1]
    }
    // forward DIF (natural in -> bit-reversed out), twiddle e^{-2*pi*i*j/len}
    for (int s = 10; s >= 0; --s) {
        int half = 1 << s;
        __syncthreads();
        for (int i = t; i < 1024; i += 256) {
            int jj = i & (half - 1);
            int i1 = ((i >> s) << (s + 1)) + jj;
            int i2 = i1 + half;
            float ar = re[i1], ai = im[i1];
            float br = re[i2], bi = im[i2];
            float sr = ar + br, si = ai + bi;
            float dr = ar - br, di = ai - bi;
            float ang = -PI_F * (float)jj / (float)half;
            float sn, cs;
            sincosf(ang, &sn, &cs);
            re[i1] = sr; im[i1] = si;
            re[i2] = dr * cs - di * sn;
            im[i2] = dr * sn + di * cs;
        }
    }
    __syncthreads();
    // spectrum: unpack real-FFT bins (ortho /64), gate multiply, modReLU, repack for inverse
    const float bias = modb[0];
    const float* gre = gri + (size_t)b * 2 * NFREQ;
    const float* gim = gre + NFREQ;
    const float inv64 = 1.0f / 64.0f;
    for (int k = t; k < 1024; k += 256) {
        if (k == 0) {
            // DC + Nyquist (both from C[0]); c2r drops imaginary parts of modified bins
            float c0r = re[0], c0i = im[0];
            float z0 = (c0r + c0i) * inv64;   // Z[0] (real)
            float zM = (c0r - c0i) * inv64;   // Z[2048] (real)
            float zr = z0 * gre[0], zi = z0 * gim[0];
            modrelu_apply(zr, zi, bias);
            float yr = zM * gre[2048], yi = zM * gim[2048];
            modrelu_apply(yr, yi, bias);
            float E0 = 0.5f * (zr + yr), O0 = 0.5f * (zr - yr);
            re[0] = E0; im[0] = O0;
            // self-paired k=1024 bin lives at bit-reversed position 1
            float cr = re[1], ci = im[1];
            float z1r = cr * inv64, z1i = -ci * inv64;   // Z[1024] = conj(C[1024])/64
            float g1r = gre[1024], g1i = gim[1024];
            float pr = z1r * g1r - z1i * g1i;
            float pi2 = z1r * g1i + z1i * g1r;
            modrelu_apply(pr, pi2, bias);
            re[1] = pr; im[1] = -pi2;                    // C'[1024] = conj(Z'[1024])
        } else {
            int kb = 2048 - k;
            int p1 = (int)(__brev((unsigned)k) >> 21);
            int p2 = (int)(__brev((unsigned)kb) >> 21);
            float car = re[p1], cai = im[p1];
            float cbr = re[p2], cbi = im[p2];
            float Er = 0.5f * (car + cbr), Ei = 0.5f * (cai - cbi);
            float Dr = 0.5f * (car - cbr), Di = 0.5f * (cai + cbi);
            float Or = Di, Oi = -Dr;                     // O = -i * D
            float th = PI_F * (float)k / 2048.0f;        // 2*pi*k/4096
            float sn, cs;
            sincosf(th, &sn, &cs);
            float Wr = cs, Wi = -sn;                     // W^k
            float WOr = Wr * Or - Wi * Oi, WOi = Wr * Oi + Wi * Or;
            float zkr = (Er + WOr) * inv64, zki = (Ei + WOi) * inv64;   // Z[k]
            float zbr = (Er - WOr) * inv64, zbi = -(Ei - WOi) * inv64;  // Z[kb] = conj(E - WO)/64
            float gkr = gre[k], gki = gim[k];
            float ar = zkr * gkr - zki * gki, ai = zkr * gki + zki * gkr;
            modrelu_apply(ar, ai, bias);
            float gbr = gre[kb], gbi = gim[kb];
            float br2 = zbr * gbr - zbi * gbi, bi2 = zbr * gbi + zbi * gbr;
            modrelu_apply(br2, bi2, bias);
            // inverse repack: C'[k] = E' + i O', C'[kb] = conj(E') + i conj(O')
            float Epr = 0.5f * (ar + br2), Epi = 0.5f * (ai - bi2);
            float Dpr = 0.5f * (ar - br2), Dpi = 0.5f * (ai + bi2);
            float Opr = cs * Dpr - sn * Dpi, Opi = cs * Dpi + sn * Dpr;  // W^{-k} * D'
            re[p1] = Epr - Opi; im[p1] = Epi + Opr;
            re[p2] = Epr + Opi; im[p2] = -Epi + Opr;
        }
    }
    __syncthreads();
    // inverse DIT (bit-reversed in -> natural out), twiddle e^{+2*pi*i*j/len}, unnormalized
    for (int s = 0; s <= 10; ++s) {
        int half = 1 << s;
        for (int i = t; i < 1024; i += 256) {
            int jj = i & (half - 1);
            int i1 = ((i >> s) << (s + 1)) + jj;
            int i2 = i1 + half;
            float ang = PI_F * (float)jj / (float)half;
            float sn, cs;
            sincosf(ang, &sn, &cs);
            float xr = re[i2], xi = im[i2];
            float cr = xr * cs - xi * sn, ci = xr * sn + xi * cs;
            float ar = re[i1], ai = im[i1];
            re[i1] = ar + cr; im[i1] = ai + ci;
            re[i2] = ar - cr; im[i2] = ai - ci;
        }
        __syncthreads();
    }
    const float s32 = 1.0f / 32.0f;  // 64 (ortho) / 2048 (ifft norm)
    for (int m = t; m < MHALF; m += 256)
        seq[m] = make_float2(re[m] * s32, im[m] * s32);
}

extern "C" void kernel_launch(void* const* d_in, const int* in_sizes, int n_in,
                              void* d_out, int out_size, void* d_ws, size_t ws_size,
                              hipStream_t stream) {
    const float* x        = (const float*)d_in[0];
    const float* W_q      = (const float*)d_in[1];
    const float* W_v      = (const float*)d_in[2];
    const float* W_o      = (const float*)d_in[3];
    const float* ln_gamma = (const float*)d_in[4];
    const float* ln_beta  = (const float*)d_in[5];
    const float* mlp_w1   = (const float*)d_in[6];
    const float* mlp_b1   = (const float*)d_in[7];
    const float* mlp_w2   = (const float*)d_in[8];
    const float* mlp_b2   = (const float*)d_in[9];
    const float* mod_bias = (const float*)d_in[10];
    float* out = (float*)d_out;

    // workspace layout (floats)
    float* ws = (float*)d_ws;
    float* partial  = ws;                    // 256*1024 = 262144
    float* xsum     = ws + 262144;           // 4096
    float* q_shared = ws + 266240;           // 256
    float* hdn      = ws + 266496;           // 4096
    float* gri      = ws + 270592;           // 4*4098 = 16392
    float* buf0     = ws + 294912;           // 1024*16384 = 16777216 floats (64 MiB)

    // gate path
    colsum1_kernel<<<256, 256, 0, stream>>>(x, partial);
    {
        dim3 g(4, 4);
        colsum2_kernel<<<g, 256, 0, stream>>>(partial, xsum);
    }
    gates1_kernel<<<4, 256, 0, stream>>>(xsum, W_q, ln_gamma, ln_beta, q_shared);
    gates2_kernel<<<16, 256, 0, stream>>>(q_shared, mlp_w1, mlp_b1, hdn);
    gates3_kernel<<<1025, 256, 0, stream>>>(hdn, mlp_w2, mlp_b2, gri);

    // V projection, output transposed: buf0[j][b*S+s] = sum_k Wv[j,k] * x[bs,k]
    {
        dim3 g(16384 / TN, 1024 / TM);
        gemm_kernel<false><<<g, 256, 0, stream>>>(W_v, x, buf0,
                                                  1024, 16384, 1024,
                                                  1024, 1024, 16384);
    }

    // fused spectral mixing, in place (4096 sequences)
    fft_gates_kernel<<<4096, 256, 0, stream>>>(buf0, gri, mod_bias);

    // O projection: out[bs][jo] = sum_j buf0[j][bs] * Wo[jo][j]
    {
        dim3 g(1024 / TN, 16384 / TM);
        gemm_kernel<true><<<g, 256, 0, stream>>>(buf0, W_o, out,
                                                 16384, 1024, 1024,
                                                 16384, 1024, 1024);
    }
}

// Round 2
// 957.944 us; speedup vs baseline: 1.3655x; 1.3655x over previous
//
#include <hip/hip_runtime.h>
#include <math.h>

#define PI_F 3.14159265358979323846f

// Problem constants
#define BB 4
#define SS 4096
#define DD 1024
#define HH 16
#define DHD 64
#define NFREQ 2049   // 4096/2 + 1
#define MHALF 2048   // half-size complex FFT length

__device__ __forceinline__ void modrelu_apply(float& zr, float& zi, float bias) {
    float mag = sqrtf(zr * zr + zi * zi);
    float scale = fmaxf(mag + bias, 0.0f) / fmaxf(mag, 1e-12f);
    zr *= scale; zi *= scale;
}

// ---------------- column-sum of x over S (two-pass, deterministic) -------------
// pass1: grid 256 = (b, s-chunk of 64); partial[blk][1024]
__global__ __launch_bounds__(256)
void colsum1_kernel(const float* __restrict__ x, float* __restrict__ partial) {
    int blk = blockIdx.x;
    int b = blk >> 6;
    int s0 = (blk & 63) * 64;
    int t = threadIdx.x;
    float acc0 = 0.f, acc1 = 0.f, acc2 = 0.f, acc3 = 0.f;
    const float* xp = x + ((size_t)b * SS + s0) * DD;
    for (int s = 0; s < 64; ++s) {
        const float* row = xp + (size_t)s * DD;
        acc0 += row[t];
        acc1 += row[t + 256];
        acc2 += row[t + 512];
        acc3 += row[t + 768];
    }
    float* pp = partial + (size_t)blk * DD;
    pp[t] = acc0; pp[t + 256] = acc1; pp[t + 512] = acc2; pp[t + 768] = acc3;
}

// pass2: grid (4 kchunks, 4 b)
__global__ __launch_bounds__(256)
void colsum2_kernel(const float* __restrict__ partial, float* __restrict__ xsum) {
    int b = blockIdx.y;
    int k = blockIdx.x * 256 + threadIdx.x;
    float acc = 0.f;
    for (int c = 0; c < 64; ++c)
        acc += partial[((size_t)(b * 64 + c)) * DD + k];
    xsum[b * DD + k] = acc;
}

// ---------------- mq[b][j] = dot(xsum[b]/S, Wq[j]) ; grid 256, 1 wave per row j
__global__ __launch_bounds__(256)
void gates1a_kernel(const float* __restrict__ xsum, const float* __restrict__ Wq,
                    float* __restrict__ mq) {
    __shared__ float xb[4][1024];
    int t = threadIdx.x;
    for (int i = t; i < 4096; i += 256)
        xb[i >> 10][i & 1023] = xsum[i] * (1.0f / 4096.0f);
    __syncthreads();
    int wv = t >> 6, l = t & 63;
    int j = blockIdx.x * 4 + wv;
    const float* wrow = Wq + (size_t)j * DD;
    float a0 = 0.f, a1 = 0.f, a2 = 0.f, a3 = 0.f;
    #pragma unroll 4
    for (int it = 0; it < 16; ++it) {
        int idx = l + it * 64;
        float wval = wrow[idx];
        a0 += xb[0][idx] * wval;
        a1 += xb[1][idx] * wval;
        a2 += xb[2][idx] * wval;
        a3 += xb[3][idx] * wval;
    }
    for (int off = 32; off > 0; off >>= 1) {
        a0 += __shfl_down(a0, off, 64);
        a1 += __shfl_down(a1, off, 64);
        a2 += __shfl_down(a2, off, 64);
        a3 += __shfl_down(a3, off, 64);
    }
    if (l == 0) {
        mq[j] = a0; mq[1024 + j] = a1; mq[2048 + j] = a2; mq[3072 + j] = a3;
    }
}

// ---------------- LayerNorm per head over mq, mean over heads -> q_shared[b][64]
__global__ __launch_bounds__(256)
void gates1b_kernel(const float* __restrict__ mq, const float* __restrict__ gamma,
                    const float* __restrict__ beta, float* __restrict__ q_shared) {
    __shared__ float qacc[4][64];
    int b = blockIdx.x;
    int t = threadIdx.x;
    int wv = t >> 6, l = t & 63;
    float part = 0.f;
    for (int hh = 0; hh < 4; ++hh) {
        int h = wv * 4 + hh;
        float v = mq[b * 1024 + h * 64 + l];
        float s1 = v, s2 = v * v;
        for (int off = 32; off > 0; off >>= 1) {
            s1 += __shfl_xor(s1, off, 64);
            s2 += __shfl_xor(s2, off, 64);
        }
        float mu = s1 * (1.0f / 64.0f);
        float var = s2 * (1.0f / 64.0f) - mu * mu;
        part += (v - mu) * rsqrtf(var + 1e-5f) * gamma[l] + beta[l];
    }
    qacc[wv][l] = part;
    __syncthreads();
    if (t < 64) {
        float s = qacc[0][t] + qacc[1][t] + qacc[2][t] + qacc[3][t];
        q_shared[b * 64 + t] = s * (1.0f / 16.0f);
    }
}

// ---------------- hdn = gelu(q_shared @ w1^T + b1) ; grid 16 = (b, i-chunk)
__global__ __launch_bounds__(256)
void gates2_kernel(const float* __restrict__ q_shared, const float* __restrict__ w1,
                   const float* __restrict__ b1, float* __restrict__ hdn) {
    __shared__ float qs[64];
    int blk = blockIdx.x;
    int b = blk >> 2;
    int i0 = (blk & 3) * 256;
    int t = threadIdx.x;
    if (t < 64) qs[t] = q_shared[b * 64 + t];
    __syncthreads();
    int i = i0 + t;
    const float* wrow = w1 + (size_t)i * DHD;
    float acc = b1[i];
    #pragma unroll 8
    for (int d = 0; d < 64; ++d) acc += qs[d] * wrow[d];
    float g = 0.5f * acc * (1.0f + erff(acc * 0.70710678118654752f));
    hdn[b * DD + i] = g;
}

// ---------------- gri = hdn @ w2^T + b2 ; one wave per output row, all 4 b at once
// grid = ceil(4098/4) = 1025
__global__ __launch_bounds__(256)
void gates3_kernel(const float* __restrict__ hdn, const float* __restrict__ w2,
                   const float* __restrict__ b2, float* __restrict__ gri) {
    int t = threadIdx.x;
    int wv = t >> 6, l = t & 63;
    int r = blockIdx.x * 4 + wv;
    if (r >= 2 * NFREQ) return;
    const float* wrow = w2 + (size_t)r * DD;
    float a0 = 0.f, a1 = 0.f, a2 = 0.f, a3 = 0.f;
    for (int it = 0; it < 16; ++it) {
        int idx = l + it * 64;
        float wval = wrow[idx];
        a0 += hdn[idx] * wval;
        a1 += hdn[1024 + idx] * wval;
        a2 += hdn[2048 + idx] * wval;
        a3 += hdn[3072 + idx] * wval;
    }
    for (int off = 32; off > 0; off >>= 1) {
        a0 += __shfl_down(a0, off, 64);
        a1 += __shfl_down(a1, off, 64);
        a2 += __shfl_down(a2, off, 64);
        a3 += __shfl_down(a3, off, 64);
    }
    if (l == 0) {
        float bb = b2[r];
        gri[r] = a0 + bb;
        gri[2 * NFREQ + r] = a1 + bb;
        gri[2 * 2 * NFREQ + r] = a2 + bb;
        gri[3 * 2 * NFREQ + r] = a3 + bb;
    }
}

// ---------------- f32 tiled GEMM: C[M,N] = A(MxK) * B^T where B is [N][K] row-major.
// A_KMAJOR=false: A is [M][K] row-major (lda=K-stride). A_KMAJOR=true: A is [K][M] (lda=M-stride).
#define TM 128
#define TN 128
#define TK 16

template <bool A_KMAJOR>
__global__ __launch_bounds__(256)
void gemm_kernel(const float* __restrict__ A, const float* __restrict__ Bm,
                 float* __restrict__ C, int M, int N, int K, int lda, int ldb, int ldc) {
    __shared__ float As[TK][TM + 4];
    __shared__ float Bs[TK][TN + 4];
    int t = threadIdx.x;
    int tx = t & 15, ty = t >> 4;
    int n0 = blockIdx.x * TN;
    int m0 = blockIdx.y * TM;
    float acc[8][8] = {};
    for (int k0 = 0; k0 < K; k0 += TK) {
        __syncthreads();
        if (A_KMAJOR) {
            #pragma unroll
            for (int it = 0; it < 2; ++it) {
                int task = t * 2 + it;       // 0..511
                int kk = task >> 5;          // 16 rows
                int f = task & 31;           // 32 float4 per row
                float4 v = *(const float4*)&A[(size_t)(k0 + kk) * lda + m0 + f * 4];
                *(float4*)&As[kk][f * 4] = v;
            }
        } else {
            #pragma unroll
            for (int it = 0; it < 2; ++it) {
                int task = t * 2 + it;
                int r = task >> 2;           // 0..127
                int q = task & 3;
                float4 v = *(const float4*)&A[(size_t)(m0 + r) * lda + k0 + q * 4];
                As[q * 4 + 0][r] = v.x; As[q * 4 + 1][r] = v.y;
                As[q * 4 + 2][r] = v.z; As[q * 4 + 3][r] = v.w;
            }
        }
        #pragma unroll
        for (int it = 0; it < 2; ++it) {
            int task = t * 2 + it;
            int c = task >> 2;
            int q = task & 3;
            float4 v = *(const float4*)&Bm[(size_t)(n0 + c) * ldb + k0 + q * 4];
            Bs[q * 4 + 0][c] = v.x; Bs[q * 4 + 1][c] = v.y;
            Bs[q * 4 + 2][c] = v.z; Bs[q * 4 + 3][c] = v.w;
        }
        __syncthreads();
        #pragma unroll
        for (int kk = 0; kk < TK; ++kk) {
            float a[8], b[8];
            *(float4*)&a[0] = *(const float4*)&As[kk][ty * 4];
            *(float4*)&a[4] = *(const float4*)&As[kk][ty * 4 + 64];
            *(float4*)&b[0] = *(const float4*)&Bs[kk][tx * 4];
            *(float4*)&b[4] = *(const float4*)&Bs[kk][tx * 4 + 64];
            #pragma unroll
            for (int i = 0; i < 8; ++i)
                #pragma unroll
                for (int j = 0; j < 8; ++j)
                    acc[i][j] += a[i] * b[j];
        }
    }
    #pragma unroll
    for (int rh = 0; rh < 2; ++rh)
        #pragma unroll
        for (int r = 0; r < 4; ++r) {
            int row = m0 + ty * 4 + r + rh * 64;
            float* crow = C + (size_t)row * ldc + n0;
            *(float4*)&crow[tx * 4] = make_float4(acc[rh * 4 + r][0], acc[rh * 4 + r][1],
                                                  acc[rh * 4 + r][2], acc[rh * 4 + r][3]);
            *(float4*)&crow[tx * 4 + 64] = make_float4(acc[rh * 4 + r][4], acc[rh * 4 + r][5],
                                                       acc[rh * 4 + r][6], acc[rh * 4 + r][7]);
        }
}

// ---------------- fused rfft -> gates -> modReLU -> irfft, in-place per sequence
// buf layout: [j=0..1023][b=0..3][s=0..4095]; block w handles sequence w (b = w & 3).
// Twiddle tables in LDS: tw1[k] = (cos,sin)(pi*k/1024) covers all stage twiddles;
// tw2[k] = (cos,sin)(pi*k/2048) for the real-FFT (un)packing step.
__global__ __launch_bounds__(256)
void fft_gates_kernel(float* __restrict__ buf, const float* __restrict__ gri,
                      const float* __restrict__ modb) {
    __shared__ float re[MHALF];
    __shared__ float im[MHALF];
    __shared__ float2 tw1[1024];
    __shared__ float2 tw2[1024];
    int t = threadIdx.x;
    int w = blockIdx.x;
    int b = w & 3;
    float2* seq = (float2*)(buf + (size_t)w * SS);
    for (int m = t; m < MHALF; m += 256) {
        float2 v = seq[m];
        re[m] = v.x; im[m] = v.y;   // c[m] = x[2m] + i x[2m+1]
    }
    for (int k = t; k < 1024; k += 256) {
        float sn, cs;
        sincosf(PI_F * (float)k * (1.0f / 1024.0f), &sn, &cs);
        tw1[k] = make_float2(cs, sn);
        sincosf(PI_F * (float)k * (1.0f / 2048.0f), &sn, &cs);
        tw2[k] = make_float2(cs, sn);
    }
    // forward DIF (natural in -> bit-reversed out), twiddle e^{-i*pi*jj/half}
    for (int s = 10; s >= 0; --s) {
        int half = 1 << s;
        __syncthreads();
        for (int i = t; i < 1024; i += 256) {
            int jj = i & (half - 1);
            int i1 = ((i >> s) << (s + 1)) + jj;
            int i2 = i1 + half;
            float ar = re[i1], ai = im[i1];
            float br = re[i2], bi = im[i2];
            float dr = ar - br, di = ai - bi;
            float2 tw = tw1[jj << (10 - s)];   // (cos th, sin th), th = pi*jj/half
            re[i1] = ar + br; im[i1] = ai + bi;
            re[i2] = dr * tw.x + di * tw.y;
            im[i2] = di * tw.x - dr * tw.y;
        }
    }
    __syncthreads();
    // spectrum: unpack real-FFT bins (ortho /64), gate multiply, modReLU, repack for inverse
    const float bias = modb[0];
    const float* gre = gri + (size_t)b * 2 * NFREQ;
    const float* gim = gre + NFREQ;
    const float inv64 = 1.0f / 64.0f;
    for (int k = t; k < 1024; k += 256) {
        if (k == 0) {
            // DC + Nyquist (both from C[0]); c2r drops imaginary parts of modified bins
            float c0r = re[0], c0i = im[0];
            float z0 = (c0r + c0i) * inv64;   // Z[0] (real)
            float zM = (c0r - c0i) * inv64;   // Z[2048] (real)
            float zr = z0 * gre[0], zi = z0 * gim[0];
            modrelu_apply(zr, zi, bias);
            float yr = zM * gre[2048], yi = zM * gim[2048];
            modrelu_apply(yr, yi, bias);
            float E0 = 0.5f * (zr + yr), O0 = 0.5f * (zr - yr);
            re[0] = E0; im[0] = O0;
            // self-paired k=1024 bin lives at bit-reversed position 1
            float cr = re[1], ci = im[1];
            float z1r = cr * inv64, z1i = -ci * inv64;   // Z[1024] = conj(C[1024])/64
            float g1r = gre[1024], g1i = gim[1024];
            float pr = z1r * g1r - z1i * g1i;
            float pi2 = z1r * g1i + z1i * g1r;
            modrelu_apply(pr, pi2, bias);
            re[1] = pr; im[1] = -pi2;                    // C'[1024] = conj(Z'[1024])
        } else {
            int kb = 2048 - k;
            int p1 = (int)(__brev((unsigned)k) >> 21);
            int p2 = (int)(__brev((unsigned)kb) >> 21);
            float car = re[p1], cai = im[p1];
            float cbr = re[p2], cbi = im[p2];
            float Er = 0.5f * (car + cbr), Ei = 0.5f * (cai - cbi);
            float Dr = 0.5f * (car - cbr), Di = 0.5f * (cai + cbi);
            float Or = Di, Oi = -Dr;                     // O = -i * D
            float2 t2 = tw2[k];                          // th = pi*k/2048
            float cs = t2.x, sn = t2.y;
            float Wr = cs, Wi = -sn;                     // W^k = e^{-i th}
            float WOr = Wr * Or - Wi * Oi, WOi = Wr * Oi + Wi * Or;
            float zkr = (Er + WOr) * inv64, zki = (Ei + WOi) * inv64;   // Z[k]
            float zbr = (Er - WOr) * inv64, zbi = -(Ei - WOi) * inv64;  // Z[kb] = conj(E - WO)/64
            float gkr = gre[k], gki = gim[k];
            float ar = zkr * gkr - zki * gki, ai = zkr * gki + zki * gkr;
            modrelu_apply(ar, ai, bias);
            float gbr = gre[kb], gbi = gim[kb];
            float br2 = zbr * gbr - zbi * gbi, bi2 = zbr * gbi + zbi * gbr;
            modrelu_apply(br2, bi2, bias);
            // inverse repack: C'[k] = E' + i O', C'[kb] = conj(E') + i conj(O')
            float Epr = 0.5f * (ar + br2), Epi = 0.5f * (ai - bi2);
            float Dpr = 0.5f * (ar - br2), Dpi = 0.5f * (ai + bi2);
            float Opr = cs * Dpr - sn * Dpi, Opi = cs * Dpi + sn * Dpr;  // W^{-k} * D'
            re[p1] = Epr - Opi; im[p1] = Epi + Opr;
            re[p2] = Epr + Opi; im[p2] = -Epi + Opr;
        }
    }
    __syncthreads();
    // inverse DIT (bit-reversed in -> natural out), twiddle e^{+i*pi*jj/half}, unnormalized
    for (int s = 0; s <= 10; ++s) {
        int half = 1 << s;
        for (int i = t; i < 1024; i += 256) {
            int jj = i & (half - 1);
            int i1 = ((i >> s) << (s + 1)) + jj;
            int i2 = i1 + half;
            float2 tw = tw1[jj << (10 - s)];   // (cos th, sin th)
            float xr = re[i2], xi = im[i2];
            float cr = xr * tw.x - xi * tw.y, ci = xr * tw.y + xi * tw.x;
            float ar = re[i1], ai = im[i1];
            re[i1] = ar + cr; im[i1] = ai + ci;
            re[i2] = ar - cr; im[i2] = ai - ci;
        }
        __syncthreads();
    }
    const float s32 = 1.0f / 32.0f;  // 64 (ortho) / 2048 (ifft norm)
    for (int m = t; m < MHALF; m += 256)
        seq[m] = make_float2(re[m] * s32, im[m] * s32);
}

extern "C" void kernel_launch(void* const* d_in, const int* in_sizes, int n_in,
                              void* d_out, int out_size, void* d_ws, size_t ws_size,
                              hipStream_t stream) {
    const float* x        = (const float*)d_in[0];
    const float* W_q      = (const float*)d_in[1];
    const float* W_v      = (const float*)d_in[2];
    const float* W_o      = (const float*)d_in[3];
    const float* ln_gamma = (const float*)d_in[4];
    const float* ln_beta  = (const float*)d_in[5];
    const float* mlp_w1   = (const float*)d_in[6];
    const float* mlp_b1   = (const float*)d_in[7];
    const float* mlp_w2   = (const float*)d_in[8];
    const float* mlp_b2   = (const float*)d_in[9];
    const float* mod_bias = (const float*)d_in[10];
    float* out = (float*)d_out;

    // workspace layout (floats)
    float* ws = (float*)d_ws;
    float* partial  = ws;                    // 256*1024 = 262144
    float* xsum     = ws + 262144;           // 4096
    float* q_shared = ws + 266240;           // 256
    float* hdn      = ws + 266496;           // 4096
    float* gri      = ws + 270592;           // 4*4098 = 16392
    float* mq       = ws + 286984;           // 4096
    float* buf0     = ws + 294912;           // 1024*16384 = 16777216 floats (64 MiB)

    // gate path
    colsum1_kernel<<<256, 256, 0, stream>>>(x, partial);
    {
        dim3 g(4, 4);
        colsum2_kernel<<<g, 256, 0, stream>>>(partial, xsum);
    }
    gates1a_kernel<<<256, 256, 0, stream>>>(xsum, W_q, mq);
    gates1b_kernel<<<4, 256, 0, stream>>>(mq, ln_gamma, ln_beta, q_shared);
    gates2_kernel<<<16, 256, 0, stream>>>(q_shared, mlp_w1, mlp_b1, hdn);
    gates3_kernel<<<1025, 256, 0, stream>>>(hdn, mlp_w2, mlp_b2, gri);

    // V projection, output transposed: buf0[j][b*S+s] = sum_k Wv[j,k] * x[bs,k]
    {
        dim3 g(16384 / TN, 1024 / TM);
        gemm_kernel<false><<<g, 256, 0, stream>>>(W_v, x, buf0,
                                                  1024, 16384, 1024,
                                                  1024, 1024, 16384);
    }

    // fused spectral mixing, in place (4096 sequences)
    fft_gates_kernel<<<4096, 256, 0, stream>>>(buf0, gri, mod_bias);

    // O projection: out[bs][jo] = sum_j buf0[j][bs] * Wo[jo][j]
    {
        dim3 g(1024 / TN, 16384 / TM);
        gemm_kernel<true><<<g, 256, 0, stream>>>(buf0, W_o, out,
                                                 16384, 1024, 1024,
                                                 16384, 1024, 1024);
    }
}

// Round 3
// 451.203 us; speedup vs baseline: 2.8991x; 2.1231x over previous
//
#include <hip/hip_runtime.h>
#include <math.h>
#include <stdint.h>

#define PI_F 3.14159265358979323846f

// Problem constants
#define BB 4
#define SS 4096
#define DD 1024
#define HH 16
#define DHD 64
#define NFREQ 2049   // 4096/2 + 1
#define MHALF 2048   // half-size complex FFT length

typedef unsigned short u16;
typedef __attribute__((ext_vector_type(8))) short short8;   // 8 bf16 = 4 VGPR (MFMA A/B frag)
typedef __attribute__((ext_vector_type(4))) float f32x4;    // MFMA C/D frag
typedef __attribute__((ext_vector_type(4))) unsigned short u16x4;

// ---- bf16 helpers (RTNE) ----
__device__ __forceinline__ u16 f2bf(float f) {
    unsigned u = __float_as_uint(f);
    unsigned r = (u + 0x7FFFu + ((u >> 16) & 1u)) >> 16;
    return (u16)r;
}
__device__ __forceinline__ float bf2f(u16 h) { return __uint_as_float(((unsigned)h) << 16); }

__device__ __forceinline__ void modrelu_apply(float& zr, float& zi, float bias) {
    float mag = sqrtf(zr * zr + zi * zi);
    float scale = fmaxf(mag + bias, 0.0f) / fmaxf(mag, 1e-12f);
    zr *= scale; zi *= scale;
}

// async global->LDS, 16B per lane (HW: dest = wave-uniform base + lane*16)
__device__ __forceinline__ void gload16(const u16* g, u16* l) {
    __builtin_amdgcn_global_load_lds(
        (const __attribute__((address_space(1))) void*)g,
        (__attribute__((address_space(3))) void*)l, 16, 0, 0);
}

// LDS byte-offset swizzle: XOR chunk bits [4:3] into chunk bits [1:0] (16B chunks)
// -> 16-lane column reads land 2-way max (free), staging stays linear-compatible.
__device__ __forceinline__ int swz(int byteoff) {
    return byteoff ^ (((byteoff >> 7) & 3) << 4);
}

// ---------------- column-sum of x over S (two-pass, deterministic) -------------
__global__ __launch_bounds__(256)
void colsum1_kernel(const float* __restrict__ x, float* __restrict__ partial) {
    int blk = blockIdx.x;
    int b = blk >> 6;
    int s0 = (blk & 63) * 64;
    int t = threadIdx.x;
    float acc0 = 0.f, acc1 = 0.f, acc2 = 0.f, acc3 = 0.f;
    const float* xp = x + ((size_t)b * SS + s0) * DD;
    for (int s = 0; s < 64; ++s) {
        const float* row = xp + (size_t)s * DD;
        acc0 += row[t];
        acc1 += row[t + 256];
        acc2 += row[t + 512];
        acc3 += row[t + 768];
    }
    float* pp = partial + (size_t)blk * DD;
    pp[t] = acc0; pp[t + 256] = acc1; pp[t + 512] = acc2; pp[t + 768] = acc3;
}

__global__ __launch_bounds__(256)
void colsum2_kernel(const float* __restrict__ partial, float* __restrict__ xsum) {
    int b = blockIdx.y;
    int k = blockIdx.x * 256 + threadIdx.x;
    float acc = 0.f;
    for (int c = 0; c < 64; ++c)
        acc += partial[((size_t)(b * 64 + c)) * DD + k];
    xsum[b * DD + k] = acc;
}

// ---------------- mq[b][j] = dot(xsum[b]/S, Wq[j]) ; grid 256, 1 wave per row j
__global__ __launch_bounds__(256)
void gates1a_kernel(const float* __restrict__ xsum, const float* __restrict__ Wq,
                    float* __restrict__ mq) {
    __shared__ float xb[4][1024];
    int t = threadIdx.x;
    for (int i = t; i < 4096; i += 256)
        xb[i >> 10][i & 1023] = xsum[i] * (1.0f / 4096.0f);
    __syncthreads();
    int wv = t >> 6, l = t & 63;
    int j = blockIdx.x * 4 + wv;
    const float* wrow = Wq + (size_t)j * DD;
    float a0 = 0.f, a1 = 0.f, a2 = 0.f, a3 = 0.f;
    #pragma unroll 4
    for (int it = 0; it < 16; ++it) {
        int idx = l + it * 64;
        float wval = wrow[idx];
        a0 += xb[0][idx] * wval;
        a1 += xb[1][idx] * wval;
        a2 += xb[2][idx] * wval;
        a3 += xb[3][idx] * wval;
    }
    for (int off = 32; off > 0; off >>= 1) {
        a0 += __shfl_down(a0, off, 64);
        a1 += __shfl_down(a1, off, 64);
        a2 += __shfl_down(a2, off, 64);
        a3 += __shfl_down(a3, off, 64);
    }
    if (l == 0) {
        mq[j] = a0; mq[1024 + j] = a1; mq[2048 + j] = a2; mq[3072 + j] = a3;
    }
}

// ---------------- LayerNorm per head over mq, mean over heads -> q_shared[b][64]
__global__ __launch_bounds__(256)
void gates1b_kernel(const float* __restrict__ mq, const float* __restrict__ gamma,
                    const float* __restrict__ beta, float* __restrict__ q_shared) {
    __shared__ float qacc[4][64];
    int b = blockIdx.x;
    int t = threadIdx.x;
    int wv = t >> 6, l = t & 63;
    float part = 0.f;
    for (int hh = 0; hh < 4; ++hh) {
        int h = wv * 4 + hh;
        float v = mq[b * 1024 + h * 64 + l];
        float s1 = v, s2 = v * v;
        for (int off = 32; off > 0; off >>= 1) {
            s1 += __shfl_xor(s1, off, 64);
            s2 += __shfl_xor(s2, off, 64);
        }
        float mu = s1 * (1.0f / 64.0f);
        float var = s2 * (1.0f / 64.0f) - mu * mu;
        part += (v - mu) * rsqrtf(var + 1e-5f) * gamma[l] + beta[l];
    }
    qacc[wv][l] = part;
    __syncthreads();
    if (t < 64) {
        float s = qacc[0][t] + qacc[1][t] + qacc[2][t] + qacc[3][t];
        q_shared[b * 64 + t] = s * (1.0f / 16.0f);
    }
}

// ---------------- hdn = gelu(q_shared @ w1^T + b1)
__global__ __launch_bounds__(256)
void gates2_kernel(const float* __restrict__ q_shared, const float* __restrict__ w1,
                   const float* __restrict__ b1, float* __restrict__ hdn) {
    __shared__ float qs[64];
    int blk = blockIdx.x;
    int b = blk >> 2;
    int i0 = (blk & 3) * 256;
    int t = threadIdx.x;
    if (t < 64) qs[t] = q_shared[b * 64 + t];
    __syncthreads();
    int i = i0 + t;
    const float* wrow = w1 + (size_t)i * DHD;
    float acc = b1[i];
    #pragma unroll 8
    for (int d = 0; d < 64; ++d) acc += qs[d] * wrow[d];
    float g = 0.5f * acc * (1.0f + erff(acc * 0.70710678118654752f));
    hdn[b * DD + i] = g;
}

// ---------------- gri = hdn @ w2^T + b2 ; one wave per output row, all 4 b at once
__global__ __launch_bounds__(256)
void gates3_kernel(const float* __restrict__ hdn, const float* __restrict__ w2,
                   const float* __restrict__ b2, float* __restrict__ gri) {
    int t = threadIdx.x;
    int wv = t >> 6, l = t & 63;
    int r = blockIdx.x * 4 + wv;
    if (r >= 2 * NFREQ) return;
    const float* wrow = w2 + (size_t)r * DD;
    float a0 = 0.f, a1 = 0.f, a2 = 0.f, a3 = 0.f;
    for (int it = 0; it < 16; ++it) {
        int idx = l + it * 64;
        float wval = wrow[idx];
        a0 += hdn[idx] * wval;
        a1 += hdn[1024 + idx] * wval;
        a2 += hdn[2048 + idx] * wval;
        a3 += hdn[3072 + idx] * wval;
    }
    for (int off = 32; off > 0; off >>= 1) {
        a0 += __shfl_down(a0, off, 64);
        a1 += __shfl_down(a1, off, 64);
        a2 += __shfl_down(a2, off, 64);
        a3 += __shfl_down(a3, off, 64);
    }
    if (l == 0) {
        float bb = b2[r];
        gri[r] = a0 + bb;
        gri[2 * NFREQ + r] = a1 + bb;
        gri[2 * 2 * NFREQ + r] = a2 + bb;
        gri[3 * 2 * NFREQ + r] = a3 + bb;
    }
}

// ---------------- f32 -> (bf16 hi, bf16 lo) split, vectorized ----------------
__global__ __launch_bounds__(256)
void split_kernel(const float* __restrict__ src, u16* __restrict__ hi,
                  u16* __restrict__ lo, int n4) {
    int idx = blockIdx.x * 256 + threadIdx.x;
    int stride = gridDim.x * 256;
    for (; idx < n4; idx += stride) {
        float4 v = ((const float4*)src)[idx];
        u16x4 h, l;
        h.x = f2bf(v.x); h.y = f2bf(v.y); h.z = f2bf(v.z); h.w = f2bf(v.w);
        l.x = f2bf(v.x - bf2f(h.x));
        l.y = f2bf(v.y - bf2f(h.y));
        l.z = f2bf(v.z - bf2f(h.z));
        l.w = f2bf(v.w - bf2f(h.w));
        ((u16x4*)hi)[idx] = h;
        ((u16x4*)lo)[idx] = l;
    }
}

// ---------------- transpose + split: src f32 [1024][16384] -> hi/lo bf16 [16384][1024]
__global__ __launch_bounds__(256)
void transpose_split_kernel(const float* __restrict__ src, u16* __restrict__ hi,
                            u16* __restrict__ lo) {
    __shared__ float tile[64][65];
    int s0 = blockIdx.x * 64;   // bs block
    int j0 = blockIdx.y * 64;   // feature block
    int t = threadIdx.x;
    int c = t & 63, r4 = t >> 6;
    #pragma unroll
    for (int rr = 0; rr < 64; rr += 4)
        tile[rr + r4][c] = src[(size_t)(j0 + rr + r4) * 16384 + s0 + c];
    __syncthreads();
    #pragma unroll
    for (int rr = 0; rr < 64; rr += 4) {
        int a = rr + r4;                 // local bs
        float v = tile[c][a];            // = src[j0+c][s0+a]
        u16 h = f2bf(v);
        size_t o = (size_t)(s0 + a) * 1024 + j0 + c;
        hi[o] = h;
        lo[o] = f2bf(v - bf2f(h));
    }
}

// ---------------- split-bf16 MFMA GEMM: C[M][N] = A[M][K] * B[N][K]^T ----------
// A,B given as bf16 hi/lo planes (row-major, stride K). C f32 row-major (ldc).
// 128x128 tile, 4 waves (2x2), each wave 4x4 frags of mfma_f32_16x16x32_bf16.
// 3-product split: C = Ah*Bh + Ah*Bl + Al*Bh  (~f32 accuracy).
// k-slot convention (ours, consistent for A and B): k = (lane>>4)*8 + e.
__global__ __launch_bounds__(256, 3)
void gemm_split_kernel(const u16* __restrict__ Ah, const u16* __restrict__ Al,
                       const u16* __restrict__ Bh, const u16* __restrict__ Bl,
                       float* __restrict__ C, int M, int N, int K, int ldc) {
    __shared__ u16 lds[4][4096];   // planes: Ah, Al, Bh, Bl; each [128 rows][32 k] swizzled
    const int t = threadIdx.x;
    const int wid = __builtin_amdgcn_readfirstlane(t >> 6);
    const int lane = t & 63;
    const int n0 = blockIdx.x * 128;
    const int m0 = blockIdx.y * 128;
    const int wm = (wid >> 1) * 64;
    const int wn = (wid & 1) * 64;

    // staging decode: physical chunk j -> logical chunk c (involution), (row, kq)
    const int j1 = wid * 128 + lane;
    const int j2 = j1 + 64;
    const int c1 = j1 ^ ((j1 >> 3) & 3);
    const int c2 = j2 ^ ((j2 >> 3) & 3);
    const int r1 = c1 >> 2, q1 = c1 & 3;
    const int r2 = c2 >> 2, q2 = c2 & 3;
    const size_t offA1 = (size_t)(m0 + r1) * K + q1 * 8;
    const size_t offA2 = (size_t)(m0 + r2) * K + q2 * 8;
    const size_t offB1 = (size_t)(n0 + r1) * K + q1 * 8;
    const size_t offB2 = (size_t)(n0 + r2) * K + q2 * 8;
    u16* d1 = &lds[0][0] + (size_t)j1 * 8;   // plane stride added via +4096*p
    u16* d2 = &lds[0][0] + (size_t)j2 * 8;

    // fragment logical byte offsets (within plane)
    const int abase = (wm + (lane & 15)) * 64 + (lane >> 4) * 16;
    const int bbase = (wn + (lane & 15)) * 64 + (lane >> 4) * 16;

    f32x4 acc[4][4] = {};

    for (int k0 = 0; k0 < K; k0 += 32) {
        __syncthreads();   // previous compute done before overwrite
        gload16(Ah + offA1 + k0, d1);
        gload16(Ah + offA2 + k0, d2);
        gload16(Al + offA1 + k0, d1 + 4096);
        gload16(Al + offA2 + k0, d2 + 4096);
        gload16(Bh + offB1 + k0, d1 + 8192);
        gload16(Bh + offB2 + k0, d2 + 8192);
        gload16(Bl + offB1 + k0, d1 + 12288);
        gload16(Bl + offB2 + k0, d2 + 12288);
        __syncthreads();   // compiler drains vmcnt before barrier

        short8 bh[4], bl[4];
        #pragma unroll
        for (int j = 0; j < 4; ++j) {
            int lb = swz(bbase + j * 1024);
            bh[j] = *(const short8*)&lds[2][lb >> 1];
            bl[j] = *(const short8*)&lds[3][lb >> 1];
        }
        #pragma unroll
        for (int i = 0; i < 4; ++i) {
            int la = swz(abase + i * 1024);
            short8 ah = *(const short8*)&lds[0][la >> 1];
            short8 al = *(const short8*)&lds[1][la >> 1];
            #pragma unroll
            for (int j = 0; j < 4; ++j) {
                acc[i][j] = __builtin_amdgcn_mfma_f32_16x16x32_bf16(ah, bl[j], acc[i][j], 0, 0, 0);
                acc[i][j] = __builtin_amdgcn_mfma_f32_16x16x32_bf16(al, bh[j], acc[i][j], 0, 0, 0);
                acc[i][j] = __builtin_amdgcn_mfma_f32_16x16x32_bf16(ah, bh[j], acc[i][j], 0, 0, 0);
            }
        }
    }

    // epilogue: C/D layout = col (lane&15), row (lane>>4)*4 + e   [m89-verified]
    const int cb = n0 + wn + (lane & 15);
    #pragma unroll
    for (int i = 0; i < 4; ++i) {
        int rb = m0 + wm + i * 16 + ((lane >> 4) << 2);
        #pragma unroll
        for (int e = 0; e < 4; ++e) {
            float* crow = C + (size_t)(rb + e) * ldc + cb;
            #pragma unroll
            for (int j = 0; j < 4; ++j)
                crow[j * 16] = acc[i][j][e];
        }
    }
}

// ---------------- fused rfft -> gates -> modReLU -> irfft, in-place per sequence
__global__ __launch_bounds__(256)
void fft_gates_kernel(float* __restrict__ buf, const float* __restrict__ gri,
                      const float* __restrict__ modb) {
    __shared__ float re[MHALF];
    __shared__ float im[MHALF];
    __shared__ float2 tw1[1024];
    __shared__ float2 tw2[1024];
    int t = threadIdx.x;
    int w = blockIdx.x;
    int b = w & 3;
    float2* seq = (float2*)(buf + (size_t)w * SS);
    for (int m = t; m < MHALF; m += 256) {
        float2 v = seq[m];
        re[m] = v.x; im[m] = v.y;   // c[m] = x[2m] + i x[2m+1]
    }
    for (int k = t; k < 1024; k += 256) {
        float sn, cs;
        sincosf(PI_F * (float)k * (1.0f / 1024.0f), &sn, &cs);
        tw1[k] = make_float2(cs, sn);
        sincosf(PI_F * (float)k * (1.0f / 2048.0f), &sn, &cs);
        tw2[k] = make_float2(cs, sn);
    }
    for (int s = 10; s >= 0; --s) {
        int half = 1 << s;
        __syncthreads();
        for (int i = t; i < 1024; i += 256) {
            int jj = i & (half - 1);
            int i1 = ((i >> s) << (s + 1)) + jj;
            int i2 = i1 + half;
            float ar = re[i1], ai = im[i1];
            float br = re[i2], bi = im[i2];
            float dr = ar - br, di = ai - bi;
            float2 tw = tw1[jj << (10 - s)];
            re[i1] = ar + br; im[i1] = ai + bi;
            re[i2] = dr * tw.x + di * tw.y;
            im[i2] = di * tw.x - dr * tw.y;
        }
    }
    __syncthreads();
    const float bias = modb[0];
    const float* gre = gri + (size_t)b * 2 * NFREQ;
    const float* gim = gre + NFREQ;
    const float inv64 = 1.0f / 64.0f;
    for (int k = t; k < 1024; k += 256) {
        if (k == 0) {
            float c0r = re[0], c0i = im[0];
            float z0 = (c0r + c0i) * inv64;
            float zM = (c0r - c0i) * inv64;
            float zr = z0 * gre[0], zi = z0 * gim[0];
            modrelu_apply(zr, zi, bias);
            float yr = zM * gre[2048], yi = zM * gim[2048];
            modrelu_apply(yr, yi, bias);
            float E0 = 0.5f * (zr + yr), O0 = 0.5f * (zr - yr);
            re[0] = E0; im[0] = O0;
            float cr = re[1], ci = im[1];
            float z1r = cr * inv64, z1i = -ci * inv64;
            float g1r = gre[1024], g1i = gim[1024];
            float pr = z1r * g1r - z1i * g1i;
            float pi2 = z1r * g1i + z1i * g1r;
            modrelu_apply(pr, pi2, bias);
            re[1] = pr; im[1] = -pi2;
        } else {
            int kb = 2048 - k;
            int p1 = (int)(__brev((unsigned)k) >> 21);
            int p2 = (int)(__brev((unsigned)kb) >> 21);
            float car = re[p1], cai = im[p1];
            float cbr = re[p2], cbi = im[p2];
            float Er = 0.5f * (car + cbr), Ei = 0.5f * (cai - cbi);
            float Dr = 0.5f * (car - cbr), Di = 0.5f * (cai + cbi);
            float Or = Di, Oi = -Dr;
            float2 t2 = tw2[k];
            float cs = t2.x, sn = t2.y;
            float Wr = cs, Wi = -sn;
            float WOr = Wr * Or - Wi * Oi, WOi = Wr * Oi + Wi * Or;
            float zkr = (Er + WOr) * inv64, zki = (Ei + WOi) * inv64;
            float zbr = (Er - WOr) * inv64, zbi = -(Ei - WOi) * inv64;
            float gkr = gre[k], gki = gim[k];
            float ar = zkr * gkr - zki * gki, ai = zkr * gki + zki * gkr;
            modrelu_apply(ar, ai, bias);
            float gbr = gre[kb], gbi = gim[kb];
            float br2 = zbr * gbr - zbi * gbi, bi2 = zbr * gbi + zbi * gbr;
            modrelu_apply(br2, bi2, bias);
            float Epr = 0.5f * (ar + br2), Epi = 0.5f * (ai - bi2);
            float Dpr = 0.5f * (ar - br2), Dpi = 0.5f * (ai + bi2);
            float Opr = cs * Dpr - sn * Dpi, Opi = cs * Dpi + sn * Dpr;
            re[p1] = Epr - Opi; im[p1] = Epi + Opr;
            re[p2] = Epr + Opi; im[p2] = -Epi + Opr;
        }
    }
    __syncthreads();
    for (int s = 0; s <= 10; ++s) {
        int half = 1 << s;
        for (int i = t; i < 1024; i += 256) {
            int jj = i & (half - 1);
            int i1 = ((i >> s) << (s + 1)) + jj;
            int i2 = i1 + half;
            float2 tw = tw1[jj << (10 - s)];
            float xr = re[i2], xi = im[i2];
            float cr = xr * tw.x - xi * tw.y, ci = xr * tw.y + xi * tw.x;
            float ar = re[i1], ai = im[i1];
            re[i1] = ar + cr; im[i1] = ai + ci;
            re[i2] = ar - cr; im[i2] = ai - ci;
        }
        __syncthreads();
    }
    const float s32 = 1.0f / 32.0f;
    for (int m = t; m < MHALF; m += 256)
        seq[m] = make_float2(re[m] * s32, im[m] * s32);
}

extern "C" void kernel_launch(void* const* d_in, const int* in_sizes, int n_in,
                              void* d_out, int out_size, void* d_ws, size_t ws_size,
                              hipStream_t stream) {
    const float* x        = (const float*)d_in[0];
    const float* W_q      = (const float*)d_in[1];
    const float* W_v      = (const float*)d_in[2];
    const float* W_o      = (const float*)d_in[3];
    const float* ln_gamma = (const float*)d_in[4];
    const float* ln_beta  = (const float*)d_in[5];
    const float* mlp_w1   = (const float*)d_in[6];
    const float* mlp_b1   = (const float*)d_in[7];
    const float* mlp_w2   = (const float*)d_in[8];
    const float* mlp_b2   = (const float*)d_in[9];
    const float* mod_bias = (const float*)d_in[10];
    float* out = (float*)d_out;

    // workspace layout
    float* ws = (float*)d_ws;
    float* partial  = ws;                    // 262144
    float* xsum     = ws + 262144;           // 4096
    float* q_shared = ws + 266240;           // 256
    float* hdn      = ws + 266496;           // 4096
    float* gri      = ws + 270592;           // 16392
    float* mq       = ws + 286984;           // 4096
    float* buf0     = ws + 294912;           // 16777216 floats (64 MiB), [1024][16384]
    u16* bfbase = (u16*)(ws + 294912 + 16777216);
    u16* xut_hi = bfbase;                    // 16777216 u16: x_hi, later reused as ut_hi
    u16* xut_lo = bfbase + 16777216;         // x_lo, later ut_lo
    u16* wv_hi  = bfbase + 33554432;         // 1048576
    u16* wv_lo  = bfbase + 34603008;
    u16* wo_hi  = bfbase + 35651584;
    u16* wo_lo  = bfbase + 36700160;         // ends at 37748736 u16 (~137 MB total ws)

    // gate path
    colsum1_kernel<<<256, 256, 0, stream>>>(x, partial);
    {
        dim3 g(4, 4);
        colsum2_kernel<<<g, 256, 0, stream>>>(partial, xsum);
    }
    gates1a_kernel<<<256, 256, 0, stream>>>(xsum, W_q, mq);
    gates1b_kernel<<<4, 256, 0, stream>>>(mq, ln_gamma, ln_beta, q_shared);
    gates2_kernel<<<16, 256, 0, stream>>>(q_shared, mlp_w1, mlp_b1, hdn);
    gates3_kernel<<<1025, 256, 0, stream>>>(hdn, mlp_w2, mlp_b2, gri);

    // bf16 hi/lo splits
    split_kernel<<<2048, 256, 0, stream>>>(x, xut_hi, xut_lo, 4194304);
    split_kernel<<<1024, 256, 0, stream>>>(W_v, wv_hi, wv_lo, 262144);
    split_kernel<<<1024, 256, 0, stream>>>(W_o, wo_hi, wo_lo, 262144);

    // V projection (transposed output): buf0[j][bs] = sum_k Wv[j,k]*x[bs,k]
    {
        dim3 g(16384 / 128, 1024 / 128);
        gemm_split_kernel<<<g, 256, 0, stream>>>(wv_hi, wv_lo, xut_hi, xut_lo,
                                                 buf0, 1024, 16384, 1024, 16384);
    }

    // fused spectral mixing, in place
    fft_gates_kernel<<<4096, 256, 0, stream>>>(buf0, gri, mod_bias);

    // transpose+split u: buf0 [1024][16384] f32 -> ut hi/lo [16384][1024] bf16
    // (aliases x_hi/x_lo, which are dead after the V GEMM)
    {
        dim3 g(256, 16);
        transpose_split_kernel<<<g, 256, 0, stream>>>(buf0, xut_hi, xut_lo);
    }

    // O projection: out[bs][jo] = sum_j ut[bs][j]*Wo[jo][j]
    {
        dim3 g(1024 / 128, 16384 / 128);
        gemm_split_kernel<<<g, 256, 0, stream>>>(xut_hi, xut_lo, wo_hi, wo_lo,
                                                 out, 16384, 1024, 1024, 1024);
    }
}

// Round 4
// 372.129 us; speedup vs baseline: 3.5152x; 1.2125x over previous
//
#include <hip/hip_runtime.h>
#include <math.h>
#include <stdint.h>

#define PI_F 3.14159265358979323846f

// Problem constants
#define BB 4
#define SS 4096
#define DD 1024
#define HH 16
#define DHD 64
#define NFREQ 2049   // 4096/2 + 1
#define MHALF 2048   // half-size complex FFT length

typedef unsigned short u16;
typedef __attribute__((ext_vector_type(8))) short short8;   // 8 bf16 = 4 VGPR (MFMA A/B frag)
typedef __attribute__((ext_vector_type(4))) float f32x4;    // MFMA C/D frag
typedef __attribute__((ext_vector_type(4))) unsigned short u16x4;

// ---- bf16 helpers (RTNE) ----
__device__ __forceinline__ u16 f2bf(float f) {
    unsigned u = __float_as_uint(f);
    unsigned r = (u + 0x7FFFu + ((u >> 16) & 1u)) >> 16;
    return (u16)r;
}
__device__ __forceinline__ float bf2f(u16 h) { return __uint_as_float(((unsigned)h) << 16); }

__device__ __forceinline__ void modrelu_apply(float& zr, float& zi, float bias) {
    float mag = sqrtf(zr * zr + zi * zi);
    float scale = fmaxf(mag + bias, 0.0f) / fmaxf(mag, 1e-12f);
    zr *= scale; zi *= scale;
}

// async global->LDS, 16B per lane (HW: dest = wave-uniform base + lane*16)
__device__ __forceinline__ void gload16(const u16* g, u16* l) {
    __builtin_amdgcn_global_load_lds(
        (const __attribute__((address_space(1))) void*)g,
        (__attribute__((address_space(3))) void*)l, 16, 0, 0);
}

// LDS byte-offset swizzle for GEMM staging (16B chunks)
__device__ __forceinline__ int swz(int byteoff) {
    return byteoff ^ (((byteoff >> 7) & 3) << 4);
}

// ---------------- fused x -> bf16 hi/lo split + column partial sums -----------
// grid 256 = (b, s-chunk of 64); thread t owns columns 4t..4t+3
__global__ __launch_bounds__(256)
void split_x_colsum_kernel(const float* __restrict__ x, u16* __restrict__ hi,
                           u16* __restrict__ lo, float* __restrict__ partial) {
    int blk = blockIdx.x;
    int b = blk >> 6;
    int s0 = (blk & 63) * 64;
    int t = threadIdx.x;
    const float* xp = x + ((size_t)b * SS + s0) * DD;
    float4 acc = make_float4(0.f, 0.f, 0.f, 0.f);
    for (int s = 0; s < 64; ++s) {
        float4 v = ((const float4*)(xp + (size_t)s * DD))[t];
        acc.x += v.x; acc.y += v.y; acc.z += v.z; acc.w += v.w;
        u16x4 h, l;
        h.x = f2bf(v.x); h.y = f2bf(v.y); h.z = f2bf(v.z); h.w = f2bf(v.w);
        l.x = f2bf(v.x - bf2f(h.x));
        l.y = f2bf(v.y - bf2f(h.y));
        l.z = f2bf(v.z - bf2f(h.z));
        l.w = f2bf(v.w - bf2f(h.w));
        size_t rowo = (size_t)(b * SS + s0 + s) * DD;
        ((u16x4*)(hi + rowo))[t] = h;
        ((u16x4*)(lo + rowo))[t] = l;
    }
    ((float4*)(partial + (size_t)blk * DD))[t] = acc;
}

__global__ __launch_bounds__(256)
void colsum2_kernel(const float* __restrict__ partial, float* __restrict__ xsum) {
    int b = blockIdx.y;
    int k = blockIdx.x * 256 + threadIdx.x;
    float acc = 0.f;
    for (int c = 0; c < 64; ++c)
        acc += partial[((size_t)(b * 64 + c)) * DD + k];
    xsum[b * DD + k] = acc;
}

// ---------------- mq[b][j] = dot(xsum[b]/S, Wq[j]) ; grid 256, 1 wave per row j
__global__ __launch_bounds__(256)
void gates1a_kernel(const float* __restrict__ xsum, const float* __restrict__ Wq,
                    float* __restrict__ mq) {
    __shared__ float xb[4][1024];
    int t = threadIdx.x;
    for (int i = t; i < 4096; i += 256)
        xb[i >> 10][i & 1023] = xsum[i] * (1.0f / 4096.0f);
    __syncthreads();
    int wv = t >> 6, l = t & 63;
    int j = blockIdx.x * 4 + wv;
    const float* wrow = Wq + (size_t)j * DD;
    float a0 = 0.f, a1 = 0.f, a2 = 0.f, a3 = 0.f;
    #pragma unroll 4
    for (int it = 0; it < 16; ++it) {
        int idx = l + it * 64;
        float wval = wrow[idx];
        a0 += xb[0][idx] * wval;
        a1 += xb[1][idx] * wval;
        a2 += xb[2][idx] * wval;
        a3 += xb[3][idx] * wval;
    }
    for (int off = 32; off > 0; off >>= 1) {
        a0 += __shfl_down(a0, off, 64);
        a1 += __shfl_down(a1, off, 64);
        a2 += __shfl_down(a2, off, 64);
        a3 += __shfl_down(a3, off, 64);
    }
    if (l == 0) {
        mq[j] = a0; mq[1024 + j] = a1; mq[2048 + j] = a2; mq[3072 + j] = a3;
    }
}

// ---------------- LayerNorm per head over mq, mean over heads -> q_shared[b][64]
__global__ __launch_bounds__(256)
void gates1b_kernel(const float* __restrict__ mq, const float* __restrict__ gamma,
                    const float* __restrict__ beta, float* __restrict__ q_shared) {
    __shared__ float qacc[4][64];
    int b = blockIdx.x;
    int t = threadIdx.x;
    int wv = t >> 6, l = t & 63;
    float part = 0.f;
    for (int hh = 0; hh < 4; ++hh) {
        int h = wv * 4 + hh;
        float v = mq[b * 1024 + h * 64 + l];
        float s1 = v, s2 = v * v;
        for (int off = 32; off > 0; off >>= 1) {
            s1 += __shfl_xor(s1, off, 64);
            s2 += __shfl_xor(s2, off, 64);
        }
        float mu = s1 * (1.0f / 64.0f);
        float var = s2 * (1.0f / 64.0f) - mu * mu;
        part += (v - mu) * rsqrtf(var + 1e-5f) * gamma[l] + beta[l];
    }
    qacc[wv][l] = part;
    __syncthreads();
    if (t < 64) {
        float s = qacc[0][t] + qacc[1][t] + qacc[2][t] + qacc[3][t];
        q_shared[b * 64 + t] = s * (1.0f / 16.0f);
    }
}

// ---------------- hdn = gelu(q_shared @ w1^T + b1)
__global__ __launch_bounds__(256)
void gates2_kernel(const float* __restrict__ q_shared, const float* __restrict__ w1,
                   const float* __restrict__ b1, float* __restrict__ hdn) {
    __shared__ float qs[64];
    int blk = blockIdx.x;
    int b = blk >> 2;
    int i0 = (blk & 3) * 256;
    int t = threadIdx.x;
    if (t < 64) qs[t] = q_shared[b * 64 + t];
    __syncthreads();
    int i = i0 + t;
    const float* wrow = w1 + (size_t)i * DHD;
    float acc = b1[i];
    #pragma unroll 8
    for (int d = 0; d < 64; ++d) acc += qs[d] * wrow[d];
    float g = 0.5f * acc * (1.0f + erff(acc * 0.70710678118654752f));
    hdn[b * DD + i] = g;
}

// ---------------- gri = hdn @ w2^T + b2 ; one wave per output row, all 4 b at once
__global__ __launch_bounds__(256)
void gates3_kernel(const float* __restrict__ hdn, const float* __restrict__ w2,
                   const float* __restrict__ b2, float* __restrict__ gri) {
    int t = threadIdx.x;
    int wv = t >> 6, l = t & 63;
    int r = blockIdx.x * 4 + wv;
    if (r >= 2 * NFREQ) return;
    const float* wrow = w2 + (size_t)r * DD;
    float a0 = 0.f, a1 = 0.f, a2 = 0.f, a3 = 0.f;
    for (int it = 0; it < 16; ++it) {
        int idx = l + it * 64;
        float wval = wrow[idx];
        a0 += hdn[idx] * wval;
        a1 += hdn[1024 + idx] * wval;
        a2 += hdn[2048 + idx] * wval;
        a3 += hdn[3072 + idx] * wval;
    }
    for (int off = 32; off > 0; off >>= 1) {
        a0 += __shfl_down(a0, off, 64);
        a1 += __shfl_down(a1, off, 64);
        a2 += __shfl_down(a2, off, 64);
        a3 += __shfl_down(a3, off, 64);
    }
    if (l == 0) {
        float bb = b2[r];
        gri[r] = a0 + bb;
        gri[2 * NFREQ + r] = a1 + bb;
        gri[2 * 2 * NFREQ + r] = a2 + bb;
        gri[3 * 2 * NFREQ + r] = a3 + bb;
    }
}

// ---------------- f32 -> (bf16 hi, bf16 lo) split (weights) ----------------
__global__ __launch_bounds__(256)
void split_kernel(const float* __restrict__ src, u16* __restrict__ hi,
                  u16* __restrict__ lo, int n4) {
    int idx = blockIdx.x * 256 + threadIdx.x;
    int stride = gridDim.x * 256;
    for (; idx < n4; idx += stride) {
        float4 v = ((const float4*)src)[idx];
        u16x4 h, l;
        h.x = f2bf(v.x); h.y = f2bf(v.y); h.z = f2bf(v.z); h.w = f2bf(v.w);
        l.x = f2bf(v.x - bf2f(h.x));
        l.y = f2bf(v.y - bf2f(h.y));
        l.z = f2bf(v.z - bf2f(h.z));
        l.w = f2bf(v.w - bf2f(h.w));
        ((u16x4*)hi)[idx] = h;
        ((u16x4*)lo)[idx] = l;
    }
}

// ---------------- transpose + split: src f32 [1024][16384] -> hi/lo bf16 [16384][1024]
__global__ __launch_bounds__(256)
void transpose_split_kernel(const float* __restrict__ src, u16* __restrict__ hi,
                            u16* __restrict__ lo) {
    __shared__ float tile[64][65];
    int s0 = blockIdx.x * 64;   // bs block
    int j0 = blockIdx.y * 64;   // feature block
    int t = threadIdx.x;
    int c = t & 63, r4 = t >> 6;
    #pragma unroll
    for (int rr = 0; rr < 64; rr += 4)
        tile[rr + r4][c] = src[(size_t)(j0 + rr + r4) * 16384 + s0 + c];
    __syncthreads();
    #pragma unroll
    for (int rr = 0; rr < 64; rr += 4) {
        int a = rr + r4;                 // local bs
        float v = tile[c][a];            // = src[j0+c][s0+a]
        u16 h = f2bf(v);
        size_t o = (size_t)(s0 + a) * 1024 + j0 + c;
        hi[o] = h;
        lo[o] = f2bf(v - bf2f(h));
    }
}

// ---------------- split-bf16 MFMA GEMM: C[M][N] = A[M][K] * B[N][K]^T ----------
__global__ __launch_bounds__(256, 3)
void gemm_split_kernel(const u16* __restrict__ Ah, const u16* __restrict__ Al,
                       const u16* __restrict__ Bh, const u16* __restrict__ Bl,
                       float* __restrict__ C, int M, int N, int K, int ldc) {
    __shared__ u16 lds[4][4096];   // planes: Ah, Al, Bh, Bl; each [128 rows][32 k] swizzled
    const int t = threadIdx.x;
    const int wid = __builtin_amdgcn_readfirstlane(t >> 6);
    const int lane = t & 63;
    const int n0 = blockIdx.x * 128;
    const int m0 = blockIdx.y * 128;
    const int wm = (wid >> 1) * 64;
    const int wn = (wid & 1) * 64;

    const int j1 = wid * 128 + lane;
    const int j2 = j1 + 64;
    const int c1 = j1 ^ ((j1 >> 3) & 3);
    const int c2 = j2 ^ ((j2 >> 3) & 3);
    const int r1 = c1 >> 2, q1 = c1 & 3;
    const int r2 = c2 >> 2, q2 = c2 & 3;
    const size_t offA1 = (size_t)(m0 + r1) * K + q1 * 8;
    const size_t offA2 = (size_t)(m0 + r2) * K + q2 * 8;
    const size_t offB1 = (size_t)(n0 + r1) * K + q1 * 8;
    const size_t offB2 = (size_t)(n0 + r2) * K + q2 * 8;
    u16* d1 = &lds[0][0] + (size_t)j1 * 8;
    u16* d2 = &lds[0][0] + (size_t)j2 * 8;

    const int abase = (wm + (lane & 15)) * 64 + (lane >> 4) * 16;
    const int bbase = (wn + (lane & 15)) * 64 + (lane >> 4) * 16;

    f32x4 acc[4][4] = {};

    for (int k0 = 0; k0 < K; k0 += 32) {
        __syncthreads();
        gload16(Ah + offA1 + k0, d1);
        gload16(Ah + offA2 + k0, d2);
        gload16(Al + offA1 + k0, d1 + 4096);
        gload16(Al + offA2 + k0, d2 + 4096);
        gload16(Bh + offB1 + k0, d1 + 8192);
        gload16(Bh + offB2 + k0, d2 + 8192);
        gload16(Bl + offB1 + k0, d1 + 12288);
        gload16(Bl + offB2 + k0, d2 + 12288);
        __syncthreads();

        short8 bh[4], bl[4];
        #pragma unroll
        for (int j = 0; j < 4; ++j) {
            int lb = swz(bbase + j * 1024);
            bh[j] = *(const short8*)&lds[2][lb >> 1];
            bl[j] = *(const short8*)&lds[3][lb >> 1];
        }
        #pragma unroll
        for (int i = 0; i < 4; ++i) {
            int la = swz(abase + i * 1024);
            short8 ah = *(const short8*)&lds[0][la >> 1];
            short8 al = *(const short8*)&lds[1][la >> 1];
            #pragma unroll
            for (int j = 0; j < 4; ++j) {
                acc[i][j] = __builtin_amdgcn_mfma_f32_16x16x32_bf16(ah, bl[j], acc[i][j], 0, 0, 0);
                acc[i][j] = __builtin_amdgcn_mfma_f32_16x16x32_bf16(al, bh[j], acc[i][j], 0, 0, 0);
                acc[i][j] = __builtin_amdgcn_mfma_f32_16x16x32_bf16(ah, bh[j], acc[i][j], 0, 0, 0);
            }
        }
    }

    const int cb = n0 + wn + (lane & 15);
    #pragma unroll
    for (int i = 0; i < 4; ++i) {
        int rb = m0 + wm + i * 16 + ((lane >> 4) << 2);
        #pragma unroll
        for (int e = 0; e < 4; ++e) {
            float* crow = C + (size_t)(rb + e) * ldc + cb;
            #pragma unroll
            for (int j = 0; j < 4; ++j)
                crow[j * 16] = acc[i][j][e];
        }
    }
}

// ---------------- twiddle table init (global, shared by all FFT blocks) -------
// Tg[h + jj] = (cos, sin)(pi*jj/h) for h = 2^s, s=0..10  (indices 1..2047)
// Tg[2048 + k] = (cos, sin)(pi*k/2048), k=0..1023  (real-FFT pack/unpack)
__global__ __launch_bounds__(256)
void twiddle_init_kernel(float2* __restrict__ Tg) {
    int idx = blockIdx.x * 256 + threadIdx.x;
    if (idx >= 3072) return;
    float cs = 1.f, sn = 0.f;
    if (idx >= 2048) {
        sincosf(PI_F * (float)(idx - 2048) * (1.0f / 2048.0f), &sn, &cs);
    } else if (idx >= 1) {
        int s = 31 - __clz(idx);
        int h = 1 << s;
        sincosf(PI_F * (float)(idx - h) / (float)h, &sn, &cs);
    }
    Tg[idx] = make_float2(cs, sn);
}

// butterflies: fwd applies e^{-i th} to the difference; inv applies e^{+i th} then add/sub
__device__ __forceinline__ void bfly_f(float2& a, float2& b, float cs, float sn) {
    float2 s = make_float2(a.x + b.x, a.y + b.y);
    float2 d = make_float2(a.x - b.x, a.y - b.y);
    a = s;
    b = make_float2(d.x * cs + d.y * sn, d.y * cs - d.x * sn);
}
__device__ __forceinline__ void bfly_i(float2& a, float2& b, float cs, float sn) {
    float cr = b.x * cs - b.y * sn;
    float ci = b.x * sn + b.y * cs;
    float2 a0 = a;
    a = make_float2(a0.x + cr, a0.y + ci);
    b = make_float2(a0.x - cr, a0.y - ci);
}
// LDS index swizzle: fold bits 5..8 into bank bits (float2 elems, bank-pair = a%16)
__device__ __forceinline__ int SW(int a) { return a ^ ((a >> 5) & 15); }

// ---------------- fused rfft -> gates -> modReLU -> irfft, in-place per sequence
// Radix-8-grouped stages in registers; LDS only for group-boundary exchanges.
__global__ __launch_bounds__(256)
void fft_gates_kernel(float* __restrict__ buf, const float* __restrict__ gri,
                      const float* __restrict__ modb, const float2* __restrict__ Tg) {
    __shared__ float2 cf[MHALF];
    const int t = threadIdx.x;
    const int w = blockIdx.x;
    const int b = w & 3;
    float2* seq = (float2*)(buf + (size_t)w * SS);

    const int t5 = t & 31;
    const int t3 = t & 3;
    const int c32 = ((t >> 5) << 8) | t5;    // base for 32-span group
    const int d4  = ((t >> 2) << 5) | t3;    // base for 4-span group

    float2 r[8];

    // ---- load + G1: stages 10,9,8 (span 256) ----
    #pragma unroll
    for (int u = 0; u < 8; ++u) r[u] = seq[t + 256 * u];
    #pragma unroll
    for (int u = 0; u < 4; ++u) {
        float2 tw = Tg[1024 + t + 256 * u];
        bfly_f(r[u], r[u + 4], tw.x, tw.y);
    }
    {
        float2 tw0 = Tg[512 + t], tw1 = Tg[512 + t + 256];
        bfly_f(r[0], r[2], tw0.x, tw0.y);
        bfly_f(r[1], r[3], tw1.x, tw1.y);
        bfly_f(r[4], r[6], tw0.x, tw0.y);
        bfly_f(r[5], r[7], tw1.x, tw1.y);
        float2 tw = Tg[256 + t];
        bfly_f(r[0], r[1], tw.x, tw.y);
        bfly_f(r[2], r[3], tw.x, tw.y);
        bfly_f(r[4], r[5], tw.x, tw.y);
        bfly_f(r[6], r[7], tw.x, tw.y);
    }
    #pragma unroll
    for (int u = 0; u < 8; ++u) cf[SW(t + 256 * u)] = r[u];
    __syncthreads();

    // ---- G2: stages 7,6,5 (span 32) ----
    #pragma unroll
    for (int u = 0; u < 8; ++u) r[u] = cf[SW(c32 + 32 * u)];
    #pragma unroll
    for (int u = 0; u < 4; ++u) {
        float2 tw = Tg[128 + t5 + 32 * u];
        bfly_f(r[u], r[u + 4], tw.x, tw.y);
    }
    {
        float2 tw0 = Tg[64 + t5], tw1 = Tg[64 + t5 + 32];
        bfly_f(r[0], r[2], tw0.x, tw0.y);
        bfly_f(r[1], r[3], tw1.x, tw1.y);
        bfly_f(r[4], r[6], tw0.x, tw0.y);
        bfly_f(r[5], r[7], tw1.x, tw1.y);
        float2 tw = Tg[32 + t5];
        bfly_f(r[0], r[1], tw.x, tw.y);
        bfly_f(r[2], r[3], tw.x, tw.y);
        bfly_f(r[4], r[5], tw.x, tw.y);
        bfly_f(r[6], r[7], tw.x, tw.y);
    }
    #pragma unroll
    for (int u = 0; u < 8; ++u) cf[SW(c32 + 32 * u)] = r[u];
    __syncthreads();

    // ---- G3: stages 4,3,2 (span 4) ----
    #pragma unroll
    for (int u = 0; u < 8; ++u) r[u] = cf[SW(d4 + 4 * u)];
    #pragma unroll
    for (int u = 0; u < 4; ++u) {
        float2 tw = Tg[16 + t3 + 4 * u];
        bfly_f(r[u], r[u + 4], tw.x, tw.y);
    }
    {
        float2 tw0 = Tg[8 + t3], tw1 = Tg[8 + t3 + 4];
        bfly_f(r[0], r[2], tw0.x, tw0.y);
        bfly_f(r[1], r[3], tw1.x, tw1.y);
        bfly_f(r[4], r[6], tw0.x, tw0.y);
        bfly_f(r[5], r[7], tw1.x, tw1.y);
        float2 tw = Tg[4 + t3];
        bfly_f(r[0], r[1], tw.x, tw.y);
        bfly_f(r[2], r[3], tw.x, tw.y);
        bfly_f(r[4], r[5], tw.x, tw.y);
        bfly_f(r[6], r[7], tw.x, tw.y);
    }
    #pragma unroll
    for (int u = 0; u < 8; ++u) cf[SW(d4 + 4 * u)] = r[u];
    __syncthreads();

    // ---- G4: stages 1,0 (span 1; 8 consecutive) ----
    #pragma unroll
    for (int u = 0; u < 8; ++u) r[u] = cf[SW(8 * t + u)];
    // stage 1: jj=0 -> tw=1; jj=1 -> tw=e^{-i pi/2}=(0,1)
    bfly_f(r[0], r[2], 1.f, 0.f);
    bfly_f(r[1], r[3], 0.f, 1.f);
    bfly_f(r[4], r[6], 1.f, 0.f);
    bfly_f(r[5], r[7], 0.f, 1.f);
    // stage 0: tw=1
    bfly_f(r[0], r[1], 1.f, 0.f);
    bfly_f(r[2], r[3], 1.f, 0.f);
    bfly_f(r[4], r[5], 1.f, 0.f);
    bfly_f(r[6], r[7], 1.f, 0.f);
    #pragma unroll
    for (int u = 0; u < 8; ++u) cf[SW(8 * t + u)] = r[u];
    __syncthreads();

    // ---- spectrum: unpack real-FFT bins (ortho /64), gates, modReLU, repack ----
    const float bias = modb[0];
    const float* gre = gri + (size_t)b * 2 * NFREQ;
    const float* gim = gre + NFREQ;
    const float inv64 = 1.0f / 64.0f;
    for (int k = t; k < 1024; k += 256) {
        if (k == 0) {
            float2 c0 = cf[SW(0)];
            float z0 = (c0.x + c0.y) * inv64;
            float zM = (c0.x - c0.y) * inv64;
            float zr = z0 * gre[0], zi = z0 * gim[0];
            modrelu_apply(zr, zi, bias);
            float yr = zM * gre[2048], yi = zM * gim[2048];
            modrelu_apply(yr, yi, bias);
            cf[SW(0)] = make_float2(0.5f * (zr + yr), 0.5f * (zr - yr));
            float2 c1 = cf[SW(1)];
            float z1r = c1.x * inv64, z1i = -c1.y * inv64;
            float g1r = gre[1024], g1i = gim[1024];
            float pr = z1r * g1r - z1i * g1i;
            float pi2 = z1r * g1i + z1i * g1r;
            modrelu_apply(pr, pi2, bias);
            cf[SW(1)] = make_float2(pr, -pi2);
        } else {
            int kb = 2048 - k;
            int p1 = SW((int)(__brev((unsigned)k) >> 21));
            int p2 = SW((int)(__brev((unsigned)kb) >> 21));
            float2 ca = cf[p1];
            float2 cb2 = cf[p2];
            float Er = 0.5f * (ca.x + cb2.x), Ei = 0.5f * (ca.y - cb2.y);
            float Dr = 0.5f * (ca.x - cb2.x), Di = 0.5f * (ca.y + cb2.y);
            float Or = Di, Oi = -Dr;
            float2 t2 = Tg[2048 + k];
            float cs = t2.x, sn = t2.y;
            float Wr = cs, Wi = -sn;
            float WOr = Wr * Or - Wi * Oi, WOi = Wr * Oi + Wi * Or;
            float zkr = (Er + WOr) * inv64, zki = (Ei + WOi) * inv64;
            float zbr = (Er - WOr) * inv64, zbi = -(Ei - WOi) * inv64;
            float gkr = gre[k], gki = gim[k];
            float ar = zkr * gkr - zki * gki, ai = zkr * gki + zki * gkr;
            modrelu_apply(ar, ai, bias);
            float gbr = gre[kb], gbi = gim[kb];
            float br2 = zbr * gbr - zbi * gbi, bi2 = zbr * gbi + zbi * gbr;
            modrelu_apply(br2, bi2, bias);
            float Epr = 0.5f * (ar + br2), Epi = 0.5f * (ai - bi2);
            float Dpr = 0.5f * (ar - br2), Dpi = 0.5f * (ai + bi2);
            float Opr = cs * Dpr - sn * Dpi, Opi = cs * Dpi + sn * Dpr;
            cf[p1] = make_float2(Epr - Opi, Epi + Opr);
            cf[p2] = make_float2(Epr + Opi, -Epi + Opr);
        }
    }
    __syncthreads();

    // ---- inverse G4': stages 0,1 ----
    #pragma unroll
    for (int u = 0; u < 8; ++u) r[u] = cf[SW(8 * t + u)];
    bfly_i(r[0], r[1], 1.f, 0.f);
    bfly_i(r[2], r[3], 1.f, 0.f);
    bfly_i(r[4], r[5], 1.f, 0.f);
    bfly_i(r[6], r[7], 1.f, 0.f);
    bfly_i(r[0], r[2], 1.f, 0.f);
    bfly_i(r[1], r[3], 0.f, 1.f);
    bfly_i(r[4], r[6], 1.f, 0.f);
    bfly_i(r[5], r[7], 0.f, 1.f);
    #pragma unroll
    for (int u = 0; u < 8; ++u) cf[SW(8 * t + u)] = r[u];
    __syncthreads();

    // ---- inverse G3': stages 2,3,4 ----
    #pragma unroll
    for (int u = 0; u < 8; ++u) r[u] = cf[SW(d4 + 4 * u)];
    {
        float2 tw = Tg[4 + t3];
        bfly_i(r[0], r[1], tw.x, tw.y);
        bfly_i(r[2], r[3], tw.x, tw.y);
        bfly_i(r[4], r[5], tw.x, tw.y);
        bfly_i(r[6], r[7], tw.x, tw.y);
        float2 tw0 = Tg[8 + t3], tw1 = Tg[8 + t3 + 4];
        bfly_i(r[0], r[2], tw0.x, tw0.y);
        bfly_i(r[1], r[3], tw1.x, tw1.y);
        bfly_i(r[4], r[6], tw0.x, tw0.y);
        bfly_i(r[5], r[7], tw1.x, tw1.y);
    }
    #pragma unroll
    for (int u = 0; u < 4; ++u) {
        float2 tw = Tg[16 + t3 + 4 * u];
        bfly_i(r[u], r[u + 4], tw.x, tw.y);
    }
    #pragma unroll
    for (int u = 0; u < 8; ++u) cf[SW(d4 + 4 * u)] = r[u];
    __syncthreads();

    // ---- inverse G2': stages 5,6,7 ----
    #pragma unroll
    for (int u = 0; u < 8; ++u) r[u] = cf[SW(c32 + 32 * u)];
    {
        float2 tw = Tg[32 + t5];
        bfly_i(r[0], r[1], tw.x, tw.y);
        bfly_i(r[2], r[3], tw.x, tw.y);
        bfly_i(r[4], r[5], tw.x, tw.y);
        bfly_i(r[6], r[7], tw.x, tw.y);
        float2 tw0 = Tg[64 + t5], tw1 = Tg[64 + t5 + 32];
        bfly_i(r[0], r[2], tw0.x, tw0.y);
        bfly_i(r[1], r[3], tw1.x, tw1.y);
        bfly_i(r[4], r[6], tw0.x, tw0.y);
        bfly_i(r[5], r[7], tw1.x, tw1.y);
    }
    #pragma unroll
    for (int u = 0; u < 4; ++u) {
        float2 tw = Tg[128 + t5 + 32 * u];
        bfly_i(r[u], r[u + 4], tw.x, tw.y);
    }
    #pragma unroll
    for (int u = 0; u < 8; ++u) cf[SW(c32 + 32 * u)] = r[u];
    __syncthreads();

    // ---- inverse G1': stages 8,9,10 + scale + store ----
    #pragma unroll
    for (int u = 0; u < 8; ++u) r[u] = cf[SW(t + 256 * u)];
    {
        float2 tw = Tg[256 + t];
        bfly_i(r[0], r[1], tw.x, tw.y);
        bfly_i(r[2], r[3], tw.x, tw.y);
        bfly_i(r[4], r[5], tw.x, tw.y);
        bfly_i(r[6], r[7], tw.x, tw.y);
        float2 tw0 = Tg[512 + t], tw1 = Tg[512 + t + 256];
        bfly_i(r[0], r[2], tw0.x, tw0.y);
        bfly_i(r[1], r[3], tw1.x, tw1.y);
        bfly_i(r[4], r[6], tw0.x, tw0.y);
        bfly_i(r[5], r[7], tw1.x, tw1.y);
    }
    #pragma unroll
    for (int u = 0; u < 4; ++u) {
        float2 tw = Tg[1024 + t + 256 * u];
        bfly_i(r[u], r[u + 4], tw.x, tw.y);
    }
    const float s32 = 1.0f / 32.0f;  // 64 (ortho) / 2048 (ifft norm)
    #pragma unroll
    for (int u = 0; u < 8; ++u)
        seq[t + 256 * u] = make_float2(r[u].x * s32, r[u].y * s32);
}

extern "C" void kernel_launch(void* const* d_in, const int* in_sizes, int n_in,
                              void* d_out, int out_size, void* d_ws, size_t ws_size,
                              hipStream_t stream) {
    const float* x        = (const float*)d_in[0];
    const float* W_q      = (const float*)d_in[1];
    const float* W_v      = (const float*)d_in[2];
    const float* W_o      = (const float*)d_in[3];
    const float* ln_gamma = (const float*)d_in[4];
    const float* ln_beta  = (const float*)d_in[5];
    const float* mlp_w1   = (const float*)d_in[6];
    const float* mlp_b1   = (const float*)d_in[7];
    const float* mlp_w2   = (const float*)d_in[8];
    const float* mlp_b2   = (const float*)d_in[9];
    const float* mod_bias = (const float*)d_in[10];
    float* out = (float*)d_out;

    // workspace layout (floats)
    float* ws = (float*)d_ws;
    float* partial  = ws;                    // 262144
    float* xsum     = ws + 262144;           // 4096
    float* q_shared = ws + 266240;           // 256
    float* hdn      = ws + 266496;           // 4096
    float* gri      = ws + 270592;           // 16392 (ends 286984)
    float* mq       = ws + 286984;           // 4096 (ends 291080)
    float2* twid    = (float2*)(ws + 291080); // 3072 float2 = 6144 (ends 297224)
    float* buf0     = ws + 297984;           // 16777216 floats (64 MiB), [1024][16384]
    u16* bfbase = (u16*)(ws + 297984 + 16777216);
    u16* xut_hi = bfbase;                    // 16777216 u16: x_hi, later reused as ut_hi
    u16* xut_lo = bfbase + 16777216;         // x_lo, later ut_lo
    u16* wv_hi  = bfbase + 33554432;         // 1048576
    u16* wv_lo  = bfbase + 34603008;
    u16* wo_hi  = bfbase + 35651584;
    u16* wo_lo  = bfbase + 36700160;

    twiddle_init_kernel<<<12, 256, 0, stream>>>(twid);

    // fused x split + colsum pass 1
    split_x_colsum_kernel<<<256, 256, 0, stream>>>(x, xut_hi, xut_lo, partial);
    {
        dim3 g(4, 4);
        colsum2_kernel<<<g, 256, 0, stream>>>(partial, xsum);
    }
    gates1a_kernel<<<256, 256, 0, stream>>>(xsum, W_q, mq);
    gates1b_kernel<<<4, 256, 0, stream>>>(mq, ln_gamma, ln_beta, q_shared);
    gates2_kernel<<<16, 256, 0, stream>>>(q_shared, mlp_w1, mlp_b1, hdn);
    gates3_kernel<<<1025, 256, 0, stream>>>(hdn, mlp_w2, mlp_b2, gri);

    // weight splits
    split_kernel<<<1024, 256, 0, stream>>>(W_v, wv_hi, wv_lo, 262144);
    split_kernel<<<1024, 256, 0, stream>>>(W_o, wo_hi, wo_lo, 262144);

    // V projection (transposed output): buf0[j][bs] = sum_k Wv[j,k]*x[bs,k]
    {
        dim3 g(16384 / 128, 1024 / 128);
        gemm_split_kernel<<<g, 256, 0, stream>>>(wv_hi, wv_lo, xut_hi, xut_lo,
                                                 buf0, 1024, 16384, 1024, 16384);
    }

    // fused spectral mixing, in place
    fft_gates_kernel<<<4096, 256, 0, stream>>>(buf0, gri, mod_bias, twid);

    // transpose+split u: buf0 [1024][16384] f32 -> ut hi/lo [16384][1024] bf16
    {
        dim3 g(256, 16);
        transpose_split_kernel<<<g, 256, 0, stream>>>(buf0, xut_hi, xut_lo);
    }

    // O projection: out[bs][jo] = sum_j ut[bs][j]*Wo[jo][j]
    {
        dim3 g(1024 / 128, 16384 / 128);
        gemm_split_kernel<<<g, 256, 0, stream>>>(xut_hi, xut_lo, wo_hi, wo_lo,
                                                 out, 16384, 1024, 1024, 1024);
    }
}

// Round 5
// 313.264 us; speedup vs baseline: 4.1757x; 1.1879x over previous
//
#include <hip/hip_runtime.h>
#include <math.h>
#include <stdint.h>

#define PI_F 3.14159265358979323846f

// Problem constants
#define BB 4
#define SS 4096
#define DD 1024
#define HH 16
#define DHD 64
#define NFREQ 2049   // 4096/2 + 1
#define MHALF 2048   // half-size complex FFT length

typedef unsigned short u16;
typedef __attribute__((ext_vector_type(8))) short short8;   // 8 bf16 = 4 VGPR (MFMA A/B frag)
typedef __attribute__((ext_vector_type(4))) float f32x4;    // MFMA C/D frag
typedef __attribute__((ext_vector_type(4))) unsigned short u16x4;

// ---- bf16 helpers (RTNE) ----
__device__ __forceinline__ u16 f2bf(float f) {
    unsigned u = __float_as_uint(f);
    unsigned r = (u + 0x7FFFu + ((u >> 16) & 1u)) >> 16;
    return (u16)r;
}
__device__ __forceinline__ float bf2f(u16 h) { return __uint_as_float(((unsigned)h) << 16); }

__device__ __forceinline__ void modrelu_apply(float& zr, float& zi, float bias) {
    float mag = sqrtf(zr * zr + zi * zi);
    float scale = fmaxf(mag + bias, 0.0f) / fmaxf(mag, 1e-12f);
    zr *= scale; zi *= scale;
}

// async global->LDS, 16B per lane (HW: dest = wave-uniform base + lane*16)
__device__ __forceinline__ void gload16(const u16* g, u16* l) {
    __builtin_amdgcn_global_load_lds(
        (const __attribute__((address_space(1))) void*)g,
        (__attribute__((address_space(3))) void*)l, 16, 0, 0);
}

// LDS byte-offset swizzle for GEMM staging (16B chunks): XOR chunk bits [4:3]
// into chunk bits [1:0]; involution, matches the pre-swizzled staging order.
__device__ __forceinline__ int swz(int byteoff) {
    return byteoff ^ (((byteoff >> 7) & 3) << 4);
}

// ---------------- fused x -> bf16 hi/lo split + column partial sums -----------
// grid 256 = (b, s-chunk of 64); thread t owns columns 4t..4t+3
__global__ __launch_bounds__(256)
void split_x_colsum_kernel(const float* __restrict__ x, u16* __restrict__ hi,
                           u16* __restrict__ lo, float* __restrict__ partial) {
    int blk = blockIdx.x;
    int b = blk >> 6;
    int s0 = (blk & 63) * 64;
    int t = threadIdx.x;
    const float* xp = x + ((size_t)b * SS + s0) * DD;
    float4 acc = make_float4(0.f, 0.f, 0.f, 0.f);
    for (int s = 0; s < 64; ++s) {
        float4 v = ((const float4*)(xp + (size_t)s * DD))[t];
        acc.x += v.x; acc.y += v.y; acc.z += v.z; acc.w += v.w;
        u16x4 h, l;
        h.x = f2bf(v.x); h.y = f2bf(v.y); h.z = f2bf(v.z); h.w = f2bf(v.w);
        l.x = f2bf(v.x - bf2f(h.x));
        l.y = f2bf(v.y - bf2f(h.y));
        l.z = f2bf(v.z - bf2f(h.z));
        l.w = f2bf(v.w - bf2f(h.w));
        size_t rowo = (size_t)(b * SS + s0 + s) * DD;
        ((u16x4*)(hi + rowo))[t] = h;
        ((u16x4*)(lo + rowo))[t] = l;
    }
    ((float4*)(partial + (size_t)blk * DD))[t] = acc;
}

__global__ __launch_bounds__(256)
void colsum2_kernel(const float* __restrict__ partial, float* __restrict__ xsum) {
    int b = blockIdx.y;
    int k = blockIdx.x * 256 + threadIdx.x;
    float acc = 0.f;
    for (int c = 0; c < 64; ++c)
        acc += partial[((size_t)(b * 64 + c)) * DD + k];
    xsum[b * DD + k] = acc;
}

// ---------------- mq[b][j] = dot(xsum[b]/S, Wq[j]) ; grid 256, 1 wave per row j
__global__ __launch_bounds__(256)
void gates1a_kernel(const float* __restrict__ xsum, const float* __restrict__ Wq,
                    float* __restrict__ mq) {
    __shared__ float xb[4][1024];
    int t = threadIdx.x;
    for (int i = t; i < 4096; i += 256)
        xb[i >> 10][i & 1023] = xsum[i] * (1.0f / 4096.0f);
    __syncthreads();
    int wv = t >> 6, l = t & 63;
    int j = blockIdx.x * 4 + wv;
    const float* wrow = Wq + (size_t)j * DD;
    float a0 = 0.f, a1 = 0.f, a2 = 0.f, a3 = 0.f;
    #pragma unroll 4
    for (int it = 0; it < 16; ++it) {
        int idx = l + it * 64;
        float wval = wrow[idx];
        a0 += xb[0][idx] * wval;
        a1 += xb[1][idx] * wval;
        a2 += xb[2][idx] * wval;
        a3 += xb[3][idx] * wval;
    }
    for (int off = 32; off > 0; off >>= 1) {
        a0 += __shfl_down(a0, off, 64);
        a1 += __shfl_down(a1, off, 64);
        a2 += __shfl_down(a2, off, 64);
        a3 += __shfl_down(a3, off, 64);
    }
    if (l == 0) {
        mq[j] = a0; mq[1024 + j] = a1; mq[2048 + j] = a2; mq[3072 + j] = a3;
    }
}

// ---------------- LayerNorm per head over mq, mean over heads -> q_shared[b][64]
__global__ __launch_bounds__(256)
void gates1b_kernel(const float* __restrict__ mq, const float* __restrict__ gamma,
                    const float* __restrict__ beta, float* __restrict__ q_shared) {
    __shared__ float qacc[4][64];
    int b = blockIdx.x;
    int t = threadIdx.x;
    int wv = t >> 6, l = t & 63;
    float part = 0.f;
    for (int hh = 0; hh < 4; ++hh) {
        int h = wv * 4 + hh;
        float v = mq[b * 1024 + h * 64 + l];
        float s1 = v, s2 = v * v;
        for (int off = 32; off > 0; off >>= 1) {
            s1 += __shfl_xor(s1, off, 64);
            s2 += __shfl_xor(s2, off, 64);
        }
        float mu = s1 * (1.0f / 64.0f);
        float var = s2 * (1.0f / 64.0f) - mu * mu;
        part += (v - mu) * rsqrtf(var + 1e-5f) * gamma[l] + beta[l];
    }
    qacc[wv][l] = part;
    __syncthreads();
    if (t < 64) {
        float s = qacc[0][t] + qacc[1][t] + qacc[2][t] + qacc[3][t];
        q_shared[b * 64 + t] = s * (1.0f / 16.0f);
    }
}

// ---------------- hdn = gelu(q_shared @ w1^T + b1)
__global__ __launch_bounds__(256)
void gates2_kernel(const float* __restrict__ q_shared, const float* __restrict__ w1,
                   const float* __restrict__ b1, float* __restrict__ hdn) {
    __shared__ float qs[64];
    int blk = blockIdx.x;
    int b = blk >> 2;
    int i0 = (blk & 3) * 256;
    int t = threadIdx.x;
    if (t < 64) qs[t] = q_shared[b * 64 + t];
    __syncthreads();
    int i = i0 + t;
    const float* wrow = w1 + (size_t)i * DHD;
    float acc = b1[i];
    #pragma unroll 8
    for (int d = 0; d < 64; ++d) acc += qs[d] * wrow[d];
    float g = 0.5f * acc * (1.0f + erff(acc * 0.70710678118654752f));
    hdn[b * DD + i] = g;
}

// ---------------- gri = hdn @ w2^T + b2 ; one wave per output row, all 4 b at once
__global__ __launch_bounds__(256)
void gates3_kernel(const float* __restrict__ hdn, const float* __restrict__ w2,
                   const float* __restrict__ b2, float* __restrict__ gri) {
    int t = threadIdx.x;
    int wv = t >> 6, l = t & 63;
    int r = blockIdx.x * 4 + wv;
    if (r >= 2 * NFREQ) return;
    const float* wrow = w2 + (size_t)r * DD;
    float a0 = 0.f, a1 = 0.f, a2 = 0.f, a3 = 0.f;
    for (int it = 0; it < 16; ++it) {
        int idx = l + it * 64;
        float wval = wrow[idx];
        a0 += hdn[idx] * wval;
        a1 += hdn[1024 + idx] * wval;
        a2 += hdn[2048 + idx] * wval;
        a3 += hdn[3072 + idx] * wval;
    }
    for (int off = 32; off > 0; off >>= 1) {
        a0 += __shfl_down(a0, off, 64);
        a1 += __shfl_down(a1, off, 64);
        a2 += __shfl_down(a2, off, 64);
        a3 += __shfl_down(a3, off, 64);
    }
    if (l == 0) {
        float bb = b2[r];
        gri[r] = a0 + bb;
        gri[2 * NFREQ + r] = a1 + bb;
        gri[2 * 2 * NFREQ + r] = a2 + bb;
        gri[3 * 2 * NFREQ + r] = a3 + bb;
    }
}

// ---------------- f32 -> (bf16 hi, bf16 lo) split (weights) ----------------
__global__ __launch_bounds__(256)
void split_kernel(const float* __restrict__ src, u16* __restrict__ hi,
                  u16* __restrict__ lo, int n4) {
    int idx = blockIdx.x * 256 + threadIdx.x;
    int stride = gridDim.x * 256;
    for (; idx < n4; idx += stride) {
        float4 v = ((const float4*)src)[idx];
        u16x4 h, l;
        h.x = f2bf(v.x); h.y = f2bf(v.y); h.z = f2bf(v.z); h.w = f2bf(v.w);
        l.x = f2bf(v.x - bf2f(h.x));
        l.y = f2bf(v.y - bf2f(h.y));
        l.z = f2bf(v.z - bf2f(h.z));
        l.w = f2bf(v.w - bf2f(h.w));
        ((u16x4*)hi)[idx] = h;
        ((u16x4*)lo)[idx] = l;
    }
}

// ---------------- transpose + split: src f32 [1024][16384] -> hi/lo bf16 [16384][1024]
__global__ __launch_bounds__(256)
void transpose_split_kernel(const float* __restrict__ src, u16* __restrict__ hi,
                            u16* __restrict__ lo) {
    __shared__ float tile[64][65];
    int s0 = blockIdx.x * 64;   // bs block
    int j0 = blockIdx.y * 64;   // feature block
    int t = threadIdx.x;
    int c = t & 63, r4 = t >> 6;
    #pragma unroll
    for (int rr = 0; rr < 64; rr += 4)
        tile[rr + r4][c] = src[(size_t)(j0 + rr + r4) * 16384 + s0 + c];
    __syncthreads();
    #pragma unroll
    for (int rr = 0; rr < 64; rr += 4) {
        int a = rr + r4;                 // local bs
        float v = tile[c][a];            // = src[j0+c][s0+a]
        u16 h = f2bf(v);
        size_t o = (size_t)(s0 + a) * 1024 + j0 + c;
        hi[o] = h;
        lo[o] = f2bf(v - bf2f(h));
    }
}

// ---------------- split-bf16 MFMA GEMM, 256x256 tile, stage-early prefetch ----
// C[M][N] = A[M][K] * B[N][K]^T ; A,B as bf16 hi/lo planes (row-major, stride K).
// 512 threads = 8 waves (2M x 4N); per-wave 128x64 out = 8x4 frags of 16x16x32.
// LDS: 2 buffers x 4 planes x [256][32] bf16 = 128 KiB. One barrier per K-tile;
// next K-tile staged into the other buffer before compute (loads fly under MFMA).
// XCD-aware tile decode: each XCD owns a disjoint slice of the long dimension,
// so each B(A)-panel is HBM-fetched exactly once chip-wide.
__global__ __launch_bounds__(512, 2)
void gemm_split256_kernel(const u16* __restrict__ Ah, const u16* __restrict__ Al,
                          const u16* __restrict__ Bh, const u16* __restrict__ Bl,
                          float* __restrict__ C, int mtiles, int ntiles, int K, int ldc) {
    __shared__ u16 lds[2][4][8192];   // [buf][plane: Ah,Al,Bh,Bl][256 rows x 32 k]
    const int t = threadIdx.x;
    const int wid = __builtin_amdgcn_readfirstlane(t >> 6);
    const int lane = t & 63;

    // XCD-aware decode (blocks dispatch round-robin over 8 XCDs)
    const int bid = blockIdx.x;
    const int xcd = bid & 7;
    const int idx = bid >> 3;
    int mt, nt;
    if (ntiles >= mtiles) { mt = idx % mtiles; nt = xcd * (ntiles >> 3) + idx / mtiles; }
    else                  { nt = idx % ntiles; mt = xcd * (mtiles >> 3) + idx / ntiles; }
    const int m0 = mt * 256;
    const int n0 = nt * 256;
    const int wm = (wid >> 2) * 128;
    const int wn = (wid & 3) * 64;

    // staging: 64 chunk-ops of 1KB (wave w gets ops g = w*8..w*8+7)
    // plane p = g>>4; 16B-subchunk j = (g&15)*64 + lane; logical c = j ^ ((j>>3)&3)
    const u16* gbase[8];
    u16* ldst[8];
    #pragma unroll
    for (int o = 0; o < 8; ++o) {
        int g = wid * 8 + o;
        int p = g >> 4;
        int j = ((g & 15) << 6) | lane;
        int c = j ^ ((j >> 3) & 3);
        int row = c >> 2, q = c & 3;
        const u16* base = (p == 0) ? Ah : (p == 1) ? Al : (p == 2) ? Bh : Bl;
        int rbase = (p < 2) ? m0 : n0;
        gbase[o] = base + (size_t)(rbase + row) * K + q * 8;
        ldst[o] = &lds[0][0][0] + (size_t)p * 8192 + (size_t)j * 8;
    }

#define STAGE256(KT, BUF)                                                        \
    {                                                                            \
        _Pragma("unroll")                                                        \
        for (int o = 0; o < 8; ++o)                                              \
            gload16(gbase[o] + (size_t)(KT) * 32, ldst[o] + (BUF) * 32768);      \
    }

    f32x4 acc[8][4] = {};

    STAGE256(0, 0);
    __syncthreads();

    const int KT = K >> 5;
    int buf = 0;
    for (int kt = 0; kt < KT; ++kt) {
        if (kt + 1 < KT) STAGE256(kt + 1, buf ^ 1);

        const u16* lb = &lds[buf][0][0];
        short8 bh[4], bl[4];
        #pragma unroll
        for (int j = 0; j < 4; ++j) {
            int s = swz((wn + (lane & 15) + j * 16) * 64 + (lane >> 4) * 16);
            bh[j] = *(const short8*)(lb + 2 * 8192 + (s >> 1));
            bl[j] = *(const short8*)(lb + 3 * 8192 + (s >> 1));
        }
        __builtin_amdgcn_s_setprio(1);
        #pragma unroll
        for (int i = 0; i < 8; ++i) {
            int s = swz((wm + (lane & 15) + i * 16) * 64 + (lane >> 4) * 16);
            short8 ah = *(const short8*)(lb + (s >> 1));
            short8 al = *(const short8*)(lb + 8192 + (s >> 1));
            #pragma unroll
            for (int j = 0; j < 4; ++j) {
                acc[i][j] = __builtin_amdgcn_mfma_f32_16x16x32_bf16(ah, bl[j], acc[i][j], 0, 0, 0);
                acc[i][j] = __builtin_amdgcn_mfma_f32_16x16x32_bf16(al, bh[j], acc[i][j], 0, 0, 0);
                acc[i][j] = __builtin_amdgcn_mfma_f32_16x16x32_bf16(ah, bh[j], acc[i][j], 0, 0, 0);
            }
        }
        __builtin_amdgcn_s_setprio(0);
        __syncthreads();   // drains vmcnt: next buffer ready; this buffer reusable
        buf ^= 1;
    }
#undef STAGE256

    // epilogue: C/D layout = col (lane&15), row (lane>>4)*4 + e   [m89-verified]
    const int cb = n0 + wn + (lane & 15);
    #pragma unroll
    for (int i = 0; i < 8; ++i) {
        int rb = m0 + wm + i * 16 + ((lane >> 4) << 2);
        #pragma unroll
        for (int e = 0; e < 4; ++e) {
            float* crow = C + (size_t)(rb + e) * ldc + cb;
            #pragma unroll
            for (int j = 0; j < 4; ++j)
                crow[j * 16] = acc[i][j][e];
        }
    }
}

// ---------------- twiddle table init (global, shared by all FFT blocks) -------
// Tg[h + jj] = (cos, sin)(pi*jj/h) for h = 2^s, s=0..10  (indices 1..2047)
// Tg[2048 + k] = (cos, sin)(pi*k/2048), k=0..1023  (real-FFT pack/unpack)
__global__ __launch_bounds__(256)
void twiddle_init_kernel(float2* __restrict__ Tg) {
    int idx = blockIdx.x * 256 + threadIdx.x;
    if (idx >= 3072) return;
    float cs = 1.f, sn = 0.f;
    if (idx >= 2048) {
        sincosf(PI_F * (float)(idx - 2048) * (1.0f / 2048.0f), &sn, &cs);
    } else if (idx >= 1) {
        int s = 31 - __clz(idx);
        int h = 1 << s;
        sincosf(PI_F * (float)(idx - h) / (float)h, &sn, &cs);
    }
    Tg[idx] = make_float2(cs, sn);
}

// butterflies: fwd applies e^{-i th} to the difference; inv applies e^{+i th} then add/sub
__device__ __forceinline__ void bfly_f(float2& a, float2& b, float cs, float sn) {
    float2 s = make_float2(a.x + b.x, a.y + b.y);
    float2 d = make_float2(a.x - b.x, a.y - b.y);
    a = s;
    b = make_float2(d.x * cs + d.y * sn, d.y * cs - d.x * sn);
}
__device__ __forceinline__ void bfly_i(float2& a, float2& b, float cs, float sn) {
    float cr = b.x * cs - b.y * sn;
    float ci = b.x * sn + b.y * cs;
    float2 a0 = a;
    a = make_float2(a0.x + cr, a0.y + ci);
    b = make_float2(a0.x - cr, a0.y - ci);
}
// LDS index swizzle: fold bits 5..8 into bank bits (float2 elems)
__device__ __forceinline__ int SW(int a) { return a ^ ((a >> 5) & 15); }

// ---------------- fused rfft -> gates -> modReLU -> irfft, in-place per sequence
// Radix-8-grouped stages in registers; LDS only for group-boundary exchanges.
__global__ __launch_bounds__(256)
void fft_gates_kernel(float* __restrict__ buf, const float* __restrict__ gri,
                      const float* __restrict__ modb, const float2* __restrict__ Tg) {
    __shared__ float2 cf[MHALF];
    const int t = threadIdx.x;
    const int w = blockIdx.x;
    const int b = w & 3;
    float2* seq = (float2*)(buf + (size_t)w * SS);

    const int t5 = t & 31;
    const int t3 = t & 3;
    const int c32 = ((t >> 5) << 8) | t5;    // base for 32-span group
    const int d4  = ((t >> 2) << 5) | t3;    // base for 4-span group

    float2 r[8];

    // ---- load + G1: stages 10,9,8 (span 256) ----
    #pragma unroll
    for (int u = 0; u < 8; ++u) r[u] = seq[t + 256 * u];
    #pragma unroll
    for (int u = 0; u < 4; ++u) {
        float2 tw = Tg[1024 + t + 256 * u];
        bfly_f(r[u], r[u + 4], tw.x, tw.y);
    }
    {
        float2 tw0 = Tg[512 + t], tw1 = Tg[512 + t + 256];
        bfly_f(r[0], r[2], tw0.x, tw0.y);
        bfly_f(r[1], r[3], tw1.x, tw1.y);
        bfly_f(r[4], r[6], tw0.x, tw0.y);
        bfly_f(r[5], r[7], tw1.x, tw1.y);
        float2 tw = Tg[256 + t];
        bfly_f(r[0], r[1], tw.x, tw.y);
        bfly_f(r[2], r[3], tw.x, tw.y);
        bfly_f(r[4], r[5], tw.x, tw.y);
        bfly_f(r[6], r[7], tw.x, tw.y);
    }
    #pragma unroll
    for (int u = 0; u < 8; ++u) cf[SW(t + 256 * u)] = r[u];
    __syncthreads();

    // ---- G2: stages 7,6,5 (span 32) ----
    #pragma unroll
    for (int u = 0; u < 8; ++u) r[u] = cf[SW(c32 + 32 * u)];
    #pragma unroll
    for (int u = 0; u < 4; ++u) {
        float2 tw = Tg[128 + t5 + 32 * u];
        bfly_f(r[u], r[u + 4], tw.x, tw.y);
    }
    {
        float2 tw0 = Tg[64 + t5], tw1 = Tg[64 + t5 + 32];
        bfly_f(r[0], r[2], tw0.x, tw0.y);
        bfly_f(r[1], r[3], tw1.x, tw1.y);
        bfly_f(r[4], r[6], tw0.x, tw0.y);
        bfly_f(r[5], r[7], tw1.x, tw1.y);
        float2 tw = Tg[32 + t5];
        bfly_f(r[0], r[1], tw.x, tw.y);
        bfly_f(r[2], r[3], tw.x, tw.y);
        bfly_f(r[4], r[5], tw.x, tw.y);
        bfly_f(r[6], r[7], tw.x, tw.y);
    }
    #pragma unroll
    for (int u = 0; u < 8; ++u) cf[SW(c32 + 32 * u)] = r[u];
    __syncthreads();

    // ---- G3: stages 4,3,2 (span 4) ----
    #pragma unroll
    for (int u = 0; u < 8; ++u) r[u] = cf[SW(d4 + 4 * u)];
    #pragma unroll
    for (int u = 0; u < 4; ++u) {
        float2 tw = Tg[16 + t3 + 4 * u];
        bfly_f(r[u], r[u + 4], tw.x, tw.y);
    }
    {
        float2 tw0 = Tg[8 + t3], tw1 = Tg[8 + t3 + 4];
        bfly_f(r[0], r[2], tw0.x, tw0.y);
        bfly_f(r[1], r[3], tw1.x, tw1.y);
        bfly_f(r[4], r[6], tw0.x, tw0.y);
        bfly_f(r[5], r[7], tw1.x, tw1.y);
        float2 tw = Tg[4 + t3];
        bfly_f(r[0], r[1], tw.x, tw.y);
        bfly_f(r[2], r[3], tw.x, tw.y);
        bfly_f(r[4], r[5], tw.x, tw.y);
        bfly_f(r[6], r[7], tw.x, tw.y);
    }
    #pragma unroll
    for (int u = 0; u < 8; ++u) cf[SW(d4 + 4 * u)] = r[u];
    __syncthreads();

    // ---- G4: stages 1,0 (span 1; 8 consecutive) ----
    #pragma unroll
    for (int u = 0; u < 8; ++u) r[u] = cf[SW(8 * t + u)];
    bfly_f(r[0], r[2], 1.f, 0.f);
    bfly_f(r[1], r[3], 0.f, 1.f);
    bfly_f(r[4], r[6], 1.f, 0.f);
    bfly_f(r[5], r[7], 0.f, 1.f);
    bfly_f(r[0], r[1], 1.f, 0.f);
    bfly_f(r[2], r[3], 1.f, 0.f);
    bfly_f(r[4], r[5], 1.f, 0.f);
    bfly_f(r[6], r[7], 1.f, 0.f);
    #pragma unroll
    for (int u = 0; u < 8; ++u) cf[SW(8 * t + u)] = r[u];
    __syncthreads();

    // ---- spectrum: unpack real-FFT bins (ortho /64), gates, modReLU, repack ----
    const float bias = modb[0];
    const float* gre = gri + (size_t)b * 2 * NFREQ;
    const float* gim = gre + NFREQ;
    const float inv64 = 1.0f / 64.0f;
    for (int k = t; k < 1024; k += 256) {
        if (k == 0) {
            float2 c0 = cf[SW(0)];
            float z0 = (c0.x + c0.y) * inv64;
            float zM = (c0.x - c0.y) * inv64;
            float zr = z0 * gre[0], zi = z0 * gim[0];
            modrelu_apply(zr, zi, bias);
            float yr = zM * gre[2048], yi = zM * gim[2048];
            modrelu_apply(yr, yi, bias);
            cf[SW(0)] = make_float2(0.5f * (zr + yr), 0.5f * (zr - yr));
            float2 c1 = cf[SW(1)];
            float z1r = c1.x * inv64, z1i = -c1.y * inv64;
            float g1r = gre[1024], g1i = gim[1024];
            float pr = z1r * g1r - z1i * g1i;
            float pi2 = z1r * g1i + z1i * g1r;
            modrelu_apply(pr, pi2, bias);
            cf[SW(1)] = make_float2(pr, -pi2);
        } else {
            int kb = 2048 - k;
            int p1 = SW((int)(__brev((unsigned)k) >> 21));
            int p2 = SW((int)(__brev((unsigned)kb) >> 21));
            float2 ca = cf[p1];
            float2 cb2 = cf[p2];
            float Er = 0.5f * (ca.x + cb2.x), Ei = 0.5f * (ca.y - cb2.y);
            float Dr = 0.5f * (ca.x - cb2.x), Di = 0.5f * (ca.y + cb2.y);
            float Or = Di, Oi = -Dr;
            float2 t2 = Tg[2048 + k];
            float cs = t2.x, sn = t2.y;
            float Wr = cs, Wi = -sn;
            float WOr = Wr * Or - Wi * Oi, WOi = Wr * Oi + Wi * Or;
            float zkr = (Er + WOr) * inv64, zki = (Ei + WOi) * inv64;
            float zbr = (Er - WOr) * inv64, zbi = -(Ei - WOi) * inv64;
            float gkr = gre[k], gki = gim[k];
            float ar = zkr * gkr - zki * gki, ai = zkr * gki + zki * gkr;
            modrelu_apply(ar, ai, bias);
            float gbr = gre[kb], gbi = gim[kb];
            float br2 = zbr * gbr - zbi * gbi, bi2 = zbr * gbi + zbi * gbr;
            modrelu_apply(br2, bi2, bias);
            float Epr = 0.5f * (ar + br2), Epi = 0.5f * (ai - bi2);
            float Dpr = 0.5f * (ar - br2), Dpi = 0.5f * (ai + bi2);
            float Opr = cs * Dpr - sn * Dpi, Opi = cs * Dpi + sn * Dpr;
            cf[p1] = make_float2(Epr - Opi, Epi + Opr);
            cf[p2] = make_float2(Epr + Opi, -Epi + Opr);
        }
    }
    __syncthreads();

    // ---- inverse G4': stages 0,1 ----
    #pragma unroll
    for (int u = 0; u < 8; ++u) r[u] = cf[SW(8 * t + u)];
    bfly_i(r[0], r[1], 1.f, 0.f);
    bfly_i(r[2], r[3], 1.f, 0.f);
    bfly_i(r[4], r[5], 1.f, 0.f);
    bfly_i(r[6], r[7], 1.f, 0.f);
    bfly_i(r[0], r[2], 1.f, 0.f);
    bfly_i(r[1], r[3], 0.f, 1.f);
    bfly_i(r[4], r[6], 1.f, 0.f);
    bfly_i(r[5], r[7], 0.f, 1.f);
    #pragma unroll
    for (int u = 0; u < 8; ++u) cf[SW(8 * t + u)] = r[u];
    __syncthreads();

    // ---- inverse G3': stages 2,3,4 ----
    #pragma unroll
    for (int u = 0; u < 8; ++u) r[u] = cf[SW(d4 + 4 * u)];
    {
        float2 tw = Tg[4 + t3];
        bfly_i(r[0], r[1], tw.x, tw.y);
        bfly_i(r[2], r[3], tw.x, tw.y);
        bfly_i(r[4], r[5], tw.x, tw.y);
        bfly_i(r[6], r[7], tw.x, tw.y);
        float2 tw0 = Tg[8 + t3], tw1 = Tg[8 + t3 + 4];
        bfly_i(r[0], r[2], tw0.x, tw0.y);
        bfly_i(r[1], r[3], tw1.x, tw1.y);
        bfly_i(r[4], r[6], tw0.x, tw0.y);
        bfly_i(r[5], r[7], tw1.x, tw1.y);
    }
    #pragma unroll
    for (int u = 0; u < 4; ++u) {
        float2 tw = Tg[16 + t3 + 4 * u];
        bfly_i(r[u], r[u + 4], tw.x, tw.y);
    }
    #pragma unroll
    for (int u = 0; u < 8; ++u) cf[SW(d4 + 4 * u)] = r[u];
    __syncthreads();

    // ---- inverse G2': stages 5,6,7 ----
    #pragma unroll
    for (int u = 0; u < 8; ++u) r[u] = cf[SW(c32 + 32 * u)];
    {
        float2 tw = Tg[32 + t5];
        bfly_i(r[0], r[1], tw.x, tw.y);
        bfly_i(r[2], r[3], tw.x, tw.y);
        bfly_i(r[4], r[5], tw.x, tw.y);
        bfly_i(r[6], r[7], tw.x, tw.y);
        float2 tw0 = Tg[64 + t5], tw1 = Tg[64 + t5 + 32];
        bfly_i(r[0], r[2], tw0.x, tw0.y);
        bfly_i(r[1], r[3], tw1.x, tw1.y);
        bfly_i(r[4], r[6], tw0.x, tw0.y);
        bfly_i(r[5], r[7], tw1.x, tw1.y);
    }
    #pragma unroll
    for (int u = 0; u < 4; ++u) {
        float2 tw = Tg[128 + t5 + 32 * u];
        bfly_i(r[u], r[u + 4], tw.x, tw.y);
    }
    #pragma unroll
    for (int u = 0; u < 8; ++u) cf[SW(c32 + 32 * u)] = r[u];
    __syncthreads();

    // ---- inverse G1': stages 8,9,10 + scale + store ----
    #pragma unroll
    for (int u = 0; u < 8; ++u) r[u] = cf[SW(t + 256 * u)];
    {
        float2 tw = Tg[256 + t];
        bfly_i(r[0], r[1], tw.x, tw.y);
        bfly_i(r[2], r[3], tw.x, tw.y);
        bfly_i(r[4], r[5], tw.x, tw.y);
        bfly_i(r[6], r[7], tw.x, tw.y);
        float2 tw0 = Tg[512 + t], tw1 = Tg[512 + t + 256];
        bfly_i(r[0], r[2], tw0.x, tw0.y);
        bfly_i(r[1], r[3], tw1.x, tw1.y);
        bfly_i(r[4], r[6], tw0.x, tw0.y);
        bfly_i(r[5], r[7], tw1.x, tw1.y);
    }
    #pragma unroll
    for (int u = 0; u < 4; ++u) {
        float2 tw = Tg[1024 + t + 256 * u];
        bfly_i(r[u], r[u + 4], tw.x, tw.y);
    }
    const float s32 = 1.0f / 32.0f;  // 64 (ortho) / 2048 (ifft norm)
    #pragma unroll
    for (int u = 0; u < 8; ++u)
        seq[t + 256 * u] = make_float2(r[u].x * s32, r[u].y * s32);
}

extern "C" void kernel_launch(void* const* d_in, const int* in_sizes, int n_in,
                              void* d_out, int out_size, void* d_ws, size_t ws_size,
                              hipStream_t stream) {
    const float* x        = (const float*)d_in[0];
    const float* W_q      = (const float*)d_in[1];
    const float* W_v      = (const float*)d_in[2];
    const float* W_o      = (const float*)d_in[3];
    const float* ln_gamma = (const float*)d_in[4];
    const float* ln_beta  = (const float*)d_in[5];
    const float* mlp_w1   = (const float*)d_in[6];
    const float* mlp_b1   = (const float*)d_in[7];
    const float* mlp_w2   = (const float*)d_in[8];
    const float* mlp_b2   = (const float*)d_in[9];
    const float* mod_bias = (const float*)d_in[10];
    float* out = (float*)d_out;

    // workspace layout (floats)
    float* ws = (float*)d_ws;
    float* partial  = ws;                    // 262144
    float* xsum     = ws + 262144;           // 4096
    float* q_shared = ws + 266240;           // 256
    float* hdn      = ws + 266496;           // 4096
    float* gri      = ws + 270592;           // 16392 (ends 286984)
    float* mq       = ws + 286984;           // 4096 (ends 291080)
    float2* twid    = (float2*)(ws + 291080); // 3072 float2 = 6144 (ends 297224)
    float* buf0     = ws + 297984;           // 16777216 floats (64 MiB), [1024][16384]
    u16* bfbase = (u16*)(ws + 297984 + 16777216);
    u16* xut_hi = bfbase;                    // 16777216 u16: x_hi, later reused as ut_hi
    u16* xut_lo = bfbase + 16777216;         // x_lo, later ut_lo
    u16* wv_hi  = bfbase + 33554432;         // 1048576
    u16* wv_lo  = bfbase + 34603008;
    u16* wo_hi  = bfbase + 35651584;
    u16* wo_lo  = bfbase + 36700160;

    twiddle_init_kernel<<<12, 256, 0, stream>>>(twid);

    // fused x split + colsum pass 1
    split_x_colsum_kernel<<<256, 256, 0, stream>>>(x, xut_hi, xut_lo, partial);
    {
        dim3 g(4, 4);
        colsum2_kernel<<<g, 256, 0, stream>>>(partial, xsum);
    }
    gates1a_kernel<<<256, 256, 0, stream>>>(xsum, W_q, mq);
    gates1b_kernel<<<4, 256, 0, stream>>>(mq, ln_gamma, ln_beta, q_shared);
    gates2_kernel<<<16, 256, 0, stream>>>(q_shared, mlp_w1, mlp_b1, hdn);
    gates3_kernel<<<1025, 256, 0, stream>>>(hdn, mlp_w2, mlp_b2, gri);

    // weight splits
    split_kernel<<<1024, 256, 0, stream>>>(W_v, wv_hi, wv_lo, 262144);
    split_kernel<<<1024, 256, 0, stream>>>(W_o, wo_hi, wo_lo, 262144);

    // V projection (transposed output): buf0[j][bs] = sum_k Wv[j,k]*x[bs,k]
    // M=1024 (j), N=16384 (bs): mtiles=4, ntiles=64 -> 256 blocks
    gemm_split256_kernel<<<256, 512, 0, stream>>>(wv_hi, wv_lo, xut_hi, xut_lo,
                                                  buf0, 4, 64, 1024, 16384);

    // fused spectral mixing, in place
    fft_gates_kernel<<<4096, 256, 0, stream>>>(buf0, gri, mod_bias, twid);

    // transpose+split u: buf0 [1024][16384] f32 -> ut hi/lo [16384][1024] bf16
    {
        dim3 g(256, 16);
        transpose_split_kernel<<<g, 256, 0, stream>>>(buf0, xut_hi, xut_lo);
    }

    // O projection: out[bs][jo] = sum_j ut[bs][j]*Wo[jo][j]
    // M=16384 (bs), N=1024 (jo): mtiles=64, ntiles=4 -> 256 blocks
    gemm_split256_kernel<<<256, 512, 0, stream>>>(xut_hi, xut_lo, wo_hi, wo_lo,
                                                  out, 64, 4, 1024, 1024);
}

// Round 6
// 291.470 us; speedup vs baseline: 4.4879x; 1.0748x over previous
//
#include <hip/hip_runtime.h>
#include <math.h>
#include <stdint.h>

#define PI_F 3.14159265358979323846f

// Problem constants
#define BB 4
#define SS 4096
#define DD 1024
#define HH 16
#define DHD 64
#define NFREQ 2049   // 4096/2 + 1
#define MHALF 2048   // half-size complex FFT length

typedef unsigned short u16;
typedef __attribute__((ext_vector_type(8))) short short8;   // 8 bf16 = 4 VGPR (MFMA A/B frag)
typedef __attribute__((ext_vector_type(4))) float f32x4;    // MFMA C/D frag
typedef __attribute__((ext_vector_type(4))) unsigned short u16x4;

// ---- bf16 helpers (RTNE) ----
__device__ __forceinline__ u16 f2bf(float f) {
    unsigned u = __float_as_uint(f);
    unsigned r = (u + 0x7FFFu + ((u >> 16) & 1u)) >> 16;
    return (u16)r;
}
__device__ __forceinline__ float bf2f(u16 h) { return __uint_as_float(((unsigned)h) << 16); }

__device__ __forceinline__ void modrelu_apply(float& zr, float& zi, float bias) {
    float mag = sqrtf(zr * zr + zi * zi);
    float scale = fmaxf(mag + bias, 0.0f) / fmaxf(mag, 1e-12f);
    zr *= scale; zi *= scale;
}

// async global->LDS, 16B per lane (HW: dest = wave-uniform base + lane*16)
__device__ __forceinline__ void gload16(const u16* g, u16* l) {
    __builtin_amdgcn_global_load_lds(
        (const __attribute__((address_space(1))) void*)g,
        (__attribute__((address_space(3))) void*)l, 16, 0, 0);
}

// LDS byte-offset swizzle for GEMM staging (16B chunks): XOR chunk bits [4:3]
// into chunk bits [1:0]; involution, matches the pre-swizzled staging order.
__device__ __forceinline__ int swz(int byteoff) {
    return byteoff ^ (((byteoff >> 7) & 3) << 4);
}

#define MFMA_BF16 __builtin_amdgcn_mfma_f32_16x16x32_bf16

// ---------------- fused x -> bf16 hi/lo split + column partial sums -----------
// grid 256 = (b, s-chunk of 64); thread t owns columns 4t..4t+3
__global__ __launch_bounds__(256)
void split_x_colsum_kernel(const float* __restrict__ x, u16* __restrict__ hi,
                           u16* __restrict__ lo, float* __restrict__ partial) {
    int blk = blockIdx.x;
    int b = blk >> 6;
    int s0 = (blk & 63) * 64;
    int t = threadIdx.x;
    const float* xp = x + ((size_t)b * SS + s0) * DD;
    float4 acc = make_float4(0.f, 0.f, 0.f, 0.f);
    for (int s = 0; s < 64; ++s) {
        float4 v = ((const float4*)(xp + (size_t)s * DD))[t];
        acc.x += v.x; acc.y += v.y; acc.z += v.z; acc.w += v.w;
        u16x4 h, l;
        h.x = f2bf(v.x); h.y = f2bf(v.y); h.z = f2bf(v.z); h.w = f2bf(v.w);
        l.x = f2bf(v.x - bf2f(h.x));
        l.y = f2bf(v.y - bf2f(h.y));
        l.z = f2bf(v.z - bf2f(h.z));
        l.w = f2bf(v.w - bf2f(h.w));
        size_t rowo = (size_t)(b * SS + s0 + s) * DD;
        ((u16x4*)(hi + rowo))[t] = h;
        ((u16x4*)(lo + rowo))[t] = l;
    }
    ((float4*)(partial + (size_t)blk * DD))[t] = acc;
}

__global__ __launch_bounds__(256)
void colsum2_kernel(const float* __restrict__ partial, float* __restrict__ xsum) {
    int b = blockIdx.y;
    int k = blockIdx.x * 256 + threadIdx.x;
    float acc = 0.f;
    for (int c = 0; c < 64; ++c)
        acc += partial[((size_t)(b * 64 + c)) * DD + k];
    xsum[b * DD + k] = acc;
}

// ---------------- mq[b][j] = dot(xsum[b]/S, Wq[j]) ; grid 256, 1 wave per row j
__global__ __launch_bounds__(256)
void gates1a_kernel(const float* __restrict__ xsum, const float* __restrict__ Wq,
                    float* __restrict__ mq) {
    __shared__ float xb[4][1024];
    int t = threadIdx.x;
    for (int i = t; i < 4096; i += 256)
        xb[i >> 10][i & 1023] = xsum[i] * (1.0f / 4096.0f);
    __syncthreads();
    int wv = t >> 6, l = t & 63;
    int j = blockIdx.x * 4 + wv;
    const float* wrow = Wq + (size_t)j * DD;
    float a0 = 0.f, a1 = 0.f, a2 = 0.f, a3 = 0.f;
    #pragma unroll 4
    for (int it = 0; it < 16; ++it) {
        int idx = l + it * 64;
        float wval = wrow[idx];
        a0 += xb[0][idx] * wval;
        a1 += xb[1][idx] * wval;
        a2 += xb[2][idx] * wval;
        a3 += xb[3][idx] * wval;
    }
    for (int off = 32; off > 0; off >>= 1) {
        a0 += __shfl_down(a0, off, 64);
        a1 += __shfl_down(a1, off, 64);
        a2 += __shfl_down(a2, off, 64);
        a3 += __shfl_down(a3, off, 64);
    }
    if (l == 0) {
        mq[j] = a0; mq[1024 + j] = a1; mq[2048 + j] = a2; mq[3072 + j] = a3;
    }
}

// ---------------- LayerNorm per head over mq, mean over heads -> q_shared[b][64]
__global__ __launch_bounds__(256)
void gates1b_kernel(const float* __restrict__ mq, const float* __restrict__ gamma,
                    const float* __restrict__ beta, float* __restrict__ q_shared) {
    __shared__ float qacc[4][64];
    int b = blockIdx.x;
    int t = threadIdx.x;
    int wv = t >> 6, l = t & 63;
    float part = 0.f;
    for (int hh = 0; hh < 4; ++hh) {
        int h = wv * 4 + hh;
        float v = mq[b * 1024 + h * 64 + l];
        float s1 = v, s2 = v * v;
        for (int off = 32; off > 0; off >>= 1) {
            s1 += __shfl_xor(s1, off, 64);
            s2 += __shfl_xor(s2, off, 64);
        }
        float mu = s1 * (1.0f / 64.0f);
        float var = s2 * (1.0f / 64.0f) - mu * mu;
        part += (v - mu) * rsqrtf(var + 1e-5f) * gamma[l] + beta[l];
    }
    qacc[wv][l] = part;
    __syncthreads();
    if (t < 64) {
        float s = qacc[0][t] + qacc[1][t] + qacc[2][t] + qacc[3][t];
        q_shared[b * 64 + t] = s * (1.0f / 16.0f);
    }
}

// ---------------- hdn = gelu(q_shared @ w1^T + b1)
__global__ __launch_bounds__(256)
void gates2_kernel(const float* __restrict__ q_shared, const float* __restrict__ w1,
                   const float* __restrict__ b1, float* __restrict__ hdn) {
    __shared__ float qs[64];
    int blk = blockIdx.x;
    int b = blk >> 2;
    int i0 = (blk & 3) * 256;
    int t = threadIdx.x;
    if (t < 64) qs[t] = q_shared[b * 64 + t];
    __syncthreads();
    int i = i0 + t;
    const float* wrow = w1 + (size_t)i * DHD;
    float acc = b1[i];
    #pragma unroll 8
    for (int d = 0; d < 64; ++d) acc += qs[d] * wrow[d];
    float g = 0.5f * acc * (1.0f + erff(acc * 0.70710678118654752f));
    hdn[b * DD + i] = g;
}

// ---------------- gri = hdn @ w2^T + b2 ; one wave per output row, all 4 b at once
__global__ __launch_bounds__(256)
void gates3_kernel(const float* __restrict__ hdn, const float* __restrict__ w2,
                   const float* __restrict__ b2, float* __restrict__ gri) {
    int t = threadIdx.x;
    int wv = t >> 6, l = t & 63;
    int r = blockIdx.x * 4 + wv;
    if (r >= 2 * NFREQ) return;
    const float* wrow = w2 + (size_t)r * DD;
    float a0 = 0.f, a1 = 0.f, a2 = 0.f, a3 = 0.f;
    for (int it = 0; it < 16; ++it) {
        int idx = l + it * 64;
        float wval = wrow[idx];
        a0 += hdn[idx] * wval;
        a1 += hdn[1024 + idx] * wval;
        a2 += hdn[2048 + idx] * wval;
        a3 += hdn[3072 + idx] * wval;
    }
    for (int off = 32; off > 0; off >>= 1) {
        a0 += __shfl_down(a0, off, 64);
        a1 += __shfl_down(a1, off, 64);
        a2 += __shfl_down(a2, off, 64);
        a3 += __shfl_down(a3, off, 64);
    }
    if (l == 0) {
        float bb = b2[r];
        gri[r] = a0 + bb;
        gri[2 * NFREQ + r] = a1 + bb;
        gri[2 * 2 * NFREQ + r] = a2 + bb;
        gri[3 * 2 * NFREQ + r] = a3 + bb;
    }
}

// ---------------- f32 -> (bf16 hi, bf16 lo) split (weights) ----------------
__global__ __launch_bounds__(256)
void split_kernel(const float* __restrict__ src, u16* __restrict__ hi,
                  u16* __restrict__ lo, int n4) {
    int idx = blockIdx.x * 256 + threadIdx.x;
    int stride = gridDim.x * 256;
    for (; idx < n4; idx += stride) {
        float4 v = ((const float4*)src)[idx];
        u16x4 h, l;
        h.x = f2bf(v.x); h.y = f2bf(v.y); h.z = f2bf(v.z); h.w = f2bf(v.w);
        l.x = f2bf(v.x - bf2f(h.x));
        l.y = f2bf(v.y - bf2f(h.y));
        l.z = f2bf(v.z - bf2f(h.z));
        l.w = f2bf(v.w - bf2f(h.w));
        ((u16x4*)hi)[idx] = h;
        ((u16x4*)lo)[idx] = l;
    }
}

// ---------------- transpose (hi only): src f32 [1024][16384] -> bf16 [16384][1024]
__global__ __launch_bounds__(256)
void transpose_hi_kernel(const float* __restrict__ src, u16* __restrict__ hi) {
    __shared__ float tile[64][65];
    int s0 = blockIdx.x * 64;   // bs block
    int j0 = blockIdx.y * 64;   // feature block
    int t = threadIdx.x;
    int c = t & 63, r4 = t >> 6;
    #pragma unroll
    for (int rr = 0; rr < 64; rr += 4)
        tile[rr + r4][c] = src[(size_t)(j0 + rr + r4) * 16384 + s0 + c];
    __syncthreads();
    #pragma unroll
    for (int rr = 0; rr < 64; rr += 4) {
        int a = rr + r4;                 // local bs
        float v = tile[c][a];            // = src[j0+c][s0+a]
        hi[(size_t)(s0 + a) * 1024 + j0 + c] = f2bf(v);
    }
}

// ---------------- split-bf16 MFMA GEMM, 256x256 tile, 3-product (V proj) ------
// C[M][N] = A[M][K] * B[N][K]^T ; A,B as bf16 hi/lo planes (row-major, stride K).
// 512 threads = 8 waves (2M x 4N); per-wave 128x64 out = 8x4 frags of 16x16x32.
// Product-outer MFMA order over i-pairs: same-acc reuse distance = 8 MFMAs
// (~38 cyc) -> no result-latency stalls on the accumulate chain.
__global__ __launch_bounds__(512, 2)
void gemm_split256_kernel(const u16* __restrict__ Ah, const u16* __restrict__ Al,
                          const u16* __restrict__ Bh, const u16* __restrict__ Bl,
                          float* __restrict__ C, int mtiles, int ntiles, int K, int ldc) {
    __shared__ u16 lds[2][4][8192];   // [buf][plane: Ah,Al,Bh,Bl][256 rows x 32 k]
    const int t = threadIdx.x;
    const int wid = __builtin_amdgcn_readfirstlane(t >> 6);
    const int lane = t & 63;

    // XCD-aware decode (blocks dispatch round-robin over 8 XCDs)
    const int bid = blockIdx.x;
    const int xcd = bid & 7;
    const int idx = bid >> 3;
    int mt, nt;
    if (ntiles >= mtiles) { mt = idx % mtiles; nt = xcd * (ntiles >> 3) + idx / mtiles; }
    else                  { nt = idx % ntiles; mt = xcd * (mtiles >> 3) + idx / ntiles; }
    const int m0 = mt * 256;
    const int n0 = nt * 256;
    const int wm = (wid >> 2) * 128;
    const int wn = (wid & 3) * 64;

    // staging: 64 chunk-ops of 1KB (wave w gets ops g = w*8..w*8+7)
    const u16* gbase[8];
    u16* ldst[8];
    #pragma unroll
    for (int o = 0; o < 8; ++o) {
        int g = wid * 8 + o;
        int p = g >> 4;
        int j = ((g & 15) << 6) | lane;
        int c = j ^ ((j >> 3) & 3);
        int row = c >> 2, q = c & 3;
        const u16* base = (p == 0) ? Ah : (p == 1) ? Al : (p == 2) ? Bh : Bl;
        int rbase = (p < 2) ? m0 : n0;
        gbase[o] = base + (size_t)(rbase + row) * K + q * 8;
        ldst[o] = &lds[0][0][0] + (size_t)p * 8192 + (size_t)j * 8;
    }

#define STAGE256(KT, BUF)                                                        \
    {                                                                            \
        _Pragma("unroll")                                                        \
        for (int o = 0; o < 8; ++o)                                              \
            gload16(gbase[o] + (size_t)(KT) * 32, ldst[o] + (BUF) * 32768);      \
    }

    f32x4 acc[8][4] = {};

    STAGE256(0, 0);
    __syncthreads();

    const int KT = K >> 5;
    int buf = 0;
    for (int kt = 0; kt < KT; ++kt) {
        if (kt + 1 < KT) STAGE256(kt + 1, buf ^ 1);

        const u16* lb = &lds[buf][0][0];
        short8 bh[4], bl[4];
        #pragma unroll
        for (int j = 0; j < 4; ++j) {
            int s = swz((wn + (lane & 15) + j * 16) * 64 + (lane >> 4) * 16);
            bh[j] = *(const short8*)(lb + 2 * 8192 + (s >> 1));
            bl[j] = *(const short8*)(lb + 3 * 8192 + (s >> 1));
        }
        __builtin_amdgcn_s_setprio(1);
        #pragma unroll
        for (int ip = 0; ip < 4; ++ip) {
            int s0 = swz((wm + (lane & 15) + (2 * ip) * 16) * 64 + (lane >> 4) * 16);
            int s1 = swz((wm + (lane & 15) + (2 * ip + 1) * 16) * 64 + (lane >> 4) * 16);
            short8 ah0 = *(const short8*)(lb + (s0 >> 1));
            short8 al0 = *(const short8*)(lb + 8192 + (s0 >> 1));
            short8 ah1 = *(const short8*)(lb + (s1 >> 1));
            short8 al1 = *(const short8*)(lb + 8192 + (s1 >> 1));
            #pragma unroll
            for (int j = 0; j < 4; ++j) acc[2 * ip][j]     = MFMA_BF16(ah0, bl[j], acc[2 * ip][j], 0, 0, 0);
            #pragma unroll
            for (int j = 0; j < 4; ++j) acc[2 * ip + 1][j] = MFMA_BF16(ah1, bl[j], acc[2 * ip + 1][j], 0, 0, 0);
            #pragma unroll
            for (int j = 0; j < 4; ++j) acc[2 * ip][j]     = MFMA_BF16(al0, bh[j], acc[2 * ip][j], 0, 0, 0);
            #pragma unroll
            for (int j = 0; j < 4; ++j) acc[2 * ip + 1][j] = MFMA_BF16(al1, bh[j], acc[2 * ip + 1][j], 0, 0, 0);
            #pragma unroll
            for (int j = 0; j < 4; ++j) acc[2 * ip][j]     = MFMA_BF16(ah0, bh[j], acc[2 * ip][j], 0, 0, 0);
            #pragma unroll
            for (int j = 0; j < 4; ++j) acc[2 * ip + 1][j] = MFMA_BF16(ah1, bh[j], acc[2 * ip + 1][j], 0, 0, 0);
        }
        __builtin_amdgcn_s_setprio(0);
        __syncthreads();   // drains vmcnt: next buffer ready; this buffer reusable
        buf ^= 1;
    }
#undef STAGE256

    // epilogue: C/D layout = col (lane&15), row (lane>>4)*4 + e   [m89-verified]
    const int cb = n0 + wn + (lane & 15);
    #pragma unroll
    for (int i = 0; i < 8; ++i) {
        int rb = m0 + wm + i * 16 + ((lane >> 4) << 2);
        #pragma unroll
        for (int e = 0; e < 4; ++e) {
            float* crow = C + (size_t)(rb + e) * ldc + cb;
            #pragma unroll
            for (int j = 0; j < 4; ++j)
                crow[j * 16] = acc[i][j][e];
        }
    }
}

// ---------------- 2-product MFMA GEMM (O proj): A plain bf16, B hi/lo ---------
// C[M][N] = A[M][K] * B[N][K]^T ; error budget: A=u already carries only
// ~1.8e-4*sigma rounding, final op is linear -> ~0.1 bf16-ulp added.
__global__ __launch_bounds__(512, 2)
void gemm_out2_kernel(const u16* __restrict__ A, const u16* __restrict__ Bh,
                      const u16* __restrict__ Bl, float* __restrict__ C,
                      int mtiles, int ntiles, int K, int ldc) {
    __shared__ u16 lds[2][3][8192];   // [buf][plane: A,Bh,Bl][256 rows x 32 k]
    const int t = threadIdx.x;
    const int wid = __builtin_amdgcn_readfirstlane(t >> 6);
    const int lane = t & 63;

    const int bid = blockIdx.x;
    const int xcd = bid & 7;
    const int idx = bid >> 3;
    int mt, nt;
    if (ntiles >= mtiles) { mt = idx % mtiles; nt = xcd * (ntiles >> 3) + idx / mtiles; }
    else                  { nt = idx % ntiles; mt = xcd * (mtiles >> 3) + idx / ntiles; }
    const int m0 = mt * 256;
    const int n0 = nt * 256;
    const int wm = (wid >> 2) * 128;
    const int wn = (wid & 3) * 64;

    // staging: 48 chunk-ops of 1KB (wave w gets ops g = w*6..w*6+5)
    const u16* gbase[6];
    u16* ldst[6];
    #pragma unroll
    for (int o = 0; o < 6; ++o) {
        int g = wid * 6 + o;
        int p = g >> 4;
        int j = ((g & 15) << 6) | lane;
        int c = j ^ ((j >> 3) & 3);
        int row = c >> 2, q = c & 3;
        const u16* base = (p == 0) ? A : (p == 1) ? Bh : Bl;
        int rbase = (p == 0) ? m0 : n0;
        gbase[o] = base + (size_t)(rbase + row) * K + q * 8;
        ldst[o] = &lds[0][0][0] + (size_t)p * 8192 + (size_t)j * 8;
    }

#define STAGEO(KT, BUF)                                                          \
    {                                                                            \
        _Pragma("unroll")                                                        \
        for (int o = 0; o < 6; ++o)                                              \
            gload16(gbase[o] + (size_t)(KT) * 32, ldst[o] + (BUF) * 24576);      \
    }

    f32x4 acc[8][4] = {};

    STAGEO(0, 0);
    __syncthreads();

    const int KT = K >> 5;
    int buf = 0;
    for (int kt = 0; kt < KT; ++kt) {
        if (kt + 1 < KT) STAGEO(kt + 1, buf ^ 1);

        const u16* lb = &lds[buf][0][0];
        short8 bh[4], bl[4];
        #pragma unroll
        for (int j = 0; j < 4; ++j) {
            int s = swz((wn + (lane & 15) + j * 16) * 64 + (lane >> 4) * 16);
            bh[j] = *(const short8*)(lb + 1 * 8192 + (s >> 1));
            bl[j] = *(const short8*)(lb + 2 * 8192 + (s >> 1));
        }
        __builtin_amdgcn_s_setprio(1);
        #pragma unroll
        for (int ip = 0; ip < 4; ++ip) {
            int s0 = swz((wm + (lane & 15) + (2 * ip) * 16) * 64 + (lane >> 4) * 16);
            int s1 = swz((wm + (lane & 15) + (2 * ip + 1) * 16) * 64 + (lane >> 4) * 16);
            short8 a0 = *(const short8*)(lb + (s0 >> 1));
            short8 a1 = *(const short8*)(lb + (s1 >> 1));
            #pragma unroll
            for (int j = 0; j < 4; ++j) acc[2 * ip][j]     = MFMA_BF16(a0, bl[j], acc[2 * ip][j], 0, 0, 0);
            #pragma unroll
            for (int j = 0; j < 4; ++j) acc[2 * ip + 1][j] = MFMA_BF16(a1, bl[j], acc[2 * ip + 1][j], 0, 0, 0);
            #pragma unroll
            for (int j = 0; j < 4; ++j) acc[2 * ip][j]     = MFMA_BF16(a0, bh[j], acc[2 * ip][j], 0, 0, 0);
            #pragma unroll
            for (int j = 0; j < 4; ++j) acc[2 * ip + 1][j] = MFMA_BF16(a1, bh[j], acc[2 * ip + 1][j], 0, 0, 0);
        }
        __builtin_amdgcn_s_setprio(0);
        __syncthreads();
        buf ^= 1;
    }
#undef STAGEO

    const int cb = n0 + wn + (lane & 15);
    #pragma unroll
    for (int i = 0; i < 8; ++i) {
        int rb = m0 + wm + i * 16 + ((lane >> 4) << 2);
        #pragma unroll
        for (int e = 0; e < 4; ++e) {
            float* crow = C + (size_t)(rb + e) * ldc + cb;
            #pragma unroll
            for (int j = 0; j < 4; ++j)
                crow[j * 16] = acc[i][j][e];
        }
    }
}

// ---------------- twiddle table init (global, shared by all FFT blocks) -------
__global__ __launch_bounds__(256)
void twiddle_init_kernel(float2* __restrict__ Tg) {
    int idx = blockIdx.x * 256 + threadIdx.x;
    if (idx >= 3072) return;
    float cs = 1.f, sn = 0.f;
    if (idx >= 2048) {
        sincosf(PI_F * (float)(idx - 2048) * (1.0f / 2048.0f), &sn, &cs);
    } else if (idx >= 1) {
        int s = 31 - __clz(idx);
        int h = 1 << s;
        sincosf(PI_F * (float)(idx - h) / (float)h, &sn, &cs);
    }
    Tg[idx] = make_float2(cs, sn);
}

__device__ __forceinline__ void bfly_f(float2& a, float2& b, float cs, float sn) {
    float2 s = make_float2(a.x + b.x, a.y + b.y);
    float2 d = make_float2(a.x - b.x, a.y - b.y);
    a = s;
    b = make_float2(d.x * cs + d.y * sn, d.y * cs - d.x * sn);
}
__device__ __forceinline__ void bfly_i(float2& a, float2& b, float cs, float sn) {
    float cr = b.x * cs - b.y * sn;
    float ci = b.x * sn + b.y * cs;
    float2 a0 = a;
    a = make_float2(a0.x + cr, a0.y + ci);
    b = make_float2(a0.x - cr, a0.y - ci);
}
__device__ __forceinline__ int SW(int a) { return a ^ ((a >> 5) & 15); }

// ---------------- fused rfft -> gates -> modReLU -> irfft, in-place per sequence
__global__ __launch_bounds__(256)
void fft_gates_kernel(float* __restrict__ buf, const float* __restrict__ gri,
                      const float* __restrict__ modb, const float2* __restrict__ Tg) {
    __shared__ float2 cf[MHALF];
    const int t = threadIdx.x;
    const int w = blockIdx.x;
    const int b = w & 3;
    float2* seq = (float2*)(buf + (size_t)w * SS);

    const int t5 = t & 31;
    const int t3 = t & 3;
    const int c32 = ((t >> 5) << 8) | t5;    // base for 32-span group
    const int d4  = ((t >> 2) << 5) | t3;    // base for 4-span group

    float2 r[8];

    // ---- load + G1: stages 10,9,8 (span 256) ----
    #pragma unroll
    for (int u = 0; u < 8; ++u) r[u] = seq[t + 256 * u];
    #pragma unroll
    for (int u = 0; u < 4; ++u) {
        float2 tw = Tg[1024 + t + 256 * u];
        bfly_f(r[u], r[u + 4], tw.x, tw.y);
    }
    {
        float2 tw0 = Tg[512 + t], tw1 = Tg[512 + t + 256];
        bfly_f(r[0], r[2], tw0.x, tw0.y);
        bfly_f(r[1], r[3], tw1.x, tw1.y);
        bfly_f(r[4], r[6], tw0.x, tw0.y);
        bfly_f(r[5], r[7], tw1.x, tw1.y);
        float2 tw = Tg[256 + t];
        bfly_f(r[0], r[1], tw.x, tw.y);
        bfly_f(r[2], r[3], tw.x, tw.y);
        bfly_f(r[4], r[5], tw.x, tw.y);
        bfly_f(r[6], r[7], tw.x, tw.y);
    }
    #pragma unroll
    for (int u = 0; u < 8; ++u) cf[SW(t + 256 * u)] = r[u];
    __syncthreads();

    // ---- G2: stages 7,6,5 (span 32) ----
    #pragma unroll
    for (int u = 0; u < 8; ++u) r[u] = cf[SW(c32 + 32 * u)];
    #pragma unroll
    for (int u = 0; u < 4; ++u) {
        float2 tw = Tg[128 + t5 + 32 * u];
        bfly_f(r[u], r[u + 4], tw.x, tw.y);
    }
    {
        float2 tw0 = Tg[64 + t5], tw1 = Tg[64 + t5 + 32];
        bfly_f(r[0], r[2], tw0.x, tw0.y);
        bfly_f(r[1], r[3], tw1.x, tw1.y);
        bfly_f(r[4], r[6], tw0.x, tw0.y);
        bfly_f(r[5], r[7], tw1.x, tw1.y);
        float2 tw = Tg[32 + t5];
        bfly_f(r[0], r[1], tw.x, tw.y);
        bfly_f(r[2], r[3], tw.x, tw.y);
        bfly_f(r[4], r[5], tw.x, tw.y);
        bfly_f(r[6], r[7], tw.x, tw.y);
    }
    #pragma unroll
    for (int u = 0; u < 8; ++u) cf[SW(c32 + 32 * u)] = r[u];
    __syncthreads();

    // ---- G3: stages 4,3,2 (span 4) ----
    #pragma unroll
    for (int u = 0; u < 8; ++u) r[u] = cf[SW(d4 + 4 * u)];
    #pragma unroll
    for (int u = 0; u < 4; ++u) {
        float2 tw = Tg[16 + t3 + 4 * u];
        bfly_f(r[u], r[u + 4], tw.x, tw.y);
    }
    {
        float2 tw0 = Tg[8 + t3], tw1 = Tg[8 + t3 + 4];
        bfly_f(r[0], r[2], tw0.x, tw0.y);
        bfly_f(r[1], r[3], tw1.x, tw1.y);
        bfly_f(r[4], r[6], tw0.x, tw0.y);
        bfly_f(r[5], r[7], tw1.x, tw1.y);
        float2 tw = Tg[4 + t3];
        bfly_f(r[0], r[1], tw.x, tw.y);
        bfly_f(r[2], r[3], tw.x, tw.y);
        bfly_f(r[4], r[5], tw.x, tw.y);
        bfly_f(r[6], r[7], tw.x, tw.y);
    }
    #pragma unroll
    for (int u = 0; u < 8; ++u) cf[SW(d4 + 4 * u)] = r[u];
    __syncthreads();

    // ---- G4: stages 1,0 (span 1; 8 consecutive) ----
    #pragma unroll
    for (int u = 0; u < 8; ++u) r[u] = cf[SW(8 * t + u)];
    bfly_f(r[0], r[2], 1.f, 0.f);
    bfly_f(r[1], r[3], 0.f, 1.f);
    bfly_f(r[4], r[6], 1.f, 0.f);
    bfly_f(r[5], r[7], 0.f, 1.f);
    bfly_f(r[0], r[1], 1.f, 0.f);
    bfly_f(r[2], r[3], 1.f, 0.f);
    bfly_f(r[4], r[5], 1.f, 0.f);
    bfly_f(r[6], r[7], 1.f, 0.f);
    #pragma unroll
    for (int u = 0; u < 8; ++u) cf[SW(8 * t + u)] = r[u];
    __syncthreads();

    // ---- spectrum: unpack real-FFT bins (ortho /64), gates, modReLU, repack ----
    const float bias = modb[0];
    const float* gre = gri + (size_t)b * 2 * NFREQ;
    const float* gim = gre + NFREQ;
    const float inv64 = 1.0f / 64.0f;
    for (int k = t; k < 1024; k += 256) {
        if (k == 0) {
            float2 c0 = cf[SW(0)];
            float z0 = (c0.x + c0.y) * inv64;
            float zM = (c0.x - c0.y) * inv64;
            float zr = z0 * gre[0], zi = z0 * gim[0];
            modrelu_apply(zr, zi, bias);
            float yr = zM * gre[2048], yi = zM * gim[2048];
            modrelu_apply(yr, yi, bias);
            cf[SW(0)] = make_float2(0.5f * (zr + yr), 0.5f * (zr - yr));
            float2 c1 = cf[SW(1)];
            float z1r = c1.x * inv64, z1i = -c1.y * inv64;
            float g1r = gre[1024], g1i = gim[1024];
            float pr = z1r * g1r - z1i * g1i;
            float pi2 = z1r * g1i + z1i * g1r;
            modrelu_apply(pr, pi2, bias);
            cf[SW(1)] = make_float2(pr, -pi2);
        } else {
            int kb = 2048 - k;
            int p1 = SW((int)(__brev((unsigned)k) >> 21));
            int p2 = SW((int)(__brev((unsigned)kb) >> 21));
            float2 ca = cf[p1];
            float2 cb2 = cf[p2];
            float Er = 0.5f * (ca.x + cb2.x), Ei = 0.5f * (ca.y - cb2.y);
            float Dr = 0.5f * (ca.x - cb2.x), Di = 0.5f * (ca.y + cb2.y);
            float Or = Di, Oi = -Dr;
            float2 t2 = Tg[2048 + k];
            float cs = t2.x, sn = t2.y;
            float Wr = cs, Wi = -sn;
            float WOr = Wr * Or - Wi * Oi, WOi = Wr * Oi + Wi * Or;
            float zkr = (Er + WOr) * inv64, zki = (Ei + WOi) * inv64;
            float zbr = (Er - WOr) * inv64, zbi = -(Ei - WOi) * inv64;
            float gkr = gre[k], gki = gim[k];
            float ar = zkr * gkr - zki * gki, ai = zkr * gki + zki * gkr;
            modrelu_apply(ar, ai, bias);
            float gbr = gre[kb], gbi = gim[kb];
            float br2 = zbr * gbr - zbi * gbi, bi2 = zbr * gbi + zbi * gbr;
            modrelu_apply(br2, bi2, bias);
            float Epr = 0.5f * (ar + br2), Epi = 0.5f * (ai - bi2);
            float Dpr = 0.5f * (ar - br2), Dpi = 0.5f * (ai + bi2);
            float Opr = cs * Dpr - sn * Dpi, Opi = cs * Dpi + sn * Dpr;
            cf[p1] = make_float2(Epr - Opi, Epi + Opr);
            cf[p2] = make_float2(Epr + Opi, -Epi + Opr);
        }
    }
    __syncthreads();

    // ---- inverse G4': stages 0,1 ----
    #pragma unroll
    for (int u = 0; u < 8; ++u) r[u] = cf[SW(8 * t + u)];
    bfly_i(r[0], r[1], 1.f, 0.f);
    bfly_i(r[2], r[3], 1.f, 0.f);
    bfly_i(r[4], r[5], 1.f, 0.f);
    bfly_i(r[6], r[7], 1.f, 0.f);
    bfly_i(r[0], r[2], 1.f, 0.f);
    bfly_i(r[1], r[3], 0.f, 1.f);
    bfly_i(r[4], r[6], 1.f, 0.f);
    bfly_i(r[5], r[7], 0.f, 1.f);
    #pragma unroll
    for (int u = 0; u < 8; ++u) cf[SW(8 * t + u)] = r[u];
    __syncthreads();

    // ---- inverse G3': stages 2,3,4 ----
    #pragma unroll
    for (int u = 0; u < 8; ++u) r[u] = cf[SW(d4 + 4 * u)];
    {
        float2 tw = Tg[4 + t3];
        bfly_i(r[0], r[1], tw.x, tw.y);
        bfly_i(r[2], r[3], tw.x, tw.y);
        bfly_i(r[4], r[5], tw.x, tw.y);
        bfly_i(r[6], r[7], tw.x, tw.y);
        float2 tw0 = Tg[8 + t3], tw1 = Tg[8 + t3 + 4];
        bfly_i(r[0], r[2], tw0.x, tw0.y);
        bfly_i(r[1], r[3], tw1.x, tw1.y);
        bfly_i(r[4], r[6], tw0.x, tw0.y);
        bfly_i(r[5], r[7], tw1.x, tw1.y);
    }
    #pragma unroll
    for (int u = 0; u < 4; ++u) {
        float2 tw = Tg[16 + t3 + 4 * u];
        bfly_i(r[u], r[u + 4], tw.x, tw.y);
    }
    #pragma unroll
    for (int u = 0; u < 8; ++u) cf[SW(d4 + 4 * u)] = r[u];
    __syncthreads();

    // ---- inverse G2': stages 5,6,7 ----
    #pragma unroll
    for (int u = 0; u < 8; ++u) r[u] = cf[SW(c32 + 32 * u)];
    {
        float2 tw = Tg[32 + t5];
        bfly_i(r[0], r[1], tw.x, tw.y);
        bfly_i(r[2], r[3], tw.x, tw.y);
        bfly_i(r[4], r[5], tw.x, tw.y);
        bfly_i(r[6], r[7], tw.x, tw.y);
        float2 tw0 = Tg[64 + t5], tw1 = Tg[64 + t5 + 32];
        bfly_i(r[0], r[2], tw0.x, tw0.y);
        bfly_i(r[1], r[3], tw1.x, tw1.y);
        bfly_i(r[4], r[6], tw0.x, tw0.y);
        bfly_i(r[5], r[7], tw1.x, tw1.y);
    }
    #pragma unroll
    for (int u = 0; u < 4; ++u) {
        float2 tw = Tg[128 + t5 + 32 * u];
        bfly_i(r[u], r[u + 4], tw.x, tw.y);
    }
    #pragma unroll
    for (int u = 0; u < 8; ++u) cf[SW(c32 + 32 * u)] = r[u];
    __syncthreads();

    // ---- inverse G1': stages 8,9,10 + scale + store ----
    #pragma unroll
    for (int u = 0; u < 8; ++u) r[u] = cf[SW(t + 256 * u)];
    {
        float2 tw = Tg[256 + t];
        bfly_i(r[0], r[1], tw.x, tw.y);
        bfly_i(r[2], r[3], tw.x, tw.y);
        bfly_i(r[4], r[5], tw.x, tw.y);
        bfly_i(r[6], r[7], tw.x, tw.y);
        float2 tw0 = Tg[512 + t], tw1 = Tg[512 + t + 256];
        bfly_i(r[0], r[2], tw0.x, tw0.y);
        bfly_i(r[1], r[3], tw1.x, tw1.y);
        bfly_i(r[4], r[6], tw0.x, tw0.y);
        bfly_i(r[5], r[7], tw1.x, tw1.y);
    }
    #pragma unroll
    for (int u = 0; u < 4; ++u) {
        float2 tw = Tg[1024 + t + 256 * u];
        bfly_i(r[u], r[u + 4], tw.x, tw.y);
    }
    const float s32 = 1.0f / 32.0f;  // 64 (ortho) / 2048 (ifft norm)
    #pragma unroll
    for (int u = 0; u < 8; ++u)
        seq[t + 256 * u] = make_float2(r[u].x * s32, r[u].y * s32);
}

extern "C" void kernel_launch(void* const* d_in, const int* in_sizes, int n_in,
                              void* d_out, int out_size, void* d_ws, size_t ws_size,
                              hipStream_t stream) {
    const float* x        = (const float*)d_in[0];
    const float* W_q      = (const float*)d_in[1];
    const float* W_v      = (const float*)d_in[2];
    const float* W_o      = (const float*)d_in[3];
    const float* ln_gamma = (const float*)d_in[4];
    const float* ln_beta  = (const float*)d_in[5];
    const float* mlp_w1   = (const float*)d_in[6];
    const float* mlp_b1   = (const float*)d_in[7];
    const float* mlp_w2   = (const float*)d_in[8];
    const float* mlp_b2   = (const float*)d_in[9];
    const float* mod_bias = (const float*)d_in[10];
    float* out = (float*)d_out;

    // workspace layout (floats)
    float* ws = (float*)d_ws;
    float* partial  = ws;                    // 262144
    float* xsum     = ws + 262144;           // 4096
    float* q_shared = ws + 266240;           // 256
    float* hdn      = ws + 266496;           // 4096
    float* gri      = ws + 270592;           // 16392 (ends 286984)
    float* mq       = ws + 286984;           // 4096 (ends 291080)
    float2* twid    = (float2*)(ws + 291080); // 3072 float2 (ends 297224)
    float* buf0     = ws + 297984;           // 16777216 floats (64 MiB), [1024][16384]
    u16* bfbase = (u16*)(ws + 297984 + 16777216);
    u16* xut_hi = bfbase;                    // 16777216 u16: x_hi, later reused as ut
    u16* x_lo   = bfbase + 16777216;         // x_lo (dead after V GEMM)
    u16* wv_hi  = bfbase + 33554432;         // 1048576
    u16* wv_lo  = bfbase + 34603008;
    u16* wo_hi  = bfbase + 35651584;
    u16* wo_lo  = bfbase + 36700160;

    twiddle_init_kernel<<<12, 256, 0, stream>>>(twid);

    // fused x split + colsum pass 1
    split_x_colsum_kernel<<<256, 256, 0, stream>>>(x, xut_hi, x_lo, partial);
    {
        dim3 g(4, 4);
        colsum2_kernel<<<g, 256, 0, stream>>>(partial, xsum);
    }
    gates1a_kernel<<<256, 256, 0, stream>>>(xsum, W_q, mq);
    gates1b_kernel<<<4, 256, 0, stream>>>(mq, ln_gamma, ln_beta, q_shared);
    gates2_kernel<<<16, 256, 0, stream>>>(q_shared, mlp_w1, mlp_b1, hdn);
    gates3_kernel<<<1025, 256, 0, stream>>>(hdn, mlp_w2, mlp_b2, gri);

    // weight splits
    split_kernel<<<1024, 256, 0, stream>>>(W_v, wv_hi, wv_lo, 262144);
    split_kernel<<<1024, 256, 0, stream>>>(W_o, wo_hi, wo_lo, 262144);

    // V projection (transposed output): buf0[j][bs] = sum_k Wv[j,k]*x[bs,k]
    // M=1024 (j), N=16384 (bs): mtiles=4, ntiles=64 -> 256 blocks
    gemm_split256_kernel<<<256, 512, 0, stream>>>(wv_hi, wv_lo, xut_hi, x_lo,
                                                  buf0, 4, 64, 1024, 16384);

    // fused spectral mixing, in place
    fft_gates_kernel<<<4096, 256, 0, stream>>>(buf0, gri, mod_bias, twid);

    // transpose u (hi only): buf0 [1024][16384] f32 -> ut bf16 [16384][1024]
    // (aliases x_hi, dead after the V GEMM)
    {
        dim3 g(256, 16);
        transpose_hi_kernel<<<g, 256, 0, stream>>>(buf0, xut_hi);
    }

    // O projection: out[bs][jo] = sum_j ut[bs][j]*Wo[jo][j]   (2-product)
    // M=16384 (bs), N=1024 (jo): mtiles=64, ntiles=4 -> 256 blocks
    gemm_out2_kernel<<<256, 512, 0, stream>>>(xut_hi, wo_hi, wo_lo,
                                              out, 64, 4, 1024, 1024);
}

// Round 7
// 290.525 us; speedup vs baseline: 4.5025x; 1.0033x over previous
//
#include <hip/hip_runtime.h>
#include <math.h>
#include <stdint.h>

#define PI_F 3.14159265358979323846f

// Problem constants
#define BB 4
#define SS 4096
#define DD 1024
#define HH 16
#define DHD 64
#define NFREQ 2049   // 4096/2 + 1
#define MHALF 2048   // half-size complex FFT length

typedef unsigned short u16;
typedef __attribute__((ext_vector_type(8))) short short8;   // 8 bf16 = 4 VGPR (MFMA A/B frag)
typedef __attribute__((ext_vector_type(4))) float f32x4;    // MFMA C/D frag
typedef __attribute__((ext_vector_type(4))) unsigned short u16x4;

// ---- bf16 helpers (RTNE) ----
__device__ __forceinline__ u16 f2bf(float f) {
    unsigned u = __float_as_uint(f);
    unsigned r = (u + 0x7FFFu + ((u >> 16) & 1u)) >> 16;
    return (u16)r;
}
__device__ __forceinline__ float bf2f(u16 h) { return __uint_as_float(((unsigned)h) << 16); }

__device__ __forceinline__ void modrelu_apply(float& zr, float& zi, float bias) {
    float mag = sqrtf(zr * zr + zi * zi);
    float scale = fmaxf(mag + bias, 0.0f) / fmaxf(mag, 1e-12f);
    zr *= scale; zi *= scale;
}

// async global->LDS, 16B per lane (HW: dest = wave-uniform base + lane*16)
__device__ __forceinline__ void gload16(const u16* g, u16* l) {
    __builtin_amdgcn_global_load_lds(
        (const __attribute__((address_space(1))) void*)g,
        (__attribute__((address_space(3))) void*)l, 16, 0, 0);
}

// LDS byte-offset swizzle for GEMM staging (16B chunks): XOR chunk bits [4:3]
// into chunk bits [1:0]; involution, matches the pre-swizzled staging order.
__device__ __forceinline__ int swz(int byteoff) {
    return byteoff ^ (((byteoff >> 7) & 3) << 4);
}

#define MFMA_BF16 __builtin_amdgcn_mfma_f32_16x16x32_bf16

// ---------------- fused x -> bf16 hi/lo split + column partial sums -----------
// grid 256 = (b, s-chunk of 64); thread t owns columns 4t..4t+3
__global__ __launch_bounds__(256)
void split_x_colsum_kernel(const float* __restrict__ x, u16* __restrict__ hi,
                           u16* __restrict__ lo, float* __restrict__ partial) {
    int blk = blockIdx.x;
    int b = blk >> 6;
    int s0 = (blk & 63) * 64;
    int t = threadIdx.x;
    const float* xp = x + ((size_t)b * SS + s0) * DD;
    float4 acc = make_float4(0.f, 0.f, 0.f, 0.f);
    for (int s = 0; s < 64; ++s) {
        float4 v = ((const float4*)(xp + (size_t)s * DD))[t];
        acc.x += v.x; acc.y += v.y; acc.z += v.z; acc.w += v.w;
        u16x4 h, l;
        h.x = f2bf(v.x); h.y = f2bf(v.y); h.z = f2bf(v.z); h.w = f2bf(v.w);
        l.x = f2bf(v.x - bf2f(h.x));
        l.y = f2bf(v.y - bf2f(h.y));
        l.z = f2bf(v.z - bf2f(h.z));
        l.w = f2bf(v.w - bf2f(h.w));
        size_t rowo = (size_t)(b * SS + s0 + s) * DD;
        ((u16x4*)(hi + rowo))[t] = h;
        ((u16x4*)(lo + rowo))[t] = l;
    }
    ((float4*)(partial + (size_t)blk * DD))[t] = acc;
}

__global__ __launch_bounds__(256)
void colsum2_kernel(const float* __restrict__ partial, float* __restrict__ xsum) {
    int b = blockIdx.y;
    int k = blockIdx.x * 256 + threadIdx.x;
    float acc = 0.f;
    for (int c = 0; c < 64; ++c)
        acc += partial[((size_t)(b * 64 + c)) * DD + k];
    xsum[b * DD + k] = acc;
}

// ---------------- mq[b][j] = dot(xsum[b]/S, Wq[j]) ; grid 256, 1 wave per row j
__global__ __launch_bounds__(256)
void gates1a_kernel(const float* __restrict__ xsum, const float* __restrict__ Wq,
                    float* __restrict__ mq) {
    __shared__ float xb[4][1024];
    int t = threadIdx.x;
    for (int i = t; i < 4096; i += 256)
        xb[i >> 10][i & 1023] = xsum[i] * (1.0f / 4096.0f);
    __syncthreads();
    int wv = t >> 6, l = t & 63;
    int j = blockIdx.x * 4 + wv;
    const float* wrow = Wq + (size_t)j * DD;
    float a0 = 0.f, a1 = 0.f, a2 = 0.f, a3 = 0.f;
    #pragma unroll 4
    for (int it = 0; it < 16; ++it) {
        int idx = l + it * 64;
        float wval = wrow[idx];
        a0 += xb[0][idx] * wval;
        a1 += xb[1][idx] * wval;
        a2 += xb[2][idx] * wval;
        a3 += xb[3][idx] * wval;
    }
    for (int off = 32; off > 0; off >>= 1) {
        a0 += __shfl_down(a0, off, 64);
        a1 += __shfl_down(a1, off, 64);
        a2 += __shfl_down(a2, off, 64);
        a3 += __shfl_down(a3, off, 64);
    }
    if (l == 0) {
        mq[j] = a0; mq[1024 + j] = a1; mq[2048 + j] = a2; mq[3072 + j] = a3;
    }
}

// ---------------- LayerNorm per head over mq, mean over heads -> q_shared[b][64]
__global__ __launch_bounds__(256)
void gates1b_kernel(const float* __restrict__ mq, const float* __restrict__ gamma,
                    const float* __restrict__ beta, float* __restrict__ q_shared) {
    __shared__ float qacc[4][64];
    int b = blockIdx.x;
    int t = threadIdx.x;
    int wv = t >> 6, l = t & 63;
    float part = 0.f;
    for (int hh = 0; hh < 4; ++hh) {
        int h = wv * 4 + hh;
        float v = mq[b * 1024 + h * 64 + l];
        float s1 = v, s2 = v * v;
        for (int off = 32; off > 0; off >>= 1) {
            s1 += __shfl_xor(s1, off, 64);
            s2 += __shfl_xor(s2, off, 64);
        }
        float mu = s1 * (1.0f / 64.0f);
        float var = s2 * (1.0f / 64.0f) - mu * mu;
        part += (v - mu) * rsqrtf(var + 1e-5f) * gamma[l] + beta[l];
    }
    qacc[wv][l] = part;
    __syncthreads();
    if (t < 64) {
        float s = qacc[0][t] + qacc[1][t] + qacc[2][t] + qacc[3][t];
        q_shared[b * 64 + t] = s * (1.0f / 16.0f);
    }
}

// ---------------- hdn = gelu(q_shared @ w1^T + b1)
__global__ __launch_bounds__(256)
void gates2_kernel(const float* __restrict__ q_shared, const float* __restrict__ w1,
                   const float* __restrict__ b1, float* __restrict__ hdn) {
    __shared__ float qs[64];
    int blk = blockIdx.x;
    int b = blk >> 2;
    int i0 = (blk & 3) * 256;
    int t = threadIdx.x;
    if (t < 64) qs[t] = q_shared[b * 64 + t];
    __syncthreads();
    int i = i0 + t;
    const float* wrow = w1 + (size_t)i * DHD;
    float acc = b1[i];
    #pragma unroll 8
    for (int d = 0; d < 64; ++d) acc += qs[d] * wrow[d];
    float g = 0.5f * acc * (1.0f + erff(acc * 0.70710678118654752f));
    hdn[b * DD + i] = g;
}

// ---------------- gri = hdn @ w2^T + b2 ; one wave per output row, all 4 b at once
__global__ __launch_bounds__(256)
void gates3_kernel(const float* __restrict__ hdn, const float* __restrict__ w2,
                   const float* __restrict__ b2, float* __restrict__ gri) {
    int t = threadIdx.x;
    int wv = t >> 6, l = t & 63;
    int r = blockIdx.x * 4 + wv;
    if (r >= 2 * NFREQ) return;
    const float* wrow = w2 + (size_t)r * DD;
    float a0 = 0.f, a1 = 0.f, a2 = 0.f, a3 = 0.f;
    for (int it = 0; it < 16; ++it) {
        int idx = l + it * 64;
        float wval = wrow[idx];
        a0 += hdn[idx] * wval;
        a1 += hdn[1024 + idx] * wval;
        a2 += hdn[2048 + idx] * wval;
        a3 += hdn[3072 + idx] * wval;
    }
    for (int off = 32; off > 0; off >>= 1) {
        a0 += __shfl_down(a0, off, 64);
        a1 += __shfl_down(a1, off, 64);
        a2 += __shfl_down(a2, off, 64);
        a3 += __shfl_down(a3, off, 64);
    }
    if (l == 0) {
        float bb = b2[r];
        gri[r] = a0 + bb;
        gri[2 * NFREQ + r] = a1 + bb;
        gri[2 * 2 * NFREQ + r] = a2 + bb;
        gri[3 * 2 * NFREQ + r] = a3 + bb;
    }
}

// ---------------- f32 -> (bf16 hi, bf16 lo) split (weights) ----------------
__global__ __launch_bounds__(256)
void split_kernel(const float* __restrict__ src, u16* __restrict__ hi,
                  u16* __restrict__ lo, int n4) {
    int idx = blockIdx.x * 256 + threadIdx.x;
    int stride = gridDim.x * 256;
    for (; idx < n4; idx += stride) {
        float4 v = ((const float4*)src)[idx];
        u16x4 h, l;
        h.x = f2bf(v.x); h.y = f2bf(v.y); h.z = f2bf(v.z); h.w = f2bf(v.w);
        l.x = f2bf(v.x - bf2f(h.x));
        l.y = f2bf(v.y - bf2f(h.y));
        l.z = f2bf(v.z - bf2f(h.z));
        l.w = f2bf(v.w - bf2f(h.w));
        ((u16x4*)hi)[idx] = h;
        ((u16x4*)lo)[idx] = l;
    }
}

// ---------------- transpose (hi only): src f32 [1024][16384] -> bf16 [16384][1024]
__global__ __launch_bounds__(256)
void transpose_hi_kernel(const float* __restrict__ src, u16* __restrict__ hi) {
    __shared__ float tile[64][65];
    int s0 = blockIdx.x * 64;   // bs block
    int j0 = blockIdx.y * 64;   // feature block
    int t = threadIdx.x;
    int c = t & 63, r4 = t >> 6;
    #pragma unroll
    for (int rr = 0; rr < 64; rr += 4)
        tile[rr + r4][c] = src[(size_t)(j0 + rr + r4) * 16384 + s0 + c];
    __syncthreads();
    #pragma unroll
    for (int rr = 0; rr < 64; rr += 4) {
        int a = rr + r4;                 // local bs
        float v = tile[c][a];            // = src[j0+c][s0+a]
        hi[(size_t)(s0 + a) * 1024 + j0 + c] = f2bf(v);
    }
}

// ---------------- split-bf16 MFMA GEMM, 256x256 tile, 4-phase schedule --------
// C[M][N] = A[M][K] * B[N][K]^T ; A,B as bf16 hi/lo planes (row-major, stride K).
// 512 threads = 8 waves (2M x 4N); per-wave 128x64 out = 8x4 frags of 16x16x32.
// K-loop: 4 phases per K-tile; each phase {ds_read A-subtile; issue 2 stage
// loads for next tile; raw s_barrier; setprio(1) MFMA cluster setprio(0);
// raw s_barrier}. Raw barriers do NOT drain vmcnt -> stage loads stay in
// flight across phases; one manual vmcnt(0) per tile (T3+T4+T5, m201 recipe).
__global__ __launch_bounds__(512, 2)
void gemm_split256_kernel(const u16* __restrict__ Ah, const u16* __restrict__ Al,
                          const u16* __restrict__ Bh, const u16* __restrict__ Bl,
                          float* __restrict__ C, int mtiles, int ntiles, int K, int ldc) {
    __shared__ u16 lds[2][4][8192];   // [buf][plane: Ah,Al,Bh,Bl][256 rows x 32 k]
    const int t = threadIdx.x;
    const int wid = __builtin_amdgcn_readfirstlane(t >> 6);
    const int lane = t & 63;

    // XCD-aware decode (blocks dispatch round-robin over 8 XCDs)
    const int bid = blockIdx.x;
    const int xcd = bid & 7;
    const int idx = bid >> 3;
    int mt, nt;
    if (ntiles >= mtiles) { mt = idx % mtiles; nt = xcd * (ntiles >> 3) + idx / mtiles; }
    else                  { nt = idx % ntiles; mt = xcd * (mtiles >> 3) + idx / ntiles; }
    const int m0 = mt * 256;
    const int n0 = nt * 256;
    const int wm = (wid >> 2) * 128;
    const int wn = (wid & 3) * 64;

    // staging: 64 chunk-ops of 1KB (wave w gets ops g = w*8..w*8+7)
    const u16* gbase[8];
    u16* ldst[8];
    #pragma unroll
    for (int o = 0; o < 8; ++o) {
        int g = wid * 8 + o;
        int p = g >> 4;
        int j = ((g & 15) << 6) | lane;
        int c = j ^ ((j >> 3) & 3);
        int row = c >> 2, q = c & 3;
        const u16* base = (p == 0) ? Ah : (p == 1) ? Al : (p == 2) ? Bh : Bl;
        int rbase = (p < 2) ? m0 : n0;
        gbase[o] = base + (size_t)(rbase + row) * K + q * 8;
        ldst[o] = &lds[0][0][0] + (size_t)p * 8192 + (size_t)j * 8;
    }

    f32x4 acc[8][4] = {};

    // prologue: stage tile 0, drain, sync
    #pragma unroll
    for (int o = 0; o < 8; ++o) gload16(gbase[o], ldst[o]);
    asm volatile("s_waitcnt vmcnt(0)" ::: "memory");
    __builtin_amdgcn_s_barrier();

#define PHASE_V(IP, O0, O1, LAST)                                                   \
    {                                                                               \
        int s0 = swz((wm + (lane & 15) + (2 * (IP)) * 16) * 64 + (lane >> 4) * 16); \
        int s1 = swz((wm + (lane & 15) + (2 * (IP) + 1) * 16) * 64 + (lane >> 4) * 16); \
        short8 ah0 = *(const short8*)(lb + (s0 >> 1));                              \
        short8 al0 = *(const short8*)(lb + 8192 + (s0 >> 1));                       \
        short8 ah1 = *(const short8*)(lb + (s1 >> 1));                              \
        short8 al1 = *(const short8*)(lb + 8192 + (s1 >> 1));                       \
        if (more) {                                                                 \
            gload16(gbase[O0] + (size_t)(kt + 1) * 32, ldst[O0] + nb * 32768);      \
            gload16(gbase[O1] + (size_t)(kt + 1) * 32, ldst[O1] + nb * 32768);      \
        }                                                                           \
        __builtin_amdgcn_s_barrier();                                               \
        __builtin_amdgcn_s_setprio(1);                                              \
        _Pragma("unroll")                                                           \
        for (int j = 0; j < 4; ++j) acc[2 * (IP)][j]     = MFMA_BF16(ah0, bl[j], acc[2 * (IP)][j], 0, 0, 0); \
        _Pragma("unroll")                                                           \
        for (int j = 0; j < 4; ++j) acc[2 * (IP) + 1][j] = MFMA_BF16(ah1, bl[j], acc[2 * (IP) + 1][j], 0, 0, 0); \
        _Pragma("unroll")                                                           \
        for (int j = 0; j < 4; ++j) acc[2 * (IP)][j]     = MFMA_BF16(al0, bh[j], acc[2 * (IP)][j], 0, 0, 0); \
        _Pragma("unroll")                                                           \
        for (int j = 0; j < 4; ++j) acc[2 * (IP) + 1][j] = MFMA_BF16(al1, bh[j], acc[2 * (IP) + 1][j], 0, 0, 0); \
        _Pragma("unroll")                                                           \
        for (int j = 0; j < 4; ++j) acc[2 * (IP)][j]     = MFMA_BF16(ah0, bh[j], acc[2 * (IP)][j], 0, 0, 0); \
        _Pragma("unroll")                                                           \
        for (int j = 0; j < 4; ++j) acc[2 * (IP) + 1][j] = MFMA_BF16(ah1, bh[j], acc[2 * (IP) + 1][j], 0, 0, 0); \
        __builtin_amdgcn_s_setprio(0);                                              \
        if (LAST) { asm volatile("s_waitcnt vmcnt(0)" ::: "memory"); }              \
        __builtin_amdgcn_s_barrier();                                               \
    }

    const int KT = K >> 5;
    int buf = 0;
    for (int kt = 0; kt < KT; ++kt) {
        const u16* lb = &lds[buf][0][0];
        const int nb = buf ^ 1;
        const bool more = (kt + 1 < KT);

        short8 bh[4], bl[4];
        #pragma unroll
        for (int j = 0; j < 4; ++j) {
            int s = swz((wn + (lane & 15) + j * 16) * 64 + (lane >> 4) * 16);
            bh[j] = *(const short8*)(lb + 2 * 8192 + (s >> 1));
            bl[j] = *(const short8*)(lb + 3 * 8192 + (s >> 1));
        }
        PHASE_V(0, 0, 1, false)
        PHASE_V(1, 2, 3, false)
        PHASE_V(2, 4, 5, false)
        PHASE_V(3, 6, 7, true)
        buf = nb;
    }
#undef PHASE_V

    // epilogue: C/D layout = col (lane&15), row (lane>>4)*4 + e   [m89-verified]
    const int cb = n0 + wn + (lane & 15);
    #pragma unroll
    for (int i = 0; i < 8; ++i) {
        int rb = m0 + wm + i * 16 + ((lane >> 4) << 2);
        #pragma unroll
        for (int e = 0; e < 4; ++e) {
            float* crow = C + (size_t)(rb + e) * ldc + cb;
            #pragma unroll
            for (int j = 0; j < 4; ++j)
                crow[j * 16] = acc[i][j][e];
        }
    }
}

// ---------------- 2-product MFMA GEMM (O proj): A plain bf16, B hi/lo ---------
// Same 4-phase schedule; 3 planes, stage ops split 2/2/1/1 across phases.
__global__ __launch_bounds__(512, 2)
void gemm_out2_kernel(const u16* __restrict__ A, const u16* __restrict__ Bh,
                      const u16* __restrict__ Bl, float* __restrict__ C,
                      int mtiles, int ntiles, int K, int ldc) {
    __shared__ u16 lds[2][3][8192];   // [buf][plane: A,Bh,Bl][256 rows x 32 k]
    const int t = threadIdx.x;
    const int wid = __builtin_amdgcn_readfirstlane(t >> 6);
    const int lane = t & 63;

    const int bid = blockIdx.x;
    const int xcd = bid & 7;
    const int idx = bid >> 3;
    int mt, nt;
    if (ntiles >= mtiles) { mt = idx % mtiles; nt = xcd * (ntiles >> 3) + idx / mtiles; }
    else                  { nt = idx % ntiles; mt = xcd * (mtiles >> 3) + idx / ntiles; }
    const int m0 = mt * 256;
    const int n0 = nt * 256;
    const int wm = (wid >> 2) * 128;
    const int wn = (wid & 3) * 64;

    // staging: 48 chunk-ops of 1KB (wave w gets ops g = w*6..w*6+5)
    const u16* gbase[6];
    u16* ldst[6];
    #pragma unroll
    for (int o = 0; o < 6; ++o) {
        int g = wid * 6 + o;
        int p = g >> 4;
        int j = ((g & 15) << 6) | lane;
        int c = j ^ ((j >> 3) & 3);
        int row = c >> 2, q = c & 3;
        const u16* base = (p == 0) ? A : (p == 1) ? Bh : Bl;
        int rbase = (p == 0) ? m0 : n0;
        gbase[o] = base + (size_t)(rbase + row) * K + q * 8;
        ldst[o] = &lds[0][0][0] + (size_t)p * 8192 + (size_t)j * 8;
    }

    f32x4 acc[8][4] = {};

    #pragma unroll
    for (int o = 0; o < 6; ++o) gload16(gbase[o], ldst[o]);
    asm volatile("s_waitcnt vmcnt(0)" ::: "memory");
    __builtin_amdgcn_s_barrier();

#define PHASE_O(IP, O0, O1, LAST)                                                   \
    {                                                                               \
        int s0 = swz((wm + (lane & 15) + (2 * (IP)) * 16) * 64 + (lane >> 4) * 16); \
        int s1 = swz((wm + (lane & 15) + (2 * (IP) + 1) * 16) * 64 + (lane >> 4) * 16); \
        short8 a0 = *(const short8*)(lb + (s0 >> 1));                               \
        short8 a1 = *(const short8*)(lb + (s1 >> 1));                               \
        if (more) {                                                                 \
            gload16(gbase[O0] + (size_t)(kt + 1) * 32, ldst[O0] + nb * 24576);      \
            if ((O1) >= 0)                                                          \
                gload16(gbase[O1] + (size_t)(kt + 1) * 32, ldst[O1] + nb * 24576);  \
        }                                                                           \
        __builtin_amdgcn_s_barrier();                                               \
        __builtin_amdgcn_s_setprio(1);                                              \
        _Pragma("unroll")                                                           \
        for (int j = 0; j < 4; ++j) acc[2 * (IP)][j]     = MFMA_BF16(a0, bl[j], acc[2 * (IP)][j], 0, 0, 0); \
        _Pragma("unroll")                                                           \
        for (int j = 0; j < 4; ++j) acc[2 * (IP) + 1][j] = MFMA_BF16(a1, bl[j], acc[2 * (IP) + 1][j], 0, 0, 0); \
        _Pragma("unroll")                                                           \
        for (int j = 0; j < 4; ++j) acc[2 * (IP)][j]     = MFMA_BF16(a0, bh[j], acc[2 * (IP)][j], 0, 0, 0); \
        _Pragma("unroll")                                                           \
        for (int j = 0; j < 4; ++j) acc[2 * (IP) + 1][j] = MFMA_BF16(a1, bh[j], acc[2 * (IP) + 1][j], 0, 0, 0); \
        __builtin_amdgcn_s_setprio(0);                                              \
        if (LAST) { asm volatile("s_waitcnt vmcnt(0)" ::: "memory"); }              \
        __builtin_amdgcn_s_barrier();                                               \
    }

    const int KT = K >> 5;
    int buf = 0;
    for (int kt = 0; kt < KT; ++kt) {
        const u16* lb = &lds[buf][0][0];
        const int nb = buf ^ 1;
        const bool more = (kt + 1 < KT);

        short8 bh[4], bl[4];
        #pragma unroll
        for (int j = 0; j < 4; ++j) {
            int s = swz((wn + (lane & 15) + j * 16) * 64 + (lane >> 4) * 16);
            bh[j] = *(const short8*)(lb + 1 * 8192 + (s >> 1));
            bl[j] = *(const short8*)(lb + 2 * 8192 + (s >> 1));
        }
        PHASE_O(0, 0, 1, false)
        PHASE_O(1, 2, 3, false)
        PHASE_O(2, 4, -1, false)
        PHASE_O(3, 5, -1, true)
        buf = nb;
    }
#undef PHASE_O

    const int cb = n0 + wn + (lane & 15);
    #pragma unroll
    for (int i = 0; i < 8; ++i) {
        int rb = m0 + wm + i * 16 + ((lane >> 4) << 2);
        #pragma unroll
        for (int e = 0; e < 4; ++e) {
            float* crow = C + (size_t)(rb + e) * ldc + cb;
            #pragma unroll
            for (int j = 0; j < 4; ++j)
                crow[j * 16] = acc[i][j][e];
        }
    }
}

// ---------------- twiddle table init (global, shared by all FFT blocks) -------
__global__ __launch_bounds__(256)
void twiddle_init_kernel(float2* __restrict__ Tg) {
    int idx = blockIdx.x * 256 + threadIdx.x;
    if (idx >= 3072) return;
    float cs = 1.f, sn = 0.f;
    if (idx >= 2048) {
        sincosf(PI_F * (float)(idx - 2048) * (1.0f / 2048.0f), &sn, &cs);
    } else if (idx >= 1) {
        int s = 31 - __clz(idx);
        int h = 1 << s;
        sincosf(PI_F * (float)(idx - h) / (float)h, &sn, &cs);
    }
    Tg[idx] = make_float2(cs, sn);
}

__device__ __forceinline__ void bfly_f(float2& a, float2& b, float cs, float sn) {
    float2 s = make_float2(a.x + b.x, a.y + b.y);
    float2 d = make_float2(a.x - b.x, a.y - b.y);
    a = s;
    b = make_float2(d.x * cs + d.y * sn, d.y * cs - d.x * sn);
}
__device__ __forceinline__ void bfly_i(float2& a, float2& b, float cs, float sn) {
    float cr = b.x * cs - b.y * sn;
    float ci = b.x * sn + b.y * cs;
    float2 a0 = a;
    a = make_float2(a0.x + cr, a0.y + ci);
    b = make_float2(a0.x - cr, a0.y - ci);
}
__device__ __forceinline__ int SW(int a) { return a ^ ((a >> 5) & 15); }

// ---------------- fused rfft -> gates -> modReLU -> irfft, in-place per sequence
__global__ __launch_bounds__(256)
void fft_gates_kernel(float* __restrict__ buf, const float* __restrict__ gri,
                      const float* __restrict__ modb, const float2* __restrict__ Tg) {
    __shared__ float2 cf[MHALF];
    const int t = threadIdx.x;
    const int w = blockIdx.x;
    const int b = w & 3;
    float2* seq = (float2*)(buf + (size_t)w * SS);

    const int t5 = t & 31;
    const int t3 = t & 3;
    const int c32 = ((t >> 5) << 8) | t5;    // base for 32-span group
    const int d4  = ((t >> 2) << 5) | t3;    // base for 4-span group

    float2 r[8];

    // ---- load + G1: stages 10,9,8 (span 256) ----
    #pragma unroll
    for (int u = 0; u < 8; ++u) r[u] = seq[t + 256 * u];
    #pragma unroll
    for (int u = 0; u < 4; ++u) {
        float2 tw = Tg[1024 + t + 256 * u];
        bfly_f(r[u], r[u + 4], tw.x, tw.y);
    }
    {
        float2 tw0 = Tg[512 + t], tw1 = Tg[512 + t + 256];
        bfly_f(r[0], r[2], tw0.x, tw0.y);
        bfly_f(r[1], r[3], tw1.x, tw1.y);
        bfly_f(r[4], r[6], tw0.x, tw0.y);
        bfly_f(r[5], r[7], tw1.x, tw1.y);
        float2 tw = Tg[256 + t];
        bfly_f(r[0], r[1], tw.x, tw.y);
        bfly_f(r[2], r[3], tw.x, tw.y);
        bfly_f(r[4], r[5], tw.x, tw.y);
        bfly_f(r[6], r[7], tw.x, tw.y);
    }
    #pragma unroll
    for (int u = 0; u < 8; ++u) cf[SW(t + 256 * u)] = r[u];
    __syncthreads();

    // ---- G2: stages 7,6,5 (span 32) ----
    #pragma unroll
    for (int u = 0; u < 8; ++u) r[u] = cf[SW(c32 + 32 * u)];
    #pragma unroll
    for (int u = 0; u < 4; ++u) {
        float2 tw = Tg[128 + t5 + 32 * u];
        bfly_f(r[u], r[u + 4], tw.x, tw.y);
    }
    {
        float2 tw0 = Tg[64 + t5], tw1 = Tg[64 + t5 + 32];
        bfly_f(r[0], r[2], tw0.x, tw0.y);
        bfly_f(r[1], r[3], tw1.x, tw1.y);
        bfly_f(r[4], r[6], tw0.x, tw0.y);
        bfly_f(r[5], r[7], tw1.x, tw1.y);
        float2 tw = Tg[32 + t5];
        bfly_f(r[0], r[1], tw.x, tw.y);
        bfly_f(r[2], r[3], tw.x, tw.y);
        bfly_f(r[4], r[5], tw.x, tw.y);
        bfly_f(r[6], r[7], tw.x, tw.y);
    }
    #pragma unroll
    for (int u = 0; u < 8; ++u) cf[SW(c32 + 32 * u)] = r[u];
    __syncthreads();

    // ---- G3: stages 4,3,2 (span 4) ----
    #pragma unroll
    for (int u = 0; u < 8; ++u) r[u] = cf[SW(d4 + 4 * u)];
    #pragma unroll
    for (int u = 0; u < 4; ++u) {
        float2 tw = Tg[16 + t3 + 4 * u];
        bfly_f(r[u], r[u + 4], tw.x, tw.y);
    }
    {
        float2 tw0 = Tg[8 + t3], tw1 = Tg[8 + t3 + 4];
        bfly_f(r[0], r[2], tw0.x, tw0.y);
        bfly_f(r[1], r[3], tw1.x, tw1.y);
        bfly_f(r[4], r[6], tw0.x, tw0.y);
        bfly_f(r[5], r[7], tw1.x, tw1.y);
        float2 tw = Tg[4 + t3];
        bfly_f(r[0], r[1], tw.x, tw.y);
        bfly_f(r[2], r[3], tw.x, tw.y);
        bfly_f(r[4], r[5], tw.x, tw.y);
        bfly_f(r[6], r[7], tw.x, tw.y);
    }
    #pragma unroll
    for (int u = 0; u < 8; ++u) cf[SW(d4 + 4 * u)] = r[u];
    __syncthreads();

    // ---- G4: stages 1,0 (span 1; 8 consecutive) ----
    #pragma unroll
    for (int u = 0; u < 8; ++u) r[u] = cf[SW(8 * t + u)];
    bfly_f(r[0], r[2], 1.f, 0.f);
    bfly_f(r[1], r[3], 0.f, 1.f);
    bfly_f(r[4], r[6], 1.f, 0.f);
    bfly_f(r[5], r[7], 0.f, 1.f);
    bfly_f(r[0], r[1], 1.f, 0.f);
    bfly_f(r[2], r[3], 1.f, 0.f);
    bfly_f(r[4], r[5], 1.f, 0.f);
    bfly_f(r[6], r[7], 1.f, 0.f);
    #pragma unroll
    for (int u = 0; u < 8; ++u) cf[SW(8 * t + u)] = r[u];
    __syncthreads();

    // ---- spectrum: unpack real-FFT bins (ortho /64), gates, modReLU, repack ----
    const float bias = modb[0];
    const float* gre = gri + (size_t)b * 2 * NFREQ;
    const float* gim = gre + NFREQ;
    const float inv64 = 1.0f / 64.0f;
    for (int k = t; k < 1024; k += 256) {
        if (k == 0) {
            float2 c0 = cf[SW(0)];
            float z0 = (c0.x + c0.y) * inv64;
            float zM = (c0.x - c0.y) * inv64;
            float zr = z0 * gre[0], zi = z0 * gim[0];
            modrelu_apply(zr, zi, bias);
            float yr = zM * gre[2048], yi = zM * gim[2048];
            modrelu_apply(yr, yi, bias);
            cf[SW(0)] = make_float2(0.5f * (zr + yr), 0.5f * (zr - yr));
            float2 c1 = cf[SW(1)];
            float z1r = c1.x * inv64, z1i = -c1.y * inv64;
            float g1r = gre[1024], g1i = gim[1024];
            float pr = z1r * g1r - z1i * g1i;
            float pi2 = z1r * g1i + z1i * g1r;
            modrelu_apply(pr, pi2, bias);
            cf[SW(1)] = make_float2(pr, -pi2);
        } else {
            int kb = 2048 - k;
            int p1 = SW((int)(__brev((unsigned)k) >> 21));
            int p2 = SW((int)(__brev((unsigned)kb) >> 21));
            float2 ca = cf[p1];
            float2 cb2 = cf[p2];
            float Er = 0.5f * (ca.x + cb2.x), Ei = 0.5f * (ca.y - cb2.y);
            float Dr = 0.5f * (ca.x - cb2.x), Di = 0.5f * (ca.y + cb2.y);
            float Or = Di, Oi = -Dr;
            float2 t2 = Tg[2048 + k];
            float cs = t2.x, sn = t2.y;
            float Wr = cs, Wi = -sn;
            float WOr = Wr * Or - Wi * Oi, WOi = Wr * Oi + Wi * Or;
            float zkr = (Er + WOr) * inv64, zki = (Ei + WOi) * inv64;
            float zbr = (Er - WOr) * inv64, zbi = -(Ei - WOi) * inv64;
            float gkr = gre[k], gki = gim[k];
            float ar = zkr * gkr - zki * gki, ai = zkr * gki + zki * gkr;
            modrelu_apply(ar, ai, bias);
            float gbr = gre[kb], gbi = gim[kb];
            float br2 = zbr * gbr - zbi * gbi, bi2 = zbr * gbi + zbi * gbr;
            modrelu_apply(br2, bi2, bias);
            float Epr = 0.5f * (ar + br2), Epi = 0.5f * (ai - bi2);
            float Dpr = 0.5f * (ar - br2), Dpi = 0.5f * (ai + bi2);
            float Opr = cs * Dpr - sn * Dpi, Opi = cs * Dpi + sn * Dpr;
            cf[p1] = make_float2(Epr - Opi, Epi + Opr);
            cf[p2] = make_float2(Epr + Opi, -Epi + Opr);
        }
    }
    __syncthreads();

    // ---- inverse G4': stages 0,1 ----
    #pragma unroll
    for (int u = 0; u < 8; ++u) r[u] = cf[SW(8 * t + u)];
    bfly_i(r[0], r[1], 1.f, 0.f);
    bfly_i(r[2], r[3], 1.f, 0.f);
    bfly_i(r[4], r[5], 1.f, 0.f);
    bfly_i(r[6], r[7], 1.f, 0.f);
    bfly_i(r[0], r[2], 1.f, 0.f);
    bfly_i(r[1], r[3], 0.f, 1.f);
    bfly_i(r[4], r[6], 1.f, 0.f);
    bfly_i(r[5], r[7], 0.f, 1.f);
    #pragma unroll
    for (int u = 0; u < 8; ++u) cf[SW(8 * t + u)] = r[u];
    __syncthreads();

    // ---- inverse G3': stages 2,3,4 ----
    #pragma unroll
    for (int u = 0; u < 8; ++u) r[u] = cf[SW(d4 + 4 * u)];
    {
        float2 tw = Tg[4 + t3];
        bfly_i(r[0], r[1], tw.x, tw.y);
        bfly_i(r[2], r[3], tw.x, tw.y);
        bfly_i(r[4], r[5], tw.x, tw.y);
        bfly_i(r[6], r[7], tw.x, tw.y);
        float2 tw0 = Tg[8 + t3], tw1 = Tg[8 + t3 + 4];
        bfly_i(r[0], r[2], tw0.x, tw0.y);
        bfly_i(r[1], r[3], tw1.x, tw1.y);
        bfly_i(r[4], r[6], tw0.x, tw0.y);
        bfly_i(r[5], r[7], tw1.x, tw1.y);
    }
    #pragma unroll
    for (int u = 0; u < 4; ++u) {
        float2 tw = Tg[16 + t3 + 4 * u];
        bfly_i(r[u], r[u + 4], tw.x, tw.y);
    }
    #pragma unroll
    for (int u = 0; u < 8; ++u) cf[SW(d4 + 4 * u)] = r[u];
    __syncthreads();

    // ---- inverse G2': stages 5,6,7 ----
    #pragma unroll
    for (int u = 0; u < 8; ++u) r[u] = cf[SW(c32 + 32 * u)];
    {
        float2 tw = Tg[32 + t5];
        bfly_i(r[0], r[1], tw.x, tw.y);
        bfly_i(r[2], r[3], tw.x, tw.y);
        bfly_i(r[4], r[5], tw.x, tw.y);
        bfly_i(r[6], r[7], tw.x, tw.y);
        float2 tw0 = Tg[64 + t5], tw1 = Tg[64 + t5 + 32];
        bfly_i(r[0], r[2], tw0.x, tw0.y);
        bfly_i(r[1], r[3], tw1.x, tw1.y);
        bfly_i(r[4], r[6], tw0.x, tw0.y);
        bfly_i(r[5], r[7], tw1.x, tw1.y);
    }
    #pragma unroll
    for (int u = 0; u < 4; ++u) {
        float2 tw = Tg[128 + t5 + 32 * u];
        bfly_i(r[u], r[u + 4], tw.x, tw.y);
    }
    #pragma unroll
    for (int u = 0; u < 8; ++u) cf[SW(c32 + 32 * u)] = r[u];
    __syncthreads();

    // ---- inverse G1': stages 8,9,10 + scale + store ----
    #pragma unroll
    for (int u = 0; u < 8; ++u) r[u] = cf[SW(t + 256 * u)];
    {
        float2 tw = Tg[256 + t];
        bfly_i(r[0], r[1], tw.x, tw.y);
        bfly_i(r[2], r[3], tw.x, tw.y);
        bfly_i(r[4], r[5], tw.x, tw.y);
        bfly_i(r[6], r[7], tw.x, tw.y);
        float2 tw0 = Tg[512 + t], tw1 = Tg[512 + t + 256];
        bfly_i(r[0], r[2], tw0.x, tw0.y);
        bfly_i(r[1], r[3], tw1.x, tw1.y);
        bfly_i(r[4], r[6], tw0.x, tw0.y);
        bfly_i(r[5], r[7], tw1.x, tw1.y);
    }
    #pragma unroll
    for (int u = 0; u < 4; ++u) {
        float2 tw = Tg[1024 + t + 256 * u];
        bfly_i(r[u], r[u + 4], tw.x, tw.y);
    }
    const float s32 = 1.0f / 32.0f;  // 64 (ortho) / 2048 (ifft norm)
    #pragma unroll
    for (int u = 0; u < 8; ++u)
        seq[t + 256 * u] = make_float2(r[u].x * s32, r[u].y * s32);
}

extern "C" void kernel_launch(void* const* d_in, const int* in_sizes, int n_in,
                              void* d_out, int out_size, void* d_ws, size_t ws_size,
                              hipStream_t stream) {
    const float* x        = (const float*)d_in[0];
    const float* W_q      = (const float*)d_in[1];
    const float* W_v      = (const float*)d_in[2];
    const float* W_o      = (const float*)d_in[3];
    const float* ln_gamma = (const float*)d_in[4];
    const float* ln_beta  = (const float*)d_in[5];
    const float* mlp_w1   = (const float*)d_in[6];
    const float* mlp_b1   = (const float*)d_in[7];
    const float* mlp_w2   = (const float*)d_in[8];
    const float* mlp_b2   = (const float*)d_in[9];
    const float* mod_bias = (const float*)d_in[10];
    float* out = (float*)d_out;

    // workspace layout (floats)
    float* ws = (float*)d_ws;
    float* partial  = ws;                    // 262144
    float* xsum     = ws + 262144;           // 4096
    float* q_shared = ws + 266240;           // 256
    float* hdn      = ws + 266496;           // 4096
    float* gri      = ws + 270592;           // 16392 (ends 286984)
    float* mq       = ws + 286984;           // 4096 (ends 291080)
    float2* twid    = (float2*)(ws + 291080); // 3072 float2 (ends 297224)
    float* buf0     = ws + 297984;           // 16777216 floats (64 MiB), [1024][16384]
    u16* bfbase = (u16*)(ws + 297984 + 16777216);
    u16* xut_hi = bfbase;                    // 16777216 u16: x_hi, later reused as ut
    u16* x_lo   = bfbase + 16777216;         // x_lo (dead after V GEMM)
    u16* wv_hi  = bfbase + 33554432;         // 1048576
    u16* wv_lo  = bfbase + 34603008;
    u16* wo_hi  = bfbase + 35651584;
    u16* wo_lo  = bfbase + 36700160;

    twiddle_init_kernel<<<12, 256, 0, stream>>>(twid);

    // fused x split + colsum pass 1
    split_x_colsum_kernel<<<256, 256, 0, stream>>>(x, xut_hi, x_lo, partial);
    {
        dim3 g(4, 4);
        colsum2_kernel<<<g, 256, 0, stream>>>(partial, xsum);
    }
    gates1a_kernel<<<256, 256, 0, stream>>>(xsum, W_q, mq);
    gates1b_kernel<<<4, 256, 0, stream>>>(mq, ln_gamma, ln_beta, q_shared);
    gates2_kernel<<<16, 256, 0, stream>>>(q_shared, mlp_w1, mlp_b1, hdn);
    gates3_kernel<<<1025, 256, 0, stream>>>(hdn, mlp_w2, mlp_b2, gri);

    // weight splits
    split_kernel<<<1024, 256, 0, stream>>>(W_v, wv_hi, wv_lo, 262144);
    split_kernel<<<1024, 256, 0, stream>>>(W_o, wo_hi, wo_lo, 262144);

    // V projection (transposed output): buf0[j][bs] = sum_k Wv[j,k]*x[bs,k]
    // M=1024 (j), N=16384 (bs): mtiles=4, ntiles=64 -> 256 blocks
    gemm_split256_kernel<<<256, 512, 0, stream>>>(wv_hi, wv_lo, xut_hi, x_lo,
                                                  buf0, 4, 64, 1024, 16384);

    // fused spectral mixing, in place
    fft_gates_kernel<<<4096, 256, 0, stream>>>(buf0, gri, mod_bias, twid);

    // transpose u (hi only): buf0 [1024][16384] f32 -> ut bf16 [16384][1024]
    {
        dim3 g(256, 16);
        transpose_hi_kernel<<<g, 256, 0, stream>>>(buf0, xut_hi);
    }

    // O projection: out[bs][jo] = sum_j ut[bs][j]*Wo[jo][j]   (2-product)
    // M=16384 (bs), N=1024 (jo): mtiles=64, ntiles=4 -> 256 blocks
    gemm_out2_kernel<<<256, 512, 0, stream>>>(xut_hi, wo_hi, wo_lo,
                                              out, 64, 4, 1024, 1024);
}

// Round 8
// 270.198 us; speedup vs baseline: 4.8412x; 1.0752x over previous
//
#include <hip/hip_runtime.h>
#include <math.h>
#include <stdint.h>

#define PI_F 3.14159265358979323846f

// Problem constants
#define BB 4
#define SS 4096
#define DD 1024
#define HH 16
#define DHD 64
#define NFREQ 2049   // 4096/2 + 1
#define MHALF 2048   // half-size complex FFT length

typedef unsigned short u16;
typedef __attribute__((ext_vector_type(8))) short short8;   // 8 bf16 = 4 VGPR (MFMA A/B frag)
typedef __attribute__((ext_vector_type(4))) float f32x4;    // MFMA C/D frag
typedef __attribute__((ext_vector_type(4))) unsigned short u16x4;

// ---- bf16 helpers (RTNE) ----
__device__ __forceinline__ u16 f2bf(float f) {
    unsigned u = __float_as_uint(f);
    unsigned r = (u + 0x7FFFu + ((u >> 16) & 1u)) >> 16;
    return (u16)r;
}
__device__ __forceinline__ float bf2f(u16 h) { return __uint_as_float(((unsigned)h) << 16); }

__device__ __forceinline__ void modrelu_apply(float& zr, float& zi, float bias) {
    float mag = sqrtf(zr * zr + zi * zi);
    float scale = fmaxf(mag + bias, 0.0f) / fmaxf(mag, 1e-12f);
    zr *= scale; zi *= scale;
}

// async global->LDS, 16B per lane (HW: dest = wave-uniform base + lane*16)
__device__ __forceinline__ void gload16(const u16* g, u16* l) {
    __builtin_amdgcn_global_load_lds(
        (const __attribute__((address_space(1))) void*)g,
        (__attribute__((address_space(3))) void*)l, 16, 0, 0);
}

// LDS byte-offset swizzle for GEMM staging (16B chunks): XOR chunk bits [4:3]
// into chunk bits [1:0]; involution, matches the pre-swizzled staging order.
__device__ __forceinline__ int swz(int byteoff) {
    return byteoff ^ (((byteoff >> 7) & 3) << 4);
}

#define MFMA_BF16 __builtin_amdgcn_mfma_f32_16x16x32_bf16

// ---------------- fused x -> bf16 hi/lo split + column partial sums -----------
// grid 256 = (b, s-chunk of 64); thread t owns columns 4t..4t+3
__global__ __launch_bounds__(256)
void split_x_colsum_kernel(const float* __restrict__ x, u16* __restrict__ hi,
                           u16* __restrict__ lo, float* __restrict__ partial) {
    int blk = blockIdx.x;
    int b = blk >> 6;
    int s0 = (blk & 63) * 64;
    int t = threadIdx.x;
    const float* xp = x + ((size_t)b * SS + s0) * DD;
    float4 acc = make_float4(0.f, 0.f, 0.f, 0.f);
    for (int s = 0; s < 64; ++s) {
        float4 v = ((const float4*)(xp + (size_t)s * DD))[t];
        acc.x += v.x; acc.y += v.y; acc.z += v.z; acc.w += v.w;
        u16x4 h, l;
        h.x = f2bf(v.x); h.y = f2bf(v.y); h.z = f2bf(v.z); h.w = f2bf(v.w);
        l.x = f2bf(v.x - bf2f(h.x));
        l.y = f2bf(v.y - bf2f(h.y));
        l.z = f2bf(v.z - bf2f(h.z));
        l.w = f2bf(v.w - bf2f(h.w));
        size_t rowo = (size_t)(b * SS + s0 + s) * DD;
        ((u16x4*)(hi + rowo))[t] = h;
        ((u16x4*)(lo + rowo))[t] = l;
    }
    ((float4*)(partial + (size_t)blk * DD))[t] = acc;
}

__global__ __launch_bounds__(256)
void colsum2_kernel(const float* __restrict__ partial, float* __restrict__ xsum) {
    int b = blockIdx.y;
    int k = blockIdx.x * 256 + threadIdx.x;
    float acc = 0.f;
    for (int c = 0; c < 64; ++c)
        acc += partial[((size_t)(b * 64 + c)) * DD + k];
    xsum[b * DD + k] = acc;
}

// ---------------- mq[b][j] = dot(xsum[b]/S, Wq[j]) ; grid 256, 1 wave per row j
__global__ __launch_bounds__(256)
void gates1a_kernel(const float* __restrict__ xsum, const float* __restrict__ Wq,
                    float* __restrict__ mq) {
    __shared__ float xb[4][1024];
    int t = threadIdx.x;
    for (int i = t; i < 4096; i += 256)
        xb[i >> 10][i & 1023] = xsum[i] * (1.0f / 4096.0f);
    __syncthreads();
    int wv = t >> 6, l = t & 63;
    int j = blockIdx.x * 4 + wv;
    const float* wrow = Wq + (size_t)j * DD;
    float a0 = 0.f, a1 = 0.f, a2 = 0.f, a3 = 0.f;
    #pragma unroll 4
    for (int it = 0; it < 16; ++it) {
        int idx = l + it * 64;
        float wval = wrow[idx];
        a0 += xb[0][idx] * wval;
        a1 += xb[1][idx] * wval;
        a2 += xb[2][idx] * wval;
        a3 += xb[3][idx] * wval;
    }
    for (int off = 32; off > 0; off >>= 1) {
        a0 += __shfl_down(a0, off, 64);
        a1 += __shfl_down(a1, off, 64);
        a2 += __shfl_down(a2, off, 64);
        a3 += __shfl_down(a3, off, 64);
    }
    if (l == 0) {
        mq[j] = a0; mq[1024 + j] = a1; mq[2048 + j] = a2; mq[3072 + j] = a3;
    }
}

// ---------------- LayerNorm per head over mq, mean over heads -> q_shared[b][64]
__global__ __launch_bounds__(256)
void gates1b_kernel(const float* __restrict__ mq, const float* __restrict__ gamma,
                    const float* __restrict__ beta, float* __restrict__ q_shared) {
    __shared__ float qacc[4][64];
    int b = blockIdx.x;
    int t = threadIdx.x;
    int wv = t >> 6, l = t & 63;
    float part = 0.f;
    for (int hh = 0; hh < 4; ++hh) {
        int h = wv * 4 + hh;
        float v = mq[b * 1024 + h * 64 + l];
        float s1 = v, s2 = v * v;
        for (int off = 32; off > 0; off >>= 1) {
            s1 += __shfl_xor(s1, off, 64);
            s2 += __shfl_xor(s2, off, 64);
        }
        float mu = s1 * (1.0f / 64.0f);
        float var = s2 * (1.0f / 64.0f) - mu * mu;
        part += (v - mu) * rsqrtf(var + 1e-5f) * gamma[l] + beta[l];
    }
    qacc[wv][l] = part;
    __syncthreads();
    if (t < 64) {
        float s = qacc[0][t] + qacc[1][t] + qacc[2][t] + qacc[3][t];
        q_shared[b * 64 + t] = s * (1.0f / 16.0f);
    }
}

// ---------------- hdn = gelu(q_shared @ w1^T + b1)
__global__ __launch_bounds__(256)
void gates2_kernel(const float* __restrict__ q_shared, const float* __restrict__ w1,
                   const float* __restrict__ b1, float* __restrict__ hdn) {
    __shared__ float qs[64];
    int blk = blockIdx.x;
    int b = blk >> 2;
    int i0 = (blk & 3) * 256;
    int t = threadIdx.x;
    if (t < 64) qs[t] = q_shared[b * 64 + t];
    __syncthreads();
    int i = i0 + t;
    const float* wrow = w1 + (size_t)i * DHD;
    float acc = b1[i];
    #pragma unroll 8
    for (int d = 0; d < 64; ++d) acc += qs[d] * wrow[d];
    float g = 0.5f * acc * (1.0f + erff(acc * 0.70710678118654752f));
    hdn[b * DD + i] = g;
}

// ---------------- gri = hdn @ w2^T + b2 ; one wave per output row, all 4 b at once
__global__ __launch_bounds__(256)
void gates3_kernel(const float* __restrict__ hdn, const float* __restrict__ w2,
                   const float* __restrict__ b2, float* __restrict__ gri) {
    int t = threadIdx.x;
    int wv = t >> 6, l = t & 63;
    int r = blockIdx.x * 4 + wv;
    if (r >= 2 * NFREQ) return;
    const float* wrow = w2 + (size_t)r * DD;
    float a0 = 0.f, a1 = 0.f, a2 = 0.f, a3 = 0.f;
    for (int it = 0; it < 16; ++it) {
        int idx = l + it * 64;
        float wval = wrow[idx];
        a0 += hdn[idx] * wval;
        a1 += hdn[1024 + idx] * wval;
        a2 += hdn[2048 + idx] * wval;
        a3 += hdn[3072 + idx] * wval;
    }
    for (int off = 32; off > 0; off >>= 1) {
        a0 += __shfl_down(a0, off, 64);
        a1 += __shfl_down(a1, off, 64);
        a2 += __shfl_down(a2, off, 64);
        a3 += __shfl_down(a3, off, 64);
    }
    if (l == 0) {
        float bb = b2[r];
        gri[r] = a0 + bb;
        gri[2 * NFREQ + r] = a1 + bb;
        gri[2 * 2 * NFREQ + r] = a2 + bb;
        gri[3 * 2 * NFREQ + r] = a3 + bb;
    }
}

// ---------------- f32 -> (bf16 hi, bf16 lo) split (weights) ----------------
__global__ __launch_bounds__(256)
void split_kernel(const float* __restrict__ src, u16* __restrict__ hi,
                  u16* __restrict__ lo, int n4) {
    int idx = blockIdx.x * 256 + threadIdx.x;
    int stride = gridDim.x * 256;
    for (; idx < n4; idx += stride) {
        float4 v = ((const float4*)src)[idx];
        u16x4 h, l;
        h.x = f2bf(v.x); h.y = f2bf(v.y); h.z = f2bf(v.z); h.w = f2bf(v.w);
        l.x = f2bf(v.x - bf2f(h.x));
        l.y = f2bf(v.y - bf2f(h.y));
        l.z = f2bf(v.z - bf2f(h.z));
        l.w = f2bf(v.w - bf2f(h.w));
        ((u16x4*)hi)[idx] = h;
        ((u16x4*)lo)[idx] = l;
    }
}

// ---------------- transpose (hi only): src f32 [1024][16384] -> bf16 [16384][1024]
__global__ __launch_bounds__(256)
void transpose_hi_kernel(const float* __restrict__ src, u16* __restrict__ hi) {
    __shared__ float tile[64][65];
    int s0 = blockIdx.x * 64;   // bs block
    int j0 = blockIdx.y * 64;   // feature block
    int t = threadIdx.x;
    int c = t & 63, r4 = t >> 6;
    #pragma unroll
    for (int rr = 0; rr < 64; rr += 4)
        tile[rr + r4][c] = src[(size_t)(j0 + rr + r4) * 16384 + s0 + c];
    __syncthreads();
    #pragma unroll
    for (int rr = 0; rr < 64; rr += 4) {
        int a = rr + r4;                 // local bs
        float v = tile[c][a];            // = src[j0+c][s0+a]
        hi[(size_t)(s0 + a) * 1024 + j0 + c] = f2bf(v);
    }
}

// ---------------- 2-product MFMA GEMM, 256x256 tile, 3-deep pipeline ----------
// C[M][N] = A[M][K] * (Bh+Bl)[N][K]^T ; A single bf16 plane, B hi/lo planes.
// 512 threads = 8 waves (2M x 4N); per-wave 128x64 out = 8x4 frags of 16x16x32.
// LDS: 3 buffers x 3 planes x [256][32] bf16 = 144 KiB. Staging prefetches
// TWO tiles ahead (~7000 cyc of cover for HBM-miss latency); per-tile wait is
// counted vmcnt(6) (this wave's next-tile loads), never a full drain until the
// tail. One barrier per tile.
__global__ __launch_bounds__(512, 2)
void gemm_2p_kernel(const u16* __restrict__ A, const u16* __restrict__ Bh,
                    const u16* __restrict__ Bl, float* __restrict__ C,
                    int mtiles, int ntiles, int K, int ldc) {
    __shared__ u16 lds[3][3][8192];   // [buf][plane: A,Bh,Bl][256 rows x 32 k]
    const int t = threadIdx.x;
    const int wid = __builtin_amdgcn_readfirstlane(t >> 6);
    const int lane = t & 63;

    // XCD-aware decode (blocks dispatch round-robin over 8 XCDs)
    const int bid = blockIdx.x;
    const int xcd = bid & 7;
    const int idx = bid >> 3;
    int mt, nt;
    if (ntiles >= mtiles) { mt = idx % mtiles; nt = xcd * (ntiles >> 3) + idx / mtiles; }
    else                  { nt = idx % ntiles; mt = xcd * (mtiles >> 3) + idx / ntiles; }
    const int m0 = mt * 256;
    const int n0 = nt * 256;
    const int wm = (wid >> 2) * 128;
    const int wn = (wid & 3) * 64;

    // staging: 48 chunk-ops of 1KB per tile (wave w gets ops g = w*6..w*6+5)
    const u16* gbase[6];
    u16* ldst[6];
    #pragma unroll
    for (int o = 0; o < 6; ++o) {
        int g = wid * 6 + o;
        int p = g >> 4;
        int j = ((g & 15) << 6) | lane;
        int c = j ^ ((j >> 3) & 3);
        int row = c >> 2, q = c & 3;
        const u16* base = (p == 0) ? A : (p == 1) ? Bh : Bl;
        int rbase = (p == 0) ? m0 : n0;
        gbase[o] = base + (size_t)(rbase + row) * K + q * 8;
        ldst[o] = &lds[0][0][0] + (size_t)p * 8192 + (size_t)j * 8;
    }

#define STG(KT, BUF)                                                             \
    {                                                                            \
        _Pragma("unroll")                                                        \
        for (int o = 0; o < 6; ++o)                                              \
            gload16(gbase[o] + (size_t)(KT) * 32, ldst[o] + (BUF) * 24576);      \
    }

    f32x4 acc[8][4] = {};
    const int KT = K >> 5;

    // prologue: stage tiles 0 and 1; wait for tile 0 only (6 newest may fly)
    STG(0, 0);
    STG(1, 1);
    asm volatile("s_waitcnt vmcnt(6)" ::: "memory");
    __builtin_amdgcn_s_barrier();

    for (int kt = 0; kt < KT; ++kt) {
        const int cb = kt % 3;
        const u16* lb = &lds[cb][0][0];
        // issue stage for tile kt+2 first: longest latency cover
        if (kt + 2 < KT) {
            const int pb = (kt + 2) % 3;
            STG(kt + 2, pb);
        }

        short8 bh[4], bl[4];
        #pragma unroll
        for (int j = 0; j < 4; ++j) {
            int s = swz((wn + (lane & 15) + j * 16) * 64 + (lane >> 4) * 16);
            bh[j] = *(const short8*)(lb + 8192 + (s >> 1));
            bl[j] = *(const short8*)(lb + 2 * 8192 + (s >> 1));
        }
        __builtin_amdgcn_s_setprio(1);
        #pragma unroll
        for (int ip = 0; ip < 4; ++ip) {
            int s0 = swz((wm + (lane & 15) + (2 * ip) * 16) * 64 + (lane >> 4) * 16);
            int s1 = swz((wm + (lane & 15) + (2 * ip + 1) * 16) * 64 + (lane >> 4) * 16);
            short8 a0 = *(const short8*)(lb + (s0 >> 1));
            short8 a1 = *(const short8*)(lb + (s1 >> 1));
            #pragma unroll
            for (int j = 0; j < 4; ++j) acc[2 * ip][j]     = MFMA_BF16(a0, bl[j], acc[2 * ip][j], 0, 0, 0);
            #pragma unroll
            for (int j = 0; j < 4; ++j) acc[2 * ip + 1][j] = MFMA_BF16(a1, bl[j], acc[2 * ip + 1][j], 0, 0, 0);
            #pragma unroll
            for (int j = 0; j < 4; ++j) acc[2 * ip][j]     = MFMA_BF16(a0, bh[j], acc[2 * ip][j], 0, 0, 0);
            #pragma unroll
            for (int j = 0; j < 4; ++j) acc[2 * ip + 1][j] = MFMA_BF16(a1, bh[j], acc[2 * ip + 1][j], 0, 0, 0);
        }
        __builtin_amdgcn_s_setprio(0);
        // make buffer kt+1 ready: wait until only tile kt+2's 6 loads remain
        if (kt + 2 < KT) { asm volatile("s_waitcnt vmcnt(6)" ::: "memory"); }
        else             { asm volatile("s_waitcnt vmcnt(0)" ::: "memory"); }
        __builtin_amdgcn_s_barrier();
    }
#undef STG

    // epilogue: C/D layout = col (lane&15), row (lane>>4)*4 + e   [m89-verified]
    const int cb2 = n0 + wn + (lane & 15);
    #pragma unroll
    for (int i = 0; i < 8; ++i) {
        int rb = m0 + wm + i * 16 + ((lane >> 4) << 2);
        #pragma unroll
        for (int e = 0; e < 4; ++e) {
            float* crow = C + (size_t)(rb + e) * ldc + cb2;
            #pragma unroll
            for (int j = 0; j < 4; ++j)
                crow[j * 16] = acc[i][j][e];
        }
    }
}

// ---------------- twiddle table init (global, shared by all FFT blocks) -------
__global__ __launch_bounds__(256)
void twiddle_init_kernel(float2* __restrict__ Tg) {
    int idx = blockIdx.x * 256 + threadIdx.x;
    if (idx >= 3072) return;
    float cs = 1.f, sn = 0.f;
    if (idx >= 2048) {
        sincosf(PI_F * (float)(idx - 2048) * (1.0f / 2048.0f), &sn, &cs);
    } else if (idx >= 1) {
        int s = 31 - __clz(idx);
        int h = 1 << s;
        sincosf(PI_F * (float)(idx - h) / (float)h, &sn, &cs);
    }
    Tg[idx] = make_float2(cs, sn);
}

__device__ __forceinline__ void bfly_f(float2& a, float2& b, float cs, float sn) {
    float2 s = make_float2(a.x + b.x, a.y + b.y);
    float2 d = make_float2(a.x - b.x, a.y - b.y);
    a = s;
    b = make_float2(d.x * cs + d.y * sn, d.y * cs - d.x * sn);
}
__device__ __forceinline__ void bfly_i(float2& a, float2& b, float cs, float sn) {
    float cr = b.x * cs - b.y * sn;
    float ci = b.x * sn + b.y * cs;
    float2 a0 = a;
    a = make_float2(a0.x + cr, a0.y + ci);
    b = make_float2(a0.x - cr, a0.y - ci);
}
__device__ __forceinline__ int SW(int a) { return a ^ ((a >> 5) & 15); }

// ---------------- fused rfft -> gates -> modReLU -> irfft, in-place per sequence
__global__ __launch_bounds__(256)
void fft_gates_kernel(float* __restrict__ buf, const float* __restrict__ gri,
                      const float* __restrict__ modb, const float2* __restrict__ Tg) {
    __shared__ float2 cf[MHALF];
    const int t = threadIdx.x;
    const int w = blockIdx.x;
    const int b = w & 3;
    float2* seq = (float2*)(buf + (size_t)w * SS);

    const int t5 = t & 31;
    const int t3 = t & 3;
    const int c32 = ((t >> 5) << 8) | t5;    // base for 32-span group
    const int d4  = ((t >> 2) << 5) | t3;    // base for 4-span group

    float2 r[8];

    // ---- load + G1: stages 10,9,8 (span 256) ----
    #pragma unroll
    for (int u = 0; u < 8; ++u) r[u] = seq[t + 256 * u];
    #pragma unroll
    for (int u = 0; u < 4; ++u) {
        float2 tw = Tg[1024 + t + 256 * u];
        bfly_f(r[u], r[u + 4], tw.x, tw.y);
    }
    {
        float2 tw0 = Tg[512 + t], tw1 = Tg[512 + t + 256];
        bfly_f(r[0], r[2], tw0.x, tw0.y);
        bfly_f(r[1], r[3], tw1.x, tw1.y);
        bfly_f(r[4], r[6], tw0.x, tw0.y);
        bfly_f(r[5], r[7], tw1.x, tw1.y);
        float2 tw = Tg[256 + t];
        bfly_f(r[0], r[1], tw.x, tw.y);
        bfly_f(r[2], r[3], tw.x, tw.y);
        bfly_f(r[4], r[5], tw.x, tw.y);
        bfly_f(r[6], r[7], tw.x, tw.y);
    }
    #pragma unroll
    for (int u = 0; u < 8; ++u) cf[SW(t + 256 * u)] = r[u];
    __syncthreads();

    // ---- G2: stages 7,6,5 (span 32) ----
    #pragma unroll
    for (int u = 0; u < 8; ++u) r[u] = cf[SW(c32 + 32 * u)];
    #pragma unroll
    for (int u = 0; u < 4; ++u) {
        float2 tw = Tg[128 + t5 + 32 * u];
        bfly_f(r[u], r[u + 4], tw.x, tw.y);
    }
    {
        float2 tw0 = Tg[64 + t5], tw1 = Tg[64 + t5 + 32];
        bfly_f(r[0], r[2], tw0.x, tw0.y);
        bfly_f(r[1], r[3], tw1.x, tw1.y);
        bfly_f(r[4], r[6], tw0.x, tw0.y);
        bfly_f(r[5], r[7], tw1.x, tw1.y);
        float2 tw = Tg[32 + t5];
        bfly_f(r[0], r[1], tw.x, tw.y);
        bfly_f(r[2], r[3], tw.x, tw.y);
        bfly_f(r[4], r[5], tw.x, tw.y);
        bfly_f(r[6], r[7], tw.x, tw.y);
    }
    #pragma unroll
    for (int u = 0; u < 8; ++u) cf[SW(c32 + 32 * u)] = r[u];
    __syncthreads();

    // ---- G3: stages 4,3,2 (span 4) ----
    #pragma unroll
    for (int u = 0; u < 8; ++u) r[u] = cf[SW(d4 + 4 * u)];
    #pragma unroll
    for (int u = 0; u < 4; ++u) {
        float2 tw = Tg[16 + t3 + 4 * u];
        bfly_f(r[u], r[u + 4], tw.x, tw.y);
    }
    {
        float2 tw0 = Tg[8 + t3], tw1 = Tg[8 + t3 + 4];
        bfly_f(r[0], r[2], tw0.x, tw0.y);
        bfly_f(r[1], r[3], tw1.x, tw1.y);
        bfly_f(r[4], r[6], tw0.x, tw0.y);
        bfly_f(r[5], r[7], tw1.x, tw1.y);
        float2 tw = Tg[4 + t3];
        bfly_f(r[0], r[1], tw.x, tw.y);
        bfly_f(r[2], r[3], tw.x, tw.y);
        bfly_f(r[4], r[5], tw.x, tw.y);
        bfly_f(r[6], r[7], tw.x, tw.y);
    }
    #pragma unroll
    for (int u = 0; u < 8; ++u) cf[SW(d4 + 4 * u)] = r[u];
    __syncthreads();

    // ---- G4: stages 1,0 (span 1; 8 consecutive) ----
    #pragma unroll
    for (int u = 0; u < 8; ++u) r[u] = cf[SW(8 * t + u)];
    bfly_f(r[0], r[2], 1.f, 0.f);
    bfly_f(r[1], r[3], 0.f, 1.f);
    bfly_f(r[4], r[6], 1.f, 0.f);
    bfly_f(r[5], r[7], 0.f, 1.f);
    bfly_f(r[0], r[1], 1.f, 0.f);
    bfly_f(r[2], r[3], 1.f, 0.f);
    bfly_f(r[4], r[5], 1.f, 0.f);
    bfly_f(r[6], r[7], 1.f, 0.f);
    #pragma unroll
    for (int u = 0; u < 8; ++u) cf[SW(8 * t + u)] = r[u];
    __syncthreads();

    // ---- spectrum: unpack real-FFT bins (ortho /64), gates, modReLU, repack ----
    const float bias = modb[0];
    const float* gre = gri + (size_t)b * 2 * NFREQ;
    const float* gim = gre + NFREQ;
    const float inv64 = 1.0f / 64.0f;
    for (int k = t; k < 1024; k += 256) {
        if (k == 0) {
            float2 c0 = cf[SW(0)];
            float z0 = (c0.x + c0.y) * inv64;
            float zM = (c0.x - c0.y) * inv64;
            float zr = z0 * gre[0], zi = z0 * gim[0];
            modrelu_apply(zr, zi, bias);
            float yr = zM * gre[2048], yi = zM * gim[2048];
            modrelu_apply(yr, yi, bias);
            cf[SW(0)] = make_float2(0.5f * (zr + yr), 0.5f * (zr - yr));
            float2 c1 = cf[SW(1)];
            float z1r = c1.x * inv64, z1i = -c1.y * inv64;
            float g1r = gre[1024], g1i = gim[1024];
            float pr = z1r * g1r - z1i * g1i;
            float pi2 = z1r * g1i + z1i * g1r;
            modrelu_apply(pr, pi2, bias);
            cf[SW(1)] = make_float2(pr, -pi2);
        } else {
            int kb = 2048 - k;
            int p1 = SW((int)(__brev((unsigned)k) >> 21));
            int p2 = SW((int)(__brev((unsigned)kb) >> 21));
            float2 ca = cf[p1];
            float2 cb2 = cf[p2];
            float Er = 0.5f * (ca.x + cb2.x), Ei = 0.5f * (ca.y - cb2.y);
            float Dr = 0.5f * (ca.x - cb2.x), Di = 0.5f * (ca.y + cb2.y);
            float Or = Di, Oi = -Dr;
            float2 t2 = Tg[2048 + k];
            float cs = t2.x, sn = t2.y;
            float Wr = cs, Wi = -sn;
            float WOr = Wr * Or - Wi * Oi, WOi = Wr * Oi + Wi * Or;
            float zkr = (Er + WOr) * inv64, zki = (Ei + WOi) * inv64;
            float zbr = (Er - WOr) * inv64, zbi = -(Ei - WOi) * inv64;
            float gkr = gre[k], gki = gim[k];
            float ar = zkr * gkr - zki * gki, ai = zkr * gki + zki * gkr;
            modrelu_apply(ar, ai, bias);
            float gbr = gre[kb], gbi = gim[kb];
            float br2 = zbr * gbr - zbi * gbi, bi2 = zbr * gbi + zbi * gbr;
            modrelu_apply(br2, bi2, bias);
            float Epr = 0.5f * (ar + br2), Epi = 0.5f * (ai - bi2);
            float Dpr = 0.5f * (ar - br2), Dpi = 0.5f * (ai + bi2);
            float Opr = cs * Dpr - sn * Dpi, Opi = cs * Dpi + sn * Dpr;
            cf[p1] = make_float2(Epr - Opi, Epi + Opr);
            cf[p2] = make_float2(Epr + Opi, -Epi + Opr);
        }
    }
    __syncthreads();

    // ---- inverse G4': stages 0,1 ----
    #pragma unroll
    for (int u = 0; u < 8; ++u) r[u] = cf[SW(8 * t + u)];
    bfly_i(r[0], r[1], 1.f, 0.f);
    bfly_i(r[2], r[3], 1.f, 0.f);
    bfly_i(r[4], r[5], 1.f, 0.f);
    bfly_i(r[6], r[7], 1.f, 0.f);
    bfly_i(r[0], r[2], 1.f, 0.f);
    bfly_i(r[1], r[3], 0.f, 1.f);
    bfly_i(r[4], r[6], 1.f, 0.f);
    bfly_i(r[5], r[7], 0.f, 1.f);
    #pragma unroll
    for (int u = 0; u < 8; ++u) cf[SW(8 * t + u)] = r[u];
    __syncthreads();

    // ---- inverse G3': stages 2,3,4 ----
    #pragma unroll
    for (int u = 0; u < 8; ++u) r[u] = cf[SW(d4 + 4 * u)];
    {
        float2 tw = Tg[4 + t3];
        bfly_i(r[0], r[1], tw.x, tw.y);
        bfly_i(r[2], r[3], tw.x, tw.y);
        bfly_i(r[4], r[5], tw.x, tw.y);
        bfly_i(r[6], r[7], tw.x, tw.y);
        float2 tw0 = Tg[8 + t3], tw1 = Tg[8 + t3 + 4];
        bfly_i(r[0], r[2], tw0.x, tw0.y);
        bfly_i(r[1], r[3], tw1.x, tw1.y);
        bfly_i(r[4], r[6], tw0.x, tw0.y);
        bfly_i(r[5], r[7], tw1.x, tw1.y);
    }
    #pragma unroll
    for (int u = 0; u < 4; ++u) {
        float2 tw = Tg[16 + t3 + 4 * u];
        bfly_i(r[u], r[u + 4], tw.x, tw.y);
    }
    #pragma unroll
    for (int u = 0; u < 8; ++u) cf[SW(d4 + 4 * u)] = r[u];
    __syncthreads();

    // ---- inverse G2': stages 5,6,7 ----
    #pragma unroll
    for (int u = 0; u < 8; ++u) r[u] = cf[SW(c32 + 32 * u)];
    {
        float2 tw = Tg[32 + t5];
        bfly_i(r[0], r[1], tw.x, tw.y);
        bfly_i(r[2], r[3], tw.x, tw.y);
        bfly_i(r[4], r[5], tw.x, tw.y);
        bfly_i(r[6], r[7], tw.x, tw.y);
        float2 tw0 = Tg[64 + t5], tw1 = Tg[64 + t5 + 32];
        bfly_i(r[0], r[2], tw0.x, tw0.y);
        bfly_i(r[1], r[3], tw1.x, tw1.y);
        bfly_i(r[4], r[6], tw0.x, tw0.y);
        bfly_i(r[5], r[7], tw1.x, tw1.y);
    }
    #pragma unroll
    for (int u = 0; u < 4; ++u) {
        float2 tw = Tg[128 + t5 + 32 * u];
        bfly_i(r[u], r[u + 4], tw.x, tw.y);
    }
    #pragma unroll
    for (int u = 0; u < 8; ++u) cf[SW(c32 + 32 * u)] = r[u];
    __syncthreads();

    // ---- inverse G1': stages 8,9,10 + scale + store ----
    #pragma unroll
    for (int u = 0; u < 8; ++u) r[u] = cf[SW(t + 256 * u)];
    {
        float2 tw = Tg[256 + t];
        bfly_i(r[0], r[1], tw.x, tw.y);
        bfly_i(r[2], r[3], tw.x, tw.y);
        bfly_i(r[4], r[5], tw.x, tw.y);
        bfly_i(r[6], r[7], tw.x, tw.y);
        float2 tw0 = Tg[512 + t], tw1 = Tg[512 + t + 256];
        bfly_i(r[0], r[2], tw0.x, tw0.y);
        bfly_i(r[1], r[3], tw1.x, tw1.y);
        bfly_i(r[4], r[6], tw0.x, tw0.y);
        bfly_i(r[5], r[7], tw1.x, tw1.y);
    }
    #pragma unroll
    for (int u = 0; u < 4; ++u) {
        float2 tw = Tg[1024 + t + 256 * u];
        bfly_i(r[u], r[u + 4], tw.x, tw.y);
    }
    const float s32 = 1.0f / 32.0f;  // 64 (ortho) / 2048 (ifft norm)
    #pragma unroll
    for (int u = 0; u < 8; ++u)
        seq[t + 256 * u] = make_float2(r[u].x * s32, r[u].y * s32);
}

extern "C" void kernel_launch(void* const* d_in, const int* in_sizes, int n_in,
                              void* d_out, int out_size, void* d_ws, size_t ws_size,
                              hipStream_t stream) {
    const float* x        = (const float*)d_in[0];
    const float* W_q      = (const float*)d_in[1];
    const float* W_v      = (const float*)d_in[2];
    const float* W_o      = (const float*)d_in[3];
    const float* ln_gamma = (const float*)d_in[4];
    const float* ln_beta  = (const float*)d_in[5];
    const float* mlp_w1   = (const float*)d_in[6];
    const float* mlp_b1   = (const float*)d_in[7];
    const float* mlp_w2   = (const float*)d_in[8];
    const float* mlp_b2   = (const float*)d_in[9];
    const float* mod_bias = (const float*)d_in[10];
    float* out = (float*)d_out;

    // workspace layout (floats)
    float* ws = (float*)d_ws;
    float* partial  = ws;                    // 262144
    float* xsum     = ws + 262144;           // 4096
    float* q_shared = ws + 266240;           // 256
    float* hdn      = ws + 266496;           // 4096
    float* gri      = ws + 270592;           // 16392 (ends 286984)
    float* mq       = ws + 286984;           // 4096 (ends 291080)
    float2* twid    = (float2*)(ws + 291080); // 3072 float2 (ends 297224)
    float* buf0     = ws + 297984;           // 16777216 floats (64 MiB), [1024][16384]
    u16* bfbase = (u16*)(ws + 297984 + 16777216);
    u16* xut_hi = bfbase;                    // 16777216 u16: x_hi, later reused as ut
    u16* x_lo   = bfbase + 16777216;         // x_lo (dead after V GEMM)
    u16* wv_hi  = bfbase + 33554432;         // 1048576
    u16* wv_lo  = bfbase + 34603008;         // written but unused (2-product V)
    u16* wo_hi  = bfbase + 35651584;
    u16* wo_lo  = bfbase + 36700160;

    twiddle_init_kernel<<<12, 256, 0, stream>>>(twid);

    // fused x split + colsum pass 1
    split_x_colsum_kernel<<<256, 256, 0, stream>>>(x, xut_hi, x_lo, partial);
    {
        dim3 g(4, 4);
        colsum2_kernel<<<g, 256, 0, stream>>>(partial, xsum);
    }
    gates1a_kernel<<<256, 256, 0, stream>>>(xsum, W_q, mq);
    gates1b_kernel<<<4, 256, 0, stream>>>(mq, ln_gamma, ln_beta, q_shared);
    gates2_kernel<<<16, 256, 0, stream>>>(q_shared, mlp_w1, mlp_b1, hdn);
    gates3_kernel<<<1025, 256, 0, stream>>>(hdn, mlp_w2, mlp_b2, gri);

    // weight splits
    split_kernel<<<1024, 256, 0, stream>>>(W_v, wv_hi, wv_lo, 262144);
    split_kernel<<<1024, 256, 0, stream>>>(W_o, wo_hi, wo_lo, 262144);

    // V projection (transposed output), 2-product: buf0[j][bs] = Wv_hi[j,:]·(x_hi+x_lo)[bs,:]
    // M=1024 (j), N=16384 (bs): mtiles=4, ntiles=64 -> 256 blocks
    gemm_2p_kernel<<<256, 512, 0, stream>>>(wv_hi, xut_hi, x_lo,
                                            buf0, 4, 64, 1024, 16384);

    // fused spectral mixing, in place
    fft_gates_kernel<<<4096, 256, 0, stream>>>(buf0, gri, mod_bias, twid);

    // transpose u (hi only): buf0 [1024][16384] f32 -> ut bf16 [16384][1024]
    {
        dim3 g(256, 16);
        transpose_hi_kernel<<<g, 256, 0, stream>>>(buf0, xut_hi);
    }

    // O projection, 2-product: out[bs][jo] = ut[bs,:]·(Wo_hi+Wo_lo)[jo,:]
    // M=16384 (bs), N=1024 (jo): mtiles=64, ntiles=4 -> 256 blocks
    gemm_2p_kernel<<<256, 512, 0, stream>>>(xut_hi, wo_hi, wo_lo,
                                            out, 64, 4, 1024, 1024);
}

// Round 9
// 269.604 us; speedup vs baseline: 4.8519x; 1.0022x over previous
//
#include <hip/hip_runtime.h>
#include <math.h>
#include <stdint.h>

#define PI_F 3.14159265358979323846f

// Problem constants
#define BB 4
#define SS 4096
#define DD 1024
#define HH 16
#define DHD 64
#define NFREQ 2049   // 4096/2 + 1
#define MHALF 2048   // half-size complex FFT length

typedef unsigned short u16;
typedef __attribute__((ext_vector_type(8))) short short8;   // 8 bf16 = 4 VGPR (MFMA A/B frag)
typedef __attribute__((ext_vector_type(4))) float f32x4;    // MFMA C/D frag
typedef __attribute__((ext_vector_type(4))) unsigned short u16x4;

// ---- bf16 helpers (RTNE) ----
__device__ __forceinline__ u16 f2bf(float f) {
    unsigned u = __float_as_uint(f);
    unsigned r = (u + 0x7FFFu + ((u >> 16) & 1u)) >> 16;
    return (u16)r;
}
__device__ __forceinline__ float bf2f(u16 h) { return __uint_as_float(((unsigned)h) << 16); }

__device__ __forceinline__ void modrelu_apply(float& zr, float& zi, float bias) {
    float mag = sqrtf(zr * zr + zi * zi);
    float scale = fmaxf(mag + bias, 0.0f) / fmaxf(mag, 1e-12f);
    zr *= scale; zi *= scale;
}

// async global->LDS, 16B per lane (HW: dest = wave-uniform base + lane*16)
__device__ __forceinline__ void gload16(const u16* g, u16* l) {
    __builtin_amdgcn_global_load_lds(
        (const __attribute__((address_space(1))) void*)g,
        (__attribute__((address_space(3))) void*)l, 16, 0, 0);
}

// LDS byte-offset swizzle for GEMM staging (16B chunks): XOR chunk bits [4:3]
// into chunk bits [1:0]; involution, matches the pre-swizzled staging order.
__device__ __forceinline__ int swz(int byteoff) {
    return byteoff ^ (((byteoff >> 7) & 3) << 4);
}

#define MFMA_BF16 __builtin_amdgcn_mfma_f32_16x16x32_bf16

// ---------------- fused x -> bf16 hi/lo split + column partial sums -----------
// grid 1024 = (b, s-chunk of 16); thread t owns columns 4t..4t+3
__global__ __launch_bounds__(256)
void split_x_colsum_kernel(const float* __restrict__ x, u16* __restrict__ hi,
                           u16* __restrict__ lo, float* __restrict__ partial) {
    int blk = blockIdx.x;
    int b = blk >> 8;
    int s0 = (blk & 255) * 16;
    int t = threadIdx.x;
    const float* xp = x + ((size_t)b * SS + s0) * DD;
    float4 acc = make_float4(0.f, 0.f, 0.f, 0.f);
    for (int s = 0; s < 16; ++s) {
        float4 v = ((const float4*)(xp + (size_t)s * DD))[t];
        acc.x += v.x; acc.y += v.y; acc.z += v.z; acc.w += v.w;
        u16x4 h, l;
        h.x = f2bf(v.x); h.y = f2bf(v.y); h.z = f2bf(v.z); h.w = f2bf(v.w);
        l.x = f2bf(v.x - bf2f(h.x));
        l.y = f2bf(v.y - bf2f(h.y));
        l.z = f2bf(v.z - bf2f(h.z));
        l.w = f2bf(v.w - bf2f(h.w));
        size_t rowo = (size_t)(b * SS + s0 + s) * DD;
        ((u16x4*)(hi + rowo))[t] = h;
        ((u16x4*)(lo + rowo))[t] = l;
    }
    ((float4*)(partial + (size_t)blk * DD))[t] = acc;
}

// grid (4 kchunks, 4 b); sums 256 partial rows per b
__global__ __launch_bounds__(256)
void colsum2_kernel(const float* __restrict__ partial, float* __restrict__ xsum) {
    int b = blockIdx.y;
    int k = blockIdx.x * 256 + threadIdx.x;
    float acc = 0.f;
    for (int c = 0; c < 256; ++c)
        acc += partial[((size_t)(b * 256 + c)) * DD + k];
    xsum[b * DD + k] = acc;
}

// ---------------- mq[b][j] = dot(xsum[b]/S, Wq[j]) ; grid 256, 1 wave per row j
__global__ __launch_bounds__(256)
void gates1a_kernel(const float* __restrict__ xsum, const float* __restrict__ Wq,
                    float* __restrict__ mq) {
    __shared__ float xb[4][1024];
    int t = threadIdx.x;
    for (int i = t; i < 4096; i += 256)
        xb[i >> 10][i & 1023] = xsum[i] * (1.0f / 4096.0f);
    __syncthreads();
    int wv = t >> 6, l = t & 63;
    int j = blockIdx.x * 4 + wv;
    const float* wrow = Wq + (size_t)j * DD;
    float a0 = 0.f, a1 = 0.f, a2 = 0.f, a3 = 0.f;
    #pragma unroll 4
    for (int it = 0; it < 16; ++it) {
        int idx = l + it * 64;
        float wval = wrow[idx];
        a0 += xb[0][idx] * wval;
        a1 += xb[1][idx] * wval;
        a2 += xb[2][idx] * wval;
        a3 += xb[3][idx] * wval;
    }
    for (int off = 32; off > 0; off >>= 1) {
        a0 += __shfl_down(a0, off, 64);
        a1 += __shfl_down(a1, off, 64);
        a2 += __shfl_down(a2, off, 64);
        a3 += __shfl_down(a3, off, 64);
    }
    if (l == 0) {
        mq[j] = a0; mq[1024 + j] = a1; mq[2048 + j] = a2; mq[3072 + j] = a3;
    }
}

// ---------------- LayerNorm per head over mq, mean over heads -> q_shared[b][64]
__global__ __launch_bounds__(256)
void gates1b_kernel(const float* __restrict__ mq, const float* __restrict__ gamma,
                    const float* __restrict__ beta, float* __restrict__ q_shared) {
    __shared__ float qacc[4][64];
    int b = blockIdx.x;
    int t = threadIdx.x;
    int wv = t >> 6, l = t & 63;
    float part = 0.f;
    for (int hh = 0; hh < 4; ++hh) {
        int h = wv * 4 + hh;
        float v = mq[b * 1024 + h * 64 + l];
        float s1 = v, s2 = v * v;
        for (int off = 32; off > 0; off >>= 1) {
            s1 += __shfl_xor(s1, off, 64);
            s2 += __shfl_xor(s2, off, 64);
        }
        float mu = s1 * (1.0f / 64.0f);
        float var = s2 * (1.0f / 64.0f) - mu * mu;
        part += (v - mu) * rsqrtf(var + 1e-5f) * gamma[l] + beta[l];
    }
    qacc[wv][l] = part;
    __syncthreads();
    if (t < 64) {
        float s = qacc[0][t] + qacc[1][t] + qacc[2][t] + qacc[3][t];
        q_shared[b * 64 + t] = s * (1.0f / 16.0f);
    }
}

// ---------------- hdn = gelu(q_shared @ w1^T + b1)
__global__ __launch_bounds__(256)
void gates2_kernel(const float* __restrict__ q_shared, const float* __restrict__ w1,
                   const float* __restrict__ b1, float* __restrict__ hdn) {
    __shared__ float qs[64];
    int blk = blockIdx.x;
    int b = blk >> 2;
    int i0 = (blk & 3) * 256;
    int t = threadIdx.x;
    if (t < 64) qs[t] = q_shared[b * 64 + t];
    __syncthreads();
    int i = i0 + t;
    const float* wrow = w1 + (size_t)i * DHD;
    float acc = b1[i];
    #pragma unroll 8
    for (int d = 0; d < 64; ++d) acc += qs[d] * wrow[d];
    float g = 0.5f * acc * (1.0f + erff(acc * 0.70710678118654752f));
    hdn[b * DD + i] = g;
}

// ---------------- gri = hdn @ w2^T + b2 ; one wave per output row, all 4 b at once
__global__ __launch_bounds__(256)
void gates3_kernel(const float* __restrict__ hdn, const float* __restrict__ w2,
                   const float* __restrict__ b2, float* __restrict__ gri) {
    int t = threadIdx.x;
    int wv = t >> 6, l = t & 63;
    int r = blockIdx.x * 4 + wv;
    if (r >= 2 * NFREQ) return;
    const float* wrow = w2 + (size_t)r * DD;
    float a0 = 0.f, a1 = 0.f, a2 = 0.f, a3 = 0.f;
    for (int it = 0; it < 16; ++it) {
        int idx = l + it * 64;
        float wval = wrow[idx];
        a0 += hdn[idx] * wval;
        a1 += hdn[1024 + idx] * wval;
        a2 += hdn[2048 + idx] * wval;
        a3 += hdn[3072 + idx] * wval;
    }
    for (int off = 32; off > 0; off >>= 1) {
        a0 += __shfl_down(a0, off, 64);
        a1 += __shfl_down(a1, off, 64);
        a2 += __shfl_down(a2, off, 64);
        a3 += __shfl_down(a3, off, 64);
    }
    if (l == 0) {
        float bb = b2[r];
        gri[r] = a0 + bb;
        gri[2 * NFREQ + r] = a1 + bb;
        gri[2 * 2 * NFREQ + r] = a2 + bb;
        gri[3 * 2 * NFREQ + r] = a3 + bb;
    }
}

// ---------------- f32 -> (bf16 hi, bf16 lo) split (weights) ----------------
__global__ __launch_bounds__(256)
void split_kernel(const float* __restrict__ src, u16* __restrict__ hi,
                  u16* __restrict__ lo, int n4) {
    int idx = blockIdx.x * 256 + threadIdx.x;
    int stride = gridDim.x * 256;
    for (; idx < n4; idx += stride) {
        float4 v = ((const float4*)src)[idx];
        u16x4 h, l;
        h.x = f2bf(v.x); h.y = f2bf(v.y); h.z = f2bf(v.z); h.w = f2bf(v.w);
        l.x = f2bf(v.x - bf2f(h.x));
        l.y = f2bf(v.y - bf2f(h.y));
        l.z = f2bf(v.z - bf2f(h.z));
        l.w = f2bf(v.w - bf2f(h.w));
        ((u16x4*)hi)[idx] = h;
        ((u16x4*)lo)[idx] = l;
    }
}

// ---------------- u16 transpose: src [1024][16384] -> dst [16384][1024] -------
__global__ __launch_bounds__(256)
void transpose_u16_kernel(const u16* __restrict__ src, u16* __restrict__ dst) {
    __shared__ u16 tile[64][66];
    int s0 = blockIdx.x * 64;   // bs block
    int j0 = blockIdx.y * 64;   // feature block
    int t = threadIdx.x;
    int c = t & 63, r4 = t >> 6;
    #pragma unroll
    for (int rr = 0; rr < 64; rr += 4)
        tile[rr + r4][c] = src[(size_t)(j0 + rr + r4) * 16384 + s0 + c];
    __syncthreads();
    #pragma unroll
    for (int rr = 0; rr < 64; rr += 4) {
        int a = rr + r4;                 // local bs
        dst[(size_t)(s0 + a) * 1024 + j0 + c] = tile[c][a];
    }
}

// ---------------- 2-product MFMA GEMM, 256x256 tile, 3-deep + 4-phase ---------
// C[M][N] = A[M][K] * (Bh+Bl)[N][K]^T ; A single bf16 plane, B hi/lo planes.
// 512 threads = 8 waves (2M x 4N); per-wave 128x64 out = 8x4 frags of 16x16x32.
// LDS: 3 buffers x 3 planes x [256][32] bf16 = 144 KiB; staging prefetches two
// tiles ahead; per-tile wait is counted vmcnt(6) (never drains same-tile loads).
// Each K-tile runs as 4 quadrant-phases {8 ds_read + 1-2 stage-gloads ->
// s_barrier -> setprio(1) 16 MFMA setprio(0) -> s_barrier}: phase p+1's LDS
// reads issue while phase p's MFMAs drain (m201-style interleave).
__global__ __launch_bounds__(512, 2)
void gemm_2p_kernel(const u16* __restrict__ A, const u16* __restrict__ Bh,
                    const u16* __restrict__ Bl, float* __restrict__ C,
                    int mtiles, int ntiles, int K, int ldc) {
    __shared__ u16 lds[3][3][8192];   // [buf][plane: A,Bh,Bl][256 rows x 32 k]
    const int t = threadIdx.x;
    const int wid = __builtin_amdgcn_readfirstlane(t >> 6);
    const int lane = t & 63;

    // XCD-aware decode (blocks dispatch round-robin over 8 XCDs)
    const int bid = blockIdx.x;
    const int xcd = bid & 7;
    const int idx = bid >> 3;
    int mt, nt;
    if (ntiles >= mtiles) { mt = idx % mtiles; nt = xcd * (ntiles >> 3) + idx / mtiles; }
    else                  { nt = idx % ntiles; mt = xcd * (mtiles >> 3) + idx / ntiles; }
    const int m0 = mt * 256;
    const int n0 = nt * 256;
    const int wm = (wid >> 2) * 128;
    const int wn = (wid & 3) * 64;

    // staging: 48 chunk-ops of 1KB per tile (wave w gets ops g = w*6..w*6+5)
    const u16* gbase[6];
    u16* ldst[6];
    #pragma unroll
    for (int o = 0; o < 6; ++o) {
        int g = wid * 6 + o;
        int p = g >> 4;
        int j = ((g & 15) << 6) | lane;
        int c = j ^ ((j >> 3) & 3);
        int row = c >> 2, q = c & 3;
        const u16* base = (p == 0) ? A : (p == 1) ? Bh : Bl;
        int rbase = (p == 0) ? m0 : n0;
        gbase[o] = base + (size_t)(rbase + row) * K + q * 8;
        ldst[o] = &lds[0][0][0] + (size_t)p * 8192 + (size_t)j * 8;
    }

#define STG(KT, BUF)                                                             \
    {                                                                            \
        _Pragma("unroll")                                                        \
        for (int o = 0; o < 6; ++o)                                              \
            gload16(gbase[o] + (size_t)(KT) * 32, ldst[o] + (BUF) * 24576);      \
    }

    f32x4 acc[8][4] = {};
    const int KT = K >> 5;

    // prologue: stage tiles 0 and 1; wait for tile 0 only (6 newest may fly)
    STG(0, 0);
    STG(1, 1);
    asm volatile("s_waitcnt vmcnt(6)" ::: "memory");
    __builtin_amdgcn_s_barrier();

// One quadrant-phase: m-half MH, n-half NH; stage ops O0 (and O1 if >=0) for
// tile kt+2; LAST=1 on the final phase adds the counted end-of-tile wait.
#define PHASE(MH, NH, O0, O1, LAST)                                                 \
    {                                                                               \
        short8 av[4], bhv[2], blv[2];                                               \
        _Pragma("unroll")                                                           \
        for (int n = 0; n < 2; ++n) {                                               \
            int s = swz((wn + ((NH) * 2 + n) * 16 + (lane & 15)) * 64 + (lane >> 4) * 16); \
            bhv[n] = *(const short8*)(lb + 8192 + (s >> 1));                        \
            blv[n] = *(const short8*)(lb + 2 * 8192 + (s >> 1));                    \
        }                                                                           \
        _Pragma("unroll")                                                           \
        for (int m = 0; m < 4; ++m) {                                               \
            int s = swz((wm + (MH) * 64 + m * 16 + (lane & 15)) * 64 + (lane >> 4) * 16); \
            av[m] = *(const short8*)(lb + (s >> 1));                                \
        }                                                                           \
        if (more) {                                                                 \
            gload16(gbase[O0] + (size_t)(kt + 2) * 32, ldst[O0] + pb * 24576);      \
            if ((O1) >= 0)                                                          \
                gload16(gbase[O1] + (size_t)(kt + 2) * 32, ldst[O1] + pb * 24576);  \
        }                                                                           \
        __builtin_amdgcn_s_barrier();                                               \
        __builtin_amdgcn_s_setprio(1);                                              \
        _Pragma("unroll")                                                           \
        for (int m = 0; m < 4; ++m)                                                 \
            _Pragma("unroll")                                                       \
            for (int n = 0; n < 2; ++n)                                             \
                acc[(MH) * 4 + m][(NH) * 2 + n] =                                   \
                    MFMA_BF16(av[m], blv[n], acc[(MH) * 4 + m][(NH) * 2 + n], 0, 0, 0); \
        _Pragma("unroll")                                                           \
        for (int m = 0; m < 4; ++m)                                                 \
            _Pragma("unroll")                                                       \
            for (int n = 0; n < 2; ++n)                                             \
                acc[(MH) * 4 + m][(NH) * 2 + n] =                                   \
                    MFMA_BF16(av[m], bhv[n], acc[(MH) * 4 + m][(NH) * 2 + n], 0, 0, 0); \
        __builtin_amdgcn_s_setprio(0);                                              \
        if (LAST) {                                                                 \
            if (more) { asm volatile("s_waitcnt vmcnt(6)" ::: "memory"); }          \
            else      { asm volatile("s_waitcnt vmcnt(0)" ::: "memory"); }          \
        }                                                                           \
        __builtin_amdgcn_s_barrier();                                               \
    }

    for (int kt = 0; kt < KT; ++kt) {
        const u16* lb = &lds[kt % 3][0][0];
        const int pb = (kt + 2) % 3;
        const bool more = (kt + 2 < KT);
        PHASE(0, 0, 0, 1, 0)
        PHASE(0, 1, 2, 3, 0)
        PHASE(1, 0, 4, -1, 0)
        PHASE(1, 1, 5, -1, 1)
    }
#undef PHASE
#undef STG

    // epilogue: C/D layout = col (lane&15), row (lane>>4)*4 + e   [m89-verified]
    const int cb2 = n0 + wn + (lane & 15);
    #pragma unroll
    for (int i = 0; i < 8; ++i) {
        int rb = m0 + wm + i * 16 + ((lane >> 4) << 2);
        #pragma unroll
        for (int e = 0; e < 4; ++e) {
            float* crow = C + (size_t)(rb + e) * ldc + cb2;
            #pragma unroll
            for (int j = 0; j < 4; ++j)
                crow[j * 16] = acc[i][j][e];
        }
    }
}

// ---------------- twiddle table init (global, shared by all FFT blocks) -------
__global__ __launch_bounds__(256)
void twiddle_init_kernel(float2* __restrict__ Tg) {
    int idx = blockIdx.x * 256 + threadIdx.x;
    if (idx >= 3072) return;
    float cs = 1.f, sn = 0.f;
    if (idx >= 2048) {
        sincosf(PI_F * (float)(idx - 2048) * (1.0f / 2048.0f), &sn, &cs);
    } else if (idx >= 1) {
        int s = 31 - __clz(idx);
        int h = 1 << s;
        sincosf(PI_F * (float)(idx - h) / (float)h, &sn, &cs);
    }
    Tg[idx] = make_float2(cs, sn);
}

__device__ __forceinline__ void bfly_f(float2& a, float2& b, float cs, float sn) {
    float2 s = make_float2(a.x + b.x, a.y + b.y);
    float2 d = make_float2(a.x - b.x, a.y - b.y);
    a = s;
    b = make_float2(d.x * cs + d.y * sn, d.y * cs - d.x * sn);
}
__device__ __forceinline__ void bfly_i(float2& a, float2& b, float cs, float sn) {
    float cr = b.x * cs - b.y * sn;
    float ci = b.x * sn + b.y * cs;
    float2 a0 = a;
    a = make_float2(a0.x + cr, a0.y + ci);
    b = make_float2(a0.x - cr, a0.y - ci);
}
__device__ __forceinline__ int SW(int a) { return a ^ ((a >> 5) & 15); }

// ---------------- fused rfft -> gates -> modReLU -> irfft ---------------------
// reads f32 sequence from buf, writes bf16 sequence to ubf (same layout).
__global__ __launch_bounds__(256)
void fft_gates_kernel(const float* __restrict__ buf, u16* __restrict__ ubf,
                      const float* __restrict__ gri, const float* __restrict__ modb,
                      const float2* __restrict__ Tg) {
    __shared__ float2 cf[MHALF];
    const int t = threadIdx.x;
    const int w = blockIdx.x;
    const int b = w & 3;
    const float2* seq = (const float2*)(buf + (size_t)w * SS);
    u16* useq = ubf + (size_t)w * SS;

    const int t5 = t & 31;
    const int t3 = t & 3;
    const int c32 = ((t >> 5) << 8) | t5;    // base for 32-span group
    const int d4  = ((t >> 2) << 5) | t3;    // base for 4-span group

    float2 r[8];

    // ---- load + G1: stages 10,9,8 (span 256) ----
    #pragma unroll
    for (int u = 0; u < 8; ++u) r[u] = seq[t + 256 * u];
    #pragma unroll
    for (int u = 0; u < 4; ++u) {
        float2 tw = Tg[1024 + t + 256 * u];
        bfly_f(r[u], r[u + 4], tw.x, tw.y);
    }
    {
        float2 tw0 = Tg[512 + t], tw1 = Tg[512 + t + 256];
        bfly_f(r[0], r[2], tw0.x, tw0.y);
        bfly_f(r[1], r[3], tw1.x, tw1.y);
        bfly_f(r[4], r[6], tw0.x, tw0.y);
        bfly_f(r[5], r[7], tw1.x, tw1.y);
        float2 tw = Tg[256 + t];
        bfly_f(r[0], r[1], tw.x, tw.y);
        bfly_f(r[2], r[3], tw.x, tw.y);
        bfly_f(r[4], r[5], tw.x, tw.y);
        bfly_f(r[6], r[7], tw.x, tw.y);
    }
    #pragma unroll
    for (int u = 0; u < 8; ++u) cf[SW(t + 256 * u)] = r[u];
    __syncthreads();

    // ---- G2: stages 7,6,5 (span 32) ----
    #pragma unroll
    for (int u = 0; u < 8; ++u) r[u] = cf[SW(c32 + 32 * u)];
    #pragma unroll
    for (int u = 0; u < 4; ++u) {
        float2 tw = Tg[128 + t5 + 32 * u];
        bfly_f(r[u], r[u + 4], tw.x, tw.y);
    }
    {
        float2 tw0 = Tg[64 + t5], tw1 = Tg[64 + t5 + 32];
        bfly_f(r[0], r[2], tw0.x, tw0.y);
        bfly_f(r[1], r[3], tw1.x, tw1.y);
        bfly_f(r[4], r[6], tw0.x, tw0.y);
        bfly_f(r[5], r[7], tw1.x, tw1.y);
        float2 tw = Tg[32 + t5];
        bfly_f(r[0], r[1], tw.x, tw.y);
        bfly_f(r[2], r[3], tw.x, tw.y);
        bfly_f(r[4], r[5], tw.x, tw.y);
        bfly_f(r[6], r[7], tw.x, tw.y);
    }
    #pragma unroll
    for (int u = 0; u < 8; ++u) cf[SW(c32 + 32 * u)] = r[u];
    __syncthreads();

    // ---- G3: stages 4,3,2 (span 4) ----
    #pragma unroll
    for (int u = 0; u < 8; ++u) r[u] = cf[SW(d4 + 4 * u)];
    #pragma unroll
    for (int u = 0; u < 4; ++u) {
        float2 tw = Tg[16 + t3 + 4 * u];
        bfly_f(r[u], r[u + 4], tw.x, tw.y);
    }
    {
        float2 tw0 = Tg[8 + t3], tw1 = Tg[8 + t3 + 4];
        bfly_f(r[0], r[2], tw0.x, tw0.y);
        bfly_f(r[1], r[3], tw1.x, tw1.y);
        bfly_f(r[4], r[6], tw0.x, tw0.y);
        bfly_f(r[5], r[7], tw1.x, tw1.y);
        float2 tw = Tg[4 + t3];
        bfly_f(r[0], r[1], tw.x, tw.y);
        bfly_f(r[2], r[3], tw.x, tw.y);
        bfly_f(r[4], r[5], tw.x, tw.y);
        bfly_f(r[6], r[7], tw.x, tw.y);
    }
    #pragma unroll
    for (int u = 0; u < 8; ++u) cf[SW(d4 + 4 * u)] = r[u];
    __syncthreads();

    // ---- G4: stages 1,0 (span 1; 8 consecutive) ----
    #pragma unroll
    for (int u = 0; u < 8; ++u) r[u] = cf[SW(8 * t + u)];
    bfly_f(r[0], r[2], 1.f, 0.f);
    bfly_f(r[1], r[3], 0.f, 1.f);
    bfly_f(r[4], r[6], 1.f, 0.f);
    bfly_f(r[5], r[7], 0.f, 1.f);
    bfly_f(r[0], r[1], 1.f, 0.f);
    bfly_f(r[2], r[3], 1.f, 0.f);
    bfly_f(r[4], r[5], 1.f, 0.f);
    bfly_f(r[6], r[7], 1.f, 0.f);
    #pragma unroll
    for (int u = 0; u < 8; ++u) cf[SW(8 * t + u)] = r[u];
    __syncthreads();

    // ---- spectrum: unpack real-FFT bins (ortho /64), gates, modReLU, repack ----
    const float bias = modb[0];
    const float* gre = gri + (size_t)b * 2 * NFREQ;
    const float* gim = gre + NFREQ;
    const float inv64 = 1.0f / 64.0f;
    for (int k = t; k < 1024; k += 256) {
        if (k == 0) {
            float2 c0 = cf[SW(0)];
            float z0 = (c0.x + c0.y) * inv64;
            float zM = (c0.x - c0.y) * inv64;
            float zr = z0 * gre[0], zi = z0 * gim[0];
            modrelu_apply(zr, zi, bias);
            float yr = zM * gre[2048], yi = zM * gim[2048];
            modrelu_apply(yr, yi, bias);
            cf[SW(0)] = make_float2(0.5f * (zr + yr), 0.5f * (zr - yr));
            float2 c1 = cf[SW(1)];
            float z1r = c1.x * inv64, z1i = -c1.y * inv64;
            float g1r = gre[1024], g1i = gim[1024];
            float pr = z1r * g1r - z1i * g1i;
            float pi2 = z1r * g1i + z1i * g1r;
            modrelu_apply(pr, pi2, bias);
            cf[SW(1)] = make_float2(pr, -pi2);
        } else {
            int kb = 2048 - k;
            int p1 = SW((int)(__brev((unsigned)k) >> 21));
            int p2 = SW((int)(__brev((unsigned)kb) >> 21));
            float2 ca = cf[p1];
            float2 cb2 = cf[p2];
            float Er = 0.5f * (ca.x + cb2.x), Ei = 0.5f * (ca.y - cb2.y);
            float Dr = 0.5f * (ca.x - cb2.x), Di = 0.5f * (ca.y + cb2.y);
            float Or = Di, Oi = -Dr;
            float2 t2 = Tg[2048 + k];
            float cs = t2.x, sn = t2.y;
            float Wr = cs, Wi = -sn;
            float WOr = Wr * Or - Wi * Oi, WOi = Wr * Oi + Wi * Or;
            float zkr = (Er + WOr) * inv64, zki = (Ei + WOi) * inv64;
            float zbr = (Er - WOr) * inv64, zbi = -(Ei - WOi) * inv64;
            float gkr = gre[k], gki = gim[k];
            float ar = zkr * gkr - zki * gki, ai = zkr * gki + zki * gkr;
            modrelu_apply(ar, ai, bias);
            float gbr = gre[kb], gbi = gim[kb];
            float br2 = zbr * gbr - zbi * gbi, bi2 = zbr * gbi + zbi * gbr;
            modrelu_apply(br2, bi2, bias);
            float Epr = 0.5f * (ar + br2), Epi = 0.5f * (ai - bi2);
            float Dpr = 0.5f * (ar - br2), Dpi = 0.5f * (ai + bi2);
            float Opr = cs * Dpr - sn * Dpi, Opi = cs * Dpi + sn * Dpr;
            cf[p1] = make_float2(Epr - Opi, Epi + Opr);
            cf[p2] = make_float2(Epr + Opi, -Epi + Opr);
        }
    }
    __syncthreads();

    // ---- inverse G4': stages 0,1 ----
    #pragma unroll
    for (int u = 0; u < 8; ++u) r[u] = cf[SW(8 * t + u)];
    bfly_i(r[0], r[1], 1.f, 0.f);
    bfly_i(r[2], r[3], 1.f, 0.f);
    bfly_i(r[4], r[5], 1.f, 0.f);
    bfly_i(r[6], r[7], 1.f, 0.f);
    bfly_i(r[0], r[2], 1.f, 0.f);
    bfly_i(r[1], r[3], 0.f, 1.f);
    bfly_i(r[4], r[6], 1.f, 0.f);
    bfly_i(r[5], r[7], 0.f, 1.f);
    #pragma unroll
    for (int u = 0; u < 8; ++u) cf[SW(8 * t + u)] = r[u];
    __syncthreads();

    // ---- inverse G3': stages 2,3,4 ----
    #pragma unroll
    for (int u = 0; u < 8; ++u) r[u] = cf[SW(d4 + 4 * u)];
    {
        float2 tw = Tg[4 + t3];
        bfly_i(r[0], r[1], tw.x, tw.y);
        bfly_i(r[2], r[3], tw.x, tw.y);
        bfly_i(r[4], r[5], tw.x, tw.y);
        bfly_i(r[6], r[7], tw.x, tw.y);
        float2 tw0 = Tg[8 + t3], tw1 = Tg[8 + t3 + 4];
        bfly_i(r[0], r[2], tw0.x, tw0.y);
        bfly_i(r[1], r[3], tw1.x, tw1.y);
        bfly_i(r[4], r[6], tw0.x, tw0.y);
        bfly_i(r[5], r[7], tw1.x, tw1.y);
    }
    #pragma unroll
    for (int u = 0; u < 4; ++u) {
        float2 tw = Tg[16 + t3 + 4 * u];
        bfly_i(r[u], r[u + 4], tw.x, tw.y);
    }
    #pragma unroll
    for (int u = 0; u < 8; ++u) cf[SW(d4 + 4 * u)] = r[u];
    __syncthreads();

    // ---- inverse G2': stages 5,6,7 ----
    #pragma unroll
    for (int u = 0; u < 8; ++u) r[u] = cf[SW(c32 + 32 * u)];
    {
        float2 tw = Tg[32 + t5];
        bfly_i(r[0], r[1], tw.x, tw.y);
        bfly_i(r[2], r[3], tw.x, tw.y);
        bfly_i(r[4], r[5], tw.x, tw.y);
        bfly_i(r[6], r[7], tw.x, tw.y);
        float2 tw0 = Tg[64 + t5], tw1 = Tg[64 + t5 + 32];
        bfly_i(r[0], r[2], tw0.x, tw0.y);
        bfly_i(r[1], r[3], tw1.x, tw1.y);
        bfly_i(r[4], r[6], tw0.x, tw0.y);
        bfly_i(r[5], r[7], tw1.x, tw1.y);
    }
    #pragma unroll
    for (int u = 0; u < 4; ++u) {
        float2 tw = Tg[128 + t5 + 32 * u];
        bfly_i(r[u], r[u + 4], tw.x, tw.y);
    }
    #pragma unroll
    for (int u = 0; u < 8; ++u) cf[SW(c32 + 32 * u)] = r[u];
    __syncthreads();

    // ---- inverse G1': stages 8,9,10 + scale + bf16 store ----
    #pragma unroll
    for (int u = 0; u < 8; ++u) r[u] = cf[SW(t + 256 * u)];
    {
        float2 tw = Tg[256 + t];
        bfly_i(r[0], r[1], tw.x, tw.y);
        bfly_i(r[2], r[3], tw.x, tw.y);
        bfly_i(r[4], r[5], tw.x, tw.y);
        bfly_i(r[6], r[7], tw.x, tw.y);
        float2 tw0 = Tg[512 + t], tw1 = Tg[512 + t + 256];
        bfly_i(r[0], r[2], tw0.x, tw0.y);
        bfly_i(r[1], r[3], tw1.x, tw1.y);
        bfly_i(r[4], r[6], tw0.x, tw0.y);
        bfly_i(r[5], r[7], tw1.x, tw1.y);
    }
    #pragma unroll
    for (int u = 0; u < 4; ++u) {
        float2 tw = Tg[1024 + t + 256 * u];
        bfly_i(r[u], r[u + 4], tw.x, tw.y);
    }
    const float s32 = 1.0f / 32.0f;  // 64 (ortho) / 2048 (ifft norm)
    #pragma unroll
    for (int u = 0; u < 8; ++u) {
        u16x4 dummy;
        ushort2 o;
        o.x = f2bf(r[u].x * s32);
        o.y = f2bf(r[u].y * s32);
        ((ushort2*)useq)[t + 256 * u] = o;
        (void)dummy;
    }
}

extern "C" void kernel_launch(void* const* d_in, const int* in_sizes, int n_in,
                              void* d_out, int out_size, void* d_ws, size_t ws_size,
                              hipStream_t stream) {
    const float* x        = (const float*)d_in[0];
    const float* W_q      = (const float*)d_in[1];
    const float* W_v      = (const float*)d_in[2];
    const float* W_o      = (const float*)d_in[3];
    const float* ln_gamma = (const float*)d_in[4];
    const float* ln_beta  = (const float*)d_in[5];
    const float* mlp_w1   = (const float*)d_in[6];
    const float* mlp_b1   = (const float*)d_in[7];
    const float* mlp_w2   = (const float*)d_in[8];
    const float* mlp_b2   = (const float*)d_in[9];
    const float* mod_bias = (const float*)d_in[10];
    float* out = (float*)d_out;

    // workspace layout (floats)
    float* ws = (float*)d_ws;
    float* xsum     = ws + 262144;           // 4096
    float* q_shared = ws + 266240;           // 256
    float* hdn      = ws + 266496;           // 4096
    float* gri      = ws + 270592;           // 16392 (ends 286984)
    float* mq       = ws + 286984;           // 4096 (ends 291080)
    float2* twid    = (float2*)(ws + 291080); // 3072 float2 (ends 297224)
    float* buf0     = ws + 297984;           // 16777216 floats (64 MiB), [1024][16384]
    float* partial  = buf0;                  // 1024*1024 floats, dead before V GEMM
    u16* bfbase = (u16*)(ws + 297984 + 16777216);
    u16* xut_hi = bfbase;                    // 16777216 u16: x_hi, later reused as ut
    u16* xlo_u  = bfbase + 16777216;         // x_lo; after V GEMM reused as bf16 u
    u16* wv_hi  = bfbase + 33554432;         // 1048576
    u16* wv_lo  = bfbase + 34603008;         // written but unused (2-product V)
    u16* wo_hi  = bfbase + 35651584;
    u16* wo_lo  = bfbase + 36700160;

    twiddle_init_kernel<<<12, 256, 0, stream>>>(twid);

    // fused x split + colsum pass 1 (partial aliases buf0; buf0 written later)
    split_x_colsum_kernel<<<1024, 256, 0, stream>>>(x, xut_hi, xlo_u, partial);
    {
        dim3 g(4, 4);
        colsum2_kernel<<<g, 256, 0, stream>>>(partial, xsum);
    }
    gates1a_kernel<<<256, 256, 0, stream>>>(xsum, W_q, mq);
    gates1b_kernel<<<4, 256, 0, stream>>>(mq, ln_gamma, ln_beta, q_shared);
    gates2_kernel<<<16, 256, 0, stream>>>(q_shared, mlp_w1, mlp_b1, hdn);
    gates3_kernel<<<1025, 256, 0, stream>>>(hdn, mlp_w2, mlp_b2, gri);

    // weight splits
    split_kernel<<<1024, 256, 0, stream>>>(W_v, wv_hi, wv_lo, 262144);
    split_kernel<<<1024, 256, 0, stream>>>(W_o, wo_hi, wo_lo, 262144);

    // V projection (transposed output), 2-product: buf0[j][bs] = Wv_hi[j,:]·(x_hi+x_lo)[bs,:]
    // M=1024 (j), N=16384 (bs): mtiles=4, ntiles=64 -> 256 blocks
    gemm_2p_kernel<<<256, 512, 0, stream>>>(wv_hi, xut_hi, xlo_u,
                                            buf0, 4, 64, 1024, 16384);

    // fused spectral mixing: buf0 f32 -> xlo_u bf16 (x_lo dead after V GEMM)
    fft_gates_kernel<<<4096, 256, 0, stream>>>(buf0, xlo_u, gri, mod_bias, twid);

    // transpose u: xlo_u [1024][16384] -> xut_hi [16384][1024] (pure u16 permute)
    {
        dim3 g(256, 16);
        transpose_u16_kernel<<<g, 256, 0, stream>>>(xlo_u, xut_hi);
    }

    // O projection, 2-product: out[bs][jo] = ut[bs,:]·(Wo_hi+Wo_lo)[jo,:]
    // M=16384 (bs), N=1024 (jo): mtiles=64, ntiles=4 -> 256 blocks
    gemm_2p_kernel<<<256, 512, 0, stream>>>(xut_hi, wo_hi, wo_lo,
                                            out, 64, 4, 1024, 1024);
}

// Round 10
// 258.265 us; speedup vs baseline: 5.0649x; 1.0439x over previous
//
#include <hip/hip_runtime.h>
#include <math.h>
#include <stdint.h>

#define PI_F 3.14159265358979323846f

// Problem constants
#define BB 4
#define SS 4096
#define DD 1024
#define HH 16
#define DHD 64
#define NFREQ 2049   // 4096/2 + 1
#define MHALF 2048   // half-size complex FFT length

typedef unsigned short u16;
typedef __attribute__((ext_vector_type(8))) short short8;   // 8 bf16 = 4 VGPR (MFMA A/B frag)
typedef __attribute__((ext_vector_type(4))) float f32x4;    // MFMA C/D frag
typedef __attribute__((ext_vector_type(4))) unsigned short u16x4;

// ---- bf16 helpers (RTNE) ----
__device__ __forceinline__ u16 f2bf(float f) {
    unsigned u = __float_as_uint(f);
    unsigned r = (u + 0x7FFFu + ((u >> 16) & 1u)) >> 16;
    return (u16)r;
}
__device__ __forceinline__ float bf2f(u16 h) { return __uint_as_float(((unsigned)h) << 16); }

__device__ __forceinline__ void modrelu_apply(float& zr, float& zi, float bias) {
    float mag = sqrtf(zr * zr + zi * zi);
    float scale = fmaxf(mag + bias, 0.0f) / fmaxf(mag, 1e-12f);
    zr *= scale; zi *= scale;
}

// async global->LDS, 16B per lane (HW: dest = wave-uniform base + lane*16)
__device__ __forceinline__ void gload16(const u16* g, u16* l) {
    __builtin_amdgcn_global_load_lds(
        (const __attribute__((address_space(1))) void*)g,
        (__attribute__((address_space(3))) void*)l, 16, 0, 0);
}

// LDS byte-offset swizzle for GEMM staging (16B chunks): XOR chunk bits [4:3]
// into chunk bits [1:0]; involution, matches the pre-swizzled staging order.
__device__ __forceinline__ int swz(int byteoff) {
    return byteoff ^ (((byteoff >> 7) & 3) << 4);
}

#define MFMA_BF16 __builtin_amdgcn_mfma_f32_16x16x32_bf16

// ---------------- fused x -> bf16 hi/lo split + column partial sums -----------
// grid 1024 = (b, s-chunk of 16); thread t owns columns 4t..4t+3
__global__ __launch_bounds__(256)
void split_x_colsum_kernel(const float* __restrict__ x, u16* __restrict__ hi,
                           u16* __restrict__ lo, float* __restrict__ partial) {
    int blk = blockIdx.x;
    int b = blk >> 8;
    int s0 = (blk & 255) * 16;
    int t = threadIdx.x;
    const float* xp = x + ((size_t)b * SS + s0) * DD;
    float4 acc = make_float4(0.f, 0.f, 0.f, 0.f);
    for (int s = 0; s < 16; ++s) {
        float4 v = ((const float4*)(xp + (size_t)s * DD))[t];
        acc.x += v.x; acc.y += v.y; acc.z += v.z; acc.w += v.w;
        u16x4 h, l;
        h.x = f2bf(v.x); h.y = f2bf(v.y); h.z = f2bf(v.z); h.w = f2bf(v.w);
        l.x = f2bf(v.x - bf2f(h.x));
        l.y = f2bf(v.y - bf2f(h.y));
        l.z = f2bf(v.z - bf2f(h.z));
        l.w = f2bf(v.w - bf2f(h.w));
        size_t rowo = (size_t)(b * SS + s0 + s) * DD;
        ((u16x4*)(hi + rowo))[t] = h;
        ((u16x4*)(lo + rowo))[t] = l;
    }
    ((float4*)(partial + (size_t)blk * DD))[t] = acc;
}

// grid (4 kchunks, 4 b); sums 256 partial rows per b
__global__ __launch_bounds__(256)
void colsum2_kernel(const float* __restrict__ partial, float* __restrict__ xsum) {
    int b = blockIdx.y;
    int k = blockIdx.x * 256 + threadIdx.x;
    float acc = 0.f;
    for (int c = 0; c < 256; ++c)
        acc += partial[((size_t)(b * 256 + c)) * DD + k];
    xsum[b * DD + k] = acc;
}

// ---------------- mq[b][j] = dot(xsum[b]/S, Wq[j]) ; grid 256, 1 wave per row j
__global__ __launch_bounds__(256)
void gates1a_kernel(const float* __restrict__ xsum, const float* __restrict__ Wq,
                    float* __restrict__ mq) {
    __shared__ float xb[4][1024];
    int t = threadIdx.x;
    for (int i = t; i < 4096; i += 256)
        xb[i >> 10][i & 1023] = xsum[i] * (1.0f / 4096.0f);
    __syncthreads();
    int wv = t >> 6, l = t & 63;
    int j = blockIdx.x * 4 + wv;
    const float* wrow = Wq + (size_t)j * DD;
    float a0 = 0.f, a1 = 0.f, a2 = 0.f, a3 = 0.f;
    #pragma unroll 4
    for (int it = 0; it < 16; ++it) {
        int idx = l + it * 64;
        float wval = wrow[idx];
        a0 += xb[0][idx] * wval;
        a1 += xb[1][idx] * wval;
        a2 += xb[2][idx] * wval;
        a3 += xb[3][idx] * wval;
    }
    for (int off = 32; off > 0; off >>= 1) {
        a0 += __shfl_down(a0, off, 64);
        a1 += __shfl_down(a1, off, 64);
        a2 += __shfl_down(a2, off, 64);
        a3 += __shfl_down(a3, off, 64);
    }
    if (l == 0) {
        mq[j] = a0; mq[1024 + j] = a1; mq[2048 + j] = a2; mq[3072 + j] = a3;
    }
}

// ---------------- LayerNorm per head over mq, mean over heads -> q_shared[b][64]
__global__ __launch_bounds__(256)
void gates1b_kernel(const float* __restrict__ mq, const float* __restrict__ gamma,
                    const float* __restrict__ beta, float* __restrict__ q_shared) {
    __shared__ float qacc[4][64];
    int b = blockIdx.x;
    int t = threadIdx.x;
    int wv = t >> 6, l = t & 63;
    float part = 0.f;
    for (int hh = 0; hh < 4; ++hh) {
        int h = wv * 4 + hh;
        float v = mq[b * 1024 + h * 64 + l];
        float s1 = v, s2 = v * v;
        for (int off = 32; off > 0; off >>= 1) {
            s1 += __shfl_xor(s1, off, 64);
            s2 += __shfl_xor(s2, off, 64);
        }
        float mu = s1 * (1.0f / 64.0f);
        float var = s2 * (1.0f / 64.0f) - mu * mu;
        part += (v - mu) * rsqrtf(var + 1e-5f) * gamma[l] + beta[l];
    }
    qacc[wv][l] = part;
    __syncthreads();
    if (t < 64) {
        float s = qacc[0][t] + qacc[1][t] + qacc[2][t] + qacc[3][t];
        q_shared[b * 64 + t] = s * (1.0f / 16.0f);
    }
}

// ---------------- hdn = gelu(q_shared @ w1^T + b1)
__global__ __launch_bounds__(256)
void gates2_kernel(const float* __restrict__ q_shared, const float* __restrict__ w1,
                   const float* __restrict__ b1, float* __restrict__ hdn) {
    __shared__ float qs[64];
    int blk = blockIdx.x;
    int b = blk >> 2;
    int i0 = (blk & 3) * 256;
    int t = threadIdx.x;
    if (t < 64) qs[t] = q_shared[b * 64 + t];
    __syncthreads();
    int i = i0 + t;
    const float* wrow = w1 + (size_t)i * DHD;
    float acc = b1[i];
    #pragma unroll 8
    for (int d = 0; d < 64; ++d) acc += qs[d] * wrow[d];
    float g = 0.5f * acc * (1.0f + erff(acc * 0.70710678118654752f));
    hdn[b * DD + i] = g;
}

// ---------------- gri = hdn @ w2^T + b2 ; one wave per output row, all 4 b at once
__global__ __launch_bounds__(256)
void gates3_kernel(const float* __restrict__ hdn, const float* __restrict__ w2,
                   const float* __restrict__ b2, float* __restrict__ gri) {
    int t = threadIdx.x;
    int wv = t >> 6, l = t & 63;
    int r = blockIdx.x * 4 + wv;
    if (r >= 2 * NFREQ) return;
    const float* wrow = w2 + (size_t)r * DD;
    float a0 = 0.f, a1 = 0.f, a2 = 0.f, a3 = 0.f;
    for (int it = 0; it < 16; ++it) {
        int idx = l + it * 64;
        float wval = wrow[idx];
        a0 += hdn[idx] * wval;
        a1 += hdn[1024 + idx] * wval;
        a2 += hdn[2048 + idx] * wval;
        a3 += hdn[3072 + idx] * wval;
    }
    for (int off = 32; off > 0; off >>= 1) {
        a0 += __shfl_down(a0, off, 64);
        a1 += __shfl_down(a1, off, 64);
        a2 += __shfl_down(a2, off, 64);
        a3 += __shfl_down(a3, off, 64);
    }
    if (l == 0) {
        float bb = b2[r];
        gri[r] = a0 + bb;
        gri[2 * NFREQ + r] = a1 + bb;
        gri[2 * 2 * NFREQ + r] = a2 + bb;
        gri[3 * 2 * NFREQ + r] = a3 + bb;
    }
}

// ---------------- f32 -> (bf16 hi, bf16 lo) split (weights) ----------------
__global__ __launch_bounds__(256)
void split_kernel(const float* __restrict__ src, u16* __restrict__ hi,
                  u16* __restrict__ lo, int n4) {
    int idx = blockIdx.x * 256 + threadIdx.x;
    int stride = gridDim.x * 256;
    for (; idx < n4; idx += stride) {
        float4 v = ((const float4*)src)[idx];
        u16x4 h, l;
        h.x = f2bf(v.x); h.y = f2bf(v.y); h.z = f2bf(v.z); h.w = f2bf(v.w);
        l.x = f2bf(v.x - bf2f(h.x));
        l.y = f2bf(v.y - bf2f(h.y));
        l.z = f2bf(v.z - bf2f(h.z));
        l.w = f2bf(v.w - bf2f(h.w));
        ((u16x4*)hi)[idx] = h;
        ((u16x4*)lo)[idx] = l;
    }
}

// ---------------- u16 transpose: src [1024][16384] -> dst [16384][1024] -------
__global__ __launch_bounds__(256)
void transpose_u16_kernel(const u16* __restrict__ src, u16* __restrict__ dst) {
    __shared__ u16 tile[64][66];
    int s0 = blockIdx.x * 64;   // bs block
    int j0 = blockIdx.y * 64;   // feature block
    int t = threadIdx.x;
    int c = t & 63, r4 = t >> 6;
    #pragma unroll
    for (int rr = 0; rr < 64; rr += 4)
        tile[rr + r4][c] = src[(size_t)(j0 + rr + r4) * 16384 + s0 + c];
    __syncthreads();
    #pragma unroll
    for (int rr = 0; rr < 64; rr += 4) {
        int a = rr + r4;                 // local bs
        dst[(size_t)(s0 + a) * 1024 + j0 + c] = tile[c][a];
    }
}

// ---------------- 2-product MFMA GEMM, 256x256 tile, 3-deep pipeline ----------
// C[M][N] = A[M][K] * (Bh+Bl)[N][K]^T ; A single bf16 plane, B hi/lo planes.
// 512 threads = 8 waves (2M x 4N); per-wave 128x64 out = 8x4 frags of 16x16x32.
// LDS: 3 buffers x 3 planes x [256][32] bf16 = 144 KiB. Staging prefetches
// TWO tiles ahead (~7000 cyc of cover for HBM-miss latency); per-tile wait is
// counted vmcnt(6) (this wave's next-tile loads), never a full drain until the
// tail. One barrier per tile. [R8-verified structure: 75.6 us; R6/R7/R9 phase
// restructures were neutral-to-regressive -- do not re-add intra-tile phases.]
__global__ __launch_bounds__(512, 2)
void gemm_2p_kernel(const u16* __restrict__ A, const u16* __restrict__ Bh,
                    const u16* __restrict__ Bl, float* __restrict__ C,
                    int mtiles, int ntiles, int K, int ldc) {
    __shared__ u16 lds[3][3][8192];   // [buf][plane: A,Bh,Bl][256 rows x 32 k]
    const int t = threadIdx.x;
    const int wid = __builtin_amdgcn_readfirstlane(t >> 6);
    const int lane = t & 63;

    // XCD-aware decode (blocks dispatch round-robin over 8 XCDs)
    const int bid = blockIdx.x;
    const int xcd = bid & 7;
    const int idx = bid >> 3;
    int mt, nt;
    if (ntiles >= mtiles) { mt = idx % mtiles; nt = xcd * (ntiles >> 3) + idx / mtiles; }
    else                  { nt = idx % ntiles; mt = xcd * (mtiles >> 3) + idx / ntiles; }
    const int m0 = mt * 256;
    const int n0 = nt * 256;
    const int wm = (wid >> 2) * 128;
    const int wn = (wid & 3) * 64;

    // staging: 48 chunk-ops of 1KB per tile (wave w gets ops g = w*6..w*6+5)
    const u16* gbase[6];
    u16* ldst[6];
    #pragma unroll
    for (int o = 0; o < 6; ++o) {
        int g = wid * 6 + o;
        int p = g >> 4;
        int j = ((g & 15) << 6) | lane;
        int c = j ^ ((j >> 3) & 3);
        int row = c >> 2, q = c & 3;
        const u16* base = (p == 0) ? A : (p == 1) ? Bh : Bl;
        int rbase = (p == 0) ? m0 : n0;
        gbase[o] = base + (size_t)(rbase + row) * K + q * 8;
        ldst[o] = &lds[0][0][0] + (size_t)p * 8192 + (size_t)j * 8;
    }

#define STG(KT, BUF)                                                             \
    {                                                                            \
        _Pragma("unroll")                                                        \
        for (int o = 0; o < 6; ++o)                                              \
            gload16(gbase[o] + (size_t)(KT) * 32, ldst[o] + (BUF) * 24576);      \
    }

    f32x4 acc[8][4] = {};
    const int KT = K >> 5;

    // prologue: stage tiles 0 and 1; wait for tile 0 only (6 newest may fly)
    STG(0, 0);
    STG(1, 1);
    asm volatile("s_waitcnt vmcnt(6)" ::: "memory");
    __builtin_amdgcn_s_barrier();

    for (int kt = 0; kt < KT; ++kt) {
        const int cb = kt % 3;
        const u16* lb = &lds[cb][0][0];
        // issue stage for tile kt+2 first: longest latency cover
        if (kt + 2 < KT) {
            const int pb = (kt + 2) % 3;
            STG(kt + 2, pb);
        }

        short8 bh[4], bl[4];
        #pragma unroll
        for (int j = 0; j < 4; ++j) {
            int s = swz((wn + (lane & 15) + j * 16) * 64 + (lane >> 4) * 16);
            bh[j] = *(const short8*)(lb + 8192 + (s >> 1));
            bl[j] = *(const short8*)(lb + 2 * 8192 + (s >> 1));
        }
        __builtin_amdgcn_s_setprio(1);
        #pragma unroll
        for (int ip = 0; ip < 4; ++ip) {
            int s0 = swz((wm + (lane & 15) + (2 * ip) * 16) * 64 + (lane >> 4) * 16);
            int s1 = swz((wm + (lane & 15) + (2 * ip + 1) * 16) * 64 + (lane >> 4) * 16);
            short8 a0 = *(const short8*)(lb + (s0 >> 1));
            short8 a1 = *(const short8*)(lb + (s1 >> 1));
            #pragma unroll
            for (int j = 0; j < 4; ++j) acc[2 * ip][j]     = MFMA_BF16(a0, bl[j], acc[2 * ip][j], 0, 0, 0);
            #pragma unroll
            for (int j = 0; j < 4; ++j) acc[2 * ip + 1][j] = MFMA_BF16(a1, bl[j], acc[2 * ip + 1][j], 0, 0, 0);
            #pragma unroll
            for (int j = 0; j < 4; ++j) acc[2 * ip][j]     = MFMA_BF16(a0, bh[j], acc[2 * ip][j], 0, 0, 0);
            #pragma unroll
            for (int j = 0; j < 4; ++j) acc[2 * ip + 1][j] = MFMA_BF16(a1, bh[j], acc[2 * ip + 1][j], 0, 0, 0);
        }
        __builtin_amdgcn_s_setprio(0);
        // make buffer kt+1 ready: wait until only tile kt+2's 6 loads remain
        if (kt + 2 < KT) { asm volatile("s_waitcnt vmcnt(6)" ::: "memory"); }
        else             { asm volatile("s_waitcnt vmcnt(0)" ::: "memory"); }
        __builtin_amdgcn_s_barrier();
    }
#undef STG

    // epilogue: C/D layout = col (lane&15), row (lane>>4)*4 + e   [m89-verified]
    const int cb2 = n0 + wn + (lane & 15);
    #pragma unroll
    for (int i = 0; i < 8; ++i) {
        int rb = m0 + wm + i * 16 + ((lane >> 4) << 2);
        #pragma unroll
        for (int e = 0; e < 4; ++e) {
            float* crow = C + (size_t)(rb + e) * ldc + cb2;
            #pragma unroll
            for (int j = 0; j < 4; ++j)
                crow[j * 16] = acc[i][j][e];
        }
    }
}

// ---------------- twiddle table init (global, shared by all FFT blocks) -------
__global__ __launch_bounds__(256)
void twiddle_init_kernel(float2* __restrict__ Tg) {
    int idx = blockIdx.x * 256 + threadIdx.x;
    if (idx >= 3072) return;
    float cs = 1.f, sn = 0.f;
    if (idx >= 2048) {
        sincosf(PI_F * (float)(idx - 2048) * (1.0f / 2048.0f), &sn, &cs);
    } else if (idx >= 1) {
        int s = 31 - __clz(idx);
        int h = 1 << s;
        sincosf(PI_F * (float)(idx - h) / (float)h, &sn, &cs);
    }
    Tg[idx] = make_float2(cs, sn);
}

__device__ __forceinline__ void bfly_f(float2& a, float2& b, float cs, float sn) {
    float2 s = make_float2(a.x + b.x, a.y + b.y);
    float2 d = make_float2(a.x - b.x, a.y - b.y);
    a = s;
    b = make_float2(d.x * cs + d.y * sn, d.y * cs - d.x * sn);
}
__device__ __forceinline__ void bfly_i(float2& a, float2& b, float cs, float sn) {
    float cr = b.x * cs - b.y * sn;
    float ci = b.x * sn + b.y * cs;
    float2 a0 = a;
    a = make_float2(a0.x + cr, a0.y + ci);
    b = make_float2(a0.x - cr, a0.y - ci);
}
__device__ __forceinline__ int SW(int a) { return a ^ ((a >> 5) & 15); }

// ---------------- fused rfft -> gates -> modReLU -> irfft ---------------------
// reads f32 sequence from buf, writes bf16 sequence to ubf (same layout).
__global__ __launch_bounds__(256)
void fft_gates_kernel(const float* __restrict__ buf, u16* __restrict__ ubf,
                      const float* __restrict__ gri, const float* __restrict__ modb,
                      const float2* __restrict__ Tg) {
    __shared__ float2 cf[MHALF];
    const int t = threadIdx.x;
    const int w = blockIdx.x;
    const int b = w & 3;
    const float2* seq = (const float2*)(buf + (size_t)w * SS);
    u16* useq = ubf + (size_t)w * SS;

    const int t5 = t & 31;
    const int t3 = t & 3;
    const int c32 = ((t >> 5) << 8) | t5;    // base for 32-span group
    const int d4  = ((t >> 2) << 5) | t3;    // base for 4-span group

    float2 r[8];

    // ---- load + G1: stages 10,9,8 (span 256) ----
    #pragma unroll
    for (int u = 0; u < 8; ++u) r[u] = seq[t + 256 * u];
    #pragma unroll
    for (int u = 0; u < 4; ++u) {
        float2 tw = Tg[1024 + t + 256 * u];
        bfly_f(r[u], r[u + 4], tw.x, tw.y);
    }
    {
        float2 tw0 = Tg[512 + t], tw1 = Tg[512 + t + 256];
        bfly_f(r[0], r[2], tw0.x, tw0.y);
        bfly_f(r[1], r[3], tw1.x, tw1.y);
        bfly_f(r[4], r[6], tw0.x, tw0.y);
        bfly_f(r[5], r[7], tw1.x, tw1.y);
        float2 tw = Tg[256 + t];
        bfly_f(r[0], r[1], tw.x, tw.y);
        bfly_f(r[2], r[3], tw.x, tw.y);
        bfly_f(r[4], r[5], tw.x, tw.y);
        bfly_f(r[6], r[7], tw.x, tw.y);
    }
    #pragma unroll
    for (int u = 0; u < 8; ++u) cf[SW(t + 256 * u)] = r[u];
    __syncthreads();

    // ---- G2: stages 7,6,5 (span 32) ----
    #pragma unroll
    for (int u = 0; u < 8; ++u) r[u] = cf[SW(c32 + 32 * u)];
    #pragma unroll
    for (int u = 0; u < 4; ++u) {
        float2 tw = Tg[128 + t5 + 32 * u];
        bfly_f(r[u], r[u + 4], tw.x, tw.y);
    }
    {
        float2 tw0 = Tg[64 + t5], tw1 = Tg[64 + t5 + 32];
        bfly_f(r[0], r[2], tw0.x, tw0.y);
        bfly_f(r[1], r[3], tw1.x, tw1.y);
        bfly_f(r[4], r[6], tw0.x, tw0.y);
        bfly_f(r[5], r[7], tw1.x, tw1.y);
        float2 tw = Tg[32 + t5];
        bfly_f(r[0], r[1], tw.x, tw.y);
        bfly_f(r[2], r[3], tw.x, tw.y);
        bfly_f(r[4], r[5], tw.x, tw.y);
        bfly_f(r[6], r[7], tw.x, tw.y);
    }
    #pragma unroll
    for (int u = 0; u < 8; ++u) cf[SW(c32 + 32 * u)] = r[u];
    __syncthreads();

    // ---- G3: stages 4,3,2 (span 4) ----
    #pragma unroll
    for (int u = 0; u < 8; ++u) r[u] = cf[SW(d4 + 4 * u)];
    #pragma unroll
    for (int u = 0; u < 4; ++u) {
        float2 tw = Tg[16 + t3 + 4 * u];
        bfly_f(r[u], r[u + 4], tw.x, tw.y);
    }
    {
        float2 tw0 = Tg[8 + t3], tw1 = Tg[8 + t3 + 4];
        bfly_f(r[0], r[2], tw0.x, tw0.y);
        bfly_f(r[1], r[3], tw1.x, tw1.y);
        bfly_f(r[4], r[6], tw0.x, tw0.y);
        bfly_f(r[5], r[7], tw1.x, tw1.y);
        float2 tw = Tg[4 + t3];
        bfly_f(r[0], r[1], tw.x, tw.y);
        bfly_f(r[2], r[3], tw.x, tw.y);
        bfly_f(r[4], r[5], tw.x, tw.y);
        bfly_f(r[6], r[7], tw.x, tw.y);
    }
    #pragma unroll
    for (int u = 0; u < 8; ++u) cf[SW(d4 + 4 * u)] = r[u];
    __syncthreads();

    // ---- G4: stages 1,0 (span 1; 8 consecutive) ----
    #pragma unroll
    for (int u = 0; u < 8; ++u) r[u] = cf[SW(8 * t + u)];
    bfly_f(r[0], r[2], 1.f, 0.f);
    bfly_f(r[1], r[3], 0.f, 1.f);
    bfly_f(r[4], r[6], 1.f, 0.f);
    bfly_f(r[5], r[7], 0.f, 1.f);
    bfly_f(r[0], r[1], 1.f, 0.f);
    bfly_f(r[2], r[3], 1.f, 0.f);
    bfly_f(r[4], r[5], 1.f, 0.f);
    bfly_f(r[6], r[7], 1.f, 0.f);
    #pragma unroll
    for (int u = 0; u < 8; ++u) cf[SW(8 * t + u)] = r[u];
    __syncthreads();

    // ---- spectrum: unpack real-FFT bins (ortho /64), gates, modReLU, repack ----
    const float bias = modb[0];
    const float* gre = gri + (size_t)b * 2 * NFREQ;
    const float* gim = gre + NFREQ;
    const float inv64 = 1.0f / 64.0f;
    for (int k = t; k < 1024; k += 256) {
        if (k == 0) {
            float2 c0 = cf[SW(0)];
            float z0 = (c0.x + c0.y) * inv64;
            float zM = (c0.x - c0.y) * inv64;
            float zr = z0 * gre[0], zi = z0 * gim[0];
            modrelu_apply(zr, zi, bias);
            float yr = zM * gre[2048], yi = zM * gim[2048];
            modrelu_apply(yr, yi, bias);
            cf[SW(0)] = make_float2(0.5f * (zr + yr), 0.5f * (zr - yr));
            float2 c1 = cf[SW(1)];
            float z1r = c1.x * inv64, z1i = -c1.y * inv64;
            float g1r = gre[1024], g1i = gim[1024];
            float pr = z1r * g1r - z1i * g1i;
            float pi2 = z1r * g1i + z1i * g1r;
            modrelu_apply(pr, pi2, bias);
            cf[SW(1)] = make_float2(pr, -pi2);
        } else {
            int kb = 2048 - k;
            int p1 = SW((int)(__brev((unsigned)k) >> 21));
            int p2 = SW((int)(__brev((unsigned)kb) >> 21));
            float2 ca = cf[p1];
            float2 cb2 = cf[p2];
            float Er = 0.5f * (ca.x + cb2.x), Ei = 0.5f * (ca.y - cb2.y);
            float Dr = 0.5f * (ca.x - cb2.x), Di = 0.5f * (ca.y + cb2.y);
            float Or = Di, Oi = -Dr;
            float2 t2 = Tg[2048 + k];
            float cs = t2.x, sn = t2.y;
            float Wr = cs, Wi = -sn;
            float WOr = Wr * Or - Wi * Oi, WOi = Wr * Oi + Wi * Or;
            float zkr = (Er + WOr) * inv64, zki = (Ei + WOi) * inv64;
            float zbr = (Er - WOr) * inv64, zbi = -(Ei - WOi) * inv64;
            float gkr = gre[k], gki = gim[k];
            float ar = zkr * gkr - zki * gki, ai = zkr * gki + zki * gkr;
            modrelu_apply(ar, ai, bias);
            float gbr = gre[kb], gbi = gim[kb];
            float br2 = zbr * gbr - zbi * gbi, bi2 = zbr * gbi + zbi * gbr;
            modrelu_apply(br2, bi2, bias);
            float Epr = 0.5f * (ar + br2), Epi = 0.5f * (ai - bi2);
            float Dpr = 0.5f * (ar - br2), Dpi = 0.5f * (ai + bi2);
            float Opr = cs * Dpr - sn * Dpi, Opi = cs * Dpi + sn * Dpr;
            cf[p1] = make_float2(Epr - Opi, Epi + Opr);
            cf[p2] = make_float2(Epr + Opi, -Epi + Opr);
        }
    }
    __syncthreads();

    // ---- inverse G4': stages 0,1 ----
    #pragma unroll
    for (int u = 0; u < 8; ++u) r[u] = cf[SW(8 * t + u)];
    bfly_i(r[0], r[1], 1.f, 0.f);
    bfly_i(r[2], r[3], 1.f, 0.f);
    bfly_i(r[4], r[5], 1.f, 0.f);
    bfly_i(r[6], r[7], 1.f, 0.f);
    bfly_i(r[0], r[2], 1.f, 0.f);
    bfly_i(r[1], r[3], 0.f, 1.f);
    bfly_i(r[4], r[6], 1.f, 0.f);
    bfly_i(r[5], r[7], 0.f, 1.f);
    #pragma unroll
    for (int u = 0; u < 8; ++u) cf[SW(8 * t + u)] = r[u];
    __syncthreads();

    // ---- inverse G3': stages 2,3,4 ----
    #pragma unroll
    for (int u = 0; u < 8; ++u) r[u] = cf[SW(d4 + 4 * u)];
    {
        float2 tw = Tg[4 + t3];
        bfly_i(r[0], r[1], tw.x, tw.y);
        bfly_i(r[2], r[3], tw.x, tw.y);
        bfly_i(r[4], r[5], tw.x, tw.y);
        bfly_i(r[6], r[7], tw.x, tw.y);
        float2 tw0 = Tg[8 + t3], tw1 = Tg[8 + t3 + 4];
        bfly_i(r[0], r[2], tw0.x, tw0.y);
        bfly_i(r[1], r[3], tw1.x, tw1.y);
        bfly_i(r[4], r[6], tw0.x, tw0.y);
        bfly_i(r[5], r[7], tw1.x, tw1.y);
    }
    #pragma unroll
    for (int u = 0; u < 4; ++u) {
        float2 tw = Tg[16 + t3 + 4 * u];
        bfly_i(r[u], r[u + 4], tw.x, tw.y);
    }
    #pragma unroll
    for (int u = 0; u < 8; ++u) cf[SW(d4 + 4 * u)] = r[u];
    __syncthreads();

    // ---- inverse G2': stages 5,6,7 ----
    #pragma unroll
    for (int u = 0; u < 8; ++u) r[u] = cf[SW(c32 + 32 * u)];
    {
        float2 tw = Tg[32 + t5];
        bfly_i(r[0], r[1], tw.x, tw.y);
        bfly_i(r[2], r[3], tw.x, tw.y);
        bfly_i(r[4], r[5], tw.x, tw.y);
        bfly_i(r[6], r[7], tw.x, tw.y);
        float2 tw0 = Tg[64 + t5], tw1 = Tg[64 + t5 + 32];
        bfly_i(r[0], r[2], tw0.x, tw0.y);
        bfly_i(r[1], r[3], tw1.x, tw1.y);
        bfly_i(r[4], r[6], tw0.x, tw0.y);
        bfly_i(r[5], r[7], tw1.x, tw1.y);
    }
    #pragma unroll
    for (int u = 0; u < 4; ++u) {
        float2 tw = Tg[128 + t5 + 32 * u];
        bfly_i(r[u], r[u + 4], tw.x, tw.y);
    }
    #pragma unroll
    for (int u = 0; u < 8; ++u) cf[SW(c32 + 32 * u)] = r[u];
    __syncthreads();

    // ---- inverse G1': stages 8,9,10 + scale + bf16 store ----
    #pragma unroll
    for (int u = 0; u < 8; ++u) r[u] = cf[SW(t + 256 * u)];
    {
        float2 tw = Tg[256 + t];
        bfly_i(r[0], r[1], tw.x, tw.y);
        bfly_i(r[2], r[3], tw.x, tw.y);
        bfly_i(r[4], r[5], tw.x, tw.y);
        bfly_i(r[6], r[7], tw.x, tw.y);
        float2 tw0 = Tg[512 + t], tw1 = Tg[512 + t + 256];
        bfly_i(r[0], r[2], tw0.x, tw0.y);
        bfly_i(r[1], r[3], tw1.x, tw1.y);
        bfly_i(r[4], r[6], tw0.x, tw0.y);
        bfly_i(r[5], r[7], tw1.x, tw1.y);
    }
    #pragma unroll
    for (int u = 0; u < 4; ++u) {
        float2 tw = Tg[1024 + t + 256 * u];
        bfly_i(r[u], r[u + 4], tw.x, tw.y);
    }
    const float s32 = 1.0f / 32.0f;  // 64 (ortho) / 2048 (ifft norm)
    #pragma unroll
    for (int u = 0; u < 8; ++u) {
        ushort2 o;
        o.x = f2bf(r[u].x * s32);
        o.y = f2bf(r[u].y * s32);
        ((ushort2*)useq)[t + 256 * u] = o;
    }
}

extern "C" void kernel_launch(void* const* d_in, const int* in_sizes, int n_in,
                              void* d_out, int out_size, void* d_ws, size_t ws_size,
                              hipStream_t stream) {
    const float* x        = (const float*)d_in[0];
    const float* W_q      = (const float*)d_in[1];
    const float* W_v      = (const float*)d_in[2];
    const float* W_o      = (const float*)d_in[3];
    const float* ln_gamma = (const float*)d_in[4];
    const float* ln_beta  = (const float*)d_in[5];
    const float* mlp_w1   = (const float*)d_in[6];
    const float* mlp_b1   = (const float*)d_in[7];
    const float* mlp_w2   = (const float*)d_in[8];
    const float* mlp_b2   = (const float*)d_in[9];
    const float* mod_bias = (const float*)d_in[10];
    float* out = (float*)d_out;

    // workspace layout (floats)
    float* ws = (float*)d_ws;
    float* xsum     = ws + 262144;           // 4096
    float* q_shared = ws + 266240;           // 256
    float* hdn      = ws + 266496;           // 4096
    float* gri      = ws + 270592;           // 16392 (ends 286984)
    float* mq       = ws + 286984;           // 4096 (ends 291080)
    float2* twid    = (float2*)(ws + 291080); // 3072 float2 (ends 297224)
    float* buf0     = ws + 297984;           // 16777216 floats (64 MiB), [1024][16384]
    float* partial  = buf0;                  // 1024*1024 floats, dead before V GEMM
    u16* bfbase = (u16*)(ws + 297984 + 16777216);
    u16* xut_hi = bfbase;                    // 16777216 u16: x_hi, later reused as ut
    u16* xlo_u  = bfbase + 16777216;         // x_lo; after V GEMM reused as bf16 u
    u16* wv_hi  = bfbase + 33554432;         // 1048576
    u16* wv_lo  = bfbase + 34603008;         // written but unused (2-product V)
    u16* wo_hi  = bfbase + 35651584;
    u16* wo_lo  = bfbase + 36700160;

    twiddle_init_kernel<<<12, 256, 0, stream>>>(twid);

    // fused x split + colsum pass 1 (partial aliases buf0; buf0 written later)
    split_x_colsum_kernel<<<1024, 256, 0, stream>>>(x, xut_hi, xlo_u, partial);
    {
        dim3 g(4, 4);
        colsum2_kernel<<<g, 256, 0, stream>>>(partial, xsum);
    }
    gates1a_kernel<<<256, 256, 0, stream>>>(xsum, W_q, mq);
    gates1b_kernel<<<4, 256, 0, stream>>>(mq, ln_gamma, ln_beta, q_shared);
    gates2_kernel<<<16, 256, 0, stream>>>(q_shared, mlp_w1, mlp_b1, hdn);
    gates3_kernel<<<1025, 256, 0, stream>>>(hdn, mlp_w2, mlp_b2, gri);

    // weight splits
    split_kernel<<<1024, 256, 0, stream>>>(W_v, wv_hi, wv_lo, 262144);
    split_kernel<<<1024, 256, 0, stream>>>(W_o, wo_hi, wo_lo, 262144);

    // V projection (transposed output), 2-product: buf0[j][bs] = Wv_hi[j,:]·(x_hi+x_lo)[bs,:]
    // M=1024 (j), N=16384 (bs): mtiles=4, ntiles=64 -> 256 blocks
    gemm_2p_kernel<<<256, 512, 0, stream>>>(wv_hi, xut_hi, xlo_u,
                                            buf0, 4, 64, 1024, 16384);

    // fused spectral mixing: buf0 f32 -> xlo_u bf16 (x_lo dead after V GEMM)
    fft_gates_kernel<<<4096, 256, 0, stream>>>(buf0, xlo_u, gri, mod_bias, twid);

    // transpose u: xlo_u [1024][16384] -> xut_hi [16384][1024] (pure u16 permute)
    {
        dim3 g(256, 16);
        transpose_u16_kernel<<<g, 256, 0, stream>>>(xlo_u, xut_hi);
    }

    // O projection, 2-product: out[bs][jo] = ut[bs,:]·(Wo_hi+Wo_lo)[jo,:]
    // M=16384 (bs), N=1024 (jo): mtiles=64, ntiles=4 -> 256 blocks
    gemm_2p_kernel<<<256, 512, 0, stream>>>(xut_hi, wo_hi, wo_lo,
                                            out, 64, 4, 1024, 1024);
}

// Round 11
// 209.454 us; speedup vs baseline: 6.2453x; 1.2330x over previous
//
#include <hip/hip_runtime.h>
#include <math.h>
#include <stdint.h>

#define PI_F 3.14159265358979323846f

// Problem constants
#define BB 4
#define SS 4096
#define DD 1024
#define HH 16
#define DHD 64
#define NFREQ 2049   // 4096/2 + 1
#define MHALF 2048   // half-size complex FFT length

typedef unsigned short u16;
typedef __attribute__((ext_vector_type(8))) _Float16 half8;  // MFMA f16 A/B frag
typedef __attribute__((ext_vector_type(4))) float f32x4;     // MFMA C/D frag
typedef __attribute__((ext_vector_type(4))) unsigned short u16x4;

// ---- f16 helper (RTNE via v_cvt_f16_f32) ----
__device__ __forceinline__ u16 f2h(float f) {
    union { _Float16 h; u16 u; } cv;
    cv.h = (_Float16)f;
    return cv.u;
}

__device__ __forceinline__ void modrelu_apply(float& zr, float& zi, float bias) {
    float mag = sqrtf(zr * zr + zi * zi);
    float scale = fmaxf(mag + bias, 0.0f) / fmaxf(mag, 1e-12f);
    zr *= scale; zi *= scale;
}

// async global->LDS, 16B per lane (HW: dest = wave-uniform base + lane*16)
__device__ __forceinline__ void gload16(const u16* g, u16* l) {
    __builtin_amdgcn_global_load_lds(
        (const __attribute__((address_space(1))) void*)g,
        (__attribute__((address_space(3))) void*)l, 16, 0, 0);
}

// LDS byte-offset swizzle for GEMM staging (16B chunks): XOR chunk bits [4:3]
// into chunk bits [1:0]; involution, matches the pre-swizzled staging order.
__device__ __forceinline__ int swz(int byteoff) {
    return byteoff ^ (((byteoff >> 7) & 3) << 4);
}

#define MFMA_F16 __builtin_amdgcn_mfma_f32_16x16x32_f16

// ---------------- fused x -> f16 convert + column partial sums ---------------
// grid 1024 = (b, s-chunk of 16); thread t owns columns 4t..4t+3
__global__ __launch_bounds__(256)
void split_x_colsum_kernel(const float* __restrict__ x, u16* __restrict__ xf,
                           float* __restrict__ partial) {
    int blk = blockIdx.x;
    int b = blk >> 8;
    int s0 = (blk & 255) * 16;
    int t = threadIdx.x;
    const float* xp = x + ((size_t)b * SS + s0) * DD;
    float4 acc = make_float4(0.f, 0.f, 0.f, 0.f);
    for (int s = 0; s < 16; ++s) {
        float4 v = ((const float4*)(xp + (size_t)s * DD))[t];
        acc.x += v.x; acc.y += v.y; acc.z += v.z; acc.w += v.w;
        u16x4 h;
        h.x = f2h(v.x); h.y = f2h(v.y); h.z = f2h(v.z); h.w = f2h(v.w);
        ((u16x4*)(xf + (size_t)(b * SS + s0 + s) * DD))[t] = h;
    }
    ((float4*)(partial + (size_t)blk * DD))[t] = acc;
}

// grid (4 kchunks, 4 b); sums 256 partial rows per b
__global__ __launch_bounds__(256)
void colsum2_kernel(const float* __restrict__ partial, float* __restrict__ xsum) {
    int b = blockIdx.y;
    int k = blockIdx.x * 256 + threadIdx.x;
    float acc = 0.f;
    for (int c = 0; c < 256; ++c)
        acc += partial[((size_t)(b * 256 + c)) * DD + k];
    xsum[b * DD + k] = acc;
}

// ---------------- mq[b][j] = dot(xsum[b]/S, Wq[j]) ; grid 256, 1 wave per row j
__global__ __launch_bounds__(256)
void gates1a_kernel(const float* __restrict__ xsum, const float* __restrict__ Wq,
                    float* __restrict__ mq) {
    __shared__ float xb[4][1024];
    int t = threadIdx.x;
    for (int i = t; i < 4096; i += 256)
        xb[i >> 10][i & 1023] = xsum[i] * (1.0f / 4096.0f);
    __syncthreads();
    int wv = t >> 6, l = t & 63;
    int j = blockIdx.x * 4 + wv;
    const float* wrow = Wq + (size_t)j * DD;
    float a0 = 0.f, a1 = 0.f, a2 = 0.f, a3 = 0.f;
    #pragma unroll 4
    for (int it = 0; it < 16; ++it) {
        int idx = l + it * 64;
        float wval = wrow[idx];
        a0 += xb[0][idx] * wval;
        a1 += xb[1][idx] * wval;
        a2 += xb[2][idx] * wval;
        a3 += xb[3][idx] * wval;
    }
    for (int off = 32; off > 0; off >>= 1) {
        a0 += __shfl_down(a0, off, 64);
        a1 += __shfl_down(a1, off, 64);
        a2 += __shfl_down(a2, off, 64);
        a3 += __shfl_down(a3, off, 64);
    }
    if (l == 0) {
        mq[j] = a0; mq[1024 + j] = a1; mq[2048 + j] = a2; mq[3072 + j] = a3;
    }
}

// ---------------- LayerNorm per head over mq, mean over heads -> q_shared[b][64]
__global__ __launch_bounds__(256)
void gates1b_kernel(const float* __restrict__ mq, const float* __restrict__ gamma,
                    const float* __restrict__ beta, float* __restrict__ q_shared) {
    __shared__ float qacc[4][64];
    int b = blockIdx.x;
    int t = threadIdx.x;
    int wv = t >> 6, l = t & 63;
    float part = 0.f;
    for (int hh = 0; hh < 4; ++hh) {
        int h = wv * 4 + hh;
        float v = mq[b * 1024 + h * 64 + l];
        float s1 = v, s2 = v * v;
        for (int off = 32; off > 0; off >>= 1) {
            s1 += __shfl_xor(s1, off, 64);
            s2 += __shfl_xor(s2, off, 64);
        }
        float mu = s1 * (1.0f / 64.0f);
        float var = s2 * (1.0f / 64.0f) - mu * mu;
        part += (v - mu) * rsqrtf(var + 1e-5f) * gamma[l] + beta[l];
    }
    qacc[wv][l] = part;
    __syncthreads();
    if (t < 64) {
        float s = qacc[0][t] + qacc[1][t] + qacc[2][t] + qacc[3][t];
        q_shared[b * 64 + t] = s * (1.0f / 16.0f);
    }
}

// ---------------- hdn = gelu(q_shared @ w1^T + b1)
__global__ __launch_bounds__(256)
void gates2_kernel(const float* __restrict__ q_shared, const float* __restrict__ w1,
                   const float* __restrict__ b1, float* __restrict__ hdn) {
    __shared__ float qs[64];
    int blk = blockIdx.x;
    int b = blk >> 2;
    int i0 = (blk & 3) * 256;
    int t = threadIdx.x;
    if (t < 64) qs[t] = q_shared[b * 64 + t];
    __syncthreads();
    int i = i0 + t;
    const float* wrow = w1 + (size_t)i * DHD;
    float acc = b1[i];
    #pragma unroll 8
    for (int d = 0; d < 64; ++d) acc += qs[d] * wrow[d];
    float g = 0.5f * acc * (1.0f + erff(acc * 0.70710678118654752f));
    hdn[b * DD + i] = g;
}

// ---------------- gri = hdn @ w2^T + b2 ; one wave per output row, all 4 b at once
__global__ __launch_bounds__(256)
void gates3_kernel(const float* __restrict__ hdn, const float* __restrict__ w2,
                   const float* __restrict__ b2, float* __restrict__ gri) {
    int t = threadIdx.x;
    int wv = t >> 6, l = t & 63;
    int r = blockIdx.x * 4 + wv;
    if (r >= 2 * NFREQ) return;
    const float* wrow = w2 + (size_t)r * DD;
    float a0 = 0.f, a1 = 0.f, a2 = 0.f, a3 = 0.f;
    for (int it = 0; it < 16; ++it) {
        int idx = l + it * 64;
        float wval = wrow[idx];
        a0 += hdn[idx] * wval;
        a1 += hdn[1024 + idx] * wval;
        a2 += hdn[2048 + idx] * wval;
        a3 += hdn[3072 + idx] * wval;
    }
    for (int off = 32; off > 0; off >>= 1) {
        a0 += __shfl_down(a0, off, 64);
        a1 += __shfl_down(a1, off, 64);
        a2 += __shfl_down(a2, off, 64);
        a3 += __shfl_down(a3, off, 64);
    }
    if (l == 0) {
        float bb = b2[r];
        gri[r] = a0 + bb;
        gri[2 * NFREQ + r] = a1 + bb;
        gri[2 * 2 * NFREQ + r] = a2 + bb;
        gri[3 * 2 * NFREQ + r] = a3 + bb;
    }
}

// ---------------- f32 -> f16 convert (weights) ----------------
__global__ __launch_bounds__(256)
void cvt_f16_kernel(const float* __restrict__ src, u16* __restrict__ dst, int n4) {
    int idx = blockIdx.x * 256 + threadIdx.x;
    int stride = gridDim.x * 256;
    for (; idx < n4; idx += stride) {
        float4 v = ((const float4*)src)[idx];
        u16x4 h;
        h.x = f2h(v.x); h.y = f2h(v.y); h.z = f2h(v.z); h.w = f2h(v.w);
        ((u16x4*)dst)[idx] = h;
    }
}

// ---------------- u16 transpose: src [1024][16384] -> dst [16384][1024] -------
__global__ __launch_bounds__(256)
void transpose_u16_kernel(const u16* __restrict__ src, u16* __restrict__ dst) {
    __shared__ u16 tile[64][66];
    int s0 = blockIdx.x * 64;   // bs block
    int j0 = blockIdx.y * 64;   // feature block
    int t = threadIdx.x;
    int c = t & 63, r4 = t >> 6;
    #pragma unroll
    for (int rr = 0; rr < 64; rr += 4)
        tile[rr + r4][c] = src[(size_t)(j0 + rr + r4) * 16384 + s0 + c];
    __syncthreads();
    #pragma unroll
    for (int rr = 0; rr < 64; rr += 4) {
        int a = rr + r4;                 // local bs
        dst[(size_t)(s0 + a) * 1024 + j0 + c] = tile[c][a];
    }
}

// ---------------- f16 single-product MFMA GEMM, 256x256 tile, 4-deep pipeline -
// C[M][N] = A[M][K] * B[N][K]^T ; A,B single f16 planes (row-major, stride K).
// f16 (rel 2^-11) beats the old bf16 hi/lo 2-product scheme on BOTH accuracy
// and work: half the MFMA, 2/3 the LDS read traffic, 2/3 the staged bytes.
// 512 threads = 8 waves (2M x 4N); per-wave 128x64 out = 8x4 frags of 16x16x32.
// LDS: 4 buffers x 2 planes x [256][32] f16 = 128 KiB. Staging prefetches
// THREE tiles ahead; per-tile wait is counted vmcnt(8) (4 ops/wave/tile, 2
// tiles allowed in flight), never draining same-tile loads. One barrier/tile.
// [R8-verified pipeline discipline; R6/R7/R9 phase restructures regressed --
//  do not re-add intra-tile phases.]
__global__ __launch_bounds__(512, 2)
void gemm_f16_kernel(const u16* __restrict__ A, const u16* __restrict__ B,
                     float* __restrict__ C, int mtiles, int ntiles, int K, int ldc) {
    __shared__ u16 lds[4][2][8192];   // [buf][plane: A,B][256 rows x 32 k]
    const int t = threadIdx.x;
    const int wid = __builtin_amdgcn_readfirstlane(t >> 6);
    const int lane = t & 63;

    // XCD-aware decode (blocks dispatch round-robin over 8 XCDs)
    const int bid = blockIdx.x;
    const int xcd = bid & 7;
    const int idx = bid >> 3;
    int mt, nt;
    if (ntiles >= mtiles) { mt = idx % mtiles; nt = xcd * (ntiles >> 3) + idx / mtiles; }
    else                  { nt = idx % ntiles; mt = xcd * (mtiles >> 3) + idx / ntiles; }
    const int m0 = mt * 256;
    const int n0 = nt * 256;
    const int wm = (wid >> 2) * 128;
    const int wn = (wid & 3) * 64;

    // staging: 32 chunk-ops of 1KB per tile (wave w gets ops g = w*4..w*4+3)
    const u16* gbase[4];
    u16* ldst[4];
    #pragma unroll
    for (int o = 0; o < 4; ++o) {
        int g = wid * 4 + o;
        int p = g >> 4;                  // 0 = A plane, 1 = B plane
        int j = ((g & 15) << 6) | lane;
        int c = j ^ ((j >> 3) & 3);
        int row = c >> 2, q = c & 3;
        const u16* base = (p == 0) ? A : B;
        int rbase = (p == 0) ? m0 : n0;
        gbase[o] = base + (size_t)(rbase + row) * K + q * 8;
        ldst[o] = &lds[0][0][0] + (size_t)p * 8192 + (size_t)j * 8;
    }

#define STG(KT, BUF)                                                             \
    {                                                                            \
        _Pragma("unroll")                                                        \
        for (int o = 0; o < 4; ++o)                                              \
            gload16(gbase[o] + (size_t)(KT) * 32, ldst[o] + (BUF) * 16384);      \
    }

    f32x4 acc[8][4] = {};
    const int KT = K >> 5;

    // prologue: stage tiles 0..2; wait for tile 0 only (8 newest may fly)
    STG(0, 0);
    STG(1, 1);
    STG(2, 2);
    asm volatile("s_waitcnt vmcnt(8)" ::: "memory");
    __builtin_amdgcn_s_barrier();

    for (int kt = 0; kt < KT; ++kt) {
        const u16* lb = &lds[kt & 3][0][0];
        // issue stage for tile kt+3 first: longest latency cover
        if (kt + 3 < KT) STG(kt + 3, (kt + 3) & 3);

        half8 b[4];
        #pragma unroll
        for (int j = 0; j < 4; ++j) {
            int s = swz((wn + (lane & 15) + j * 16) * 64 + (lane >> 4) * 16);
            b[j] = *(const half8*)(lb + 8192 + (s >> 1));
        }
        __builtin_amdgcn_s_setprio(1);
        #pragma unroll
        for (int ip = 0; ip < 4; ++ip) {
            int s0 = swz((wm + (lane & 15) + (2 * ip) * 16) * 64 + (lane >> 4) * 16);
            int s1 = swz((wm + (lane & 15) + (2 * ip + 1) * 16) * 64 + (lane >> 4) * 16);
            half8 a0 = *(const half8*)(lb + (s0 >> 1));
            half8 a1 = *(const half8*)(lb + (s1 >> 1));
            #pragma unroll
            for (int j = 0; j < 4; ++j) acc[2 * ip][j]     = MFMA_F16(a0, b[j], acc[2 * ip][j], 0, 0, 0);
            #pragma unroll
            for (int j = 0; j < 4; ++j) acc[2 * ip + 1][j] = MFMA_F16(a1, b[j], acc[2 * ip + 1][j], 0, 0, 0);
        }
        __builtin_amdgcn_s_setprio(0);
        // make buffer kt+1 ready: wait until only younger tiles' loads remain
        if (kt <= KT - 4)      { asm volatile("s_waitcnt vmcnt(8)" ::: "memory"); }
        else if (kt == KT - 3) { asm volatile("s_waitcnt vmcnt(4)" ::: "memory"); }
        else                   { asm volatile("s_waitcnt vmcnt(0)" ::: "memory"); }
        __builtin_amdgcn_s_barrier();
    }
#undef STG

    // epilogue: C/D layout = col (lane&15), row (lane>>4)*4 + e   [m89-verified]
    const int cb2 = n0 + wn + (lane & 15);
    #pragma unroll
    for (int i = 0; i < 8; ++i) {
        int rb = m0 + wm + i * 16 + ((lane >> 4) << 2);
        #pragma unroll
        for (int e = 0; e < 4; ++e) {
            float* crow = C + (size_t)(rb + e) * ldc + cb2;
            #pragma unroll
            for (int j = 0; j < 4; ++j)
                crow[j * 16] = acc[i][j][e];
        }
    }
}

// ---------------- twiddle table init (global, shared by all FFT blocks) -------
__global__ __launch_bounds__(256)
void twiddle_init_kernel(float2* __restrict__ Tg) {
    int idx = blockIdx.x * 256 + threadIdx.x;
    if (idx >= 3072) return;
    float cs = 1.f, sn = 0.f;
    if (idx >= 2048) {
        sincosf(PI_F * (float)(idx - 2048) * (1.0f / 2048.0f), &sn, &cs);
    } else if (idx >= 1) {
        int s = 31 - __clz(idx);
        int h = 1 << s;
        sincosf(PI_F * (float)(idx - h) / (float)h, &sn, &cs);
    }
    Tg[idx] = make_float2(cs, sn);
}

__device__ __forceinline__ void bfly_f(float2& a, float2& b, float cs, float sn) {
    float2 s = make_float2(a.x + b.x, a.y + b.y);
    float2 d = make_float2(a.x - b.x, a.y - b.y);
    a = s;
    b = make_float2(d.x * cs + d.y * sn, d.y * cs - d.x * sn);
}
__device__ __forceinline__ void bfly_i(float2& a, float2& b, float cs, float sn) {
    float cr = b.x * cs - b.y * sn;
    float ci = b.x * sn + b.y * cs;
    float2 a0 = a;
    a = make_float2(a0.x + cr, a0.y + ci);
    b = make_float2(a0.x - cr, a0.y - ci);
}
__device__ __forceinline__ int SW(int a) { return a ^ ((a >> 5) & 15); }

// ---------------- fused rfft -> gates -> modReLU -> irfft ---------------------
// reads f32 sequence from buf, writes f16 sequence to ubf (same layout).
__global__ __launch_bounds__(256)
void fft_gates_kernel(const float* __restrict__ buf, u16* __restrict__ ubf,
                      const float* __restrict__ gri, const float* __restrict__ modb,
                      const float2* __restrict__ Tg) {
    __shared__ float2 cf[MHALF];
    const int t = threadIdx.x;
    const int w = blockIdx.x;
    const int b = w & 3;
    const float2* seq = (const float2*)(buf + (size_t)w * SS);
    u16* useq = ubf + (size_t)w * SS;

    const int t5 = t & 31;
    const int t3 = t & 3;
    const int c32 = ((t >> 5) << 8) | t5;    // base for 32-span group
    const int d4  = ((t >> 2) << 5) | t3;    // base for 4-span group

    float2 r[8];

    // ---- load + G1: stages 10,9,8 (span 256) ----
    #pragma unroll
    for (int u = 0; u < 8; ++u) r[u] = seq[t + 256 * u];
    #pragma unroll
    for (int u = 0; u < 4; ++u) {
        float2 tw = Tg[1024 + t + 256 * u];
        bfly_f(r[u], r[u + 4], tw.x, tw.y);
    }
    {
        float2 tw0 = Tg[512 + t], tw1 = Tg[512 + t + 256];
        bfly_f(r[0], r[2], tw0.x, tw0.y);
        bfly_f(r[1], r[3], tw1.x, tw1.y);
        bfly_f(r[4], r[6], tw0.x, tw0.y);
        bfly_f(r[5], r[7], tw1.x, tw1.y);
        float2 tw = Tg[256 + t];
        bfly_f(r[0], r[1], tw.x, tw.y);
        bfly_f(r[2], r[3], tw.x, tw.y);
        bfly_f(r[4], r[5], tw.x, tw.y);
        bfly_f(r[6], r[7], tw.x, tw.y);
    }
    #pragma unroll
    for (int u = 0; u < 8; ++u) cf[SW(t + 256 * u)] = r[u];
    __syncthreads();

    // ---- G2: stages 7,6,5 (span 32) ----
    #pragma unroll
    for (int u = 0; u < 8; ++u) r[u] = cf[SW(c32 + 32 * u)];
    #pragma unroll
    for (int u = 0; u < 4; ++u) {
        float2 tw = Tg[128 + t5 + 32 * u];
        bfly_f(r[u], r[u + 4], tw.x, tw.y);
    }
    {
        float2 tw0 = Tg[64 + t5], tw1 = Tg[64 + t5 + 32];
        bfly_f(r[0], r[2], tw0.x, tw0.y);
        bfly_f(r[1], r[3], tw1.x, tw1.y);
        bfly_f(r[4], r[6], tw0.x, tw0.y);
        bfly_f(r[5], r[7], tw1.x, tw1.y);
        float2 tw = Tg[32 + t5];
        bfly_f(r[0], r[1], tw.x, tw.y);
        bfly_f(r[2], r[3], tw.x, tw.y);
        bfly_f(r[4], r[5], tw.x, tw.y);
        bfly_f(r[6], r[7], tw.x, tw.y);
    }
    #pragma unroll
    for (int u = 0; u < 8; ++u) cf[SW(c32 + 32 * u)] = r[u];
    __syncthreads();

    // ---- G3: stages 4,3,2 (span 4) ----
    #pragma unroll
    for (int u = 0; u < 8; ++u) r[u] = cf[SW(d4 + 4 * u)];
    #pragma unroll
    for (int u = 0; u < 4; ++u) {
        float2 tw = Tg[16 + t3 + 4 * u];
        bfly_f(r[u], r[u + 4], tw.x, tw.y);
    }
    {
        float2 tw0 = Tg[8 + t3], tw1 = Tg[8 + t3 + 4];
        bfly_f(r[0], r[2], tw0.x, tw0.y);
        bfly_f(r[1], r[3], tw1.x, tw1.y);
        bfly_f(r[4], r[6], tw0.x, tw0.y);
        bfly_f(r[5], r[7], tw1.x, tw1.y);
        float2 tw = Tg[4 + t3];
        bfly_f(r[0], r[1], tw.x, tw.y);
        bfly_f(r[2], r[3], tw.x, tw.y);
        bfly_f(r[4], r[5], tw.x, tw.y);
        bfly_f(r[6], r[7], tw.x, tw.y);
    }
    #pragma unroll
    for (int u = 0; u < 8; ++u) cf[SW(d4 + 4 * u)] = r[u];
    __syncthreads();

    // ---- G4: stages 1,0 (span 1; 8 consecutive) ----
    #pragma unroll
    for (int u = 0; u < 8; ++u) r[u] = cf[SW(8 * t + u)];
    bfly_f(r[0], r[2], 1.f, 0.f);
    bfly_f(r[1], r[3], 0.f, 1.f);
    bfly_f(r[4], r[6], 1.f, 0.f);
    bfly_f(r[5], r[7], 0.f, 1.f);
    bfly_f(r[0], r[1], 1.f, 0.f);
    bfly_f(r[2], r[3], 1.f, 0.f);
    bfly_f(r[4], r[5], 1.f, 0.f);
    bfly_f(r[6], r[7], 1.f, 0.f);
    #pragma unroll
    for (int u = 0; u < 8; ++u) cf[SW(8 * t + u)] = r[u];
    __syncthreads();

    // ---- spectrum: unpack real-FFT bins (ortho /64), gates, modReLU, repack ----
    const float bias = modb[0];
    const float* gre = gri + (size_t)b * 2 * NFREQ;
    const float* gim = gre + NFREQ;
    const float inv64 = 1.0f / 64.0f;
    for (int k = t; k < 1024; k += 256) {
        if (k == 0) {
            float2 c0 = cf[SW(0)];
            float z0 = (c0.x + c0.y) * inv64;
            float zM = (c0.x - c0.y) * inv64;
            float zr = z0 * gre[0], zi = z0 * gim[0];
            modrelu_apply(zr, zi, bias);
            float yr = zM * gre[2048], yi = zM * gim[2048];
            modrelu_apply(yr, yi, bias);
            cf[SW(0)] = make_float2(0.5f * (zr + yr), 0.5f * (zr - yr));
            float2 c1 = cf[SW(1)];
            float z1r = c1.x * inv64, z1i = -c1.y * inv64;
            float g1r = gre[1024], g1i = gim[1024];
            float pr = z1r * g1r - z1i * g1i;
            float pi2 = z1r * g1i + z1i * g1r;
            modrelu_apply(pr, pi2, bias);
            cf[SW(1)] = make_float2(pr, -pi2);
        } else {
            int kb = 2048 - k;
            int p1 = SW((int)(__brev((unsigned)k) >> 21));
            int p2 = SW((int)(__brev((unsigned)kb) >> 21));
            float2 ca = cf[p1];
            float2 cb2 = cf[p2];
            float Er = 0.5f * (ca.x + cb2.x), Ei = 0.5f * (ca.y - cb2.y);
            float Dr = 0.5f * (ca.x - cb2.x), Di = 0.5f * (ca.y + cb2.y);
            float Or = Di, Oi = -Dr;
            float2 t2 = Tg[2048 + k];
            float cs = t2.x, sn = t2.y;
            float Wr = cs, Wi = -sn;
            float WOr = Wr * Or - Wi * Oi, WOi = Wr * Oi + Wi * Or;
            float zkr = (Er + WOr) * inv64, zki = (Ei + WOi) * inv64;
            float zbr = (Er - WOr) * inv64, zbi = -(Ei - WOi) * inv64;
            float gkr = gre[k], gki = gim[k];
            float ar = zkr * gkr - zki * gki, ai = zkr * gki + zki * gkr;
            modrelu_apply(ar, ai, bias);
            float gbr = gre[kb], gbi = gim[kb];
            float br2 = zbr * gbr - zbi * gbi, bi2 = zbr * gbi + zbi * gbr;
            modrelu_apply(br2, bi2, bias);
            float Epr = 0.5f * (ar + br2), Epi = 0.5f * (ai - bi2);
            float Dpr = 0.5f * (ar - br2), Dpi = 0.5f * (ai + bi2);
            float Opr = cs * Dpr - sn * Dpi, Opi = cs * Dpi + sn * Dpr;
            cf[p1] = make_float2(Epr - Opi, Epi + Opr);
            cf[p2] = make_float2(Epr + Opi, -Epi + Opr);
        }
    }
    __syncthreads();

    // ---- inverse G4': stages 0,1 ----
    #pragma unroll
    for (int u = 0; u < 8; ++u) r[u] = cf[SW(8 * t + u)];
    bfly_i(r[0], r[1], 1.f, 0.f);
    bfly_i(r[2], r[3], 1.f, 0.f);
    bfly_i(r[4], r[5], 1.f, 0.f);
    bfly_i(r[6], r[7], 1.f, 0.f);
    bfly_i(r[0], r[2], 1.f, 0.f);
    bfly_i(r[1], r[3], 0.f, 1.f);
    bfly_i(r[4], r[6], 1.f, 0.f);
    bfly_i(r[5], r[7], 0.f, 1.f);
    #pragma unroll
    for (int u = 0; u < 8; ++u) cf[SW(8 * t + u)] = r[u];
    __syncthreads();

    // ---- inverse G3': stages 2,3,4 ----
    #pragma unroll
    for (int u = 0; u < 8; ++u) r[u] = cf[SW(d4 + 4 * u)];
    {
        float2 tw = Tg[4 + t3];
        bfly_i(r[0], r[1], tw.x, tw.y);
        bfly_i(r[2], r[3], tw.x, tw.y);
        bfly_i(r[4], r[5], tw.x, tw.y);
        bfly_i(r[6], r[7], tw.x, tw.y);
        float2 tw0 = Tg[8 + t3], tw1 = Tg[8 + t3 + 4];
        bfly_i(r[0], r[2], tw0.x, tw0.y);
        bfly_i(r[1], r[3], tw1.x, tw1.y);
        bfly_i(r[4], r[6], tw0.x, tw0.y);
        bfly_i(r[5], r[7], tw1.x, tw1.y);
    }
    #pragma unroll
    for (int u = 0; u < 4; ++u) {
        float2 tw = Tg[16 + t3 + 4 * u];
        bfly_i(r[u], r[u + 4], tw.x, tw.y);
    }
    #pragma unroll
    for (int u = 0; u < 8; ++u) cf[SW(d4 + 4 * u)] = r[u];
    __syncthreads();

    // ---- inverse G2': stages 5,6,7 ----
    #pragma unroll
    for (int u = 0; u < 8; ++u) r[u] = cf[SW(c32 + 32 * u)];
    {
        float2 tw = Tg[32 + t5];
        bfly_i(r[0], r[1], tw.x, tw.y);
        bfly_i(r[2], r[3], tw.x, tw.y);
        bfly_i(r[4], r[5], tw.x, tw.y);
        bfly_i(r[6], r[7], tw.x, tw.y);
        float2 tw0 = Tg[64 + t5], tw1 = Tg[64 + t5 + 32];
        bfly_i(r[0], r[2], tw0.x, tw0.y);
        bfly_i(r[1], r[3], tw1.x, tw1.y);
        bfly_i(r[4], r[6], tw0.x, tw0.y);
        bfly_i(r[5], r[7], tw1.x, tw1.y);
    }
    #pragma unroll
    for (int u = 0; u < 4; ++u) {
        float2 tw = Tg[128 + t5 + 32 * u];
        bfly_i(r[u], r[u + 4], tw.x, tw.y);
    }
    #pragma unroll
    for (int u = 0; u < 8; ++u) cf[SW(c32 + 32 * u)] = r[u];
    __syncthreads();

    // ---- inverse G1': stages 8,9,10 + scale + f16 store ----
    #pragma unroll
    for (int u = 0; u < 8; ++u) r[u] = cf[SW(t + 256 * u)];
    {
        float2 tw = Tg[256 + t];
        bfly_i(r[0], r[1], tw.x, tw.y);
        bfly_i(r[2], r[3], tw.x, tw.y);
        bfly_i(r[4], r[5], tw.x, tw.y);
        bfly_i(r[6], r[7], tw.x, tw.y);
        float2 tw0 = Tg[512 + t], tw1 = Tg[512 + t + 256];
        bfly_i(r[0], r[2], tw0.x, tw0.y);
        bfly_i(r[1], r[3], tw1.x, tw1.y);
        bfly_i(r[4], r[6], tw0.x, tw0.y);
        bfly_i(r[5], r[7], tw1.x, tw1.y);
    }
    #pragma unroll
    for (int u = 0; u < 4; ++u) {
        float2 tw = Tg[1024 + t + 256 * u];
        bfly_i(r[u], r[u + 4], tw.x, tw.y);
    }
    const float s32 = 1.0f / 32.0f;  // 64 (ortho) / 2048 (ifft norm)
    #pragma unroll
    for (int u = 0; u < 8; ++u) {
        ushort2 o;
        o.x = f2h(r[u].x * s32);
        o.y = f2h(r[u].y * s32);
        ((ushort2*)useq)[t + 256 * u] = o;
    }
}

extern "C" void kernel_launch(void* const* d_in, const int* in_sizes, int n_in,
                              void* d_out, int out_size, void* d_ws, size_t ws_size,
                              hipStream_t stream) {
    const float* x        = (const float*)d_in[0];
    const float* W_q      = (const float*)d_in[1];
    const float* W_v      = (const float*)d_in[2];
    const float* W_o      = (const float*)d_in[3];
    const float* ln_gamma = (const float*)d_in[4];
    const float* ln_beta  = (const float*)d_in[5];
    const float* mlp_w1   = (const float*)d_in[6];
    const float* mlp_b1   = (const float*)d_in[7];
    const float* mlp_w2   = (const float*)d_in[8];
    const float* mlp_b2   = (const float*)d_in[9];
    const float* mod_bias = (const float*)d_in[10];
    float* out = (float*)d_out;

    // workspace layout (floats)
    float* ws = (float*)d_ws;
    float* xsum     = ws + 262144;           // 4096
    float* q_shared = ws + 266240;           // 256
    float* hdn      = ws + 266496;           // 4096
    float* gri      = ws + 270592;           // 16392 (ends 286984)
    float* mq       = ws + 286984;           // 4096 (ends 291080)
    float2* twid    = (float2*)(ws + 291080); // 3072 float2 (ends 297224)
    float* buf0     = ws + 297984;           // 16777216 floats (64 MiB), [1024][16384]
    float* partial  = buf0;                  // 1024*1024 floats, dead before V GEMM
    u16* bfbase = (u16*)(ws + 297984 + 16777216);
    u16* xut_f  = bfbase;                    // 16777216 u16: x_f16, later reused as ut
    u16* u_f    = bfbase + 16777216;         // f16 u [1024][16384] (fft output)
    u16* wv_f   = bfbase + 33554432;         // 1048576
    u16* wo_f   = bfbase + 35651584;         // 1048576

    twiddle_init_kernel<<<12, 256, 0, stream>>>(twid);

    // fused x f16-convert + colsum pass 1 (partial aliases buf0)
    split_x_colsum_kernel<<<1024, 256, 0, stream>>>(x, xut_f, partial);
    {
        dim3 g(4, 4);
        colsum2_kernel<<<g, 256, 0, stream>>>(partial, xsum);
    }
    gates1a_kernel<<<256, 256, 0, stream>>>(xsum, W_q, mq);
    gates1b_kernel<<<4, 256, 0, stream>>>(mq, ln_gamma, ln_beta, q_shared);
    gates2_kernel<<<16, 256, 0, stream>>>(q_shared, mlp_w1, mlp_b1, hdn);
    gates3_kernel<<<1025, 256, 0, stream>>>(hdn, mlp_w2, mlp_b2, gri);

    // weight f16 conversions
    cvt_f16_kernel<<<512, 256, 0, stream>>>(W_v, wv_f, 262144);
    cvt_f16_kernel<<<512, 256, 0, stream>>>(W_o, wo_f, 262144);

    // V projection (transposed output), f16: buf0[j][bs] = Wv[j,:]·x[bs,:]
    // M=1024 (j), N=16384 (bs): mtiles=4, ntiles=64 -> 256 blocks
    gemm_f16_kernel<<<256, 512, 0, stream>>>(wv_f, xut_f,
                                             buf0, 4, 64, 1024, 16384);

    // fused spectral mixing: buf0 f32 -> u_f f16
    fft_gates_kernel<<<4096, 256, 0, stream>>>(buf0, u_f, gri, mod_bias, twid);

    // transpose u: u_f [1024][16384] -> xut_f [16384][1024] (pure u16 permute)
    {
        dim3 g(256, 16);
        transpose_u16_kernel<<<g, 256, 0, stream>>>(u_f, xut_f);
    }

    // O projection, f16: out[bs][jo] = ut[bs,:]·Wo[jo,:]
    // M=16384 (bs), N=1024 (jo): mtiles=64, ntiles=4 -> 256 blocks
    gemm_f16_kernel<<<256, 512, 0, stream>>>(xut_f, wo_f,
                                             out, 64, 4, 1024, 1024);
}

// Round 12
// 194.661 us; speedup vs baseline: 6.7199x; 1.0760x over previous
//
#include <hip/hip_runtime.h>
#include <math.h>
#include <stdint.h>

#define PI_F 3.14159265358979323846f

// Problem constants
#define BB 4
#define SS 4096
#define DD 1024
#define HH 16
#define DHD 64
#define NFREQ 2049   // 4096/2 + 1
#define MHALF 2048   // half-size complex FFT length

typedef unsigned short u16;
typedef __attribute__((ext_vector_type(8))) _Float16 half8;  // MFMA f16 A/B frag
typedef __attribute__((ext_vector_type(4))) float f32x4;     // MFMA C/D frag
typedef __attribute__((ext_vector_type(2))) float f32x2;     // packed-f32 complex
typedef __attribute__((ext_vector_type(4))) unsigned short u16x4;

// ---- f16 helpers (RTNE via v_cvt) ----
__device__ __forceinline__ u16 f2h(float f) {
    union { _Float16 h; u16 u; } cv;
    cv.h = (_Float16)f;
    return cv.u;
}
__device__ __forceinline__ float h2f(u16 u) {
    union { u16 u; _Float16 h; } cv;
    cv.u = u;
    return (float)cv.h;
}

__device__ __forceinline__ void modrelu_apply(float& zr, float& zi, float bias) {
    float mag = sqrtf(zr * zr + zi * zi);
    float scale = fmaxf(mag + bias, 0.0f) / fmaxf(mag, 1e-12f);
    zr *= scale; zi *= scale;
}

// async global->LDS, 16B per lane (HW: dest = wave-uniform base + lane*16)
__device__ __forceinline__ void gload16(const u16* g, u16* l) {
    __builtin_amdgcn_global_load_lds(
        (const __attribute__((address_space(1))) void*)g,
        (__attribute__((address_space(3))) void*)l, 16, 0, 0);
}

// LDS byte-offset swizzle for GEMM staging (16B chunks): XOR chunk bits [4:3]
// into chunk bits [1:0]; involution, matches the pre-swizzled staging order.
__device__ __forceinline__ int swz(int byteoff) {
    return byteoff ^ (((byteoff >> 7) & 3) << 4);
}

#define MFMA_F16 __builtin_amdgcn_mfma_f32_16x16x32_f16

// ---------------- fused x -> f16 convert + column partial sums ---------------
// grid 1024 = (b, s-chunk of 16); thread t owns columns 4t..4t+3
__global__ __launch_bounds__(256)
void split_x_colsum_kernel(const float* __restrict__ x, u16* __restrict__ xf,
                           float* __restrict__ partial) {
    int blk = blockIdx.x;
    int b = blk >> 8;
    int s0 = (blk & 255) * 16;
    int t = threadIdx.x;
    const float* xp = x + ((size_t)b * SS + s0) * DD;
    float4 acc = make_float4(0.f, 0.f, 0.f, 0.f);
    for (int s = 0; s < 16; ++s) {
        float4 v = ((const float4*)(xp + (size_t)s * DD))[t];
        acc.x += v.x; acc.y += v.y; acc.z += v.z; acc.w += v.w;
        u16x4 h;
        h.x = f2h(v.x); h.y = f2h(v.y); h.z = f2h(v.z); h.w = f2h(v.w);
        ((u16x4*)(xf + (size_t)(b * SS + s0 + s) * DD))[t] = h;
    }
    ((float4*)(partial + (size_t)blk * DD))[t] = acc;
}

// grid (4 kchunks, 4 b); sums 256 partial rows per b
__global__ __launch_bounds__(256)
void colsum2_kernel(const float* __restrict__ partial, float* __restrict__ xsum) {
    int b = blockIdx.y;
    int k = blockIdx.x * 256 + threadIdx.x;
    float acc = 0.f;
    for (int c = 0; c < 256; ++c)
        acc += partial[((size_t)(b * 256 + c)) * DD + k];
    xsum[b * DD + k] = acc;
}

// ---------------- mq[b][j] = dot(xsum[b]/S, Wq[j]) ; grid 256, 1 wave per row j
__global__ __launch_bounds__(256)
void gates1a_kernel(const float* __restrict__ xsum, const float* __restrict__ Wq,
                    float* __restrict__ mq) {
    __shared__ float xb[4][1024];
    int t = threadIdx.x;
    for (int i = t; i < 4096; i += 256)
        xb[i >> 10][i & 1023] = xsum[i] * (1.0f / 4096.0f);
    __syncthreads();
    int wv = t >> 6, l = t & 63;
    int j = blockIdx.x * 4 + wv;
    const float* wrow = Wq + (size_t)j * DD;
    float a0 = 0.f, a1 = 0.f, a2 = 0.f, a3 = 0.f;
    #pragma unroll 4
    for (int it = 0; it < 16; ++it) {
        int idx = l + it * 64;
        float wval = wrow[idx];
        a0 += xb[0][idx] * wval;
        a1 += xb[1][idx] * wval;
        a2 += xb[2][idx] * wval;
        a3 += xb[3][idx] * wval;
    }
    for (int off = 32; off > 0; off >>= 1) {
        a0 += __shfl_down(a0, off, 64);
        a1 += __shfl_down(a1, off, 64);
        a2 += __shfl_down(a2, off, 64);
        a3 += __shfl_down(a3, off, 64);
    }
    if (l == 0) {
        mq[j] = a0; mq[1024 + j] = a1; mq[2048 + j] = a2; mq[3072 + j] = a3;
    }
}

// ---------------- LayerNorm per head over mq, mean over heads -> q_shared[b][64]
__global__ __launch_bounds__(256)
void gates1b_kernel(const float* __restrict__ mq, const float* __restrict__ gamma,
                    const float* __restrict__ beta, float* __restrict__ q_shared) {
    __shared__ float qacc[4][64];
    int b = blockIdx.x;
    int t = threadIdx.x;
    int wv = t >> 6, l = t & 63;
    float part = 0.f;
    for (int hh = 0; hh < 4; ++hh) {
        int h = wv * 4 + hh;
        float v = mq[b * 1024 + h * 64 + l];
        float s1 = v, s2 = v * v;
        for (int off = 32; off > 0; off >>= 1) {
            s1 += __shfl_xor(s1, off, 64);
            s2 += __shfl_xor(s2, off, 64);
        }
        float mu = s1 * (1.0f / 64.0f);
        float var = s2 * (1.0f / 64.0f) - mu * mu;
        part += (v - mu) * rsqrtf(var + 1e-5f) * gamma[l] + beta[l];
    }
    qacc[wv][l] = part;
    __syncthreads();
    if (t < 64) {
        float s = qacc[0][t] + qacc[1][t] + qacc[2][t] + qacc[3][t];
        q_shared[b * 64 + t] = s * (1.0f / 16.0f);
    }
}

// ---------------- hdn = gelu(q_shared @ w1^T + b1)
__global__ __launch_bounds__(256)
void gates2_kernel(const float* __restrict__ q_shared, const float* __restrict__ w1,
                   const float* __restrict__ b1, float* __restrict__ hdn) {
    __shared__ float qs[64];
    int blk = blockIdx.x;
    int b = blk >> 2;
    int i0 = (blk & 3) * 256;
    int t = threadIdx.x;
    if (t < 64) qs[t] = q_shared[b * 64 + t];
    __syncthreads();
    int i = i0 + t;
    const float* wrow = w1 + (size_t)i * DHD;
    float acc = b1[i];
    #pragma unroll 8
    for (int d = 0; d < 64; ++d) acc += qs[d] * wrow[d];
    float g = 0.5f * acc * (1.0f + erff(acc * 0.70710678118654752f));
    hdn[b * DD + i] = g;
}

// ---------------- gri = hdn @ w2^T + b2 ; one wave per output row, all 4 b at once
__global__ __launch_bounds__(256)
void gates3_kernel(const float* __restrict__ hdn, const float* __restrict__ w2,
                   const float* __restrict__ b2, float* __restrict__ gri) {
    int t = threadIdx.x;
    int wv = t >> 6, l = t & 63;
    int r = blockIdx.x * 4 + wv;
    if (r >= 2 * NFREQ) return;
    const float* wrow = w2 + (size_t)r * DD;
    float a0 = 0.f, a1 = 0.f, a2 = 0.f, a3 = 0.f;
    for (int it = 0; it < 16; ++it) {
        int idx = l + it * 64;
        float wval = wrow[idx];
        a0 += hdn[idx] * wval;
        a1 += hdn[1024 + idx] * wval;
        a2 += hdn[2048 + idx] * wval;
        a3 += hdn[3072 + idx] * wval;
    }
    for (int off = 32; off > 0; off >>= 1) {
        a0 += __shfl_down(a0, off, 64);
        a1 += __shfl_down(a1, off, 64);
        a2 += __shfl_down(a2, off, 64);
        a3 += __shfl_down(a3, off, 64);
    }
    if (l == 0) {
        float bb = b2[r];
        gri[r] = a0 + bb;
        gri[2 * NFREQ + r] = a1 + bb;
        gri[2 * 2 * NFREQ + r] = a2 + bb;
        gri[3 * 2 * NFREQ + r] = a3 + bb;
    }
}

// ---------------- f32 -> f16 convert (weights) ----------------
__global__ __launch_bounds__(256)
void cvt_f16_kernel(const float* __restrict__ src, u16* __restrict__ dst, int n4) {
    int idx = blockIdx.x * 256 + threadIdx.x;
    int stride = gridDim.x * 256;
    for (; idx < n4; idx += stride) {
        float4 v = ((const float4*)src)[idx];
        u16x4 h;
        h.x = f2h(v.x); h.y = f2h(v.y); h.z = f2h(v.z); h.w = f2h(v.w);
        ((u16x4*)dst)[idx] = h;
    }
}

// ---------------- u16 transpose: src [1024][16384] -> dst [16384][1024] -------
__global__ __launch_bounds__(256)
void transpose_u16_kernel(const u16* __restrict__ src, u16* __restrict__ dst) {
    __shared__ u16 tile[64][66];
    int s0 = blockIdx.x * 64;   // bs block
    int j0 = blockIdx.y * 64;   // feature block
    int t = threadIdx.x;
    int c = t & 63, r4 = t >> 6;
    #pragma unroll
    for (int rr = 0; rr < 64; rr += 4)
        tile[rr + r4][c] = src[(size_t)(j0 + rr + r4) * 16384 + s0 + c];
    __syncthreads();
    #pragma unroll
    for (int rr = 0; rr < 64; rr += 4) {
        int a = rr + r4;                 // local bs
        dst[(size_t)(s0 + a) * 1024 + j0 + c] = tile[c][a];
    }
}

// ---------------- f16 single-product MFMA GEMM, 256x256 tile, 4-deep pipeline -
// C[M][N] = A[M][K] * B[N][K]^T ; A,B single f16 planes (row-major, stride K).
// F16OUT: write C as f16 (u16) instead of f32 -- halves the C write traffic.
// [R8-verified pipeline discipline; R6/R7/R9 phase restructures regressed.]
template <bool F16OUT>
__global__ __launch_bounds__(512, 2)
void gemm_f16_kernel(const u16* __restrict__ A, const u16* __restrict__ B,
                     void* __restrict__ Cv, int mtiles, int ntiles, int K, int ldc) {
    __shared__ u16 lds[4][2][8192];   // [buf][plane: A,B][256 rows x 32 k]
    const int t = threadIdx.x;
    const int wid = __builtin_amdgcn_readfirstlane(t >> 6);
    const int lane = t & 63;

    // XCD-aware decode (blocks dispatch round-robin over 8 XCDs)
    const int bid = blockIdx.x;
    const int xcd = bid & 7;
    const int idx = bid >> 3;
    int mt, nt;
    if (ntiles >= mtiles) { mt = idx % mtiles; nt = xcd * (ntiles >> 3) + idx / mtiles; }
    else                  { nt = idx % ntiles; mt = xcd * (mtiles >> 3) + idx / ntiles; }
    const int m0 = mt * 256;
    const int n0 = nt * 256;
    const int wm = (wid >> 2) * 128;
    const int wn = (wid & 3) * 64;

    // staging: 32 chunk-ops of 1KB per tile (wave w gets ops g = w*4..w*4+3)
    const u16* gbase[4];
    u16* ldst[4];
    #pragma unroll
    for (int o = 0; o < 4; ++o) {
        int g = wid * 4 + o;
        int p = g >> 4;                  // 0 = A plane, 1 = B plane
        int j = ((g & 15) << 6) | lane;
        int c = j ^ ((j >> 3) & 3);
        int row = c >> 2, q = c & 3;
        const u16* base = (p == 0) ? A : B;
        int rbase = (p == 0) ? m0 : n0;
        gbase[o] = base + (size_t)(rbase + row) * K + q * 8;
        ldst[o] = &lds[0][0][0] + (size_t)p * 8192 + (size_t)j * 8;
    }

#define STG(KT, BUF)                                                             \
    {                                                                            \
        _Pragma("unroll")                                                        \
        for (int o = 0; o < 4; ++o)                                              \
            gload16(gbase[o] + (size_t)(KT) * 32, ldst[o] + (BUF) * 16384);      \
    }

    f32x4 acc[8][4] = {};
    const int KT = K >> 5;

    // prologue: stage tiles 0..2; wait for tile 0 only (8 newest may fly)
    STG(0, 0);
    STG(1, 1);
    STG(2, 2);
    asm volatile("s_waitcnt vmcnt(8)" ::: "memory");
    __builtin_amdgcn_s_barrier();

    for (int kt = 0; kt < KT; ++kt) {
        const u16* lb = &lds[kt & 3][0][0];
        // issue stage for tile kt+3 first: longest latency cover
        if (kt + 3 < KT) STG(kt + 3, (kt + 3) & 3);

        half8 b[4];
        #pragma unroll
        for (int j = 0; j < 4; ++j) {
            int s = swz((wn + (lane & 15) + j * 16) * 64 + (lane >> 4) * 16);
            b[j] = *(const half8*)(lb + 8192 + (s >> 1));
        }
        __builtin_amdgcn_s_setprio(1);
        #pragma unroll
        for (int ip = 0; ip < 4; ++ip) {
            int s0 = swz((wm + (lane & 15) + (2 * ip) * 16) * 64 + (lane >> 4) * 16);
            int s1 = swz((wm + (lane & 15) + (2 * ip + 1) * 16) * 64 + (lane >> 4) * 16);
            half8 a0 = *(const half8*)(lb + (s0 >> 1));
            half8 a1 = *(const half8*)(lb + (s1 >> 1));
            #pragma unroll
            for (int j = 0; j < 4; ++j) acc[2 * ip][j]     = MFMA_F16(a0, b[j], acc[2 * ip][j], 0, 0, 0);
            #pragma unroll
            for (int j = 0; j < 4; ++j) acc[2 * ip + 1][j] = MFMA_F16(a1, b[j], acc[2 * ip + 1][j], 0, 0, 0);
        }
        __builtin_amdgcn_s_setprio(0);
        // make buffer kt+1 ready: wait until only younger tiles' loads remain
        if (kt <= KT - 4)      { asm volatile("s_waitcnt vmcnt(8)" ::: "memory"); }
        else if (kt == KT - 3) { asm volatile("s_waitcnt vmcnt(4)" ::: "memory"); }
        else                   { asm volatile("s_waitcnt vmcnt(0)" ::: "memory"); }
        __builtin_amdgcn_s_barrier();
    }
#undef STG

    // epilogue: C/D layout = col (lane&15), row (lane>>4)*4 + e   [m89-verified]
    const int cb2 = n0 + wn + (lane & 15);
    #pragma unroll
    for (int i = 0; i < 8; ++i) {
        int rb = m0 + wm + i * 16 + ((lane >> 4) << 2);
        #pragma unroll
        for (int e = 0; e < 4; ++e) {
            if (F16OUT) {
                u16* crow = (u16*)Cv + (size_t)(rb + e) * ldc + cb2;
                #pragma unroll
                for (int j = 0; j < 4; ++j)
                    crow[j * 16] = f2h(acc[i][j][e]);
            } else {
                float* crow = (float*)Cv + (size_t)(rb + e) * ldc + cb2;
                #pragma unroll
                for (int j = 0; j < 4; ++j)
                    crow[j * 16] = acc[i][j][e];
            }
        }
    }
}

// ---------------- twiddle table init (global, shared by all FFT blocks) -------
__global__ __launch_bounds__(256)
void twiddle_init_kernel(float2* __restrict__ Tg) {
    int idx = blockIdx.x * 256 + threadIdx.x;
    if (idx >= 3072) return;
    float cs = 1.f, sn = 0.f;
    if (idx >= 2048) {
        sincosf(PI_F * (float)(idx - 2048) * (1.0f / 2048.0f), &sn, &cs);
    } else if (idx >= 1) {
        int s = 31 - __clz(idx);
        int h = 1 << s;
        sincosf(PI_F * (float)(idx - h) / (float)h, &sn, &cs);
    }
    Tg[idx] = make_float2(cs, sn);
}

// ---- packed-f32 butterflies: a,b are (re,im); compiles to v_pk_*_f32 ----
__device__ __forceinline__ void bfly_f(f32x2& a, f32x2& b, float cs, float sn) {
    f32x2 s = a + b;
    f32x2 d = a - b;
    f32x2 dsw = __builtin_shufflevector(d, d, 1, 0);   // (im, re)
    a = s;
    b = d * cs + dsw * (f32x2){sn, -sn};   // (dr*cs+di*sn, di*cs-dr*sn)
}
__device__ __forceinline__ void bfly_i(f32x2& a, f32x2& b, float cs, float sn) {
    f32x2 bsw = __builtin_shufflevector(b, b, 1, 0);   // (im, re)
    f32x2 c = b * cs + bsw * (f32x2){-sn, sn};         // b * e^{+i th}
    b = a - c;
    a = a + c;
}
__device__ __forceinline__ int SW(int a) { return a ^ ((a >> 5) & 15); }

// ---------------- fused rfft -> gates -> modReLU -> irfft, in-place f16 ------
__global__ __launch_bounds__(256)
void fft_gates_kernel(u16* __restrict__ vbuf, const float* __restrict__ gri,
                      const float* __restrict__ modb, const float2* __restrict__ Tg) {
    __shared__ f32x2 cf[MHALF];
    const int t = threadIdx.x;
    const int w = blockIdx.x;
    const int b = w & 3;
    u16* seq = vbuf + (size_t)w * SS;

    const int t5 = t & 31;
    const int t3 = t & 3;
    const int c32 = ((t >> 5) << 8) | t5;    // base for 32-span group
    const int d4  = ((t >> 2) << 5) | t3;    // base for 4-span group

    f32x2 r[8];

    // ---- load (f16 pairs) + G1: stages 10,9,8 (span 256) ----
    #pragma unroll
    for (int u = 0; u < 8; ++u) {
        ushort2 v = ((const ushort2*)seq)[t + 256 * u];
        r[u] = (f32x2){h2f(v.x), h2f(v.y)};
    }
    #pragma unroll
    for (int u = 0; u < 4; ++u) {
        float2 tw = Tg[1024 + t + 256 * u];
        bfly_f(r[u], r[u + 4], tw.x, tw.y);
    }
    {
        float2 tw0 = Tg[512 + t], tw1 = Tg[512 + t + 256];
        bfly_f(r[0], r[2], tw0.x, tw0.y);
        bfly_f(r[1], r[3], tw1.x, tw1.y);
        bfly_f(r[4], r[6], tw0.x, tw0.y);
        bfly_f(r[5], r[7], tw1.x, tw1.y);
        float2 tw = Tg[256 + t];
        bfly_f(r[0], r[1], tw.x, tw.y);
        bfly_f(r[2], r[3], tw.x, tw.y);
        bfly_f(r[4], r[5], tw.x, tw.y);
        bfly_f(r[6], r[7], tw.x, tw.y);
    }
    #pragma unroll
    for (int u = 0; u < 8; ++u) cf[SW(t + 256 * u)] = r[u];
    __syncthreads();

    // ---- G2: stages 7,6,5 (span 32) ----
    #pragma unroll
    for (int u = 0; u < 8; ++u) r[u] = cf[SW(c32 + 32 * u)];
    #pragma unroll
    for (int u = 0; u < 4; ++u) {
        float2 tw = Tg[128 + t5 + 32 * u];
        bfly_f(r[u], r[u + 4], tw.x, tw.y);
    }
    {
        float2 tw0 = Tg[64 + t5], tw1 = Tg[64 + t5 + 32];
        bfly_f(r[0], r[2], tw0.x, tw0.y);
        bfly_f(r[1], r[3], tw1.x, tw1.y);
        bfly_f(r[4], r[6], tw0.x, tw0.y);
        bfly_f(r[5], r[7], tw1.x, tw1.y);
        float2 tw = Tg[32 + t5];
        bfly_f(r[0], r[1], tw.x, tw.y);
        bfly_f(r[2], r[3], tw.x, tw.y);
        bfly_f(r[4], r[5], tw.x, tw.y);
        bfly_f(r[6], r[7], tw.x, tw.y);
    }
    #pragma unroll
    for (int u = 0; u < 8; ++u) cf[SW(c32 + 32 * u)] = r[u];
    __syncthreads();

    // ---- G3: stages 4,3,2 (span 4) ----
    #pragma unroll
    for (int u = 0; u < 8; ++u) r[u] = cf[SW(d4 + 4 * u)];
    #pragma unroll
    for (int u = 0; u < 4; ++u) {
        float2 tw = Tg[16 + t3 + 4 * u];
        bfly_f(r[u], r[u + 4], tw.x, tw.y);
    }
    {
        float2 tw0 = Tg[8 + t3], tw1 = Tg[8 + t3 + 4];
        bfly_f(r[0], r[2], tw0.x, tw0.y);
        bfly_f(r[1], r[3], tw1.x, tw1.y);
        bfly_f(r[4], r[6], tw0.x, tw0.y);
        bfly_f(r[5], r[7], tw1.x, tw1.y);
        float2 tw = Tg[4 + t3];
        bfly_f(r[0], r[1], tw.x, tw.y);
        bfly_f(r[2], r[3], tw.x, tw.y);
        bfly_f(r[4], r[5], tw.x, tw.y);
        bfly_f(r[6], r[7], tw.x, tw.y);
    }
    #pragma unroll
    for (int u = 0; u < 8; ++u) cf[SW(d4 + 4 * u)] = r[u];
    __syncthreads();

    // ---- G4: stages 1,0 (span 1; 8 consecutive) ----
    #pragma unroll
    for (int u = 0; u < 8; ++u) r[u] = cf[SW(8 * t + u)];
    bfly_f(r[0], r[2], 1.f, 0.f);
    bfly_f(r[1], r[3], 0.f, 1.f);
    bfly_f(r[4], r[6], 1.f, 0.f);
    bfly_f(r[5], r[7], 0.f, 1.f);
    bfly_f(r[0], r[1], 1.f, 0.f);
    bfly_f(r[2], r[3], 1.f, 0.f);
    bfly_f(r[4], r[5], 1.f, 0.f);
    bfly_f(r[6], r[7], 1.f, 0.f);
    #pragma unroll
    for (int u = 0; u < 8; ++u) cf[SW(8 * t + u)] = r[u];
    __syncthreads();

    // ---- spectrum: unpack real-FFT bins (ortho /64), gates, modReLU, repack ----
    const float bias = modb[0];
    const float* gre = gri + (size_t)b * 2 * NFREQ;
    const float* gim = gre + NFREQ;
    const float inv64 = 1.0f / 64.0f;
    for (int k = t; k < 1024; k += 256) {
        if (k == 0) {
            f32x2 c0 = cf[SW(0)];
            float z0 = (c0.x + c0.y) * inv64;
            float zM = (c0.x - c0.y) * inv64;
            float zr = z0 * gre[0], zi = z0 * gim[0];
            modrelu_apply(zr, zi, bias);
            float yr = zM * gre[2048], yi = zM * gim[2048];
            modrelu_apply(yr, yi, bias);
            cf[SW(0)] = (f32x2){0.5f * (zr + yr), 0.5f * (zr - yr)};
            f32x2 c1 = cf[SW(1)];
            float z1r = c1.x * inv64, z1i = -c1.y * inv64;
            float g1r = gre[1024], g1i = gim[1024];
            float pr = z1r * g1r - z1i * g1i;
            float pi2 = z1r * g1i + z1i * g1r;
            modrelu_apply(pr, pi2, bias);
            cf[SW(1)] = (f32x2){pr, -pi2};
        } else {
            int kb = 2048 - k;
            int p1 = SW((int)(__brev((unsigned)k) >> 21));
            int p2 = SW((int)(__brev((unsigned)kb) >> 21));
            f32x2 ca = cf[p1];
            f32x2 cb2 = cf[p2];
            float Er = 0.5f * (ca.x + cb2.x), Ei = 0.5f * (ca.y - cb2.y);
            float Dr = 0.5f * (ca.x - cb2.x), Di = 0.5f * (ca.y + cb2.y);
            float Or = Di, Oi = -Dr;
            float2 t2 = Tg[2048 + k];
            float cs = t2.x, sn = t2.y;
            float Wr = cs, Wi = -sn;
            float WOr = Wr * Or - Wi * Oi, WOi = Wr * Oi + Wi * Or;
            float zkr = (Er + WOr) * inv64, zki = (Ei + WOi) * inv64;
            float zbr = (Er - WOr) * inv64, zbi = -(Ei - WOi) * inv64;
            float gkr = gre[k], gki = gim[k];
            float ar = zkr * gkr - zki * gki, ai = zkr * gki + zki * gkr;
            modrelu_apply(ar, ai, bias);
            float gbr = gre[kb], gbi = gim[kb];
            float br2 = zbr * gbr - zbi * gbi, bi2 = zbr * gbi + zbi * gbr;
            modrelu_apply(br2, bi2, bias);
            float Epr = 0.5f * (ar + br2), Epi = 0.5f * (ai - bi2);
            float Dpr = 0.5f * (ar - br2), Dpi = 0.5f * (ai + bi2);
            float Opr = cs * Dpr - sn * Dpi, Opi = cs * Dpi + sn * Dpr;
            cf[p1] = (f32x2){Epr - Opi, Epi + Opr};
            cf[p2] = (f32x2){Epr + Opi, -Epi + Opr};
        }
    }
    __syncthreads();

    // ---- inverse G4': stages 0,1 ----
    #pragma unroll
    for (int u = 0; u < 8; ++u) r[u] = cf[SW(8 * t + u)];
    bfly_i(r[0], r[1], 1.f, 0.f);
    bfly_i(r[2], r[3], 1.f, 0.f);
    bfly_i(r[4], r[5], 1.f, 0.f);
    bfly_i(r[6], r[7], 1.f, 0.f);
    bfly_i(r[0], r[2], 1.f, 0.f);
    bfly_i(r[1], r[3], 0.f, 1.f);
    bfly_i(r[4], r[6], 1.f, 0.f);
    bfly_i(r[5], r[7], 0.f, 1.f);
    #pragma unroll
    for (int u = 0; u < 8; ++u) cf[SW(8 * t + u)] = r[u];
    __syncthreads();

    // ---- inverse G3': stages 2,3,4 ----
    #pragma unroll
    for (int u = 0; u < 8; ++u) r[u] = cf[SW(d4 + 4 * u)];
    {
        float2 tw = Tg[4 + t3];
        bfly_i(r[0], r[1], tw.x, tw.y);
        bfly_i(r[2], r[3], tw.x, tw.y);
        bfly_i(r[4], r[5], tw.x, tw.y);
        bfly_i(r[6], r[7], tw.x, tw.y);
        float2 tw0 = Tg[8 + t3], tw1 = Tg[8 + t3 + 4];
        bfly_i(r[0], r[2], tw0.x, tw0.y);
        bfly_i(r[1], r[3], tw1.x, tw1.y);
        bfly_i(r[4], r[6], tw0.x, tw0.y);
        bfly_i(r[5], r[7], tw1.x, tw1.y);
    }
    #pragma unroll
    for (int u = 0; u < 4; ++u) {
        float2 tw = Tg[16 + t3 + 4 * u];
        bfly_i(r[u], r[u + 4], tw.x, tw.y);
    }
    #pragma unroll
    for (int u = 0; u < 8; ++u) cf[SW(d4 + 4 * u)] = r[u];
    __syncthreads();

    // ---- inverse G2': stages 5,6,7 ----
    #pragma unroll
    for (int u = 0; u < 8; ++u) r[u] = cf[SW(c32 + 32 * u)];
    {
        float2 tw = Tg[32 + t5];
        bfly_i(r[0], r[1], tw.x, tw.y);
        bfly_i(r[2], r[3], tw.x, tw.y);
        bfly_i(r[4], r[5], tw.x, tw.y);
        bfly_i(r[6], r[7], tw.x, tw.y);
        float2 tw0 = Tg[64 + t5], tw1 = Tg[64 + t5 + 32];
        bfly_i(r[0], r[2], tw0.x, tw0.y);
        bfly_i(r[1], r[3], tw1.x, tw1.y);
        bfly_i(r[4], r[6], tw0.x, tw0.y);
        bfly_i(r[5], r[7], tw1.x, tw1.y);
    }
    #pragma unroll
    for (int u = 0; u < 4; ++u) {
        float2 tw = Tg[128 + t5 + 32 * u];
        bfly_i(r[u], r[u + 4], tw.x, tw.y);
    }
    #pragma unroll
    for (int u = 0; u < 8; ++u) cf[SW(c32 + 32 * u)] = r[u];
    __syncthreads();

    // ---- inverse G1': stages 8,9,10 + scale + f16 store ----
    #pragma unroll
    for (int u = 0; u < 8; ++u) r[u] = cf[SW(t + 256 * u)];
    {
        float2 tw = Tg[256 + t];
        bfly_i(r[0], r[1], tw.x, tw.y);
        bfly_i(r[2], r[3], tw.x, tw.y);
        bfly_i(r[4], r[5], tw.x, tw.y);
        bfly_i(r[6], r[7], tw.x, tw.y);
        float2 tw0 = Tg[512 + t], tw1 = Tg[512 + t + 256];
        bfly_i(r[0], r[2], tw0.x, tw0.y);
        bfly_i(r[1], r[3], tw1.x, tw1.y);
        bfly_i(r[4], r[6], tw0.x, tw0.y);
        bfly_i(r[5], r[7], tw1.x, tw1.y);
    }
    #pragma unroll
    for (int u = 0; u < 4; ++u) {
        float2 tw = Tg[1024 + t + 256 * u];
        bfly_i(r[u], r[u + 4], tw.x, tw.y);
    }
    const float s32 = 1.0f / 32.0f;  // 64 (ortho) / 2048 (ifft norm)
    #pragma unroll
    for (int u = 0; u < 8; ++u) {
        ushort2 o;
        o.x = f2h(r[u].x * s32);
        o.y = f2h(r[u].y * s32);
        ((ushort2*)seq)[t + 256 * u] = o;
    }
}

extern "C" void kernel_launch(void* const* d_in, const int* in_sizes, int n_in,
                              void* d_out, int out_size, void* d_ws, size_t ws_size,
                              hipStream_t stream) {
    const float* x        = (const float*)d_in[0];
    const float* W_q      = (const float*)d_in[1];
    const float* W_v      = (const float*)d_in[2];
    const float* W_o      = (const float*)d_in[3];
    const float* ln_gamma = (const float*)d_in[4];
    const float* ln_beta  = (const float*)d_in[5];
    const float* mlp_w1   = (const float*)d_in[6];
    const float* mlp_b1   = (const float*)d_in[7];
    const float* mlp_w2   = (const float*)d_in[8];
    const float* mlp_b2   = (const float*)d_in[9];
    const float* mod_bias = (const float*)d_in[10];
    float* out = (float*)d_out;

    // workspace layout (floats)
    float* ws = (float*)d_ws;
    float* partial  = ws;                    // 1048576 (1024 blocks x 1024)
    float* xsum     = ws + 1048576;          // 4096
    float* q_shared = ws + 1052672;          // 256
    float* hdn      = ws + 1052928;          // 4096
    float* gri      = ws + 1057024;          // 16392
    float* mq       = ws + 1073416;          // 4096 (ends 1077512)
    float2* twid    = (float2*)(ws + 1077512); // 3072 float2 (ends 1083656)
    u16* bfbase = (u16*)(ws + 1083904);
    u16* xut_f  = bfbase;                    // 16777216 u16: x_f16, later reused as ut
    u16* vbuf   = bfbase + 16777216;         // f16 V then u, [1024][16384] in-place fft
    u16* wv_f   = bfbase + 33554432;         // 1048576
    u16* wo_f   = bfbase + 34603008;         // 1048576

    twiddle_init_kernel<<<12, 256, 0, stream>>>(twid);

    // fused x f16-convert + colsum pass 1
    split_x_colsum_kernel<<<1024, 256, 0, stream>>>(x, xut_f, partial);
    {
        dim3 g(4, 4);
        colsum2_kernel<<<g, 256, 0, stream>>>(partial, xsum);
    }
    gates1a_kernel<<<256, 256, 0, stream>>>(xsum, W_q, mq);
    gates1b_kernel<<<4, 256, 0, stream>>>(mq, ln_gamma, ln_beta, q_shared);
    gates2_kernel<<<16, 256, 0, stream>>>(q_shared, mlp_w1, mlp_b1, hdn);
    gates3_kernel<<<1025, 256, 0, stream>>>(hdn, mlp_w2, mlp_b2, gri);

    // weight f16 conversions
    cvt_f16_kernel<<<512, 256, 0, stream>>>(W_v, wv_f, 262144);
    cvt_f16_kernel<<<512, 256, 0, stream>>>(W_o, wo_f, 262144);

    // V projection (transposed output), f16 in/out: vbuf[j][bs] = Wv[j,:]·x[bs,:]
    // M=1024 (j), N=16384 (bs): mtiles=4, ntiles=64 -> 256 blocks
    gemm_f16_kernel<true><<<256, 512, 0, stream>>>(wv_f, xut_f,
                                                   vbuf, 4, 64, 1024, 16384);

    // fused spectral mixing, in place on vbuf (f16 -> f16)
    fft_gates_kernel<<<4096, 256, 0, stream>>>(vbuf, gri, mod_bias, twid);

    // transpose u: vbuf [1024][16384] -> xut_f [16384][1024] (pure u16 permute)
    {
        dim3 g(256, 16);
        transpose_u16_kernel<<<g, 256, 0, stream>>>(vbuf, xut_f);
    }

    // O projection, f16 in / f32 out: out[bs][jo] = ut[bs,:]·Wo[jo,:]
    // M=16384 (bs), N=1024 (jo): mtiles=64, ntiles=4 -> 256 blocks
    gemm_f16_kernel<false><<<256, 512, 0, stream>>>(xut_f, wo_f,
                                                    out, 64, 4, 1024, 1024);
}

// Round 13
// 192.134 us; speedup vs baseline: 6.8082x; 1.0131x over previous
//
#include <hip/hip_runtime.h>
#include <math.h>
#include <stdint.h>

#define PI_F 3.14159265358979323846f

// Problem constants
#define BB 4
#define SS 4096
#define DD 1024
#define HH 16
#define DHD 64
#define NFREQ 2049   // 4096/2 + 1
#define MHALF 2048   // half-size complex FFT length

typedef unsigned short u16;
typedef __attribute__((ext_vector_type(8))) _Float16 half8;  // MFMA f16 A/B frag
typedef __attribute__((ext_vector_type(4))) float f32x4;     // MFMA C/D frag
typedef __attribute__((ext_vector_type(2))) float f32x2;     // packed-f32 complex
typedef __attribute__((ext_vector_type(4))) unsigned short u16x4;

// ---- f16 helpers (RTNE via v_cvt) ----
__device__ __forceinline__ u16 f2h(float f) {
    union { _Float16 h; u16 u; } cv;
    cv.h = (_Float16)f;
    return cv.u;
}
__device__ __forceinline__ float h2f(u16 u) {
    union { u16 u; _Float16 h; } cv;
    cv.u = u;
    return (float)cv.h;
}

__device__ __forceinline__ void modrelu_apply(float& zr, float& zi, float bias) {
    float mag = sqrtf(zr * zr + zi * zi);
    float scale = fmaxf(mag + bias, 0.0f) / fmaxf(mag, 1e-12f);
    zr *= scale; zi *= scale;
}

// async global->LDS, 16B per lane (HW: dest = wave-uniform base + lane*16)
__device__ __forceinline__ void gload16(const u16* g, u16* l) {
    __builtin_amdgcn_global_load_lds(
        (const __attribute__((address_space(1))) void*)g,
        (__attribute__((address_space(3))) void*)l, 16, 0, 0);
}

// LDS byte-offset swizzle for GEMM staging (16B chunks): XOR chunk bits [4:3]
// into chunk bits [1:0]; involution, matches the pre-swizzled staging order.
__device__ __forceinline__ int swz(int byteoff) {
    return byteoff ^ (((byteoff >> 7) & 3) << 4);
}

#define MFMA_F16 __builtin_amdgcn_mfma_f32_16x16x32_f16

// ---------------- fused x -> f16 convert + column partial sums ---------------
// grid 1024 = (b, s-chunk of 16); thread t owns columns 4t..4t+3
__global__ __launch_bounds__(256)
void split_x_colsum_kernel(const float* __restrict__ x, u16* __restrict__ xf,
                           float* __restrict__ partial) {
    int blk = blockIdx.x;
    int b = blk >> 8;
    int s0 = (blk & 255) * 16;
    int t = threadIdx.x;
    const float* xp = x + ((size_t)b * SS + s0) * DD;
    float4 acc = make_float4(0.f, 0.f, 0.f, 0.f);
    for (int s = 0; s < 16; ++s) {
        float4 v = ((const float4*)(xp + (size_t)s * DD))[t];
        acc.x += v.x; acc.y += v.y; acc.z += v.z; acc.w += v.w;
        u16x4 h;
        h.x = f2h(v.x); h.y = f2h(v.y); h.z = f2h(v.z); h.w = f2h(v.w);
        ((u16x4*)(xf + (size_t)(b * SS + s0 + s) * DD))[t] = h;
    }
    ((float4*)(partial + (size_t)blk * DD))[t] = acc;
}

// grid (4 kchunks, 4 b); sums 256 partial rows per b
__global__ __launch_bounds__(256)
void colsum2_kernel(const float* __restrict__ partial, float* __restrict__ xsum) {
    int b = blockIdx.y;
    int k = blockIdx.x * 256 + threadIdx.x;
    float acc = 0.f;
    for (int c = 0; c < 256; ++c)
        acc += partial[((size_t)(b * 256 + c)) * DD + k];
    xsum[b * DD + k] = acc;
}

// ---------------- mq[b][j] = dot(xsum[b]/S, Wq[j]) ; grid 256, 1 wave per row j
__global__ __launch_bounds__(256)
void gates1a_kernel(const float* __restrict__ xsum, const float* __restrict__ Wq,
                    float* __restrict__ mq) {
    __shared__ float xb[4][1024];
    int t = threadIdx.x;
    for (int i = t; i < 4096; i += 256)
        xb[i >> 10][i & 1023] = xsum[i] * (1.0f / 4096.0f);
    __syncthreads();
    int wv = t >> 6, l = t & 63;
    int j = blockIdx.x * 4 + wv;
    const float* wrow = Wq + (size_t)j * DD;
    float a0 = 0.f, a1 = 0.f, a2 = 0.f, a3 = 0.f;
    #pragma unroll 4
    for (int it = 0; it < 16; ++it) {
        int idx = l + it * 64;
        float wval = wrow[idx];
        a0 += xb[0][idx] * wval;
        a1 += xb[1][idx] * wval;
        a2 += xb[2][idx] * wval;
        a3 += xb[3][idx] * wval;
    }
    for (int off = 32; off > 0; off >>= 1) {
        a0 += __shfl_down(a0, off, 64);
        a1 += __shfl_down(a1, off, 64);
        a2 += __shfl_down(a2, off, 64);
        a3 += __shfl_down(a3, off, 64);
    }
    if (l == 0) {
        mq[j] = a0; mq[1024 + j] = a1; mq[2048 + j] = a2; mq[3072 + j] = a3;
    }
}

// ---------------- LayerNorm per head over mq, mean over heads -> q_shared[b][64]
__global__ __launch_bounds__(256)
void gates1b_kernel(const float* __restrict__ mq, const float* __restrict__ gamma,
                    const float* __restrict__ beta, float* __restrict__ q_shared) {
    __shared__ float qacc[4][64];
    int b = blockIdx.x;
    int t = threadIdx.x;
    int wv = t >> 6, l = t & 63;
    float part = 0.f;
    for (int hh = 0; hh < 4; ++hh) {
        int h = wv * 4 + hh;
        float v = mq[b * 1024 + h * 64 + l];
        float s1 = v, s2 = v * v;
        for (int off = 32; off > 0; off >>= 1) {
            s1 += __shfl_xor(s1, off, 64);
            s2 += __shfl_xor(s2, off, 64);
        }
        float mu = s1 * (1.0f / 64.0f);
        float var = s2 * (1.0f / 64.0f) - mu * mu;
        part += (v - mu) * rsqrtf(var + 1e-5f) * gamma[l] + beta[l];
    }
    qacc[wv][l] = part;
    __syncthreads();
    if (t < 64) {
        float s = qacc[0][t] + qacc[1][t] + qacc[2][t] + qacc[3][t];
        q_shared[b * 64 + t] = s * (1.0f / 16.0f);
    }
}

// ---------------- hdn = gelu(q_shared @ w1^T + b1)
__global__ __launch_bounds__(256)
void gates2_kernel(const float* __restrict__ q_shared, const float* __restrict__ w1,
                   const float* __restrict__ b1, float* __restrict__ hdn) {
    __shared__ float qs[64];
    int blk = blockIdx.x;
    int b = blk >> 2;
    int i0 = (blk & 3) * 256;
    int t = threadIdx.x;
    if (t < 64) qs[t] = q_shared[b * 64 + t];
    __syncthreads();
    int i = i0 + t;
    const float* wrow = w1 + (size_t)i * DHD;
    float acc = b1[i];
    #pragma unroll 8
    for (int d = 0; d < 64; ++d) acc += qs[d] * wrow[d];
    float g = 0.5f * acc * (1.0f + erff(acc * 0.70710678118654752f));
    hdn[b * DD + i] = g;
}

// ---------------- gri = hdn @ w2^T + b2 ; one wave per output row, all 4 b at once
__global__ __launch_bounds__(256)
void gates3_kernel(const float* __restrict__ hdn, const float* __restrict__ w2,
                   const float* __restrict__ b2, float* __restrict__ gri) {
    int t = threadIdx.x;
    int wv = t >> 6, l = t & 63;
    int r = blockIdx.x * 4 + wv;
    if (r >= 2 * NFREQ) return;
    const float* wrow = w2 + (size_t)r * DD;
    float a0 = 0.f, a1 = 0.f, a2 = 0.f, a3 = 0.f;
    for (int it = 0; it < 16; ++it) {
        int idx = l + it * 64;
        float wval = wrow[idx];
        a0 += hdn[idx] * wval;
        a1 += hdn[1024 + idx] * wval;
        a2 += hdn[2048 + idx] * wval;
        a3 += hdn[3072 + idx] * wval;
    }
    for (int off = 32; off > 0; off >>= 1) {
        a0 += __shfl_down(a0, off, 64);
        a1 += __shfl_down(a1, off, 64);
        a2 += __shfl_down(a2, off, 64);
        a3 += __shfl_down(a3, off, 64);
    }
    if (l == 0) {
        float bb = b2[r];
        gri[r] = a0 + bb;
        gri[2 * NFREQ + r] = a1 + bb;
        gri[2 * 2 * NFREQ + r] = a2 + bb;
        gri[3 * 2 * NFREQ + r] = a3 + bb;
    }
}

// ---------------- f32 -> f16 convert (weights) ----------------
__global__ __launch_bounds__(256)
void cvt_f16_kernel(const float* __restrict__ src, u16* __restrict__ dst, int n4) {
    int idx = blockIdx.x * 256 + threadIdx.x;
    int stride = gridDim.x * 256;
    for (; idx < n4; idx += stride) {
        float4 v = ((const float4*)src)[idx];
        u16x4 h;
        h.x = f2h(v.x); h.y = f2h(v.y); h.z = f2h(v.z); h.w = f2h(v.w);
        ((u16x4*)dst)[idx] = h;
    }
}

// ---------------- u16 transpose: src [1024][16384] -> dst [16384][1024] -------
__global__ __launch_bounds__(256)
void transpose_u16_kernel(const u16* __restrict__ src, u16* __restrict__ dst) {
    __shared__ u16 tile[64][66];
    int s0 = blockIdx.x * 64;   // bs block
    int j0 = blockIdx.y * 64;   // feature block
    int t = threadIdx.x;
    int c = t & 63, r4 = t >> 6;
    #pragma unroll
    for (int rr = 0; rr < 64; rr += 4)
        tile[rr + r4][c] = src[(size_t)(j0 + rr + r4) * 16384 + s0 + c];
    __syncthreads();
    #pragma unroll
    for (int rr = 0; rr < 64; rr += 4) {
        int a = rr + r4;                 // local bs
        dst[(size_t)(s0 + a) * 1024 + j0 + c] = tile[c][a];
    }
}

// ---------------- f16 single-product MFMA GEMM, 256x256 tile, 4-deep pipeline -
// C[M][N] = A[M][K] * B[N][K]^T ; A,B single f16 planes (row-major, stride K).
// F16OUT: write C as f16 (u16) instead of f32 -- halves the C write traffic.
// [R8-verified pipeline discipline; R6/R7/R9 phase restructures regressed.]
template <bool F16OUT>
__global__ __launch_bounds__(512, 2)
void gemm_f16_kernel(const u16* __restrict__ A, const u16* __restrict__ B,
                     void* __restrict__ Cv, int mtiles, int ntiles, int K, int ldc) {
    __shared__ u16 lds[4][2][8192];   // [buf][plane: A,B][256 rows x 32 k]
    const int t = threadIdx.x;
    const int wid = __builtin_amdgcn_readfirstlane(t >> 6);
    const int lane = t & 63;

    // XCD-aware decode (blocks dispatch round-robin over 8 XCDs)
    const int bid = blockIdx.x;
    const int xcd = bid & 7;
    const int idx = bid >> 3;
    int mt, nt;
    if (ntiles >= mtiles) { mt = idx % mtiles; nt = xcd * (ntiles >> 3) + idx / mtiles; }
    else                  { nt = idx % ntiles; mt = xcd * (mtiles >> 3) + idx / ntiles; }
    const int m0 = mt * 256;
    const int n0 = nt * 256;
    const int wm = (wid >> 2) * 128;
    const int wn = (wid & 3) * 64;

    // staging: 32 chunk-ops of 1KB per tile (wave w gets ops g = w*4..w*4+3)
    const u16* gbase[4];
    u16* ldst[4];
    #pragma unroll
    for (int o = 0; o < 4; ++o) {
        int g = wid * 4 + o;
        int p = g >> 4;                  // 0 = A plane, 1 = B plane
        int j = ((g & 15) << 6) | lane;
        int c = j ^ ((j >> 3) & 3);
        int row = c >> 2, q = c & 3;
        const u16* base = (p == 0) ? A : B;
        int rbase = (p == 0) ? m0 : n0;
        gbase[o] = base + (size_t)(rbase + row) * K + q * 8;
        ldst[o] = &lds[0][0][0] + (size_t)p * 8192 + (size_t)j * 8;
    }

#define STG(KT, BUF)                                                             \
    {                                                                            \
        _Pragma("unroll")                                                        \
        for (int o = 0; o < 4; ++o)                                              \
            gload16(gbase[o] + (size_t)(KT) * 32, ldst[o] + (BUF) * 16384);      \
    }

    f32x4 acc[8][4] = {};
    const int KT = K >> 5;

    // prologue: stage tiles 0..2; wait for tile 0 only (8 newest may fly)
    STG(0, 0);
    STG(1, 1);
    STG(2, 2);
    asm volatile("s_waitcnt vmcnt(8)" ::: "memory");
    __builtin_amdgcn_s_barrier();

    for (int kt = 0; kt < KT; ++kt) {
        const u16* lb = &lds[kt & 3][0][0];
        // issue stage for tile kt+3 first: longest latency cover
        if (kt + 3 < KT) STG(kt + 3, (kt + 3) & 3);

        half8 b[4];
        #pragma unroll
        for (int j = 0; j < 4; ++j) {
            int s = swz((wn + (lane & 15) + j * 16) * 64 + (lane >> 4) * 16);
            b[j] = *(const half8*)(lb + 8192 + (s >> 1));
        }
        __builtin_amdgcn_s_setprio(1);
        #pragma unroll
        for (int ip = 0; ip < 4; ++ip) {
            int s0 = swz((wm + (lane & 15) + (2 * ip) * 16) * 64 + (lane >> 4) * 16);
            int s1 = swz((wm + (lane & 15) + (2 * ip + 1) * 16) * 64 + (lane >> 4) * 16);
            half8 a0 = *(const half8*)(lb + (s0 >> 1));
            half8 a1 = *(const half8*)(lb + (s1 >> 1));
            #pragma unroll
            for (int j = 0; j < 4; ++j) acc[2 * ip][j]     = MFMA_F16(a0, b[j], acc[2 * ip][j], 0, 0, 0);
            #pragma unroll
            for (int j = 0; j < 4; ++j) acc[2 * ip + 1][j] = MFMA_F16(a1, b[j], acc[2 * ip + 1][j], 0, 0, 0);
        }
        __builtin_amdgcn_s_setprio(0);
        // make buffer kt+1 ready: wait until only younger tiles' loads remain
        if (kt <= KT - 4)      { asm volatile("s_waitcnt vmcnt(8)" ::: "memory"); }
        else if (kt == KT - 3) { asm volatile("s_waitcnt vmcnt(4)" ::: "memory"); }
        else                   { asm volatile("s_waitcnt vmcnt(0)" ::: "memory"); }
        __builtin_amdgcn_s_barrier();
    }
#undef STG

    // epilogue: C/D layout = col (lane&15), row (lane>>4)*4 + e   [m89-verified]
    const int cb2 = n0 + wn + (lane & 15);
    #pragma unroll
    for (int i = 0; i < 8; ++i) {
        int rb = m0 + wm + i * 16 + ((lane >> 4) << 2);
        #pragma unroll
        for (int e = 0; e < 4; ++e) {
            if (F16OUT) {
                u16* crow = (u16*)Cv + (size_t)(rb + e) * ldc + cb2;
                #pragma unroll
                for (int j = 0; j < 4; ++j)
                    crow[j * 16] = f2h(acc[i][j][e]);
            } else {
                float* crow = (float*)Cv + (size_t)(rb + e) * ldc + cb2;
                #pragma unroll
                for (int j = 0; j < 4; ++j)
                    crow[j * 16] = acc[i][j][e];
            }
        }
    }
}

// ---------------- twiddle table init (global, shared by all FFT blocks) -------
__global__ __launch_bounds__(256)
void twiddle_init_kernel(float2* __restrict__ Tg) {
    int idx = blockIdx.x * 256 + threadIdx.x;
    if (idx >= 3072) return;
    float cs = 1.f, sn = 0.f;
    if (idx >= 2048) {
        sincosf(PI_F * (float)(idx - 2048) * (1.0f / 2048.0f), &sn, &cs);
    } else if (idx >= 1) {
        int s = 31 - __clz(idx);
        int h = 1 << s;
        sincosf(PI_F * (float)(idx - h) / (float)h, &sn, &cs);
    }
    Tg[idx] = make_float2(cs, sn);
}

// ---- packed-f32 butterflies: a,b are (re,im); compiles to v_pk_*_f32 ----
__device__ __forceinline__ void bfly_f(f32x2& a, f32x2& b, float cs, float sn) {
    f32x2 s = a + b;
    f32x2 d = a - b;
    f32x2 dsw = __builtin_shufflevector(d, d, 1, 0);   // (im, re)
    a = s;
    b = d * cs + dsw * (f32x2){sn, -sn};   // (dr*cs+di*sn, di*cs-dr*sn)
}
__device__ __forceinline__ void bfly_i(f32x2& a, f32x2& b, float cs, float sn) {
    f32x2 bsw = __builtin_shufflevector(b, b, 1, 0);   // (im, re)
    f32x2 c = b * cs + bsw * (f32x2){-sn, sn};         // b * e^{+i th}
    b = a - c;
    a = a + c;
}
// pad-based LDS index map: 2 float2 of pad per 32 elements.
// Bank math (8B elems, bank-pair = idx mod 16): G3's (32g + t3 + 4u) pattern
// maps to pair (2g + t3) mod 16 -> 4 lanes/pair = HW minimum for wave64 b64;
// G1/G2 stride-1 optimal; G4's 8-consecutive stays contiguous (8t mod 32 in
// {0,8,16,24}) -> b128-able, 2 lanes per 4-bank group = optimal.
__device__ __forceinline__ int IDX(int a) { return a + 2 * (a >> 5); }

// ---------------- fused rfft -> gates -> modReLU -> irfft, in-place f16 ------
__global__ __launch_bounds__(256)
void fft_gates_kernel(u16* __restrict__ vbuf, const float* __restrict__ gri,
                      const float* __restrict__ modb, const float2* __restrict__ Tg) {
    __shared__ f32x2 cf[2176];   // 2048 + 128 pad
    const int t = threadIdx.x;
    const int w = blockIdx.x;
    const int b = w & 3;
    u16* seq = vbuf + (size_t)w * SS;

    const int t5 = t & 31;
    const int t3 = t & 3;
    const int c32 = ((t >> 5) << 8) | t5;    // base for 32-span group
    const int d4  = ((t >> 2) << 5) | t3;    // base for 4-span group

    f32x2 r[8];

    // ---- load (f16 pairs) + G1: stages 10,9,8 (span 256) ----
    #pragma unroll
    for (int u = 0; u < 8; ++u) {
        ushort2 v = ((const ushort2*)seq)[t + 256 * u];
        r[u] = (f32x2){h2f(v.x), h2f(v.y)};
    }
    #pragma unroll
    for (int u = 0; u < 4; ++u) {
        float2 tw = Tg[1024 + t + 256 * u];
        bfly_f(r[u], r[u + 4], tw.x, tw.y);
    }
    {
        float2 tw0 = Tg[512 + t], tw1 = Tg[512 + t + 256];
        bfly_f(r[0], r[2], tw0.x, tw0.y);
        bfly_f(r[1], r[3], tw1.x, tw1.y);
        bfly_f(r[4], r[6], tw0.x, tw0.y);
        bfly_f(r[5], r[7], tw1.x, tw1.y);
        float2 tw = Tg[256 + t];
        bfly_f(r[0], r[1], tw.x, tw.y);
        bfly_f(r[2], r[3], tw.x, tw.y);
        bfly_f(r[4], r[5], tw.x, tw.y);
        bfly_f(r[6], r[7], tw.x, tw.y);
    }
    #pragma unroll
    for (int u = 0; u < 8; ++u) cf[IDX(t + 256 * u)] = r[u];
    __syncthreads();

    // ---- G2: stages 7,6,5 (span 32) ----
    #pragma unroll
    for (int u = 0; u < 8; ++u) r[u] = cf[IDX(c32 + 32 * u)];
    #pragma unroll
    for (int u = 0; u < 4; ++u) {
        float2 tw = Tg[128 + t5 + 32 * u];
        bfly_f(r[u], r[u + 4], tw.x, tw.y);
    }
    {
        float2 tw0 = Tg[64 + t5], tw1 = Tg[64 + t5 + 32];
        bfly_f(r[0], r[2], tw0.x, tw0.y);
        bfly_f(r[1], r[3], tw1.x, tw1.y);
        bfly_f(r[4], r[6], tw0.x, tw0.y);
        bfly_f(r[5], r[7], tw1.x, tw1.y);
        float2 tw = Tg[32 + t5];
        bfly_f(r[0], r[1], tw.x, tw.y);
        bfly_f(r[2], r[3], tw.x, tw.y);
        bfly_f(r[4], r[5], tw.x, tw.y);
        bfly_f(r[6], r[7], tw.x, tw.y);
    }
    #pragma unroll
    for (int u = 0; u < 8; ++u) cf[IDX(c32 + 32 * u)] = r[u];
    __syncthreads();

    // ---- G3: stages 4,3,2 (span 4) ----
    {
        f32x2* p3 = &cf[IDX(d4)];   // d4 mod 32 = t3; offsets 4u+? stay in-block
        #pragma unroll
        for (int u = 0; u < 8; ++u) r[u] = p3[4 * u];
        #pragma unroll
        for (int u = 0; u < 4; ++u) {
            float2 tw = Tg[16 + t3 + 4 * u];
            bfly_f(r[u], r[u + 4], tw.x, tw.y);
        }
        {
            float2 tw0 = Tg[8 + t3], tw1 = Tg[8 + t3 + 4];
            bfly_f(r[0], r[2], tw0.x, tw0.y);
            bfly_f(r[1], r[3], tw1.x, tw1.y);
            bfly_f(r[4], r[6], tw0.x, tw0.y);
            bfly_f(r[5], r[7], tw1.x, tw1.y);
            float2 tw = Tg[4 + t3];
            bfly_f(r[0], r[1], tw.x, tw.y);
            bfly_f(r[2], r[3], tw.x, tw.y);
            bfly_f(r[4], r[5], tw.x, tw.y);
            bfly_f(r[6], r[7], tw.x, tw.y);
        }
        #pragma unroll
        for (int u = 0; u < 8; ++u) p3[4 * u] = r[u];
    }
    __syncthreads();

    // ---- G4: stages 1,0 (span 1; 8 consecutive -> b128-able) ----
    {
        f32x2* p4 = &cf[IDX(8 * t)];   // 8t mod 32 in {0,8,16,24}; +7 in-block
        #pragma unroll
        for (int u = 0; u < 8; ++u) r[u] = p4[u];
        bfly_f(r[0], r[2], 1.f, 0.f);
        bfly_f(r[1], r[3], 0.f, 1.f);
        bfly_f(r[4], r[6], 1.f, 0.f);
        bfly_f(r[5], r[7], 0.f, 1.f);
        bfly_f(r[0], r[1], 1.f, 0.f);
        bfly_f(r[2], r[3], 1.f, 0.f);
        bfly_f(r[4], r[5], 1.f, 0.f);
        bfly_f(r[6], r[7], 1.f, 0.f);
        #pragma unroll
        for (int u = 0; u < 8; ++u) p4[u] = r[u];
    }
    __syncthreads();

    // ---- spectrum: unpack real-FFT bins (ortho /64), gates, modReLU, repack ----
    const float bias = modb[0];
    const float* gre = gri + (size_t)b * 2 * NFREQ;
    const float* gim = gre + NFREQ;
    const float inv64 = 1.0f / 64.0f;
    for (int k = t; k < 1024; k += 256) {
        if (k == 0) {
            f32x2 c0 = cf[IDX(0)];
            float z0 = (c0.x + c0.y) * inv64;
            float zM = (c0.x - c0.y) * inv64;
            float zr = z0 * gre[0], zi = z0 * gim[0];
            modrelu_apply(zr, zi, bias);
            float yr = zM * gre[2048], yi = zM * gim[2048];
            modrelu_apply(yr, yi, bias);
            cf[IDX(0)] = (f32x2){0.5f * (zr + yr), 0.5f * (zr - yr)};
            f32x2 c1 = cf[IDX(1)];
            float z1r = c1.x * inv64, z1i = -c1.y * inv64;
            float g1r = gre[1024], g1i = gim[1024];
            float pr = z1r * g1r - z1i * g1i;
            float pi2 = z1r * g1i + z1i * g1r;
            modrelu_apply(pr, pi2, bias);
            cf[IDX(1)] = (f32x2){pr, -pi2};
        } else {
            int kb = 2048 - k;
            int p1 = IDX((int)(__brev((unsigned)k) >> 21));
            int p2 = IDX((int)(__brev((unsigned)kb) >> 21));
            f32x2 ca = cf[p1];
            f32x2 cb2 = cf[p2];
            float Er = 0.5f * (ca.x + cb2.x), Ei = 0.5f * (ca.y - cb2.y);
            float Dr = 0.5f * (ca.x - cb2.x), Di = 0.5f * (ca.y + cb2.y);
            float Or = Di, Oi = -Dr;
            float2 t2 = Tg[2048 + k];
            float cs = t2.x, sn = t2.y;
            float Wr = cs, Wi = -sn;
            float WOr = Wr * Or - Wi * Oi, WOi = Wr * Oi + Wi * Or;
            float zkr = (Er + WOr) * inv64, zki = (Ei + WOi) * inv64;
            float zbr = (Er - WOr) * inv64, zbi = -(Ei - WOi) * inv64;
            float gkr = gre[k], gki = gim[k];
            float ar = zkr * gkr - zki * gki, ai = zkr * gki + zki * gkr;
            modrelu_apply(ar, ai, bias);
            float gbr = gre[kb], gbi = gim[kb];
            float br2 = zbr * gbr - zbi * gbi, bi2 = zbr * gbi + zbi * gbr;
            modrelu_apply(br2, bi2, bias);
            float Epr = 0.5f * (ar + br2), Epi = 0.5f * (ai - bi2);
            float Dpr = 0.5f * (ar - br2), Dpi = 0.5f * (ai + bi2);
            float Opr = cs * Dpr - sn * Dpi, Opi = cs * Dpi + sn * Dpr;
            cf[p1] = (f32x2){Epr - Opi, Epi + Opr};
            cf[p2] = (f32x2){Epr + Opi, -Epi + Opr};
        }
    }
    __syncthreads();

    // ---- inverse G4': stages 0,1 ----
    {
        f32x2* p4 = &cf[IDX(8 * t)];
        #pragma unroll
        for (int u = 0; u < 8; ++u) r[u] = p4[u];
        bfly_i(r[0], r[1], 1.f, 0.f);
        bfly_i(r[2], r[3], 1.f, 0.f);
        bfly_i(r[4], r[5], 1.f, 0.f);
        bfly_i(r[6], r[7], 1.f, 0.f);
        bfly_i(r[0], r[2], 1.f, 0.f);
        bfly_i(r[1], r[3], 0.f, 1.f);
        bfly_i(r[4], r[6], 1.f, 0.f);
        bfly_i(r[5], r[7], 0.f, 1.f);
        #pragma unroll
        for (int u = 0; u < 8; ++u) p4[u] = r[u];
    }
    __syncthreads();

    // ---- inverse G3': stages 2,3,4 ----
    {
        f32x2* p3 = &cf[IDX(d4)];
        #pragma unroll
        for (int u = 0; u < 8; ++u) r[u] = p3[4 * u];
        {
            float2 tw = Tg[4 + t3];
            bfly_i(r[0], r[1], tw.x, tw.y);
            bfly_i(r[2], r[3], tw.x, tw.y);
            bfly_i(r[4], r[5], tw.x, tw.y);
            bfly_i(r[6], r[7], tw.x, tw.y);
            float2 tw0 = Tg[8 + t3], tw1 = Tg[8 + t3 + 4];
            bfly_i(r[0], r[2], tw0.x, tw0.y);
            bfly_i(r[1], r[3], tw1.x, tw1.y);
            bfly_i(r[4], r[6], tw0.x, tw0.y);
            bfly_i(r[5], r[7], tw1.x, tw1.y);
        }
        #pragma unroll
        for (int u = 0; u < 4; ++u) {
            float2 tw = Tg[16 + t3 + 4 * u];
            bfly_i(r[u], r[u + 4], tw.x, tw.y);
        }
        #pragma unroll
        for (int u = 0; u < 8; ++u) p3[4 * u] = r[u];
    }
    __syncthreads();

    // ---- inverse G2': stages 5,6,7 ----
    #pragma unroll
    for (int u = 0; u < 8; ++u) r[u] = cf[IDX(c32 + 32 * u)];
    {
        float2 tw = Tg[32 + t5];
        bfly_i(r[0], r[1], tw.x, tw.y);
        bfly_i(r[2], r[3], tw.x, tw.y);
        bfly_i(r[4], r[5], tw.x, tw.y);
        bfly_i(r[6], r[7], tw.x, tw.y);
        float2 tw0 = Tg[64 + t5], tw1 = Tg[64 + t5 + 32];
        bfly_i(r[0], r[2], tw0.x, tw0.y);
        bfly_i(r[1], r[3], tw1.x, tw1.y);
        bfly_i(r[4], r[6], tw0.x, tw0.y);
        bfly_i(r[5], r[7], tw1.x, tw1.y);
    }
    #pragma unroll
    for (int u = 0; u < 4; ++u) {
        float2 tw = Tg[128 + t5 + 32 * u];
        bfly_i(r[u], r[u + 4], tw.x, tw.y);
    }
    #pragma unroll
    for (int u = 0; u < 8; ++u) cf[IDX(c32 + 32 * u)] = r[u];
    __syncthreads();

    // ---- inverse G1': stages 8,9,10 + scale + f16 store ----
    #pragma unroll
    for (int u = 0; u < 8; ++u) r[u] = cf[IDX(t + 256 * u)];
    {
        float2 tw = Tg[256 + t];
        bfly_i(r[0], r[1], tw.x, tw.y);
        bfly_i(r[2], r[3], tw.x, tw.y);
        bfly_i(r[4], r[5], tw.x, tw.y);
        bfly_i(r[6], r[7], tw.x, tw.y);
        float2 tw0 = Tg[512 + t], tw1 = Tg[512 + t + 256];
        bfly_i(r[0], r[2], tw0.x, tw0.y);
        bfly_i(r[1], r[3], tw1.x, tw1.y);
        bfly_i(r[4], r[6], tw0.x, tw0.y);
        bfly_i(r[5], r[7], tw1.x, tw1.y);
    }
    #pragma unroll
    for (int u = 0; u < 4; ++u) {
        float2 tw = Tg[1024 + t + 256 * u];
        bfly_i(r[u], r[u + 4], tw.x, tw.y);
    }
    const float s32 = 1.0f / 32.0f;  // 64 (ortho) / 2048 (ifft norm)
    #pragma unroll
    for (int u = 0; u < 8; ++u) {
        ushort2 o;
        o.x = f2h(r[u].x * s32);
        o.y = f2h(r[u].y * s32);
        ((ushort2*)seq)[t + 256 * u] = o;
    }
}

extern "C" void kernel_launch(void* const* d_in, const int* in_sizes, int n_in,
                              void* d_out, int out_size, void* d_ws, size_t ws_size,
                              hipStream_t stream) {
    const float* x        = (const float*)d_in[0];
    const float* W_q      = (const float*)d_in[1];
    const float* W_v      = (const float*)d_in[2];
    const float* W_o      = (const float*)d_in[3];
    const float* ln_gamma = (const float*)d_in[4];
    const float* ln_beta  = (const float*)d_in[5];
    const float* mlp_w1   = (const float*)d_in[6];
    const float* mlp_b1   = (const float*)d_in[7];
    const float* mlp_w2   = (const float*)d_in[8];
    const float* mlp_b2   = (const float*)d_in[9];
    const float* mod_bias = (const float*)d_in[10];
    float* out = (float*)d_out;

    // workspace layout (floats)
    float* ws = (float*)d_ws;
    float* partial  = ws;                    // 1048576 (1024 blocks x 1024)
    float* xsum     = ws + 1048576;          // 4096
    float* q_shared = ws + 1052672;          // 256
    float* hdn      = ws + 1052928;          // 4096
    float* gri      = ws + 1057024;          // 16392
    float* mq       = ws + 1073416;          // 4096 (ends 1077512)
    float2* twid    = (float2*)(ws + 1077512); // 3072 float2 (ends 1083656)
    u16* bfbase = (u16*)(ws + 1083904);
    u16* xut_f  = bfbase;                    // 16777216 u16: x_f16, later reused as ut
    u16* vbuf   = bfbase + 16777216;         // f16 V then u, [1024][16384] in-place fft
    u16* wv_f   = bfbase + 33554432;         // 1048576
    u16* wo_f   = bfbase + 34603008;         // 1048576

    twiddle_init_kernel<<<12, 256, 0, stream>>>(twid);

    // fused x f16-convert + colsum pass 1
    split_x_colsum_kernel<<<1024, 256, 0, stream>>>(x, xut_f, partial);
    {
        dim3 g(4, 4);
        colsum2_kernel<<<g, 256, 0, stream>>>(partial, xsum);
    }
    gates1a_kernel<<<256, 256, 0, stream>>>(xsum, W_q, mq);
    gates1b_kernel<<<4, 256, 0, stream>>>(mq, ln_gamma, ln_beta, q_shared);
    gates2_kernel<<<16, 256, 0, stream>>>(q_shared, mlp_w1, mlp_b1, hdn);
    gates3_kernel<<<1025, 256, 0, stream>>>(hdn, mlp_w2, mlp_b2, gri);

    // weight f16 conversions
    cvt_f16_kernel<<<512, 256, 0, stream>>>(W_v, wv_f, 262144);
    cvt_f16_kernel<<<512, 256, 0, stream>>>(W_o, wo_f, 262144);

    // V projection (transposed output), f16 in/out: vbuf[j][bs] = Wv[j,:]·x[bs,:]
    // M=1024 (j), N=16384 (bs): mtiles=4, ntiles=64 -> 256 blocks
    gemm_f16_kernel<true><<<256, 512, 0, stream>>>(wv_f, xut_f,
                                                   vbuf, 4, 64, 1024, 16384);

    // fused spectral mixing, in place on vbuf (f16 -> f16)
    fft_gates_kernel<<<4096, 256, 0, stream>>>(vbuf, gri, mod_bias, twid);

    // transpose u: vbuf [1024][16384] -> xut_f [16384][1024] (pure u16 permute)
    {
        dim3 g(256, 16);
        transpose_u16_kernel<<<g, 256, 0, stream>>>(vbuf, xut_f);
    }

    // O projection, f16 in / f32 out: out[bs][jo] = ut[bs,:]·Wo[jo,:]
    // M=16384 (bs), N=1024 (jo): mtiles=64, ntiles=4 -> 256 blocks
    gemm_f16_kernel<false><<<256, 512, 0, stream>>>(xut_f, wo_f,
                                                    out, 64, 4, 1024, 1024);
}